// Round 9
// baseline (90456.305 us; speedup 1.0000x reference)
//
#include <hip/hip_runtime.h>
#include <hip/hip_bf16.h>
#include <math.h>

namespace {

constexpr int BATCH  = 4;
constexpr int T_IN   = 160000;
constexpr int DMODEL = 768;
constexpr int NHEAD  = 12;
constexpr int DHEAD  = 64;
constexpr int FFN    = 3072;
constexpr int NLAYER = 12;
constexpr int SEQ    = 499;
constexpr int NREL   = 2 * SEQ - 1;   // 997 relative offsets

__device__ __forceinline__ float gelu_f(float x){
  return 0.5f * x * (1.0f + erff(x * 0.70710678118654752f));
}

__global__ void fill_f32_kernel(float* __restrict__ out, int n, float val){
  int i = blockIdx.x * 256 + threadIdx.x;
  if (i < n) out[i] = val;
}

// ---- conv stage 0: k=10, s=5 (src pre-offset), cross-correlation (lax semantics) ----
__global__ void conv0_kernel(const float* __restrict__ src, const float* __restrict__ w,
                             float* __restrict__ out, int Lout){
  int idx = blockIdx.x * 256 + threadIdx.x;
  if (idx >= 512 * Lout) return;
  int c = idx / Lout, t = idx - c * Lout;
  const float* wr = w + c * 10;
  const float* s  = src + t * 5;
  float acc = 0.f;
#pragma unroll
  for (int k = 0; k < 10; k++) acc += wr[k] * s[k];
  out[idx] = acc;
}

// ---- LayerNorm over channels + exact GELU, layout (512, Lt), in place ----
__global__ void ln_gelu_ch_kernel(float* __restrict__ x, const float* __restrict__ g,
                                  const float* __restrict__ b, int Lt){
  int t = blockIdx.x * 256 + threadIdx.x;
  if (t >= Lt) return;
  float s = 0.f, sq = 0.f;
  for (int c = 0; c < 512; c++){ float v = x[c * Lt + t]; s += v; sq += v * v; }
  float m = s * (1.f / 512.f);
  float var = sq * (1.f / 512.f) - m * m;
  float rs = rsqrtf(var + 1e-5f);
  for (int c = 0; c < 512; c++){
    float v = (x[c * Lt + t] - m) * rs * g[c] + b[c];
    x[c * Lt + t] = gelu_f(v);
  }
}

// ---- conv stages 1..6: 512->512, kernel KW, stride 2, naive ----
template<int KW>
__global__ void conv_naive(const float* __restrict__ in, const float* __restrict__ w,
                           float* __restrict__ out, int Lin, int Lout,
                           int outLd, int outOff){
  const int co = blockIdx.y;
  const int t = blockIdx.x * 256 + threadIdx.x;
  __shared__ float ws_[512 * KW];
  for (int i = threadIdx.x; i < 512 * KW; i += 256)
    ws_[i] = w[(size_t)co * (512 * KW) + i];
  __syncthreads();
  if (t >= Lout) return;
  float acc = 0.f;
  for (int ci = 0; ci < 512; ci++){
    const float* ir = in + (size_t)ci * Lin + 2 * t;
#pragma unroll
    for (int k = 0; k < KW; k++) acc += ws_[ci * KW + k] * ir[k];
  }
  out[(size_t)co * outLd + outOff + t] = acc;
}

// ---- final feature LN + transpose (512,S)->(S,512) ----
__global__ void featln_transpose_kernel(const float* __restrict__ xin,
                                        const float* __restrict__ g, const float* __restrict__ b,
                                        float* __restrict__ feat){
  int t = blockIdx.x * 256 + threadIdx.x;
  if (t >= SEQ) return;
  float s = 0.f, sq = 0.f;
  for (int c = 0; c < 512; c++){ float v = xin[c * SEQ + t]; s += v; sq += v * v; }
  float m = s * (1.f / 512.f), var = sq * (1.f / 512.f) - m * m, rs = rsqrtf(var + 1e-5f);
  for (int c = 0; c < 512; c++)
    feat[t * 512 + c] = (xin[c * SEQ + t] - m) * rs * g[c] + b[c];
}

// ---- textbook GEMM: C = act(alpha*(A @ W^T + bias)) ----
template<int ACT>
__global__ void gemm16(const float* __restrict__ A, const float* __restrict__ W,
                       const float* __restrict__ bias, float* __restrict__ C,
                       int M, int N, int K, float alpha){
  __shared__ float As[16][17];
  __shared__ float Bs[16][17];
  const int tx = threadIdx.x, ty = threadIdx.y;
  const int n0 = blockIdx.x * 16, m0 = blockIdx.y * 16;
  const int m = m0 + ty, n = n0 + tx;
  float acc = 0.f;
  for (int k0 = 0; k0 < K; k0 += 16){
    As[ty][tx] = (m < M) ? A[(size_t)m * K + k0 + tx] : 0.f;
    Bs[ty][tx] = W[(size_t)(n0 + ty) * K + k0 + tx];
    __syncthreads();
#pragma unroll
    for (int kk = 0; kk < 16; kk++) acc += As[ty][kk] * Bs[tx][kk];
    __syncthreads();
  }
  if (m < M){
    float v = alpha * (acc + bias[n]);
    if (ACT == 1) v = gelu_f(v);
    C[(size_t)m * N + n] = v;
  }
}

// ---- naive positional grouped conv: k=128, pad 64, groups 16 ----
__global__ void posconv_naive(const float* __restrict__ x, const float* __restrict__ w,
                              const float* __restrict__ bias, float* __restrict__ xc){
  const int b = blockIdx.z, co = blockIdx.y;
  const int t = blockIdx.x * 64 + threadIdx.x;
  __shared__ float ws_[48 * 128];
  for (int i = threadIdx.x; i < 48 * 128; i += 64)
    ws_[i] = w[(size_t)co * (48 * 128) + i];
  __syncthreads();
  if (t >= SEQ) return;
  const int g = co / 48;
  float acc = bias[co];
  for (int ci = 0; ci < 48; ci++){
    const float* wc = ws_ + ci * 128;
    for (int k = 0; k < 128; k++){
      int p = t - 64 + k;
      if (p >= 0 && p < SEQ)
        acc += wc[k] * x[((size_t)(b * SEQ + p)) * DMODEL + g * 48 + ci];
    }
  }
  xc[((size_t)(b * SEQ + t)) * DMODEL + co] = acc;
}

// ---- residual add (+optional GELU on added term) + row LayerNorm over DMODEL ----
template<int GELU_ADD>
__global__ void add_ln_kernel(float* __restrict__ x, const float* __restrict__ add,
                              const float* __restrict__ g, const float* __restrict__ b){
  int row = blockIdx.x;
  float* xr = x + (size_t)row * DMODEL;
  const float* ar = add + (size_t)row * DMODEL;
  __shared__ float buf[DMODEL];
  __shared__ float red[256];
  int tid = threadIdx.x;
  float s = 0.f;
  for (int i = tid; i < DMODEL; i += 256){
    float v = ar[i];
    if (GELU_ADD) v = gelu_f(v);
    v += xr[i];
    buf[i] = v; s += v;
  }
  red[tid] = s; __syncthreads();
  for (int st = 128; st > 0; st >>= 1){ if (tid < st) red[tid] += red[tid + st]; __syncthreads(); }
  float m = red[0] * (1.f / DMODEL); __syncthreads();
  float sq = 0.f;
  for (int i = tid; i < DMODEL; i += 256){ float d = buf[i] - m; sq += d * d; }
  red[tid] = sq; __syncthreads();
  for (int st = 128; st > 0; st >>= 1){ if (tid < st) red[tid] += red[tid + st]; __syncthreads(); }
  float rs = rsqrtf(red[0] * (1.f / DMODEL) + 1e-5f);
  for (int i = tid; i < DMODEL; i += 256) xr[i] = (buf[i] - m) * rs * g[i] + b[i];
}

// ---- T5-style relative position bias table: tab[h][rel+498], rel = j-i ----
__global__ void relbias_kernel(const float* __restrict__ rel_emb, float* __restrict__ tab){
  int idx = blockIdx.x * 256 + threadIdx.x;
  if (idx >= NREL * NHEAD) return;
  int rr = idx / NHEAD, h = idx - rr * NHEAD;
  int rel = rr - (SEQ - 1);
  int bkt = (rel > 0) ? 160 : 0;
  int n = (rel < 0) ? -rel : rel;
  if (n < 80) bkt += n;
  else {
    int large = 80 + (int)(logf((float)n / 80.f) / logf(10.f) * 80.f);
    bkt += (large < 159) ? large : 159;
  }
  tab[h * NREL + rr] = rel_emb[bkt * NHEAD + h];
}

// ---- gated rel-pos gate values; sigmoid AFTER 4-logit sums ----
__global__ void gate_kernel(const float* __restrict__ x, const float* __restrict__ gwl,
                            const float* __restrict__ gbl, const float* __restrict__ gal,
                            float* __restrict__ gate){
  int idx = blockIdx.x * 256 + threadIdx.x;
  if (idx >= BATCH * NHEAD * SEQ) return;
  int s = idx % SEQ; int bh = idx / SEQ; int h = bh % NHEAD; int b = bh / NHEAD;
  const float* xv = x + ((size_t)(b * SEQ + s)) * DMODEL + h * DHEAD;
  float a0 = 0.f, a1 = 0.f;
#pragma unroll
  for (int gg = 0; gg < 8; gg++){
    float a = gbl[gg];
    const float* wrow = gwl + gg * DHEAD;
#pragma unroll
    for (int d = 0; d < DHEAD; d++) a += xv[d] * wrow[d];
    if (gg < 4) a0 += a; else a1 += a;
  }
  float g0 = 1.f / (1.f + expf(-a0));
  float g1 = 1.f / (1.f + expf(-a1));
  gate[idx] = g0 * (g1 * gal[h] - 1.f) + 2.f;
}

// ---- naive per-batch Q@K^T ----
__global__ void qk_naive(const float* __restrict__ q, const float* __restrict__ k,
                         float* __restrict__ sc){
  const int h = blockIdx.z, i = blockIdx.y;
  const int j = blockIdx.x * 256 + threadIdx.x;
  if (j >= SEQ) return;
  const float* qr = q + (size_t)i * DMODEL + h * DHEAD;
  const float* kr = k + (size_t)j * DMODEL + h * DHEAD;
  float acc = 0.f;
#pragma unroll
  for (int d = 0; d < DHEAD; d++) acc += qr[d] * kr[d];
  sc[((size_t)h * SEQ + i) * SEQ + j] = acc;
}

// ---- per-batch softmax with fused gate * relbias add, in place ----
__global__ void softmax_bias_kernel(float* __restrict__ sc, const float* __restrict__ gate_b,
                                    const float* __restrict__ tab){
  int row = blockIdx.x;               // h*S + i
  int h = row / SEQ, i = row - h * SEQ;
  float gt = gate_b[row];
  float* p = sc + (size_t)row * SEQ;
  const float* tb = tab + (size_t)h * NREL + (SEQ - 1 - i);
  __shared__ float buf[512];
  __shared__ float red[256];
  int tid = threadIdx.x;
  float mx = -1e30f;
  for (int j = tid; j < SEQ; j += 256){
    float v = p[j] + gt * tb[j];
    buf[j] = v; mx = fmaxf(mx, v);
  }
  red[tid] = mx; __syncthreads();
  for (int st = 128; st > 0; st >>= 1){ if (tid < st) red[tid] = fmaxf(red[tid], red[tid + st]); __syncthreads(); }
  mx = red[0]; __syncthreads();
  float sum = 0.f;
  for (int j = tid; j < SEQ; j += 256){ float e = expf(buf[j] - mx); buf[j] = e; sum += e; }
  red[tid] = sum; __syncthreads();
  for (int st = 128; st > 0; st >>= 1){ if (tid < st) red[tid] += red[tid + st]; __syncthreads(); }
  float inv = 1.0f / red[0];
  for (int j = tid; j < SEQ; j += 256) p[j] = buf[j] * inv;
}

// ---- naive per-batch P @ V ----
__global__ void pv_naive(const float* __restrict__ p, const float* __restrict__ v,
                         float* __restrict__ ctx){
  const int h = blockIdx.y, i = blockIdx.x;
  const int d = threadIdx.x;  // 64
  const float* pr = p + ((size_t)h * SEQ + i) * SEQ;
  float acc = 0.f;
  for (int j = 0; j < SEQ; j++)
    acc += pr[j] * v[(size_t)j * DMODEL + h * DHEAD + d];
  ctx[(size_t)i * DMODEL + h * DHEAD + d] = acc;
}

} // anonymous namespace

extern "C" void kernel_launch(void* const* d_in, const int* in_sizes, int n_in,
                              void* d_out, int out_size, void* d_ws, size_t ws_size,
                              hipStream_t stream){
  (void)ws_size;

  static const int DS[34] = {640000,5120,3145728,1048576,3584,3584,512,512,393216,768,
                             4718592,768,768,768,7077888,9216,7077888,9216,7077888,9216,
                             7077888,9216,6144,96,144,9216,9216,28311552,36864,28311552,
                             9216,9216,9216,3840};
  bool ok = (n_in == 34) && (out_size == BATCH * SEQ * DMODEL);
  if (ok) for (int i = 0; i < 34; i++) if (in_sizes[i] != DS[i]) { ok = false; break; }
  if (!ok){
    fill_f32_kernel<<<(out_size + 255) / 256, 256, 0, stream>>>((float*)d_out, out_size, 1000.0f);
    return;
  }

  const float* src  = (const float*)d_in[0];
  const float* w0   = (const float*)d_in[1];
  const float* w14  = (const float*)d_in[2];
  const float* w56  = (const float*)d_in[3];
  const float* clng = (const float*)d_in[4];
  const float* clnb = (const float*)d_in[5];
  const float* flng = (const float*)d_in[6];
  const float* flnb = (const float*)d_in[7];
  const float* pjw  = (const float*)d_in[8];
  const float* pjb  = (const float*)d_in[9];
  const float* pcw  = (const float*)d_in[10];
  const float* pcb  = (const float*)d_in[11];
  const float* eng  = (const float*)d_in[12];
  const float* enb  = (const float*)d_in[13];
  const float* Wq   = (const float*)d_in[14];
  const float* bq   = (const float*)d_in[15];
  const float* Wk   = (const float*)d_in[16];
  const float* bk   = (const float*)d_in[17];
  const float* Wv   = (const float*)d_in[18];
  const float* bv   = (const float*)d_in[19];
  const float* Wo   = (const float*)d_in[20];
  const float* bo   = (const float*)d_in[21];
  const float* gw   = (const float*)d_in[22];
  const float* gbp  = (const float*)d_in[23];
  const float* ga   = (const float*)d_in[24];
  const float* l1g  = (const float*)d_in[25];
  const float* l1b  = (const float*)d_in[26];
  const float* f1w  = (const float*)d_in[27];
  const float* f1b  = (const float*)d_in[28];
  const float* f2w  = (const float*)d_in[29];
  const float* f2b  = (const float*)d_in[30];
  const float* l2g  = (const float*)d_in[31];
  const float* l2b  = (const float*)d_in[32];
  const float* rel  = (const float*)d_in[33];

  // OUTPUT IS FP32: the reference returns jnp.float32, so d_out is float*.
  // x (residual stream, (B*S, D)) lives directly in d_out — proj GEMM fully
  // writes it before any read; final add_ln leaves the result in place.
  float* x = (float*)d_out;

  // workspace: no aliasing (~103 MB)
  float* wsf = (float*)d_ws;
  size_t off = 0;
  auto alloc = [&](size_t n){ float* pp = wsf + off; off += (n + 63) & ~(size_t)63; return pp; };
  const size_t XSZ = (size_t)BATCH * SEQ * DMODEL;
  float* tmp  = alloc(XSZ);
  float* qb   = alloc(XSZ);
  float* kb   = alloc(XSZ);
  float* vb   = alloc(XSZ);
  float* ctx  = alloc(XSZ);
  float* feat = alloc((size_t)BATCH * SEQ * 512);
  float* c6   = alloc((size_t)512 * SEQ);
  float* gate = alloc((size_t)BATCH * NHEAD * SEQ);
  float* tab  = alloc((size_t)NHEAD * NREL);
  float* attn = alloc((size_t)NHEAD * SEQ * SEQ);
  float* ffh  = alloc((size_t)BATCH * SEQ * FFN);
  constexpr size_t CA_SZ = (size_t)512 * (64 * 125 + 15);
  constexpr size_t CB_SZ = (size_t)512 * (32 * 125 + 7);
  float* cA   = alloc(CA_SZ);
  float* cB   = alloc(CB_SZ);

  // ---- conv feature extractor: per batch, 4 time-chunks with exact halos ----
  for (int b = 0; b < BATCH; b++){
    for (int c = 0; c < 4; c++){
      int o0 = c * 125, o1 = (o0 + 125 < SEQ) ? o0 + 125 : SEQ;
      int C  = o1 - o0;
      int L[7];
      L[6] = C; L[5] = 2 * C; L[4] = 4 * C; L[3] = 8 * C + 1;
      L[2] = 16 * C + 3; L[1] = 32 * C + 7; L[0] = 64 * C + 15;
      conv0_kernel<<<(512 * L[0] + 255) / 256, 256, 0, stream>>>(
          src + (size_t)b * T_IN + 320 * o0, w0, cA, L[0]);
      ln_gelu_ch_kernel<<<(L[0] + 255) / 256, 256, 0, stream>>>(cA, clng, clnb, L[0]);
      float* bufs[2] = {cA, cB};
      for (int st = 1; st <= 6; st++){
        const float* inb = bufs[(st + 1) & 1];
        float* outb      = (st == 6) ? c6 : bufs[st & 1];
        int Lin = L[st - 1], Lout = L[st];
        int oLd = (st == 6) ? SEQ : Lout;
        int oOf = (st == 6) ? o0 : 0;
        dim3 grd((Lout + 255) / 256, 512);
        if (st <= 4)
          conv_naive<3><<<grd, 256, 0, stream>>>(inb, w14 + (size_t)(st - 1) * 512 * 512 * 3, outb, Lin, Lout, oLd, oOf);
        else
          conv_naive<2><<<grd, 256, 0, stream>>>(inb, w56 + (size_t)(st - 5) * 512 * 512 * 2, outb, Lin, Lout, oLd, oOf);
        if (st < 6)
          ln_gelu_ch_kernel<<<(Lout + 255) / 256, 256, 0, stream>>>(outb, clng + st * 512, clnb + st * 512, Lout);
      }
    }
    ln_gelu_ch_kernel<<<(SEQ + 255) / 256, 256, 0, stream>>>(c6, clng + 6 * 512, clnb + 6 * 512, SEQ);
    featln_transpose_kernel<<<(SEQ + 255) / 256, 256, 0, stream>>>(c6, flng, flnb, feat + (size_t)b * SEQ * 512);
  }

  const int Mrows = BATCH * SEQ; // 1996
  const dim3 blk16(16, 16);
  gemm16<0><<<dim3(DMODEL / 16, (Mrows + 15) / 16), blk16, 0, stream>>>(feat, pjw, pjb, x, Mrows, DMODEL, 512, 1.0f);
  posconv_naive<<<dim3((SEQ + 63) / 64, DMODEL, BATCH), 64, 0, stream>>>(x, pcw, pcb, tmp);
  add_ln_kernel<1><<<Mrows, 256, 0, stream>>>(x, tmp, eng, enb);
  relbias_kernel<<<(NREL * NHEAD + 255) / 256, 256, 0, stream>>>(rel, tab);

  for (int l = 0; l < NLAYER; l++){
    gate_kernel<<<(BATCH * NHEAD * SEQ + 255) / 256, 256, 0, stream>>>(
        x, gw + (size_t)l * 8 * DHEAD, gbp + l * 8, ga + l * NHEAD, gate);
    gemm16<0><<<dim3(48, 125), blk16, 0, stream>>>(x, Wq + (size_t)l * DMODEL * DMODEL, bq + l * DMODEL, qb, Mrows, DMODEL, DMODEL, 0.125f);
    gemm16<0><<<dim3(48, 125), blk16, 0, stream>>>(x, Wk + (size_t)l * DMODEL * DMODEL, bk + l * DMODEL, kb, Mrows, DMODEL, DMODEL, 1.0f);
    gemm16<0><<<dim3(48, 125), blk16, 0, stream>>>(x, Wv + (size_t)l * DMODEL * DMODEL, bv + l * DMODEL, vb, Mrows, DMODEL, DMODEL, 1.0f);
    for (int b = 0; b < BATCH; b++){
      const size_t bo_ = (size_t)b * SEQ * DMODEL;
      qk_naive<<<dim3(2, SEQ, NHEAD), 256, 0, stream>>>(qb + bo_, kb + bo_, attn);
      softmax_bias_kernel<<<NHEAD * SEQ, 256, 0, stream>>>(attn, gate + (size_t)b * NHEAD * SEQ, tab);
      pv_naive<<<dim3(SEQ, NHEAD), 64, 0, stream>>>(attn, vb + bo_, ctx + bo_);
    }
    gemm16<0><<<dim3(48, 125), blk16, 0, stream>>>(ctx, Wo + (size_t)l * DMODEL * DMODEL, bo + l * DMODEL, tmp, Mrows, DMODEL, DMODEL, 1.0f);
    add_ln_kernel<0><<<Mrows, 256, 0, stream>>>(x, tmp, l1g + l * DMODEL, l1b + l * DMODEL);
    gemm16<1><<<dim3(FFN / 16, 125), blk16, 0, stream>>>(x, f1w + (size_t)l * FFN * DMODEL, f1b + l * FFN, ffh, Mrows, FFN, DMODEL, 1.0f);
    gemm16<0><<<dim3(48, 125), blk16, 0, stream>>>(ffh, f2w + (size_t)l * DMODEL * FFN, f2b + l * DMODEL, tmp, Mrows, DMODEL, FFN, 1.0f);
    add_ln_kernel<0><<<Mrows, 256, 0, stream>>>(x, tmp, l2g + l * DMODEL, l2b + l * DMODEL);
  }
  // result is already in d_out (x aliases it)
}

// Round 10
// 62799.493 us; speedup vs baseline: 1.4404x; 1.4404x over previous
//
#include <hip/hip_runtime.h>
#include <hip/hip_bf16.h>
#include <math.h>

namespace {

constexpr int BATCH  = 4;
constexpr int T_IN   = 160000;
constexpr int DMODEL = 768;
constexpr int NHEAD  = 12;
constexpr int DHEAD  = 64;
constexpr int FFN    = 3072;
constexpr int NLAYER = 12;
constexpr int SEQ    = 499;
constexpr int NREL   = 2 * SEQ - 1;   // 997 relative offsets

__device__ __forceinline__ float gelu_f(float x){
  return 0.5f * x * (1.0f + erff(x * 0.70710678118654752f));
}

__global__ void fill_f32_kernel(float* __restrict__ out, int n, float val){
  int i = blockIdx.x * 256 + threadIdx.x;
  if (i < n) out[i] = val;
}

// ---- conv stage 0: k=10, s=5 (src pre-offset), cross-correlation ----
__global__ void conv0_kernel(const float* __restrict__ src, const float* __restrict__ w,
                             float* __restrict__ out, int Lout){
  int idx = blockIdx.x * 256 + threadIdx.x;
  if (idx >= 512 * Lout) return;
  int c = idx / Lout, t = idx - c * Lout;
  const float* wr = w + c * 10;
  const float* s  = src + t * 5;
  float acc = 0.f;
#pragma unroll
  for (int k = 0; k < 10; k++) acc += wr[k] * s[k];
  out[idx] = acc;
}

// ---- LayerNorm over channels + exact GELU, layout (512, Lt), in place ----
__global__ void ln_gelu_ch_kernel(float* __restrict__ x, const float* __restrict__ g,
                                  const float* __restrict__ b, int Lt){
  int t = blockIdx.x * 256 + threadIdx.x;
  if (t >= Lt) return;
  float s = 0.f, sq = 0.f;
  for (int c = 0; c < 512; c++){ float v = x[c * Lt + t]; s += v; sq += v * v; }
  float m = s * (1.f / 512.f);
  float var = sq * (1.f / 512.f) - m * m;
  float rs = rsqrtf(var + 1e-5f);
  for (int c = 0; c < 512; c++){
    float v = (x[c * Lt + t] - m) * rs * g[c] + b[c];
    x[c * Lt + t] = gelu_f(v);
  }
}

// ---- TILED conv stages 1..6: 512->512, kernel KW, stride 2, 64co x 64t tile ----
template<int KW>
__global__ void conv_tiled_kernel(const float* __restrict__ in, const float* __restrict__ w,
                                  float* __restrict__ out, int Lin, int Lout,
                                  int outLd, int outOff){
  constexpr int ISPAN = 128 + KW;
  __shared__ float ins[8][ISPAN];
  __shared__ float wgt[8][KW][64];
  const int t0 = blockIdx.x * 64, co0 = blockIdx.y * 64;
  const int tid = threadIdx.x;
  const int tx = tid & 15, ty = tid >> 4;
  float acc[4][4] = {};
  for (int ci0 = 0; ci0 < 512; ci0 += 8){
    for (int idx = tid; idx < 8 * ISPAN; idx += 256){
      int ci = idx / ISPAN, j = idx - ci * ISPAN;
      int gp = t0 * 2 + j;
      ins[ci][j] = (gp < Lin) ? in[(size_t)(ci0 + ci) * Lin + gp] : 0.f;
    }
    for (int idx = tid; idx < 64 * 8 * KW; idx += 256){
      int co = idx / (8 * KW), r = idx - co * (8 * KW);
      int ci = r / KW, k = r - ci * KW;
      wgt[ci][k][co] = w[(size_t)(co0 + co) * (512 * KW) + (ci0 + ci) * KW + k];
    }
    __syncthreads();
#pragma unroll
    for (int ci = 0; ci < 8; ci++){
#pragma unroll
      for (int k = 0; k < KW; k++){
        float4 wv = *reinterpret_cast<const float4*>(&wgt[ci][k][ty * 4]);
        float wa[4] = {wv.x, wv.y, wv.z, wv.w};
        float iv[4];
#pragma unroll
        for (int j = 0; j < 4; j++) iv[j] = ins[ci][(tx * 4 + j) * 2 + k];
#pragma unroll
        for (int ii = 0; ii < 4; ii++)
#pragma unroll
          for (int jj = 0; jj < 4; jj++) acc[ii][jj] += wa[ii] * iv[jj];
      }
    }
    __syncthreads();
  }
#pragma unroll
  for (int ii = 0; ii < 4; ii++){
    int co = co0 + ty * 4 + ii;
#pragma unroll
    for (int jj = 0; jj < 4; jj++){
      int t = t0 + tx * 4 + jj;
      if (t < Lout) out[(size_t)co * outLd + outOff + t] = acc[ii][jj];
    }
  }
}

// ---- final feature LN + transpose (512,S)->(S,512) ----
__global__ void featln_transpose_kernel(const float* __restrict__ xin,
                                        const float* __restrict__ g, const float* __restrict__ b,
                                        float* __restrict__ feat){
  int t = blockIdx.x * 256 + threadIdx.x;
  if (t >= SEQ) return;
  float s = 0.f, sq = 0.f;
  for (int c = 0; c < 512; c++){ float v = xin[c * SEQ + t]; s += v; sq += v * v; }
  float m = s * (1.f / 512.f), var = sq * (1.f / 512.f) - m * m, rs = rsqrtf(var + 1e-5f);
  for (int c = 0; c < 512; c++)
    feat[t * 512 + c] = (xin[c * SEQ + t] - m) * rs * g[c] + b[c];
}

// ---- TILED GEMM: C(M,N) = act(alpha*(A(M,K) @ W(N,K)^T + bias)), 64x64, 4x4 micro ----
template<int ACT>  // 0 linear, 1 gelu
__global__ void gemm_kernel(const float* __restrict__ A, const float* __restrict__ W,
                            const float* __restrict__ bias, float* __restrict__ C,
                            int M, int N, int K, float alpha){
  __shared__ float As[16][64];
  __shared__ float Ws[16][64];
  const int n0 = blockIdx.x * 64, m0 = blockIdx.y * 64;
  const int tid = threadIdx.x, tx = tid & 15, ty = tid >> 4;
  const int lrow = tid >> 2, lcol = (tid & 3) * 4;
  float acc[4][4] = {};
  for (int k0 = 0; k0 < K; k0 += 16){
    {
      int m = m0 + lrow;
      float4 v = make_float4(0.f, 0.f, 0.f, 0.f);
      if (m < M) v = *reinterpret_cast<const float4*>(&A[(size_t)m * K + k0 + lcol]);
      As[lcol + 0][lrow] = v.x; As[lcol + 1][lrow] = v.y;
      As[lcol + 2][lrow] = v.z; As[lcol + 3][lrow] = v.w;
      float4 u = *reinterpret_cast<const float4*>(&W[(size_t)(n0 + lrow) * K + k0 + lcol]);
      Ws[lcol + 0][lrow] = u.x; Ws[lcol + 1][lrow] = u.y;
      Ws[lcol + 2][lrow] = u.z; Ws[lcol + 3][lrow] = u.w;
    }
    __syncthreads();
#pragma unroll
    for (int k = 0; k < 16; k++){
      float4 av = *reinterpret_cast<const float4*>(&As[k][ty * 4]);
      float4 wv = *reinterpret_cast<const float4*>(&Ws[k][tx * 4]);
      float a4[4] = {av.x, av.y, av.z, av.w};
      float w4[4] = {wv.x, wv.y, wv.z, wv.w};
#pragma unroll
      for (int ii = 0; ii < 4; ii++)
#pragma unroll
        for (int jj = 0; jj < 4; jj++) acc[ii][jj] += a4[ii] * w4[jj];
    }
    __syncthreads();
  }
#pragma unroll
  for (int ii = 0; ii < 4; ii++){
    int m = m0 + ty * 4 + ii;
    if (m >= M) continue;
#pragma unroll
    for (int jj = 0; jj < 4; jj++){
      int n = n0 + tx * 4 + jj;
      float v = alpha * (acc[ii][jj] + bias[n]);
      if (ACT == 1) v = gelu_f(v);
      C[(size_t)m * N + n] = v;
    }
  }
}

// ---- tiled positional grouped conv: k=128, pad 64, groups 16 (48 ch/group) ----
__global__ void posconv_kernel(const float* __restrict__ x, const float* __restrict__ w,
                               const float* __restrict__ bias, float* __restrict__ xc){
  const int b = blockIdx.z;
  const int t0 = blockIdx.x * 64;
  const int co_base = blockIdx.y * 4;
  const int g = co_base / 48;
  const int tid = threadIdx.x, lane = tid & 63, wid = tid >> 6;
  const int co = co_base + wid;
  __shared__ float xin[48][193];
  for (int idx = tid; idx < 48 * 191; idx += 256){
    int jj = idx / 48, ci = idx - jj * 48;
    int p = t0 - 64 + jj;
    xin[ci][jj] = (p >= 0 && p < SEQ) ? x[((size_t)(b * SEQ + p)) * DMODEL + g * 48 + ci] : 0.f;
  }
  __syncthreads();
  const float* wr = w + (size_t)co * 48 * 128;
  float acc = bias[co];
  for (int ci = 0; ci < 48; ci++){
    const float* wc = wr + ci * 128;
    const float* xr = &xin[ci][lane];
#pragma unroll
    for (int k = 0; k < 128; k += 4){
      float4 w4 = *reinterpret_cast<const float4*>(&wc[k]);
      acc += w4.x * xr[k] + w4.y * xr[k + 1] + w4.z * xr[k + 2] + w4.w * xr[k + 3];
    }
  }
  int t = t0 + lane;
  if (t < SEQ) xc[((size_t)(b * SEQ + t)) * DMODEL + co] = acc;
}

// ---- residual add (+optional GELU on added term) + row LayerNorm over DMODEL ----
template<int GELU_ADD>
__global__ void add_ln_kernel(float* __restrict__ x, const float* __restrict__ add,
                              const float* __restrict__ g, const float* __restrict__ b){
  int row = blockIdx.x;
  float* xr = x + (size_t)row * DMODEL;
  const float* ar = add + (size_t)row * DMODEL;
  __shared__ float buf[DMODEL];
  __shared__ float red[256];
  int tid = threadIdx.x;
  float s = 0.f;
  for (int i = tid; i < DMODEL; i += 256){
    float v = ar[i];
    if (GELU_ADD) v = gelu_f(v);
    v += xr[i];
    buf[i] = v; s += v;
  }
  red[tid] = s; __syncthreads();
  for (int st = 128; st > 0; st >>= 1){ if (tid < st) red[tid] += red[tid + st]; __syncthreads(); }
  float m = red[0] * (1.f / DMODEL); __syncthreads();
  float sq = 0.f;
  for (int i = tid; i < DMODEL; i += 256){ float d = buf[i] - m; sq += d * d; }
  red[tid] = sq; __syncthreads();
  for (int st = 128; st > 0; st >>= 1){ if (tid < st) red[tid] += red[tid + st]; __syncthreads(); }
  float rs = rsqrtf(red[0] * (1.f / DMODEL) + 1e-5f);
  for (int i = tid; i < DMODEL; i += 256) xr[i] = (buf[i] - m) * rs * g[i] + b[i];
}

// ---- T5-style relative position bias table: tab[h][rel+498], rel = j-i ----
__global__ void relbias_kernel(const float* __restrict__ rel_emb, float* __restrict__ tab){
  int idx = blockIdx.x * 256 + threadIdx.x;
  if (idx >= NREL * NHEAD) return;
  int rr = idx / NHEAD, h = idx - rr * NHEAD;
  int rel = rr - (SEQ - 1);
  int bkt = (rel > 0) ? 160 : 0;
  int n = (rel < 0) ? -rel : rel;
  if (n < 80) bkt += n;
  else {
    int large = 80 + (int)(logf((float)n / 80.f) / logf(10.f) * 80.f);
    bkt += (large < 159) ? large : 159;
  }
  tab[h * NREL + rr] = rel_emb[bkt * NHEAD + h];
}

// ---- gated rel-pos gate values; sigmoid AFTER 4-logit sums ----
__global__ void gate_kernel(const float* __restrict__ x, const float* __restrict__ gwl,
                            const float* __restrict__ gbl, const float* __restrict__ gal,
                            float* __restrict__ gate){
  int idx = blockIdx.x * 256 + threadIdx.x;
  if (idx >= BATCH * NHEAD * SEQ) return;
  int s = idx % SEQ; int bh = idx / SEQ; int h = bh % NHEAD; int b = bh / NHEAD;
  const float* xv = x + ((size_t)(b * SEQ + s)) * DMODEL + h * DHEAD;
  float a0 = 0.f, a1 = 0.f;
#pragma unroll
  for (int gg = 0; gg < 8; gg++){
    float a = gbl[gg];
    const float* wrow = gwl + gg * DHEAD;
#pragma unroll
    for (int d = 0; d < DHEAD; d++) a += xv[d] * wrow[d];
    if (gg < 4) a0 += a; else a1 += a;
  }
  float g0 = 1.f / (1.f + expf(-a0));
  float g1 = 1.f / (1.f + expf(-a1));
  gate[idx] = g0 * (g1 * gal[h] - 1.f) + 2.f;
}

// ---- per-batch TILED Q@K^T: q,k are (S,768); sc is (H,S,S); h = blockIdx.z ----
__global__ void qk_kernel(const float* __restrict__ q, const float* __restrict__ k,
                          float* __restrict__ sc){
  int h = blockIdx.z;
  int i0 = blockIdx.y * 32, j0 = blockIdx.x * 32;
  __shared__ float qs[32][68], ks[32][68];
  int tid = threadIdx.x;
  for (int idx = tid; idx < 2048; idx += 256){
    int r = idx >> 6, c = idx & 63;
    int i = i0 + r;
    qs[r][c] = (i < SEQ) ? q[(size_t)i * DMODEL + h * DHEAD + c] : 0.f;
    int j = j0 + r;
    ks[r][c] = (j < SEQ) ? k[(size_t)j * DMODEL + h * DHEAD + c] : 0.f;
  }
  __syncthreads();
  int tx = tid & 31, ty = tid >> 5;
  float acc[4] = {};
  for (int kk = 0; kk < 64; kk += 4){
    float4 kv = *reinterpret_cast<const float4*>(&ks[tx][kk]);
#pragma unroll
    for (int ii = 0; ii < 4; ii++){
      float4 qv = *reinterpret_cast<const float4*>(&qs[ty * 4 + ii][kk]);
      acc[ii] += qv.x * kv.x + qv.y * kv.y + qv.z * kv.z + qv.w * kv.w;
    }
  }
#pragma unroll
  for (int ii = 0; ii < 4; ii++){
    int i = i0 + ty * 4 + ii, j = j0 + tx;
    if (i < SEQ && j < SEQ) sc[((size_t)h * SEQ + i) * SEQ + j] = acc[ii];
  }
}

// ---- per-batch softmax with fused gate * relbias add, in place ----
__global__ void softmax_bias_kernel(float* __restrict__ sc, const float* __restrict__ gate_b,
                                    const float* __restrict__ tab){
  int row = blockIdx.x;               // h*S + i
  int h = row / SEQ, i = row - h * SEQ;
  float gt = gate_b[row];
  float* p = sc + (size_t)row * SEQ;
  const float* tb = tab + (size_t)h * NREL + (SEQ - 1 - i);
  __shared__ float buf[512];
  __shared__ float red[256];
  int tid = threadIdx.x;
  float mx = -1e30f;
  for (int j = tid; j < SEQ; j += 256){
    float v = p[j] + gt * tb[j];
    buf[j] = v; mx = fmaxf(mx, v);
  }
  red[tid] = mx; __syncthreads();
  for (int st = 128; st > 0; st >>= 1){ if (tid < st) red[tid] = fmaxf(red[tid], red[tid + st]); __syncthreads(); }
  mx = red[0]; __syncthreads();
  float sum = 0.f;
  for (int j = tid; j < SEQ; j += 256){ float e = expf(buf[j] - mx); buf[j] = e; sum += e; }
  red[tid] = sum; __syncthreads();
  for (int st = 128; st > 0; st >>= 1){ if (tid < st) red[tid] += red[tid + st]; __syncthreads(); }
  float inv = 1.0f / red[0];
  for (int j = tid; j < SEQ; j += 256) p[j] = buf[j] * inv;
}

// ---- per-batch TILED P @ V: p (H,S,S); v (S,768); ctx (S,768); h = blockIdx.y ----
__global__ void pv_kernel(const float* __restrict__ p, const float* __restrict__ v,
                          float* __restrict__ ctx){
  int h = blockIdx.y;
  int i0 = blockIdx.x * 32;
  __shared__ float ps[32][33];
  __shared__ float vs[32][64];
  int tid = threadIdx.x, tx = tid & 63, ty = tid >> 6;
  float acc[8] = {};
  for (int j0 = 0; j0 < SEQ; j0 += 32){
    for (int idx = tid; idx < 1024; idx += 256){
      int r = idx >> 5, c = idx & 31;
      int i = i0 + r, j = j0 + c;
      ps[r][c] = (i < SEQ && j < SEQ) ? p[((size_t)h * SEQ + i) * SEQ + j] : 0.f;
    }
    for (int idx = tid; idx < 2048; idx += 256){
      int r = idx >> 6, c = idx & 63;
      int j = j0 + r;
      vs[r][c] = (j < SEQ) ? v[(size_t)j * DMODEL + h * DHEAD + c] : 0.f;
    }
    __syncthreads();
#pragma unroll
    for (int jj = 0; jj < 32; jj++){
      float vv = vs[jj][tx];
#pragma unroll
      for (int ii = 0; ii < 8; ii++) acc[ii] += ps[ty * 8 + ii][jj] * vv;
    }
    __syncthreads();
  }
#pragma unroll
  for (int ii = 0; ii < 8; ii++){
    int i = i0 + ty * 8 + ii;
    if (i < SEQ) ctx[(size_t)i * DMODEL + h * DHEAD + tx] = acc[ii];
  }
}

} // anonymous namespace

extern "C" void kernel_launch(void* const* d_in, const int* in_sizes, int n_in,
                              void* d_out, int out_size, void* d_ws, size_t ws_size,
                              hipStream_t stream){
  (void)ws_size;

  static const int DS[34] = {640000,5120,3145728,1048576,3584,3584,512,512,393216,768,
                             4718592,768,768,768,7077888,9216,7077888,9216,7077888,9216,
                             7077888,9216,6144,96,144,9216,9216,28311552,36864,28311552,
                             9216,9216,9216,3840};
  bool ok = (n_in == 34) && (out_size == BATCH * SEQ * DMODEL);
  if (ok) for (int i = 0; i < 34; i++) if (in_sizes[i] != DS[i]) { ok = false; break; }
  if (!ok){
    fill_f32_kernel<<<(out_size + 255) / 256, 256, 0, stream>>>((float*)d_out, out_size, 1000.0f);
    return;
  }

  const float* src  = (const float*)d_in[0];
  const float* w0   = (const float*)d_in[1];
  const float* w14  = (const float*)d_in[2];
  const float* w56  = (const float*)d_in[3];
  const float* clng = (const float*)d_in[4];
  const float* clnb = (const float*)d_in[5];
  const float* flng = (const float*)d_in[6];
  const float* flnb = (const float*)d_in[7];
  const float* pjw  = (const float*)d_in[8];
  const float* pjb  = (const float*)d_in[9];
  const float* pcw  = (const float*)d_in[10];
  const float* pcb  = (const float*)d_in[11];
  const float* eng  = (const float*)d_in[12];
  const float* enb  = (const float*)d_in[13];
  const float* Wq   = (const float*)d_in[14];
  const float* bq   = (const float*)d_in[15];
  const float* Wk   = (const float*)d_in[16];
  const float* bk   = (const float*)d_in[17];
  const float* Wv   = (const float*)d_in[18];
  const float* bv   = (const float*)d_in[19];
  const float* Wo   = (const float*)d_in[20];
  const float* bo   = (const float*)d_in[21];
  const float* gw   = (const float*)d_in[22];
  const float* gbp  = (const float*)d_in[23];
  const float* ga   = (const float*)d_in[24];
  const float* l1g  = (const float*)d_in[25];
  const float* l1b  = (const float*)d_in[26];
  const float* f1w  = (const float*)d_in[27];
  const float* f1b  = (const float*)d_in[28];
  const float* f2w  = (const float*)d_in[29];
  const float* f2b  = (const float*)d_in[30];
  const float* l2g  = (const float*)d_in[31];
  const float* l2b  = (const float*)d_in[32];
  const float* rel  = (const float*)d_in[33];

  // OUTPUT IS FP32; residual stream x lives directly in d_out.
  float* x = (float*)d_out;

  // workspace: no aliasing (~103 MB, verified available)
  float* wsf = (float*)d_ws;
  size_t off = 0;
  auto alloc = [&](size_t n){ float* pp = wsf + off; off += (n + 63) & ~(size_t)63; return pp; };
  const size_t XSZ = (size_t)BATCH * SEQ * DMODEL;
  float* tmp  = alloc(XSZ);
  float* qb   = alloc(XSZ);
  float* kb   = alloc(XSZ);
  float* vb   = alloc(XSZ);
  float* ctx  = alloc(XSZ);
  float* feat = alloc((size_t)BATCH * SEQ * 512);
  float* c6   = alloc((size_t)512 * SEQ);
  float* gate = alloc((size_t)BATCH * NHEAD * SEQ);
  float* tab  = alloc((size_t)NHEAD * NREL);
  float* attn = alloc((size_t)NHEAD * SEQ * SEQ);
  float* ffh  = alloc((size_t)BATCH * SEQ * FFN);
  constexpr size_t CA_SZ = (size_t)512 * (64 * 125 + 15);
  constexpr size_t CB_SZ = (size_t)512 * (32 * 125 + 7);
  float* cA   = alloc(CA_SZ);
  float* cB   = alloc(CB_SZ);

  // ---- conv feature extractor: per batch, 4 time-chunks with exact halos ----
  for (int b = 0; b < BATCH; b++){
    for (int c = 0; c < 4; c++){
      int o0 = c * 125, o1 = (o0 + 125 < SEQ) ? o0 + 125 : SEQ;
      int C  = o1 - o0;
      int L[7];
      L[6] = C; L[5] = 2 * C; L[4] = 4 * C; L[3] = 8 * C + 1;
      L[2] = 16 * C + 3; L[1] = 32 * C + 7; L[0] = 64 * C + 15;
      conv0_kernel<<<(512 * L[0] + 255) / 256, 256, 0, stream>>>(
          src + (size_t)b * T_IN + 320 * o0, w0, cA, L[0]);
      ln_gelu_ch_kernel<<<(L[0] + 255) / 256, 256, 0, stream>>>(cA, clng, clnb, L[0]);
      float* bufs[2] = {cA, cB};
      for (int st = 1; st <= 6; st++){
        const float* inb = bufs[(st + 1) & 1];
        float* outb      = (st == 6) ? c6 : bufs[st & 1];
        int Lin = L[st - 1], Lout = L[st];
        int oLd = (st == 6) ? SEQ : Lout;
        int oOf = (st == 6) ? o0 : 0;
        dim3 grd((Lout + 63) / 64, 8);
        if (st <= 4)
          conv_tiled_kernel<3><<<grd, 256, 0, stream>>>(inb, w14 + (size_t)(st - 1) * 512 * 512 * 3, outb, Lin, Lout, oLd, oOf);
        else
          conv_tiled_kernel<2><<<grd, 256, 0, stream>>>(inb, w56 + (size_t)(st - 5) * 512 * 512 * 2, outb, Lin, Lout, oLd, oOf);
        if (st < 6)
          ln_gelu_ch_kernel<<<(Lout + 255) / 256, 256, 0, stream>>>(outb, clng + st * 512, clnb + st * 512, Lout);
      }
    }
    ln_gelu_ch_kernel<<<(SEQ + 255) / 256, 256, 0, stream>>>(c6, clng + 6 * 512, clnb + 6 * 512, SEQ);
    featln_transpose_kernel<<<(SEQ + 255) / 256, 256, 0, stream>>>(c6, flng, flnb, feat + (size_t)b * SEQ * 512);
  }

  const int Mrows = BATCH * SEQ; // 1996
  gemm_kernel<0><<<dim3(DMODEL / 64, (Mrows + 63) / 64), 256, 0, stream>>>(feat, pjw, pjb, x, Mrows, DMODEL, 512, 1.0f);
  posconv_kernel<<<dim3((SEQ + 63) / 64, DMODEL / 4, BATCH), 256, 0, stream>>>(x, pcw, pcb, tmp);
  add_ln_kernel<1><<<Mrows, 256, 0, stream>>>(x, tmp, eng, enb);
  relbias_kernel<<<(NREL * NHEAD + 255) / 256, 256, 0, stream>>>(rel, tab);

  for (int l = 0; l < NLAYER; l++){
    gate_kernel<<<(BATCH * NHEAD * SEQ + 255) / 256, 256, 0, stream>>>(
        x, gw + (size_t)l * 8 * DHEAD, gbp + l * 8, ga + l * NHEAD, gate);
    gemm_kernel<0><<<dim3(12, 32), 256, 0, stream>>>(x, Wq + (size_t)l * DMODEL * DMODEL, bq + l * DMODEL, qb, Mrows, DMODEL, DMODEL, 0.125f);
    gemm_kernel<0><<<dim3(12, 32), 256, 0, stream>>>(x, Wk + (size_t)l * DMODEL * DMODEL, bk + l * DMODEL, kb, Mrows, DMODEL, DMODEL, 1.0f);
    gemm_kernel<0><<<dim3(12, 32), 256, 0, stream>>>(x, Wv + (size_t)l * DMODEL * DMODEL, bv + l * DMODEL, vb, Mrows, DMODEL, DMODEL, 1.0f);
    for (int b = 0; b < BATCH; b++){
      const size_t bo_ = (size_t)b * SEQ * DMODEL;
      qk_kernel<<<dim3(16, 16, NHEAD), 256, 0, stream>>>(qb + bo_, kb + bo_, attn);
      softmax_bias_kernel<<<NHEAD * SEQ, 256, 0, stream>>>(attn, gate + (size_t)b * NHEAD * SEQ, tab);
      pv_kernel<<<dim3(16, NHEAD), 256, 0, stream>>>(attn, vb + bo_, ctx + bo_);
    }
    gemm_kernel<0><<<dim3(12, 32), 256, 0, stream>>>(ctx, Wo + (size_t)l * DMODEL * DMODEL, bo + l * DMODEL, tmp, Mrows, DMODEL, DMODEL, 1.0f);
    add_ln_kernel<0><<<Mrows, 256, 0, stream>>>(x, tmp, l1g + l * DMODEL, l1b + l * DMODEL);
    gemm_kernel<1><<<dim3(FFN / 64, 32), 256, 0, stream>>>(x, f1w + (size_t)l * FFN * DMODEL, f1b + l * FFN, ffh, Mrows, FFN, DMODEL, 1.0f);
    gemm_kernel<0><<<dim3(12, 32), 256, 0, stream>>>(ffh, f2w + (size_t)l * DMODEL * FFN, f2b + l * DMODEL, tmp, Mrows, DMODEL, FFN, 1.0f);
    add_ln_kernel<0><<<Mrows, 256, 0, stream>>>(x, tmp, l2g + l * DMODEL, l2b + l * DMODEL);
  }
  // result is already in d_out (x aliases it)
}

// Round 11
// 54715.399 us; speedup vs baseline: 1.6532x; 1.1477x over previous
//
#include <hip/hip_runtime.h>
#include <hip/hip_bf16.h>
#include <math.h>

namespace {

constexpr int BATCH  = 4;
constexpr int T_IN   = 160000;
constexpr int DMODEL = 768;
constexpr int NHEAD  = 12;
constexpr int DHEAD  = 64;
constexpr int FFN    = 3072;
constexpr int NLAYER = 12;
constexpr int SEQ    = 499;
constexpr int NREL   = 2 * SEQ - 1;

typedef __hip_bfloat16 bf16;
using f32x4 = __attribute__((ext_vector_type(4))) float;
using s16x8 = __attribute__((ext_vector_type(8))) short;

__device__ __forceinline__ float gelu_f(float x){
  return 0.5f * x * (1.0f + erff(x * 0.70710678118654752f));
}

__global__ void fill_f32_kernel(float* __restrict__ out, int n, float val){
  int i = blockIdx.x * 256 + threadIdx.x;
  if (i < n) out[i] = val;
}

// ---- fp32 -> bf16 cast ----
__global__ void f2bf_kernel(const float* __restrict__ in, bf16* __restrict__ out, int n){
  int i = blockIdx.x * 256 + threadIdx.x;
  if (i < n) out[i] = __float2bfloat16(in[i]);
}

// ---- conv stage 0: k=10, s=5 (src pre-offset) ----
__global__ void conv0_kernel(const float* __restrict__ src, const float* __restrict__ w,
                             float* __restrict__ out, int Lout){
  int idx = blockIdx.x * 256 + threadIdx.x;
  if (idx >= 512 * Lout) return;
  int c = idx / Lout, t = idx - c * Lout;
  const float* wr = w + c * 10;
  const float* s  = src + t * 5;
  float acc = 0.f;
#pragma unroll
  for (int k = 0; k < 10; k++) acc += wr[k] * s[k];
  out[idx] = acc;
}

// ---- LayerNorm over channels + GELU, layout (512, Lt), in place ----
__global__ void ln_gelu_ch_kernel(float* __restrict__ x, const float* __restrict__ g,
                                  const float* __restrict__ b, int Lt){
  int t = blockIdx.x * 256 + threadIdx.x;
  if (t >= Lt) return;
  float s = 0.f, sq = 0.f;
  for (int c = 0; c < 512; c++){ float v = x[c * Lt + t]; s += v; sq += v * v; }
  float m = s * (1.f / 512.f);
  float var = sq * (1.f / 512.f) - m * m;
  float rs = rsqrtf(var + 1e-5f);
  for (int c = 0; c < 512; c++){
    float v = (x[c * Lt + t] - m) * rs * g[c] + b[c];
    x[c * Lt + t] = gelu_f(v);
  }
}

// ---- TILED conv stages 1..6: 512->512, kernel KW, stride 2 ----
template<int KW>
__global__ void conv_tiled_kernel(const float* __restrict__ in, const float* __restrict__ w,
                                  float* __restrict__ out, int Lin, int Lout,
                                  int outLd, int outOff){
  constexpr int ISPAN = 128 + KW;
  __shared__ float ins[8][ISPAN];
  __shared__ float wgt[8][KW][64];
  const int t0 = blockIdx.x * 64, co0 = blockIdx.y * 64;
  const int tid = threadIdx.x;
  const int tx = tid & 15, ty = tid >> 4;
  float acc[4][4] = {};
  for (int ci0 = 0; ci0 < 512; ci0 += 8){
    for (int idx = tid; idx < 8 * ISPAN; idx += 256){
      int ci = idx / ISPAN, j = idx - ci * ISPAN;
      int gp = t0 * 2 + j;
      ins[ci][j] = (gp < Lin) ? in[(size_t)(ci0 + ci) * Lin + gp] : 0.f;
    }
    for (int idx = tid; idx < 64 * 8 * KW; idx += 256){
      int co = idx / (8 * KW), r = idx - co * (8 * KW);
      int ci = r / KW, k = r - ci * KW;
      wgt[ci][k][co] = w[(size_t)(co0 + co) * (512 * KW) + (ci0 + ci) * KW + k];
    }
    __syncthreads();
#pragma unroll
    for (int ci = 0; ci < 8; ci++){
#pragma unroll
      for (int k = 0; k < KW; k++){
        float4 wv = *reinterpret_cast<const float4*>(&wgt[ci][k][ty * 4]);
        float wa[4] = {wv.x, wv.y, wv.z, wv.w};
        float iv[4];
#pragma unroll
        for (int j = 0; j < 4; j++) iv[j] = ins[ci][(tx * 4 + j) * 2 + k];
#pragma unroll
        for (int ii = 0; ii < 4; ii++)
#pragma unroll
          for (int jj = 0; jj < 4; jj++) acc[ii][jj] += wa[ii] * iv[jj];
      }
    }
    __syncthreads();
  }
#pragma unroll
  for (int ii = 0; ii < 4; ii++){
    int co = co0 + ty * 4 + ii;
#pragma unroll
    for (int jj = 0; jj < 4; jj++){
      int t = t0 + tx * 4 + jj;
      if (t < Lout) out[(size_t)co * outLd + outOff + t] = acc[ii][jj];
    }
  }
}

// ---- final feature LN + transpose (512,S)->(S,512) ----
__global__ void featln_transpose_kernel(const float* __restrict__ xin,
                                        const float* __restrict__ g, const float* __restrict__ b,
                                        float* __restrict__ feat){
  int t = blockIdx.x * 256 + threadIdx.x;
  if (t >= SEQ) return;
  float s = 0.f, sq = 0.f;
  for (int c = 0; c < 512; c++){ float v = xin[c * SEQ + t]; s += v; sq += v * v; }
  float m = s * (1.f / 512.f), var = sq * (1.f / 512.f) - m * m, rs = rsqrtf(var + 1e-5f);
  for (int c = 0; c < 512; c++)
    feat[t * 512 + c] = (xin[c * SEQ + t] - m) * rs * g[c] + b[c];
}

// ---- MFMA bf16 GEMM: C(M,N) = act(alpha*(A(M,K) @ W(N,K)^T + bias)) ----
// 64x64 block, 4 waves (2x2), wave = 32x32 via 2x2 mfma_f32_16x16x32_bf16.
// A,W bf16 row-major with K contiguous; K%32==0, N%64==0; M guarded.
template<int ACT>
__global__ void gemm_mfma(const bf16* __restrict__ A, const bf16* __restrict__ W,
                          const float* __restrict__ bias, float* __restrict__ C,
                          int M, int N, int K, float alpha){
  __shared__ bf16 As[64][40];   // row stride 80 B (16B-aligned, banks spread)
  __shared__ bf16 Ws[64][40];
  const int tid = threadIdx.x;
  const int wid = tid >> 6, lane = tid & 63;
  const int m0 = blockIdx.y * 64, n0 = blockIdx.x * 64;
  const int wm = (wid >> 1) * 32, wn = (wid & 1) * 32;
  const int lrow = tid >> 2;        // 0..63
  const int lk   = (tid & 3) * 8;   // 0,8,16,24
  const int fr = lane & 15, fk = (lane >> 4) * 8;
  f32x4 acc[2][2] = {};
  for (int k0 = 0; k0 < K; k0 += 32){
    uint4 av = make_uint4(0, 0, 0, 0);
    int gm = m0 + lrow;
    if (gm < M) av = *reinterpret_cast<const uint4*>(&A[(size_t)gm * K + k0 + lk]);
    *reinterpret_cast<uint4*>(&As[lrow][lk]) = av;
    uint4 wv = *reinterpret_cast<const uint4*>(&W[(size_t)(n0 + lrow) * K + k0 + lk]);
    *reinterpret_cast<uint4*>(&Ws[lrow][lk]) = wv;
    __syncthreads();
    s16x8 a0 = *reinterpret_cast<const s16x8*>(&As[wm + fr][fk]);
    s16x8 a1 = *reinterpret_cast<const s16x8*>(&As[wm + 16 + fr][fk]);
    s16x8 b0 = *reinterpret_cast<const s16x8*>(&Ws[wn + fr][fk]);
    s16x8 b1 = *reinterpret_cast<const s16x8*>(&Ws[wn + 16 + fr][fk]);
    acc[0][0] = __builtin_amdgcn_mfma_f32_16x16x32_bf16(a0, b0, acc[0][0], 0, 0, 0);
    acc[0][1] = __builtin_amdgcn_mfma_f32_16x16x32_bf16(a0, b1, acc[0][1], 0, 0, 0);
    acc[1][0] = __builtin_amdgcn_mfma_f32_16x16x32_bf16(a1, b0, acc[1][0], 0, 0, 0);
    acc[1][1] = __builtin_amdgcn_mfma_f32_16x16x32_bf16(a1, b1, acc[1][1], 0, 0, 0);
    __syncthreads();
  }
  // C/D layout (m89-verified): col = lane&15, row = 4*(lane>>4) + r
  const int cc = lane & 15, cr = (lane >> 4) * 4;
#pragma unroll
  for (int mi = 0; mi < 2; mi++){
#pragma unroll
    for (int ni = 0; ni < 2; ni++){
      int n = n0 + wn + ni * 16 + cc;
      float bn = bias[n];
#pragma unroll
      for (int r = 0; r < 4; r++){
        int m = m0 + wm + mi * 16 + cr + r;
        if (m < M){
          float v = alpha * (acc[mi][ni][r] + bn);
          if (ACT == 1) v = gelu_f(v);
          C[(size_t)m * N + n] = v;
        }
      }
    }
  }
}

// ---- tiled positional grouped conv: k=128, pad 64, groups 16 ----
__global__ void posconv_kernel(const float* __restrict__ x, const float* __restrict__ w,
                               const float* __restrict__ bias, float* __restrict__ xc){
  const int b = blockIdx.z;
  const int t0 = blockIdx.x * 64;
  const int co_base = blockIdx.y * 4;
  const int g = co_base / 48;
  const int tid = threadIdx.x, lane = tid & 63, wid = tid >> 6;
  const int co = co_base + wid;
  __shared__ float xin[48][193];
  for (int idx = tid; idx < 48 * 191; idx += 256){
    int jj = idx / 48, ci = idx - jj * 48;
    int p = t0 - 64 + jj;
    xin[ci][jj] = (p >= 0 && p < SEQ) ? x[((size_t)(b * SEQ + p)) * DMODEL + g * 48 + ci] : 0.f;
  }
  __syncthreads();
  const float* wr = w + (size_t)co * 48 * 128;
  float acc = bias[co];
  for (int ci = 0; ci < 48; ci++){
    const float* wc = wr + ci * 128;
    const float* xr = &xin[ci][lane];
#pragma unroll
    for (int k = 0; k < 128; k += 4){
      float4 w4 = *reinterpret_cast<const float4*>(&wc[k]);
      acc += w4.x * xr[k] + w4.y * xr[k + 1] + w4.z * xr[k + 2] + w4.w * xr[k + 3];
    }
  }
  int t = t0 + lane;
  if (t < SEQ) xc[((size_t)(b * SEQ + t)) * DMODEL + co] = acc;
}

// ---- residual add (+optional GELU on added term) + row LayerNorm over DMODEL ----
template<int GELU_ADD>
__global__ void add_ln_kernel(float* __restrict__ x, const float* __restrict__ add,
                              const float* __restrict__ g, const float* __restrict__ b){
  int row = blockIdx.x;
  float* xr = x + (size_t)row * DMODEL;
  const float* ar = add + (size_t)row * DMODEL;
  __shared__ float buf[DMODEL];
  __shared__ float red[256];
  int tid = threadIdx.x;
  float s = 0.f;
  for (int i = tid; i < DMODEL; i += 256){
    float v = ar[i];
    if (GELU_ADD) v = gelu_f(v);
    v += xr[i];
    buf[i] = v; s += v;
  }
  red[tid] = s; __syncthreads();
  for (int st = 128; st > 0; st >>= 1){ if (tid < st) red[tid] += red[tid + st]; __syncthreads(); }
  float m = red[0] * (1.f / DMODEL); __syncthreads();
  float sq = 0.f;
  for (int i = tid; i < DMODEL; i += 256){ float d = buf[i] - m; sq += d * d; }
  red[tid] = sq; __syncthreads();
  for (int st = 128; st > 0; st >>= 1){ if (tid < st) red[tid] += red[tid + st]; __syncthreads(); }
  float rs = rsqrtf(red[0] * (1.f / DMODEL) + 1e-5f);
  for (int i = tid; i < DMODEL; i += 256) xr[i] = (buf[i] - m) * rs * g[i] + b[i];
}

// ---- T5-style relative position bias table: tab[h][rel+498], rel = j-i ----
__global__ void relbias_kernel(const float* __restrict__ rel_emb, float* __restrict__ tab){
  int idx = blockIdx.x * 256 + threadIdx.x;
  if (idx >= NREL * NHEAD) return;
  int rr = idx / NHEAD, h = idx - rr * NHEAD;
  int rel = rr - (SEQ - 1);
  int bkt = (rel > 0) ? 160 : 0;
  int n = (rel < 0) ? -rel : rel;
  if (n < 80) bkt += n;
  else {
    int large = 80 + (int)(logf((float)n / 80.f) / logf(10.f) * 80.f);
    bkt += (large < 159) ? large : 159;
  }
  tab[h * NREL + rr] = rel_emb[bkt * NHEAD + h];
}

// ---- gated rel-pos gate values; sigmoid AFTER 4-logit sums ----
__global__ void gate_kernel(const float* __restrict__ x, const float* __restrict__ gwl,
                            const float* __restrict__ gbl, const float* __restrict__ gal,
                            float* __restrict__ gate){
  int idx = blockIdx.x * 256 + threadIdx.x;
  if (idx >= BATCH * NHEAD * SEQ) return;
  int s = idx % SEQ; int bh = idx / SEQ; int h = bh % NHEAD; int b = bh / NHEAD;
  const float* xv = x + ((size_t)(b * SEQ + s)) * DMODEL + h * DHEAD;
  float a0 = 0.f, a1 = 0.f;
#pragma unroll
  for (int gg = 0; gg < 8; gg++){
    float a = gbl[gg];
    const float* wrow = gwl + gg * DHEAD;
#pragma unroll
    for (int d = 0; d < DHEAD; d++) a += xv[d] * wrow[d];
    if (gg < 4) a0 += a; else a1 += a;
  }
  float g0 = 1.f / (1.f + expf(-a0));
  float g1 = 1.f / (1.f + expf(-a1));
  gate[idx] = g0 * (g1 * gal[h] - 1.f) + 2.f;
}

// ---- all-batch TILED Q@K^T: (b,h) = blockIdx.z; sc (B,H,S,S) ----
__global__ void qk_kernel(const float* __restrict__ q, const float* __restrict__ k,
                          float* __restrict__ sc){
  int bh = blockIdx.z; int b = bh / NHEAD, h = bh % NHEAD;
  int i0 = blockIdx.y * 32, j0 = blockIdx.x * 32;
  __shared__ float qs[32][68], ks[32][68];
  int tid = threadIdx.x;
  for (int idx = tid; idx < 2048; idx += 256){
    int r = idx >> 6, c = idx & 63;
    int i = i0 + r;
    qs[r][c] = (i < SEQ) ? q[((size_t)(b * SEQ + i)) * DMODEL + h * DHEAD + c] : 0.f;
    int j = j0 + r;
    ks[r][c] = (j < SEQ) ? k[((size_t)(b * SEQ + j)) * DMODEL + h * DHEAD + c] : 0.f;
  }
  __syncthreads();
  int tx = tid & 31, ty = tid >> 5;
  float acc[4] = {};
  for (int kk = 0; kk < 64; kk += 4){
    float4 kv = *reinterpret_cast<const float4*>(&ks[tx][kk]);
#pragma unroll
    for (int ii = 0; ii < 4; ii++){
      float4 qv = *reinterpret_cast<const float4*>(&qs[ty * 4 + ii][kk]);
      acc[ii] += qv.x * kv.x + qv.y * kv.y + qv.z * kv.z + qv.w * kv.w;
    }
  }
#pragma unroll
  for (int ii = 0; ii < 4; ii++){
    int i = i0 + ty * 4 + ii, j = j0 + tx;
    if (i < SEQ && j < SEQ) sc[((size_t)bh * SEQ + i) * SEQ + j] = acc[ii];
  }
}

// ---- softmax over last dim with fused gate*relbias add, in place; row=(b,h,i) ----
__global__ void softmax_bias_kernel(float* __restrict__ sc, const float* __restrict__ gate,
                                    const float* __restrict__ tab){
  int row = blockIdx.x;               // (b*H+h)*S + i
  int bh = row / SEQ, i = row - bh * SEQ;
  int h = bh % NHEAD;
  float gt = gate[row];
  float* p = sc + (size_t)row * SEQ;
  const float* tb = tab + (size_t)h * NREL + (SEQ - 1 - i);
  __shared__ float buf[512];
  __shared__ float red[256];
  int tid = threadIdx.x;
  float mx = -1e30f;
  for (int j = tid; j < SEQ; j += 256){
    float v = p[j] + gt * tb[j];
    buf[j] = v; mx = fmaxf(mx, v);
  }
  red[tid] = mx; __syncthreads();
  for (int st = 128; st > 0; st >>= 1){ if (tid < st) red[tid] = fmaxf(red[tid], red[tid + st]); __syncthreads(); }
  mx = red[0]; __syncthreads();
  float sum = 0.f;
  for (int j = tid; j < SEQ; j += 256){ float e = expf(buf[j] - mx); buf[j] = e; sum += e; }
  red[tid] = sum; __syncthreads();
  for (int st = 128; st > 0; st >>= 1){ if (tid < st) red[tid] += red[tid + st]; __syncthreads(); }
  float inv = 1.0f / red[0];
  for (int j = tid; j < SEQ; j += 256) p[j] = buf[j] * inv;
}

// ---- all-batch TILED P @ V: (b,h) = blockIdx.y ----
__global__ void pv_kernel(const float* __restrict__ p, const float* __restrict__ v,
                          float* __restrict__ ctx){
  int bh = blockIdx.y, b = bh / NHEAD, h = bh % NHEAD;
  int i0 = blockIdx.x * 32;
  __shared__ float ps[32][33];
  __shared__ float vs[32][64];
  int tid = threadIdx.x, tx = tid & 63, ty = tid >> 6;
  float acc[8] = {};
  for (int j0 = 0; j0 < SEQ; j0 += 32){
    for (int idx = tid; idx < 1024; idx += 256){
      int r = idx >> 5, c = idx & 31;
      int i = i0 + r, j = j0 + c;
      ps[r][c] = (i < SEQ && j < SEQ) ? p[((size_t)bh * SEQ + i) * SEQ + j] : 0.f;
    }
    for (int idx = tid; idx < 2048; idx += 256){
      int r = idx >> 6, c = idx & 63;
      int j = j0 + r;
      vs[r][c] = (j < SEQ) ? v[((size_t)(b * SEQ + j)) * DMODEL + h * DHEAD + c] : 0.f;
    }
    __syncthreads();
#pragma unroll
    for (int jj = 0; jj < 32; jj++){
      float vv = vs[jj][tx];
#pragma unroll
      for (int ii = 0; ii < 8; ii++) acc[ii] += ps[ty * 8 + ii][jj] * vv;
    }
    __syncthreads();
  }
#pragma unroll
  for (int ii = 0; ii < 8; ii++){
    int i = i0 + ty * 8 + ii;
    if (i < SEQ) ctx[((size_t)(b * SEQ + i)) * DMODEL + h * DHEAD + tx] = acc[ii];
  }
}

} // anonymous namespace

extern "C" void kernel_launch(void* const* d_in, const int* in_sizes, int n_in,
                              void* d_out, int out_size, void* d_ws, size_t ws_size,
                              hipStream_t stream){
  (void)ws_size;

  static const int DS[34] = {640000,5120,3145728,1048576,3584,3584,512,512,393216,768,
                             4718592,768,768,768,7077888,9216,7077888,9216,7077888,9216,
                             7077888,9216,6144,96,144,9216,9216,28311552,36864,28311552,
                             9216,9216,9216,3840};
  bool ok = (n_in == 34) && (out_size == BATCH * SEQ * DMODEL);
  if (ok) for (int i = 0; i < 34; i++) if (in_sizes[i] != DS[i]) { ok = false; break; }
  if (!ok){
    fill_f32_kernel<<<(out_size + 255) / 256, 256, 0, stream>>>((float*)d_out, out_size, 1000.0f);
    return;
  }

  const float* src  = (const float*)d_in[0];
  const float* w0   = (const float*)d_in[1];
  const float* w14  = (const float*)d_in[2];
  const float* w56  = (const float*)d_in[3];
  const float* clng = (const float*)d_in[4];
  const float* clnb = (const float*)d_in[5];
  const float* flng = (const float*)d_in[6];
  const float* flnb = (const float*)d_in[7];
  const float* pjw  = (const float*)d_in[8];
  const float* pjb  = (const float*)d_in[9];
  const float* pcw  = (const float*)d_in[10];
  const float* pcb  = (const float*)d_in[11];
  const float* eng  = (const float*)d_in[12];
  const float* enb  = (const float*)d_in[13];
  const float* Wq   = (const float*)d_in[14];
  const float* bq   = (const float*)d_in[15];
  const float* Wk   = (const float*)d_in[16];
  const float* bk   = (const float*)d_in[17];
  const float* Wv   = (const float*)d_in[18];
  const float* bv   = (const float*)d_in[19];
  const float* Wo   = (const float*)d_in[20];
  const float* bo   = (const float*)d_in[21];
  const float* gw   = (const float*)d_in[22];
  const float* gbp  = (const float*)d_in[23];
  const float* ga   = (const float*)d_in[24];
  const float* l1g  = (const float*)d_in[25];
  const float* l1b  = (const float*)d_in[26];
  const float* f1w  = (const float*)d_in[27];
  const float* f1b  = (const float*)d_in[28];
  const float* f2w  = (const float*)d_in[29];
  const float* f2b  = (const float*)d_in[30];
  const float* l2g  = (const float*)d_in[31];
  const float* l2b  = (const float*)d_in[32];
  const float* rel  = (const float*)d_in[33];

  float* x = (float*)d_out;  // residual stream lives in d_out (fp32)

  // workspace (~134 MB; 151 MB validated in rounds 1-3)
  float* wsf = (float*)d_ws;
  size_t off = 0;
  auto alloc = [&](size_t n){ float* pp = wsf + off; off += (n + 63) & ~(size_t)63; return pp; };
  const size_t XSZ = (size_t)BATCH * SEQ * DMODEL;           // 1,532,928
  float* tmp  = alloc(XSZ);
  float* qb   = alloc(XSZ);
  float* kb   = alloc(XSZ);
  float* vb   = alloc(XSZ);
  float* ctx  = alloc(XSZ);
  float* feat = alloc((size_t)BATCH * SEQ * 512);
  float* c6   = alloc((size_t)512 * SEQ);
  float* gate = alloc((size_t)BATCH * NHEAD * SEQ);
  float* tab  = alloc((size_t)NHEAD * NREL);
  float* attn = alloc((size_t)BATCH * NHEAD * SEQ * SEQ);    // 11.95M floats
  float* ffh  = alloc((size_t)BATCH * SEQ * FFN);            // 6.13M
  // bf16 buffers (allocated in float units, reinterpret)
  bf16* xbf = (bf16*)alloc((XSZ + 1) / 2);
  bf16* cbf = (bf16*)alloc((XSZ + 1) / 2);
  bf16* fbf = (bf16*)alloc(((size_t)BATCH * SEQ * 512 + 1) / 2);
  bf16* hbf = (bf16*)alloc(((size_t)BATCH * SEQ * FFN + 1) / 2);
  bf16* wbf = (bf16*)alloc(((size_t)FFN * DMODEL + 1) / 2);  // max weight 2.36M elems
  // conv ping-pong aliases attn region (disjoint lifetime: conv before layers)
  constexpr size_t CA_SZ = (size_t)512 * (64 * 125 + 15);    // 4.10M
  float* cA = attn;
  float* cB = attn + CA_SZ;

  const int Mrows = BATCH * SEQ; // 1996

  // ---- conv feature extractor: per batch, 4 time-chunks with exact halos ----
  for (int b = 0; b < BATCH; b++){
    for (int c = 0; c < 4; c++){
      int o0 = c * 125, o1 = (o0 + 125 < SEQ) ? o0 + 125 : SEQ;
      int C  = o1 - o0;
      int L[7];
      L[6] = C; L[5] = 2 * C; L[4] = 4 * C; L[3] = 8 * C + 1;
      L[2] = 16 * C + 3; L[1] = 32 * C + 7; L[0] = 64 * C + 15;
      conv0_kernel<<<(512 * L[0] + 255) / 256, 256, 0, stream>>>(
          src + (size_t)b * T_IN + 320 * o0, w0, cA, L[0]);
      ln_gelu_ch_kernel<<<(L[0] + 255) / 256, 256, 0, stream>>>(cA, clng, clnb, L[0]);
      float* bufs[2] = {cA, cB};
      for (int st = 1; st <= 6; st++){
        const float* inb = bufs[(st + 1) & 1];
        float* outb      = (st == 6) ? c6 : bufs[st & 1];
        int Lin = L[st - 1], Lout = L[st];
        int oLd = (st == 6) ? SEQ : Lout;
        int oOf = (st == 6) ? o0 : 0;
        dim3 grd((Lout + 63) / 64, 8);
        if (st <= 4)
          conv_tiled_kernel<3><<<grd, 256, 0, stream>>>(inb, w14 + (size_t)(st - 1) * 512 * 512 * 3, outb, Lin, Lout, oLd, oOf);
        else
          conv_tiled_kernel<2><<<grd, 256, 0, stream>>>(inb, w56 + (size_t)(st - 5) * 512 * 512 * 2, outb, Lin, Lout, oLd, oOf);
        if (st < 6)
          ln_gelu_ch_kernel<<<(Lout + 255) / 256, 256, 0, stream>>>(outb, clng + st * 512, clnb + st * 512, Lout);
      }
    }
    ln_gelu_ch_kernel<<<(SEQ + 255) / 256, 256, 0, stream>>>(c6, clng + 6 * 512, clnb + 6 * 512, SEQ);
    featln_transpose_kernel<<<(SEQ + 255) / 256, 256, 0, stream>>>(c6, flng, flnb, feat + (size_t)b * SEQ * 512);
  }

  auto cast = [&](const float* in, bf16* out, size_t n){
    f2bf_kernel<<<((int)n + 255) / 256, 256, 0, stream>>>(in, out, (int)n);
  };

  // post_extract_proj via MFMA
  cast(feat, fbf, (size_t)Mrows * 512);
  cast(pjw, wbf, (size_t)DMODEL * 512);
  gemm_mfma<0><<<dim3(DMODEL / 64, (Mrows + 63) / 64), 256, 0, stream>>>(fbf, wbf, pjb, x, Mrows, DMODEL, 512, 1.0f);
  posconv_kernel<<<dim3((SEQ + 63) / 64, DMODEL / 4, BATCH), 256, 0, stream>>>(x, pcw, pcb, tmp);
  add_ln_kernel<1><<<Mrows, 256, 0, stream>>>(x, tmp, eng, enb);
  relbias_kernel<<<(NREL * NHEAD + 255) / 256, 256, 0, stream>>>(rel, tab);

  const size_t WQK = (size_t)DMODEL * DMODEL;
  const size_t WF  = (size_t)FFN * DMODEL;
  for (int l = 0; l < NLAYER; l++){
    gate_kernel<<<(BATCH * NHEAD * SEQ + 255) / 256, 256, 0, stream>>>(
        x, gw + (size_t)l * 8 * DHEAD, gbp + l * 8, ga + l * NHEAD, gate);
    cast(x, xbf, XSZ);
    cast(Wq + l * WQK, wbf, WQK);
    gemm_mfma<0><<<dim3(12, 32), 256, 0, stream>>>(xbf, wbf, bq + l * DMODEL, qb, Mrows, DMODEL, DMODEL, 0.125f);
    cast(Wk + l * WQK, wbf, WQK);
    gemm_mfma<0><<<dim3(12, 32), 256, 0, stream>>>(xbf, wbf, bk + l * DMODEL, kb, Mrows, DMODEL, DMODEL, 1.0f);
    cast(Wv + l * WQK, wbf, WQK);
    gemm_mfma<0><<<dim3(12, 32), 256, 0, stream>>>(xbf, wbf, bv + l * DMODEL, vb, Mrows, DMODEL, DMODEL, 1.0f);
    qk_kernel<<<dim3(16, 16, BATCH * NHEAD), 256, 0, stream>>>(qb, kb, attn);
    softmax_bias_kernel<<<BATCH * NHEAD * SEQ, 256, 0, stream>>>(attn, gate, tab);
    pv_kernel<<<dim3(16, BATCH * NHEAD), 256, 0, stream>>>(attn, vb, ctx);
    cast(ctx, cbf, XSZ);
    cast(Wo + l * WQK, wbf, WQK);
    gemm_mfma<0><<<dim3(12, 32), 256, 0, stream>>>(cbf, wbf, bo + l * DMODEL, tmp, Mrows, DMODEL, DMODEL, 1.0f);
    add_ln_kernel<0><<<Mrows, 256, 0, stream>>>(x, tmp, l1g + l * DMODEL, l1b + l * DMODEL);
    cast(x, xbf, XSZ);
    cast(f1w + l * WF, wbf, WF);
    gemm_mfma<1><<<dim3(FFN / 64, 32), 256, 0, stream>>>(xbf, wbf, f1b + l * FFN, ffh, Mrows, FFN, DMODEL, 1.0f);
    cast(ffh, hbf, (size_t)Mrows * FFN);
    cast(f2w + l * WF, wbf, WF);
    gemm_mfma<0><<<dim3(12, 32), 256, 0, stream>>>(hbf, wbf, f2b + l * DMODEL, tmp, Mrows, DMODEL, FFN, 1.0f);
    add_ln_kernel<0><<<Mrows, 256, 0, stream>>>(x, tmp, l2g + l * DMODEL, l2b + l * DMODEL);
  }
  // result is already in d_out
}

// Round 12
// 27011.102 us; speedup vs baseline: 3.3489x; 2.0257x over previous
//
#include <hip/hip_runtime.h>
#include <hip/hip_bf16.h>
#include <math.h>

namespace {

constexpr int BATCH  = 4;
constexpr int T_IN   = 160000;
constexpr int DMODEL = 768;
constexpr int NHEAD  = 12;
constexpr int DHEAD  = 64;
constexpr int FFN    = 3072;
constexpr int NLAYER = 12;
constexpr int SEQ    = 499;
constexpr int NREL   = 2 * SEQ - 1;

typedef __hip_bfloat16 bf16;
using f32x4 = __attribute__((ext_vector_type(4))) float;
using s16x8 = __attribute__((ext_vector_type(8))) short;

__device__ __forceinline__ float gelu_f(float x){
  return 0.5f * x * (1.0f + erff(x * 0.70710678118654752f));
}

__device__ __forceinline__ unsigned f2bf_rne(float f){
  unsigned u = __float_as_uint(f);
  return (u + 0x7FFFu + ((u >> 16) & 1u)) >> 16;
}

__global__ void fill_f32_kernel(float* __restrict__ out, int n, float val){
  int i = blockIdx.x * 256 + threadIdx.x;
  if (i < n) out[i] = val;
}

// ---- conv stage 0: k=10, s=5 ----
__global__ void conv0_kernel(const float* __restrict__ src, const float* __restrict__ w,
                             float* __restrict__ out, int Lout){
  int idx = blockIdx.x * 256 + threadIdx.x;
  if (idx >= 512 * Lout) return;
  int c = idx / Lout, t = idx - c * Lout;
  const float* wr = w + c * 10;
  const float* s  = src + t * 5;
  float acc = 0.f;
#pragma unroll
  for (int k = 0; k < 10; k++) acc += wr[k] * s[k];
  out[idx] = acc;
}

// ---- LayerNorm over channels + GELU, layout (512, Lt), in place ----
__global__ void ln_gelu_ch_kernel(float* __restrict__ x, const float* __restrict__ g,
                                  const float* __restrict__ b, int Lt){
  int t = blockIdx.x * 256 + threadIdx.x;
  if (t >= Lt) return;
  float s = 0.f, sq = 0.f;
  for (int c = 0; c < 512; c++){ float v = x[c * Lt + t]; s += v; sq += v * v; }
  float m = s * (1.f / 512.f);
  float var = sq * (1.f / 512.f) - m * m;
  float rs = rsqrtf(var + 1e-5f);
  for (int c = 0; c < 512; c++){
    float v = (x[c * Lt + t] - m) * rs * g[c] + b[c];
    x[c * Lt + t] = gelu_f(v);
  }
}

// ---- TILED conv stages 1..6: 512->512, kernel KW, stride 2, full length ----
template<int KW>
__global__ void conv_tiled_kernel(const float* __restrict__ in, const float* __restrict__ w,
                                  float* __restrict__ out, int Lin, int Lout, int outLd){
  constexpr int ISPAN = 128 + KW;
  __shared__ float ins[8][ISPAN];
  __shared__ float wgt[8][KW][64];
  const int t0 = blockIdx.x * 64, co0 = blockIdx.y * 64;
  const int tid = threadIdx.x;
  const int tx = tid & 15, ty = tid >> 4;
  float acc[4][4] = {};
  for (int ci0 = 0; ci0 < 512; ci0 += 8){
    for (int idx = tid; idx < 8 * ISPAN; idx += 256){
      int ci = idx / ISPAN, j = idx - ci * ISPAN;
      int gp = t0 * 2 + j;
      ins[ci][j] = (gp < Lin) ? in[(size_t)(ci0 + ci) * Lin + gp] : 0.f;
    }
    for (int idx = tid; idx < 64 * 8 * KW; idx += 256){
      int co = idx / (8 * KW), r = idx - co * (8 * KW);
      int ci = r / KW, k = r - ci * KW;
      wgt[ci][k][co] = w[(size_t)(co0 + co) * (512 * KW) + (ci0 + ci) * KW + k];
    }
    __syncthreads();
#pragma unroll
    for (int ci = 0; ci < 8; ci++){
#pragma unroll
      for (int k = 0; k < KW; k++){
        float4 wv = *reinterpret_cast<const float4*>(&wgt[ci][k][ty * 4]);
        float wa[4] = {wv.x, wv.y, wv.z, wv.w};
        float iv[4];
#pragma unroll
        for (int j = 0; j < 4; j++) iv[j] = ins[ci][(tx * 4 + j) * 2 + k];
#pragma unroll
        for (int ii = 0; ii < 4; ii++)
#pragma unroll
          for (int jj = 0; jj < 4; jj++) acc[ii][jj] += wa[ii] * iv[jj];
      }
    }
    __syncthreads();
  }
#pragma unroll
  for (int ii = 0; ii < 4; ii++){
    int co = co0 + ty * 4 + ii;
#pragma unroll
    for (int jj = 0; jj < 4; jj++){
      int t = t0 + tx * 4 + jj;
      if (t < Lout) out[(size_t)co * outLd + t] = acc[ii][jj];
    }
  }
}

// ---- final feature LN + transpose (512,S)->(S,512) ----
__global__ void featln_transpose_kernel(const float* __restrict__ xin,
                                        const float* __restrict__ g, const float* __restrict__ b,
                                        float* __restrict__ feat){
  int t = blockIdx.x * 256 + threadIdx.x;
  if (t >= SEQ) return;
  float s = 0.f, sq = 0.f;
  for (int c = 0; c < 512; c++){ float v = xin[c * SEQ + t]; s += v; sq += v * v; }
  float m = s * (1.f / 512.f), var = sq * (1.f / 512.f) - m * m, rs = rsqrtf(var + 1e-5f);
  for (int c = 0; c < 512; c++)
    feat[t * 512 + c] = (xin[c * SEQ + t] - m) * rs * g[c] + b[c];
}

// ---- MFMA GEMM, fp32 inputs (bf16 cast fused in staging) ----
// C(M,N) = act(alpha*(A(M,K) @ W(N,K)^T + bias)); K%32==0, N%64==0, M guarded.
// 64x64 block, 4 waves 2x2, wave=32x32 via 2x2 mfma_f32_16x16x32_bf16.
template<int ACT>
__global__ void gemm_mfma_f32(const float* __restrict__ A, const float* __restrict__ W,
                              const float* __restrict__ bias, float* __restrict__ C,
                              int M, int N, int K, float alpha){
  __shared__ bf16 As[64][40];
  __shared__ bf16 Ws[64][40];
  const int tid = threadIdx.x;
  const int wid = tid >> 6, lane = tid & 63;
  const int m0 = blockIdx.y * 64, n0 = blockIdx.x * 64;
  const int wm = (wid >> 1) * 32, wn = (wid & 1) * 32;
  const int lrow = tid >> 2;
  const int lk   = (tid & 3) * 8;
  const int fr = lane & 15, fk = (lane >> 4) * 8;
  f32x4 acc[2][2] = {};
  for (int k0 = 0; k0 < K; k0 += 32){
    float4 a0 = make_float4(0.f,0.f,0.f,0.f), a1 = make_float4(0.f,0.f,0.f,0.f);
    int gm = m0 + lrow;
    if (gm < M){
      const float* ap = &A[(size_t)gm * K + k0 + lk];
      a0 = *reinterpret_cast<const float4*>(ap);
      a1 = *reinterpret_cast<const float4*>(ap + 4);
    }
    uint4 pa;
    pa.x = f2bf_rne(a0.x) | (f2bf_rne(a0.y) << 16);
    pa.y = f2bf_rne(a0.z) | (f2bf_rne(a0.w) << 16);
    pa.z = f2bf_rne(a1.x) | (f2bf_rne(a1.y) << 16);
    pa.w = f2bf_rne(a1.z) | (f2bf_rne(a1.w) << 16);
    *reinterpret_cast<uint4*>(&As[lrow][lk]) = pa;
    const float* wp = &W[(size_t)(n0 + lrow) * K + k0 + lk];
    float4 w0 = *reinterpret_cast<const float4*>(wp);
    float4 w1 = *reinterpret_cast<const float4*>(wp + 4);
    uint4 pw;
    pw.x = f2bf_rne(w0.x) | (f2bf_rne(w0.y) << 16);
    pw.y = f2bf_rne(w0.z) | (f2bf_rne(w0.w) << 16);
    pw.z = f2bf_rne(w1.x) | (f2bf_rne(w1.y) << 16);
    pw.w = f2bf_rne(w1.z) | (f2bf_rne(w1.w) << 16);
    *reinterpret_cast<uint4*>(&Ws[lrow][lk]) = pw;
    __syncthreads();
    s16x8 av0 = *reinterpret_cast<const s16x8*>(&As[wm + fr][fk]);
    s16x8 av1 = *reinterpret_cast<const s16x8*>(&As[wm + 16 + fr][fk]);
    s16x8 bv0 = *reinterpret_cast<const s16x8*>(&Ws[wn + fr][fk]);
    s16x8 bv1 = *reinterpret_cast<const s16x8*>(&Ws[wn + 16 + fr][fk]);
    acc[0][0] = __builtin_amdgcn_mfma_f32_16x16x32_bf16(av0, bv0, acc[0][0], 0, 0, 0);
    acc[0][1] = __builtin_amdgcn_mfma_f32_16x16x32_bf16(av0, bv1, acc[0][1], 0, 0, 0);
    acc[1][0] = __builtin_amdgcn_mfma_f32_16x16x32_bf16(av1, bv0, acc[1][0], 0, 0, 0);
    acc[1][1] = __builtin_amdgcn_mfma_f32_16x16x32_bf16(av1, bv1, acc[1][1], 0, 0, 0);
    __syncthreads();
  }
  const int cc = lane & 15, cr = (lane >> 4) * 4;
#pragma unroll
  for (int mi = 0; mi < 2; mi++){
#pragma unroll
    for (int ni = 0; ni < 2; ni++){
      int n = n0 + wn + ni * 16 + cc;
      float bn = bias[n];
#pragma unroll
      for (int r = 0; r < 4; r++){
        int m = m0 + wm + mi * 16 + cr + r;
        if (m < M){
          float v = alpha * (acc[mi][ni][r] + bn);
          if (ACT == 1) v = gelu_f(v);
          C[(size_t)m * N + n] = v;
        }
      }
    }
  }
}

// ---- fused QKV: blockIdx.z selects {Wq->qb(*0.125), Wk->kb, Wv->vb}; M,K=N=768 ----
__global__ void gemm_qkv_mfma(const float* __restrict__ A,
                              const float* __restrict__ Wq, const float* __restrict__ Wk,
                              const float* __restrict__ Wv,
                              const float* __restrict__ bq, const float* __restrict__ bk,
                              const float* __restrict__ bv,
                              float* __restrict__ qb, float* __restrict__ kb,
                              float* __restrict__ vb, int M){
  const int z = blockIdx.z;
  const float* W   = (z == 0) ? Wq : (z == 1) ? Wk : Wv;
  const float* bia = (z == 0) ? bq : (z == 1) ? bk : bv;
  float* C         = (z == 0) ? qb : (z == 1) ? kb : vb;
  const float alpha = (z == 0) ? 0.125f : 1.0f;
  const int K = DMODEL, N = DMODEL;
  __shared__ bf16 As[64][40];
  __shared__ bf16 Ws[64][40];
  const int tid = threadIdx.x;
  const int wid = tid >> 6, lane = tid & 63;
  const int m0 = blockIdx.y * 64, n0 = blockIdx.x * 64;
  const int wm = (wid >> 1) * 32, wn = (wid & 1) * 32;
  const int lrow = tid >> 2;
  const int lk   = (tid & 3) * 8;
  const int fr = lane & 15, fk = (lane >> 4) * 8;
  f32x4 acc[2][2] = {};
  for (int k0 = 0; k0 < K; k0 += 32){
    float4 a0 = make_float4(0.f,0.f,0.f,0.f), a1 = make_float4(0.f,0.f,0.f,0.f);
    int gm = m0 + lrow;
    if (gm < M){
      const float* ap = &A[(size_t)gm * K + k0 + lk];
      a0 = *reinterpret_cast<const float4*>(ap);
      a1 = *reinterpret_cast<const float4*>(ap + 4);
    }
    uint4 pa;
    pa.x = f2bf_rne(a0.x) | (f2bf_rne(a0.y) << 16);
    pa.y = f2bf_rne(a0.z) | (f2bf_rne(a0.w) << 16);
    pa.z = f2bf_rne(a1.x) | (f2bf_rne(a1.y) << 16);
    pa.w = f2bf_rne(a1.z) | (f2bf_rne(a1.w) << 16);
    *reinterpret_cast<uint4*>(&As[lrow][lk]) = pa;
    const float* wp = &W[(size_t)(n0 + lrow) * K + k0 + lk];
    float4 w0 = *reinterpret_cast<const float4*>(wp);
    float4 w1 = *reinterpret_cast<const float4*>(wp + 4);
    uint4 pw;
    pw.x = f2bf_rne(w0.x) | (f2bf_rne(w0.y) << 16);
    pw.y = f2bf_rne(w0.z) | (f2bf_rne(w0.w) << 16);
    pw.z = f2bf_rne(w1.x) | (f2bf_rne(w1.y) << 16);
    pw.w = f2bf_rne(w1.z) | (f2bf_rne(w1.w) << 16);
    *reinterpret_cast<uint4*>(&Ws[lrow][lk]) = pw;
    __syncthreads();
    s16x8 av0 = *reinterpret_cast<const s16x8*>(&As[wm + fr][fk]);
    s16x8 av1 = *reinterpret_cast<const s16x8*>(&As[wm + 16 + fr][fk]);
    s16x8 bv0 = *reinterpret_cast<const s16x8*>(&Ws[wn + fr][fk]);
    s16x8 bv1 = *reinterpret_cast<const s16x8*>(&Ws[wn + 16 + fr][fk]);
    acc[0][0] = __builtin_amdgcn_mfma_f32_16x16x32_bf16(av0, bv0, acc[0][0], 0, 0, 0);
    acc[0][1] = __builtin_amdgcn_mfma_f32_16x16x32_bf16(av0, bv1, acc[0][1], 0, 0, 0);
    acc[1][0] = __builtin_amdgcn_mfma_f32_16x16x32_bf16(av1, bv0, acc[1][0], 0, 0, 0);
    acc[1][1] = __builtin_amdgcn_mfma_f32_16x16x32_bf16(av1, bv1, acc[1][1], 0, 0, 0);
    __syncthreads();
  }
  const int cc = lane & 15, cr = (lane >> 4) * 4;
#pragma unroll
  for (int mi = 0; mi < 2; mi++){
#pragma unroll
    for (int ni = 0; ni < 2; ni++){
      int n = n0 + wn + ni * 16 + cc;
      float bn = bia[n];
#pragma unroll
      for (int r = 0; r < 4; r++){
        int m = m0 + wm + mi * 16 + cr + r;
        if (m < M){
          C[(size_t)m * N + n] = alpha * (acc[mi][ni][r] + bn);
        }
      }
    }
  }
}

// ---- tiled positional grouped conv: k=128, pad 64, groups 16 ----
__global__ void posconv_kernel(const float* __restrict__ x, const float* __restrict__ w,
                               const float* __restrict__ bias, float* __restrict__ xc){
  const int b = blockIdx.z;
  const int t0 = blockIdx.x * 64;
  const int co_base = blockIdx.y * 4;
  const int g = co_base / 48;
  const int tid = threadIdx.x, lane = tid & 63, wid = tid >> 6;
  const int co = co_base + wid;
  __shared__ float xin[48][193];
  for (int idx = tid; idx < 48 * 191; idx += 256){
    int jj = idx / 48, ci = idx - jj * 48;
    int p = t0 - 64 + jj;
    xin[ci][jj] = (p >= 0 && p < SEQ) ? x[((size_t)(b * SEQ + p)) * DMODEL + g * 48 + ci] : 0.f;
  }
  __syncthreads();
  const float* wr = w + (size_t)co * 48 * 128;
  float acc = bias[co];
  for (int ci = 0; ci < 48; ci++){
    const float* wc = wr + ci * 128;
    const float* xr = &xin[ci][lane];
#pragma unroll
    for (int k = 0; k < 128; k += 4){
      float4 w4 = *reinterpret_cast<const float4*>(&wc[k]);
      acc += w4.x * xr[k] + w4.y * xr[k + 1] + w4.z * xr[k + 2] + w4.w * xr[k + 3];
    }
  }
  int t = t0 + lane;
  if (t < SEQ) xc[((size_t)(b * SEQ + t)) * DMODEL + co] = acc;
}

// ---- residual add (+optional GELU) + row LayerNorm over DMODEL ----
template<int GELU_ADD>
__global__ void add_ln_kernel(float* __restrict__ x, const float* __restrict__ add,
                              const float* __restrict__ g, const float* __restrict__ b){
  int row = blockIdx.x;
  float* xr = x + (size_t)row * DMODEL;
  const float* ar = add + (size_t)row * DMODEL;
  __shared__ float buf[DMODEL];
  __shared__ float red[256];
  int tid = threadIdx.x;
  float s = 0.f;
  for (int i = tid; i < DMODEL; i += 256){
    float v = ar[i];
    if (GELU_ADD) v = gelu_f(v);
    v += xr[i];
    buf[i] = v; s += v;
  }
  red[tid] = s; __syncthreads();
  for (int st = 128; st > 0; st >>= 1){ if (tid < st) red[tid] += red[tid + st]; __syncthreads(); }
  float m = red[0] * (1.f / DMODEL); __syncthreads();
  float sq = 0.f;
  for (int i = tid; i < DMODEL; i += 256){ float d = buf[i] - m; sq += d * d; }
  red[tid] = sq; __syncthreads();
  for (int st = 128; st > 0; st >>= 1){ if (tid < st) red[tid] += red[tid + st]; __syncthreads(); }
  float rs = rsqrtf(red[0] * (1.f / DMODEL) + 1e-5f);
  for (int i = tid; i < DMODEL; i += 256) xr[i] = (buf[i] - m) * rs * g[i] + b[i];
}

// ---- T5-style relative position bias table ----
__global__ void relbias_kernel(const float* __restrict__ rel_emb, float* __restrict__ tab){
  int idx = blockIdx.x * 256 + threadIdx.x;
  if (idx >= NREL * NHEAD) return;
  int rr = idx / NHEAD, h = idx - rr * NHEAD;
  int rel = rr - (SEQ - 1);
  int bkt = (rel > 0) ? 160 : 0;
  int n = (rel < 0) ? -rel : rel;
  if (n < 80) bkt += n;
  else {
    int large = 80 + (int)(logf((float)n / 80.f) / logf(10.f) * 80.f);
    bkt += (large < 159) ? large : 159;
  }
  tab[h * NREL + rr] = rel_emb[bkt * NHEAD + h];
}

// ---- gated rel-pos gate values; sigmoid AFTER 4-logit sums ----
__global__ void gate_kernel(const float* __restrict__ x, const float* __restrict__ gwl,
                            const float* __restrict__ gbl, const float* __restrict__ gal,
                            float* __restrict__ gate){
  int idx = blockIdx.x * 256 + threadIdx.x;
  if (idx >= BATCH * NHEAD * SEQ) return;
  int s = idx % SEQ; int bh = idx / SEQ; int h = bh % NHEAD; int b = bh / NHEAD;
  const float* xv = x + ((size_t)(b * SEQ + s)) * DMODEL + h * DHEAD;
  float a0 = 0.f, a1 = 0.f;
#pragma unroll
  for (int gg = 0; gg < 8; gg++){
    float a = gbl[gg];
    const float* wrow = gwl + gg * DHEAD;
#pragma unroll
    for (int d = 0; d < DHEAD; d++) a += xv[d] * wrow[d];
    if (gg < 4) a0 += a; else a1 += a;
  }
  float g0 = 1.f / (1.f + expf(-a0));
  float g1 = 1.f / (1.f + expf(-a1));
  gate[idx] = g0 * (g1 * gal[h] - 1.f) + 2.f;
}

// ---- all-batch TILED Q@K^T ----
__global__ void qk_kernel(const float* __restrict__ q, const float* __restrict__ k,
                          float* __restrict__ sc){
  int bh = blockIdx.z; int b = bh / NHEAD, h = bh % NHEAD;
  int i0 = blockIdx.y * 32, j0 = blockIdx.x * 32;
  __shared__ float qs[32][68], ks[32][68];
  int tid = threadIdx.x;
  for (int idx = tid; idx < 2048; idx += 256){
    int r = idx >> 6, c = idx & 63;
    int i = i0 + r;
    qs[r][c] = (i < SEQ) ? q[((size_t)(b * SEQ + i)) * DMODEL + h * DHEAD + c] : 0.f;
    int j = j0 + r;
    ks[r][c] = (j < SEQ) ? k[((size_t)(b * SEQ + j)) * DMODEL + h * DHEAD + c] : 0.f;
  }
  __syncthreads();
  int tx = tid & 31, ty = tid >> 5;
  float acc[4] = {};
  for (int kk = 0; kk < 64; kk += 4){
    float4 kv = *reinterpret_cast<const float4*>(&ks[tx][kk]);
#pragma unroll
    for (int ii = 0; ii < 4; ii++){
      float4 qv = *reinterpret_cast<const float4*>(&qs[ty * 4 + ii][kk]);
      acc[ii] += qv.x * kv.x + qv.y * kv.y + qv.z * kv.z + qv.w * kv.w;
    }
  }
#pragma unroll
  for (int ii = 0; ii < 4; ii++){
    int i = i0 + ty * 4 + ii, j = j0 + tx;
    if (i < SEQ && j < SEQ) sc[((size_t)bh * SEQ + i) * SEQ + j] = acc[ii];
  }
}

// ---- softmax with fused gate*relbias add, in place ----
__global__ void softmax_bias_kernel(float* __restrict__ sc, const float* __restrict__ gate,
                                    const float* __restrict__ tab){
  int row = blockIdx.x;
  int bh = row / SEQ, i = row - bh * SEQ;
  int h = bh % NHEAD;
  float gt = gate[row];
  float* p = sc + (size_t)row * SEQ;
  const float* tb = tab + (size_t)h * NREL + (SEQ - 1 - i);
  __shared__ float buf[512];
  __shared__ float red[256];
  int tid = threadIdx.x;
  float mx = -1e30f;
  for (int j = tid; j < SEQ; j += 256){
    float v = p[j] + gt * tb[j];
    buf[j] = v; mx = fmaxf(mx, v);
  }
  red[tid] = mx; __syncthreads();
  for (int st = 128; st > 0; st >>= 1){ if (tid < st) red[tid] = fmaxf(red[tid], red[tid + st]); __syncthreads(); }
  mx = red[0]; __syncthreads();
  float sum = 0.f;
  for (int j = tid; j < SEQ; j += 256){ float e = expf(buf[j] - mx); buf[j] = e; sum += e; }
  red[tid] = sum; __syncthreads();
  for (int st = 128; st > 0; st >>= 1){ if (tid < st) red[tid] += red[tid + st]; __syncthreads(); }
  float inv = 1.0f / red[0];
  for (int j = tid; j < SEQ; j += 256) p[j] = buf[j] * inv;
}

// ---- all-batch TILED P @ V ----
__global__ void pv_kernel(const float* __restrict__ p, const float* __restrict__ v,
                          float* __restrict__ ctx){
  int bh = blockIdx.y, b = bh / NHEAD, h = bh % NHEAD;
  int i0 = blockIdx.x * 32;
  __shared__ float ps[32][33];
  __shared__ float vs[32][64];
  int tid = threadIdx.x, tx = tid & 63, ty = tid >> 6;
  float acc[8] = {};
  for (int j0 = 0; j0 < SEQ; j0 += 32){
    for (int idx = tid; idx < 1024; idx += 256){
      int r = idx >> 5, c = idx & 31;
      int i = i0 + r, j = j0 + c;
      ps[r][c] = (i < SEQ && j < SEQ) ? p[((size_t)bh * SEQ + i) * SEQ + j] : 0.f;
    }
    for (int idx = tid; idx < 2048; idx += 256){
      int r = idx >> 6, c = idx & 63;
      int j = j0 + r;
      vs[r][c] = (j < SEQ) ? v[((size_t)(b * SEQ + j)) * DMODEL + h * DHEAD + c] : 0.f;
    }
    __syncthreads();
#pragma unroll
    for (int jj = 0; jj < 32; jj++){
      float vv = vs[jj][tx];
#pragma unroll
      for (int ii = 0; ii < 8; ii++) acc[ii] += ps[ty * 8 + ii][jj] * vv;
    }
    __syncthreads();
  }
#pragma unroll
  for (int ii = 0; ii < 8; ii++){
    int i = i0 + ty * 8 + ii;
    if (i < SEQ) ctx[((size_t)(b * SEQ + i)) * DMODEL + h * DHEAD + tx] = acc[ii];
  }
}

} // anonymous namespace

extern "C" void kernel_launch(void* const* d_in, const int* in_sizes, int n_in,
                              void* d_out, int out_size, void* d_ws, size_t ws_size,
                              hipStream_t stream){
  (void)ws_size;

  static const int DS[34] = {640000,5120,3145728,1048576,3584,3584,512,512,393216,768,
                             4718592,768,768,768,7077888,9216,7077888,9216,7077888,9216,
                             7077888,9216,6144,96,144,9216,9216,28311552,36864,28311552,
                             9216,9216,9216,3840};
  bool ok = (n_in == 34) && (out_size == BATCH * SEQ * DMODEL);
  if (ok) for (int i = 0; i < 34; i++) if (in_sizes[i] != DS[i]) { ok = false; break; }
  if (!ok){
    fill_f32_kernel<<<(out_size + 255) / 256, 256, 0, stream>>>((float*)d_out, out_size, 1000.0f);
    return;
  }

  const float* src  = (const float*)d_in[0];
  const float* w0   = (const float*)d_in[1];
  const float* w14  = (const float*)d_in[2];
  const float* w56  = (const float*)d_in[3];
  const float* clng = (const float*)d_in[4];
  const float* clnb = (const float*)d_in[5];
  const float* flng = (const float*)d_in[6];
  const float* flnb = (const float*)d_in[7];
  const float* pjw  = (const float*)d_in[8];
  const float* pjb  = (const float*)d_in[9];
  const float* pcw  = (const float*)d_in[10];
  const float* pcb  = (const float*)d_in[11];
  const float* eng  = (const float*)d_in[12];
  const float* enb  = (const float*)d_in[13];
  const float* Wq   = (const float*)d_in[14];
  const float* bq   = (const float*)d_in[15];
  const float* Wk   = (const float*)d_in[16];
  const float* bk   = (const float*)d_in[17];
  const float* Wv   = (const float*)d_in[18];
  const float* bv   = (const float*)d_in[19];
  const float* Wo   = (const float*)d_in[20];
  const float* bo   = (const float*)d_in[21];
  const float* gw   = (const float*)d_in[22];
  const float* gbp  = (const float*)d_in[23];
  const float* ga   = (const float*)d_in[24];
  const float* l1g  = (const float*)d_in[25];
  const float* l1b  = (const float*)d_in[26];
  const float* f1w  = (const float*)d_in[27];
  const float* f1b  = (const float*)d_in[28];
  const float* f2w  = (const float*)d_in[29];
  const float* f2b  = (const float*)d_in[30];
  const float* l2g  = (const float*)d_in[31];
  const float* l2b  = (const float*)d_in[32];
  const float* rel  = (const float*)d_in[33];

  float* x = (float*)d_out;  // residual stream lives in d_out (fp32)

  // workspace (~108 MB). Conv buffers alias the layer-phase region.
  float* wsf = (float*)d_ws;
  size_t off = 0;
  auto alloc = [&](size_t n){ float* pp = wsf + off; off += (n + 63) & ~(size_t)63; return pp; };
  const size_t XSZ = (size_t)BATCH * SEQ * DMODEL;
  float* attn = alloc((size_t)BATCH * NHEAD * SEQ * SEQ);   // 11.95M
  float* ffh  = alloc((size_t)BATCH * SEQ * FFN);           // 6.13M
  float* tmp  = alloc(XSZ);
  float* qb   = alloc(XSZ);
  float* kb   = alloc(XSZ);
  float* vb   = alloc(XSZ);
  float* ctx  = alloc(XSZ);
  float* feat = alloc((size_t)BATCH * SEQ * 512);
  float* c6   = alloc((size_t)512 * SEQ);
  float* gate = alloc((size_t)BATCH * NHEAD * SEQ);
  float* tab  = alloc((size_t)NHEAD * NREL);
  // conv ping-pong: full-length, aliases [attn .. ctx] (dead during conv phase)
  float* cA = attn;                          // needs 512*31999 = 16,383,488
  float* cB = attn + (size_t)16383488;       // needs 512*15999 =  8,191,488 (ends 24.57M < 25.7M span)

  const int Ls[8] = {160000, 31999, 15999, 7999, 3999, 1999, 999, 499};
  const int Mrows = BATCH * SEQ; // 1996

  // ---- conv feature extractor: per batch, full length (no chunking) ----
  for (int b = 0; b < BATCH; b++){
    conv0_kernel<<<(512 * Ls[1] + 255) / 256, 256, 0, stream>>>(src + (size_t)b * T_IN, w0, cA, Ls[1]);
    ln_gelu_ch_kernel<<<(Ls[1] + 255) / 256, 256, 0, stream>>>(cA, clng, clnb, Ls[1]);
    float* bufs[2] = {cA, cB};
    for (int st = 1; st <= 6; st++){
      const float* inb = bufs[(st + 1) & 1];
      float* outb      = (st == 6) ? c6 : bufs[st & 1];
      int Lin = Ls[st], Lout = Ls[st + 1];
      int oLd = (st == 6) ? SEQ : Lout;
      dim3 grd((Lout + 63) / 64, 8);
      if (st <= 4)
        conv_tiled_kernel<3><<<grd, 256, 0, stream>>>(inb, w14 + (size_t)(st - 1) * 512 * 512 * 3, outb, Lin, Lout, oLd);
      else
        conv_tiled_kernel<2><<<grd, 256, 0, stream>>>(inb, w56 + (size_t)(st - 5) * 512 * 512 * 2, outb, Lin, Lout, oLd);
      if (st < 6)
        ln_gelu_ch_kernel<<<(Lout + 255) / 256, 256, 0, stream>>>(outb, clng + st * 512, clnb + st * 512, Lout);
    }
    ln_gelu_ch_kernel<<<(SEQ + 255) / 256, 256, 0, stream>>>(c6, clng + 6 * 512, clnb + 6 * 512, SEQ);
    featln_transpose_kernel<<<(SEQ + 255) / 256, 256, 0, stream>>>(c6, flng, flnb, feat + (size_t)b * SEQ * 512);
  }

  // post_extract_proj (MFMA, fused cast)
  gemm_mfma_f32<0><<<dim3(DMODEL / 64, (Mrows + 63) / 64), 256, 0, stream>>>(feat, pjw, pjb, x, Mrows, DMODEL, 512, 1.0f);
  posconv_kernel<<<dim3((SEQ + 63) / 64, DMODEL / 4, BATCH), 256, 0, stream>>>(x, pcw, pcb, tmp);
  add_ln_kernel<1><<<Mrows, 256, 0, stream>>>(x, tmp, eng, enb);
  relbias_kernel<<<(NREL * NHEAD + 255) / 256, 256, 0, stream>>>(rel, tab);

  const size_t WQK = (size_t)DMODEL * DMODEL;
  const size_t WF  = (size_t)FFN * DMODEL;
  for (int l = 0; l < NLAYER; l++){
    gate_kernel<<<(BATCH * NHEAD * SEQ + 255) / 256, 256, 0, stream>>>(
        x, gw + (size_t)l * 8 * DHEAD, gbp + l * 8, ga + l * NHEAD, gate);
    gemm_qkv_mfma<<<dim3(12, 32, 3), 256, 0, stream>>>(
        x, Wq + l * WQK, Wk + l * WQK, Wv + l * WQK,
        bq + l * DMODEL, bk + l * DMODEL, bv + l * DMODEL, qb, kb, vb, Mrows);
    qk_kernel<<<dim3(16, 16, BATCH * NHEAD), 256, 0, stream>>>(qb, kb, attn);
    softmax_bias_kernel<<<BATCH * NHEAD * SEQ, 256, 0, stream>>>(attn, gate, tab);
    pv_kernel<<<dim3(16, BATCH * NHEAD), 256, 0, stream>>>(attn, vb, ctx);
    gemm_mfma_f32<0><<<dim3(12, 32), 256, 0, stream>>>(ctx, Wo + l * WQK, bo + l * DMODEL, tmp, Mrows, DMODEL, DMODEL, 1.0f);
    add_ln_kernel<0><<<Mrows, 256, 0, stream>>>(x, tmp, l1g + l * DMODEL, l1b + l * DMODEL);
    gemm_mfma_f32<1><<<dim3(FFN / 64, 32), 256, 0, stream>>>(x, f1w + l * WF, f1b + l * FFN, ffh, Mrows, FFN, DMODEL, 1.0f);
    gemm_mfma_f32<0><<<dim3(12, 32), 256, 0, stream>>>(ffh, f2w + l * WF, f2b + l * DMODEL, tmp, Mrows, DMODEL, FFN, 1.0f);
    add_ln_kernel<0><<<Mrows, 256, 0, stream>>>(x, tmp, l2g + l * DMODEL, l2b + l * DMODEL);
  }
  // result is already in d_out
}

// Round 13
// 12204.525 us; speedup vs baseline: 7.4117x; 2.2132x over previous
//
#include <hip/hip_runtime.h>
#include <hip/hip_bf16.h>
#include <math.h>

namespace {

constexpr int BATCH  = 4;
constexpr int T_IN   = 160000;
constexpr int DMODEL = 768;
constexpr int NHEAD  = 12;
constexpr int DHEAD  = 64;
constexpr int FFN    = 3072;
constexpr int NLAYER = 12;
constexpr int SEQ    = 499;
constexpr int SP     = 512;            // padded attention row stride
constexpr int NREL   = 2 * SEQ - 1;

typedef __hip_bfloat16 bf16;
using f32x4 = __attribute__((ext_vector_type(4))) float;
using s16x8 = __attribute__((ext_vector_type(8))) short;

__device__ __forceinline__ float gelu_f(float x){
  return 0.5f * x * (1.0f + erff(x * 0.70710678118654752f));
}

__device__ __forceinline__ unsigned f2bf_rne(float f){
  unsigned u = __float_as_uint(f);
  return (u + 0x7FFFu + ((u >> 16) & 1u)) >> 16;
}

__global__ void fill_f32_kernel(float* __restrict__ out, int n, float val){
  int i = blockIdx.x * 256 + threadIdx.x;
  if (i < n) out[i] = val;
}

__global__ void f2bf_kernel(const float* __restrict__ in, bf16* __restrict__ out, int n){
  int i = blockIdx.x * 256 + threadIdx.x;
  if (i < n) out[i] = __float2bfloat16(in[i]);
}

// ---- conv stage 0: k=10, s=5 ----
__global__ void conv0_kernel(const float* __restrict__ src, const float* __restrict__ w,
                             float* __restrict__ out, int Lout){
  int idx = blockIdx.x * 256 + threadIdx.x;
  if (idx >= 512 * Lout) return;
  int c = idx / Lout, t = idx - c * Lout;
  const float* wr = w + c * 10;
  const float* s  = src + t * 5;
  float acc = 0.f;
#pragma unroll
  for (int k = 0; k < 10; k++) acc += wr[k] * s[k];
  out[idx] = acc;
}

// ---- LayerNorm over channels + GELU, layout (512, Lt), in place ----
__global__ void ln_gelu_ch_kernel(float* __restrict__ x, const float* __restrict__ g,
                                  const float* __restrict__ b, int Lt){
  int t = blockIdx.x * 256 + threadIdx.x;
  if (t >= Lt) return;
  float s = 0.f, sq = 0.f;
  for (int c = 0; c < 512; c++){ float v = x[c * Lt + t]; s += v; sq += v * v; }
  float m = s * (1.f / 512.f);
  float var = sq * (1.f / 512.f) - m * m;
  float rs = rsqrtf(var + 1e-5f);
  for (int c = 0; c < 512; c++){
    float v = (x[c * Lt + t] - m) * rs * g[c] + b[c];
    x[c * Lt + t] = gelu_f(v);
  }
}

// ---- pad conv weights: w[co][ci][KW] fp32 -> wpad[co][ci*4+k] bf16 (k>=KW -> 0) ----
template<int KW>
__global__ void convw_pad_kernel(const float* __restrict__ w, bf16* __restrict__ wpad){
  int idx = blockIdx.x * 256 + threadIdx.x;        // over 512*512*4
  if (idx >= 512 * 512 * 4) return;
  int k = idx & 3, ci = (idx >> 2) & 511, co = idx >> 11;
  float v = (k < KW) ? w[((size_t)co * 512 + ci) * KW + k] : 0.f;
  wpad[idx] = __float2bfloat16(v);
}

// ---- conv stages 1..6 via MFMA: C[co][t] = sum w*in, K = ci*4+k (padded) ----
// block 64co x 64t, 4 waves 2x2 (wave 32x32), mfma_f32_16x16x32_bf16
template<int KW>
__global__ void conv_mfma_kernel(const float* __restrict__ in, const bf16* __restrict__ wpad,
                                 float* __restrict__ out, int Lin, int Lout, int outLd){
  constexpr int SPAN = 128 + KW;
  __shared__ bf16 As[64][40];
  __shared__ float ins[8][136];
  const int tid = threadIdx.x, wid = tid >> 6, lane = tid & 63;
  const int t0 = blockIdx.x * 64, co0 = blockIdx.y * 64;
  const int wm = (wid >> 1) * 32, wn = (wid & 1) * 32;   // wm: co, wn: t
  const int lrow = tid >> 2, lk = (tid & 3) * 8;
  const int fr = lane & 15, fk = (lane >> 4) * 8;
  f32x4 acc[2][2] = {};
  for (int ci0 = 0; ci0 < 512; ci0 += 8){
    *reinterpret_cast<uint4*>(&As[lrow][lk]) =
        *reinterpret_cast<const uint4*>(&wpad[(size_t)(co0 + lrow) * 2048 + ci0 * 4 + lk]);
    for (int idx = tid; idx < 8 * SPAN; idx += 256){
      int ci = idx / SPAN, j = idx - ci * SPAN;
      int gp = t0 * 2 + j;
      ins[ci][j] = (gp < Lin) ? in[(size_t)(ci0 + ci) * Lin + gp] : 0.f;
    }
    __syncthreads();
    const int cia = fk >> 2;   // two ci per fragment: cia, cia+1
    auto bfrag = [&](int tr)->s16x8 {
      float2 pa0 = *reinterpret_cast<const float2*>(&ins[cia][2 * tr]);
      float2 pb0 = *reinterpret_cast<const float2*>(&ins[cia + 1][2 * tr]);
      s16x8 r;
      r[0] = (short)f2bf_rne(pa0.x);
      r[1] = (short)f2bf_rne(pa0.y);
      r[2] = (KW > 2) ? (short)f2bf_rne(ins[cia][2 * tr + 2]) : (short)0;
      r[3] = 0;
      r[4] = (short)f2bf_rne(pb0.x);
      r[5] = (short)f2bf_rne(pb0.y);
      r[6] = (KW > 2) ? (short)f2bf_rne(ins[cia + 1][2 * tr + 2]) : (short)0;
      r[7] = 0;
      return r;
    };
    s16x8 a0 = *reinterpret_cast<const s16x8*>(&As[wm + fr][fk]);
    s16x8 a1 = *reinterpret_cast<const s16x8*>(&As[wm + 16 + fr][fk]);
    s16x8 b0 = bfrag(wn + fr);
    s16x8 b1 = bfrag(wn + 16 + fr);
    acc[0][0] = __builtin_amdgcn_mfma_f32_16x16x32_bf16(a0, b0, acc[0][0], 0, 0, 0);
    acc[0][1] = __builtin_amdgcn_mfma_f32_16x16x32_bf16(a0, b1, acc[0][1], 0, 0, 0);
    acc[1][0] = __builtin_amdgcn_mfma_f32_16x16x32_bf16(a1, b0, acc[1][0], 0, 0, 0);
    acc[1][1] = __builtin_amdgcn_mfma_f32_16x16x32_bf16(a1, b1, acc[1][1], 0, 0, 0);
    __syncthreads();
  }
  const int cc = lane & 15, cr = (lane >> 4) * 4;
#pragma unroll
  for (int mi = 0; mi < 2; mi++){
#pragma unroll
    for (int ni = 0; ni < 2; ni++){
      int t = t0 + wn + ni * 16 + cc;
      if (t >= Lout) continue;
#pragma unroll
      for (int r = 0; r < 4; r++){
        int co = co0 + wm + mi * 16 + cr + r;
        out[(size_t)co * outLd + t] = acc[mi][ni][r];
      }
    }
  }
}

// ---- final feature LN + transpose (512,S)->(S,512) ----
__global__ void featln_transpose_kernel(const float* __restrict__ xin,
                                        const float* __restrict__ g, const float* __restrict__ b,
                                        float* __restrict__ feat){
  int t = blockIdx.x * 256 + threadIdx.x;
  if (t >= SEQ) return;
  float s = 0.f, sq = 0.f;
  for (int c = 0; c < 512; c++){ float v = xin[c * SEQ + t]; s += v; sq += v * v; }
  float m = s * (1.f / 512.f), var = sq * (1.f / 512.f) - m * m, rs = rsqrtf(var + 1e-5f);
  for (int c = 0; c < 512; c++)
    feat[t * 512 + c] = (xin[c * SEQ + t] - m) * rs * g[c] + b[c];
}

// ---- MFMA GEMM, fp32 inputs (bf16 cast fused): C = act(alpha*(A @ W^T + bias)) ----
template<int ACT>
__global__ void gemm_mfma_f32(const float* __restrict__ A, const float* __restrict__ W,
                              const float* __restrict__ bias, float* __restrict__ C,
                              int M, int N, int K, float alpha){
  __shared__ bf16 As[64][40];
  __shared__ bf16 Ws[64][40];
  const int tid = threadIdx.x;
  const int wid = tid >> 6, lane = tid & 63;
  const int m0 = blockIdx.y * 64, n0 = blockIdx.x * 64;
  const int wm = (wid >> 1) * 32, wn = (wid & 1) * 32;
  const int lrow = tid >> 2;
  const int lk   = (tid & 3) * 8;
  const int fr = lane & 15, fk = (lane >> 4) * 8;
  f32x4 acc[2][2] = {};
  for (int k0 = 0; k0 < K; k0 += 32){
    float4 a0 = make_float4(0.f,0.f,0.f,0.f), a1 = make_float4(0.f,0.f,0.f,0.f);
    int gm = m0 + lrow;
    if (gm < M){
      const float* ap = &A[(size_t)gm * K + k0 + lk];
      a0 = *reinterpret_cast<const float4*>(ap);
      a1 = *reinterpret_cast<const float4*>(ap + 4);
    }
    uint4 pa;
    pa.x = f2bf_rne(a0.x) | (f2bf_rne(a0.y) << 16);
    pa.y = f2bf_rne(a0.z) | (f2bf_rne(a0.w) << 16);
    pa.z = f2bf_rne(a1.x) | (f2bf_rne(a1.y) << 16);
    pa.w = f2bf_rne(a1.z) | (f2bf_rne(a1.w) << 16);
    *reinterpret_cast<uint4*>(&As[lrow][lk]) = pa;
    const float* wp = &W[(size_t)(n0 + lrow) * K + k0 + lk];
    float4 w0 = *reinterpret_cast<const float4*>(wp);
    float4 w1 = *reinterpret_cast<const float4*>(wp + 4);
    uint4 pw;
    pw.x = f2bf_rne(w0.x) | (f2bf_rne(w0.y) << 16);
    pw.y = f2bf_rne(w0.z) | (f2bf_rne(w0.w) << 16);
    pw.z = f2bf_rne(w1.x) | (f2bf_rne(w1.y) << 16);
    pw.w = f2bf_rne(w1.z) | (f2bf_rne(w1.w) << 16);
    *reinterpret_cast<uint4*>(&Ws[lrow][lk]) = pw;
    __syncthreads();
    s16x8 av0 = *reinterpret_cast<const s16x8*>(&As[wm + fr][fk]);
    s16x8 av1 = *reinterpret_cast<const s16x8*>(&As[wm + 16 + fr][fk]);
    s16x8 bv0 = *reinterpret_cast<const s16x8*>(&Ws[wn + fr][fk]);
    s16x8 bv1 = *reinterpret_cast<const s16x8*>(&Ws[wn + 16 + fr][fk]);
    acc[0][0] = __builtin_amdgcn_mfma_f32_16x16x32_bf16(av0, bv0, acc[0][0], 0, 0, 0);
    acc[0][1] = __builtin_amdgcn_mfma_f32_16x16x32_bf16(av0, bv1, acc[0][1], 0, 0, 0);
    acc[1][0] = __builtin_amdgcn_mfma_f32_16x16x32_bf16(av1, bv0, acc[1][0], 0, 0, 0);
    acc[1][1] = __builtin_amdgcn_mfma_f32_16x16x32_bf16(av1, bv1, acc[1][1], 0, 0, 0);
    __syncthreads();
  }
  const int cc = lane & 15, cr = (lane >> 4) * 4;
#pragma unroll
  for (int mi = 0; mi < 2; mi++){
#pragma unroll
    for (int ni = 0; ni < 2; ni++){
      int n = n0 + wn + ni * 16 + cc;
      float bn = bias[n];
#pragma unroll
      for (int r = 0; r < 4; r++){
        int m = m0 + wm + mi * 16 + cr + r;
        if (m < M){
          float v = alpha * (acc[mi][ni][r] + bn);
          if (ACT == 1) v = gelu_f(v);
          C[(size_t)m * N + n] = v;
        }
      }
    }
  }
}

// ---- fused QKV (z selects Wq/Wk/Wv) ----
__global__ void gemm_qkv_mfma(const float* __restrict__ A,
                              const float* __restrict__ Wq, const float* __restrict__ Wk,
                              const float* __restrict__ Wv,
                              const float* __restrict__ bqv, const float* __restrict__ bkv,
                              const float* __restrict__ bvv,
                              float* __restrict__ qb, float* __restrict__ kb,
                              float* __restrict__ vb, int M){
  const int z = blockIdx.z;
  const float* W   = (z == 0) ? Wq : (z == 1) ? Wk : Wv;
  const float* bia = (z == 0) ? bqv : (z == 1) ? bkv : bvv;
  float* C         = (z == 0) ? qb : (z == 1) ? kb : vb;
  const float alpha = (z == 0) ? 0.125f : 1.0f;
  const int K = DMODEL, N = DMODEL;
  __shared__ bf16 As[64][40];
  __shared__ bf16 Ws[64][40];
  const int tid = threadIdx.x;
  const int wid = tid >> 6, lane = tid & 63;
  const int m0 = blockIdx.y * 64, n0 = blockIdx.x * 64;
  const int wm = (wid >> 1) * 32, wn = (wid & 1) * 32;
  const int lrow = tid >> 2;
  const int lk   = (tid & 3) * 8;
  const int fr = lane & 15, fk = (lane >> 4) * 8;
  f32x4 acc[2][2] = {};
  for (int k0 = 0; k0 < K; k0 += 32){
    float4 a0 = make_float4(0.f,0.f,0.f,0.f), a1 = make_float4(0.f,0.f,0.f,0.f);
    int gm = m0 + lrow;
    if (gm < M){
      const float* ap = &A[(size_t)gm * K + k0 + lk];
      a0 = *reinterpret_cast<const float4*>(ap);
      a1 = *reinterpret_cast<const float4*>(ap + 4);
    }
    uint4 pa;
    pa.x = f2bf_rne(a0.x) | (f2bf_rne(a0.y) << 16);
    pa.y = f2bf_rne(a0.z) | (f2bf_rne(a0.w) << 16);
    pa.z = f2bf_rne(a1.x) | (f2bf_rne(a1.y) << 16);
    pa.w = f2bf_rne(a1.z) | (f2bf_rne(a1.w) << 16);
    *reinterpret_cast<uint4*>(&As[lrow][lk]) = pa;
    const float* wp = &W[(size_t)(n0 + lrow) * K + k0 + lk];
    float4 w0 = *reinterpret_cast<const float4*>(wp);
    float4 w1 = *reinterpret_cast<const float4*>(wp + 4);
    uint4 pw;
    pw.x = f2bf_rne(w0.x) | (f2bf_rne(w0.y) << 16);
    pw.y = f2bf_rne(w0.z) | (f2bf_rne(w0.w) << 16);
    pw.z = f2bf_rne(w1.x) | (f2bf_rne(w1.y) << 16);
    pw.w = f2bf_rne(w1.z) | (f2bf_rne(w1.w) << 16);
    *reinterpret_cast<uint4*>(&Ws[lrow][lk]) = pw;
    __syncthreads();
    s16x8 av0 = *reinterpret_cast<const s16x8*>(&As[wm + fr][fk]);
    s16x8 av1 = *reinterpret_cast<const s16x8*>(&As[wm + 16 + fr][fk]);
    s16x8 bv0 = *reinterpret_cast<const s16x8*>(&Ws[wn + fr][fk]);
    s16x8 bv1 = *reinterpret_cast<const s16x8*>(&Ws[wn + 16 + fr][fk]);
    acc[0][0] = __builtin_amdgcn_mfma_f32_16x16x32_bf16(av0, bv0, acc[0][0], 0, 0, 0);
    acc[0][1] = __builtin_amdgcn_mfma_f32_16x16x32_bf16(av0, bv1, acc[0][1], 0, 0, 0);
    acc[1][0] = __builtin_amdgcn_mfma_f32_16x16x32_bf16(av1, bv0, acc[1][0], 0, 0, 0);
    acc[1][1] = __builtin_amdgcn_mfma_f32_16x16x32_bf16(av1, bv1, acc[1][1], 0, 0, 0);
    __syncthreads();
  }
  const int cc = lane & 15, cr = (lane >> 4) * 4;
#pragma unroll
  for (int mi = 0; mi < 2; mi++){
#pragma unroll
    for (int ni = 0; ni < 2; ni++){
      int n = n0 + wn + ni * 16 + cc;
      float bn = bia[n];
#pragma unroll
      for (int r = 0; r < 4; r++){
        int m = m0 + wm + mi * 16 + cr + r;
        if (m < M) C[(size_t)m * N + n] = alpha * (acc[mi][ni][r] + bn);
      }
    }
  }
}

// ---- posconv via MFMA: per (t-tile, group, batch): C[co'][t] over K=48ci*128k ----
__global__ void posconv_mfma(const float* __restrict__ x, const bf16* __restrict__ wpos,
                             const float* __restrict__ bias, float* __restrict__ xc){
  const int t0 = blockIdx.x * 64, g = blockIdx.y, b = blockIdx.z;
  __shared__ bf16 As[64][40];
  __shared__ float xw[224];     // window [t0-64 .. t0+126], 191 used
  const int tid = threadIdx.x, wid = tid >> 6, lane = tid & 63;
  const int wm = (wid >> 1) * 32, wn = (wid & 1) * 32;  // wm: co', wn: t
  const int lrow = tid >> 2, lk = (tid & 3) * 8;
  const int fr = lane & 15, fk = (lane >> 4) * 8;
  f32x4 acc[2][2] = {};
  for (int ci = 0; ci < 48; ci++){
    // stage x window for this ci (once per 4 K-steps)
    for (int idx = tid; idx < 191; idx += 256){
      int p = t0 - 64 + idx;
      xw[idx] = (p >= 0 && p < SEQ) ? x[((size_t)(b * SEQ + p)) * DMODEL + g * 48 + ci] : 0.f;
    }
    for (int kk = 0; kk < 128; kk += 32){
      uint4 wa = make_uint4(0, 0, 0, 0);
      if (lrow < 48)
        wa = *reinterpret_cast<const uint4*>(&wpos[(size_t)(g * 48 + lrow) * 6144 + ci * 128 + kk + lk]);
      *reinterpret_cast<uint4*>(&As[lrow][lk]) = wa;
      __syncthreads();
      auto bfragp = [&](int tr)->s16x8{
        int base = tr + kk + fk;
        s16x8 r;
#pragma unroll
        for (int j = 0; j < 8; j++) r[j] = (short)f2bf_rne(xw[base + j]);
        return r;
      };
      s16x8 a0 = *reinterpret_cast<const s16x8*>(&As[wm + fr][fk]);
      s16x8 a1 = *reinterpret_cast<const s16x8*>(&As[wm + 16 + fr][fk]);
      s16x8 b0 = bfragp(wn + fr);
      s16x8 b1 = bfragp(wn + 16 + fr);
      acc[0][0] = __builtin_amdgcn_mfma_f32_16x16x32_bf16(a0, b0, acc[0][0], 0, 0, 0);
      acc[0][1] = __builtin_amdgcn_mfma_f32_16x16x32_bf16(a0, b1, acc[0][1], 0, 0, 0);
      acc[1][0] = __builtin_amdgcn_mfma_f32_16x16x32_bf16(a1, b0, acc[1][0], 0, 0, 0);
      acc[1][1] = __builtin_amdgcn_mfma_f32_16x16x32_bf16(a1, b1, acc[1][1], 0, 0, 0);
      __syncthreads();
    }
  }
  const int cc = lane & 15, cr = (lane >> 4) * 4;
#pragma unroll
  for (int mi = 0; mi < 2; mi++){
#pragma unroll
    for (int ni = 0; ni < 2; ni++){
      int t = t0 + wn + ni * 16 + cc;
      if (t >= SEQ) continue;
#pragma unroll
      for (int r = 0; r < 4; r++){
        int cop = wm + mi * 16 + cr + r;
        if (cop < 48){
          int co = g * 48 + cop;
          xc[((size_t)(b * SEQ + t)) * DMODEL + co] = acc[mi][ni][r] + bias[co];
        }
      }
    }
  }
}

// ---- qk via MFMA: per bh, sc row-stride 512, pads get natural zeros ----
__global__ void qk_mfma(const float* __restrict__ q, const float* __restrict__ k,
                        float* __restrict__ sc){
  const int bh = blockIdx.z, b = bh / NHEAD, h = bh % NHEAD;
  const int m0 = blockIdx.y * 64, n0 = blockIdx.x * 64;
  const float* A  = q + (size_t)b * SEQ * DMODEL + h * DHEAD;
  const float* Bp = k + (size_t)b * SEQ * DMODEL + h * DHEAD;
  __shared__ bf16 As[64][40];
  __shared__ bf16 Ws[64][40];
  const int tid = threadIdx.x, wid = tid >> 6, lane = tid & 63;
  const int wm = (wid >> 1) * 32, wn = (wid & 1) * 32;
  const int lrow = tid >> 2, lk = (tid & 3) * 8;
  const int fr = lane & 15, fk = (lane >> 4) * 8;
  f32x4 acc[2][2] = {};
  for (int k0 = 0; k0 < 64; k0 += 32){
    float4 a0 = make_float4(0.f,0.f,0.f,0.f), a1 = make_float4(0.f,0.f,0.f,0.f);
    if (m0 + lrow < SEQ){
      const float* ap = &A[(size_t)(m0 + lrow) * DMODEL + k0 + lk];
      a0 = *reinterpret_cast<const float4*>(ap);
      a1 = *reinterpret_cast<const float4*>(ap + 4);
    }
    uint4 pa;
    pa.x = f2bf_rne(a0.x) | (f2bf_rne(a0.y) << 16);
    pa.y = f2bf_rne(a0.z) | (f2bf_rne(a0.w) << 16);
    pa.z = f2bf_rne(a1.x) | (f2bf_rne(a1.y) << 16);
    pa.w = f2bf_rne(a1.z) | (f2bf_rne(a1.w) << 16);
    *reinterpret_cast<uint4*>(&As[lrow][lk]) = pa;
    float4 w0 = make_float4(0.f,0.f,0.f,0.f), w1 = make_float4(0.f,0.f,0.f,0.f);
    if (n0 + lrow < SEQ){
      const float* wp = &Bp[(size_t)(n0 + lrow) * DMODEL + k0 + lk];
      w0 = *reinterpret_cast<const float4*>(wp);
      w1 = *reinterpret_cast<const float4*>(wp + 4);
    }
    uint4 pw;
    pw.x = f2bf_rne(w0.x) | (f2bf_rne(w0.y) << 16);
    pw.y = f2bf_rne(w0.z) | (f2bf_rne(w0.w) << 16);
    pw.z = f2bf_rne(w1.x) | (f2bf_rne(w1.y) << 16);
    pw.w = f2bf_rne(w1.z) | (f2bf_rne(w1.w) << 16);
    *reinterpret_cast<uint4*>(&Ws[lrow][lk]) = pw;
    __syncthreads();
    s16x8 av0 = *reinterpret_cast<const s16x8*>(&As[wm + fr][fk]);
    s16x8 av1 = *reinterpret_cast<const s16x8*>(&As[wm + 16 + fr][fk]);
    s16x8 bv0 = *reinterpret_cast<const s16x8*>(&Ws[wn + fr][fk]);
    s16x8 bv1 = *reinterpret_cast<const s16x8*>(&Ws[wn + 16 + fr][fk]);
    acc[0][0] = __builtin_amdgcn_mfma_f32_16x16x32_bf16(av0, bv0, acc[0][0], 0, 0, 0);
    acc[0][1] = __builtin_amdgcn_mfma_f32_16x16x32_bf16(av0, bv1, acc[0][1], 0, 0, 0);
    acc[1][0] = __builtin_amdgcn_mfma_f32_16x16x32_bf16(av1, bv0, acc[1][0], 0, 0, 0);
    acc[1][1] = __builtin_amdgcn_mfma_f32_16x16x32_bf16(av1, bv1, acc[1][1], 0, 0, 0);
    __syncthreads();
  }
  const int cc = lane & 15, cr = (lane >> 4) * 4;
  float* scb = sc + (size_t)bh * SEQ * SP;
#pragma unroll
  for (int mi = 0; mi < 2; mi++){
#pragma unroll
    for (int ni = 0; ni < 2; ni++){
      int j = n0 + wn + ni * 16 + cc;
#pragma unroll
      for (int r = 0; r < 4; r++){
        int i = m0 + wm + mi * 16 + cr + r;
        if (i < SEQ) scb[(size_t)i * SP + j] = acc[mi][ni][r];
      }
    }
  }
}

// ---- V transpose: vt[bh][d][j(512)] with zero pad ----
__global__ void vtrans_kernel(const float* __restrict__ v, float* __restrict__ vt){
  int idx = blockIdx.x * 256 + threadIdx.x;       // 48*64*512
  if (idx >= 48 * 64 * SP) return;
  int j = idx & (SP - 1), d = (idx >> 9) & 63, bh = idx >> 15;
  int b = bh / NHEAD, h = bh % NHEAD;
  vt[idx] = (j < SEQ) ? v[((size_t)(b * SEQ + j)) * DMODEL + h * DHEAD + d] : 0.f;
}

// ---- pv via MFMA: per bh: ctx[i][d] = sum_j p[i][j] vt[d][j]; K=512 ----
__global__ void pv_mfma(const float* __restrict__ attn, const float* __restrict__ vt,
                        float* __restrict__ ctx){
  const int bh = blockIdx.y, b = bh / NHEAD, h = bh % NHEAD;
  const int m0 = blockIdx.x * 64;
  const float* A  = attn + (size_t)bh * SEQ * SP;   // row i, stride 512, guard i<SEQ
  const float* Bp = vt + (size_t)bh * 64 * SP;      // row d, stride 512
  __shared__ bf16 As[64][40];
  __shared__ bf16 Ws[64][40];
  const int tid = threadIdx.x, wid = tid >> 6, lane = tid & 63;
  const int wm = (wid >> 1) * 32, wn = (wid & 1) * 32;
  const int lrow = tid >> 2, lk = (tid & 3) * 8;
  const int fr = lane & 15, fk = (lane >> 4) * 8;
  f32x4 acc[2][2] = {};
  for (int k0 = 0; k0 < SP; k0 += 32){
    float4 a0 = make_float4(0.f,0.f,0.f,0.f), a1 = make_float4(0.f,0.f,0.f,0.f);
    if (m0 + lrow < SEQ){
      const float* ap = &A[(size_t)(m0 + lrow) * SP + k0 + lk];
      a0 = *reinterpret_cast<const float4*>(ap);
      a1 = *reinterpret_cast<const float4*>(ap + 4);
    }
    uint4 pa;
    pa.x = f2bf_rne(a0.x) | (f2bf_rne(a0.y) << 16);
    pa.y = f2bf_rne(a0.z) | (f2bf_rne(a0.w) << 16);
    pa.z = f2bf_rne(a1.x) | (f2bf_rne(a1.y) << 16);
    pa.w = f2bf_rne(a1.z) | (f2bf_rne(a1.w) << 16);
    *reinterpret_cast<uint4*>(&As[lrow][lk]) = pa;
    const float* wp = &Bp[(size_t)lrow * SP + k0 + lk];
    float4 w0 = *reinterpret_cast<const float4*>(wp);
    float4 w1 = *reinterpret_cast<const float4*>(wp + 4);
    uint4 pw;
    pw.x = f2bf_rne(w0.x) | (f2bf_rne(w0.y) << 16);
    pw.y = f2bf_rne(w0.z) | (f2bf_rne(w0.w) << 16);
    pw.z = f2bf_rne(w1.x) | (f2bf_rne(w1.y) << 16);
    pw.w = f2bf_rne(w1.z) | (f2bf_rne(w1.w) << 16);
    *reinterpret_cast<uint4*>(&Ws[lrow][lk]) = pw;
    __syncthreads();
    s16x8 av0 = *reinterpret_cast<const s16x8*>(&As[wm + fr][fk]);
    s16x8 av1 = *reinterpret_cast<const s16x8*>(&As[wm + 16 + fr][fk]);
    s16x8 bv0 = *reinterpret_cast<const s16x8*>(&Ws[wn + fr][fk]);
    s16x8 bv1 = *reinterpret_cast<const s16x8*>(&Ws[wn + 16 + fr][fk]);
    acc[0][0] = __builtin_amdgcn_mfma_f32_16x16x32_bf16(av0, bv0, acc[0][0], 0, 0, 0);
    acc[0][1] = __builtin_amdgcn_mfma_f32_16x16x32_bf16(av0, bv1, acc[0][1], 0, 0, 0);
    acc[1][0] = __builtin_amdgcn_mfma_f32_16x16x32_bf16(av1, bv0, acc[1][0], 0, 0, 0);
    acc[1][1] = __builtin_amdgcn_mfma_f32_16x16x32_bf16(av1, bv1, acc[1][1], 0, 0, 0);
    __syncthreads();
  }
  const int cc = lane & 15, cr = (lane >> 4) * 4;
#pragma unroll
  for (int mi = 0; mi < 2; mi++){
#pragma unroll
    for (int ni = 0; ni < 2; ni++){
      int d = wn + ni * 16 + cc;
      if (d >= 64) continue;
#pragma unroll
      for (int r = 0; r < 4; r++){
        int i = m0 + wm + mi * 16 + cr + r;
        if (i < SEQ)
          ctx[((size_t)(b * SEQ + i)) * DMODEL + h * DHEAD + d] = acc[mi][ni][r];
      }
    }
  }
}

// ---- residual add (+optional GELU) + row LayerNorm over DMODEL ----
template<int GELU_ADD>
__global__ void add_ln_kernel(float* __restrict__ x, const float* __restrict__ add,
                              const float* __restrict__ g, const float* __restrict__ b){
  int row = blockIdx.x;
  float* xr = x + (size_t)row * DMODEL;
  const float* ar = add + (size_t)row * DMODEL;
  __shared__ float buf[DMODEL];
  __shared__ float red[256];
  int tid = threadIdx.x;
  float s = 0.f;
  for (int i = tid; i < DMODEL; i += 256){
    float v = ar[i];
    if (GELU_ADD) v = gelu_f(v);
    v += xr[i];
    buf[i] = v; s += v;
  }
  red[tid] = s; __syncthreads();
  for (int st = 128; st > 0; st >>= 1){ if (tid < st) red[tid] += red[tid + st]; __syncthreads(); }
  float m = red[0] * (1.f / DMODEL); __syncthreads();
  float sq = 0.f;
  for (int i = tid; i < DMODEL; i += 256){ float d = buf[i] - m; sq += d * d; }
  red[tid] = sq; __syncthreads();
  for (int st = 128; st > 0; st >>= 1){ if (tid < st) red[tid] += red[tid + st]; __syncthreads(); }
  float rs = rsqrtf(red[0] * (1.f / DMODEL) + 1e-5f);
  for (int i = tid; i < DMODEL; i += 256) xr[i] = (buf[i] - m) * rs * g[i] + b[i];
}

// ---- T5-style relative position bias table ----
__global__ void relbias_kernel(const float* __restrict__ rel_emb, float* __restrict__ tab){
  int idx = blockIdx.x * 256 + threadIdx.x;
  if (idx >= NREL * NHEAD) return;
  int rr = idx / NHEAD, h = idx - rr * NHEAD;
  int rel = rr - (SEQ - 1);
  int bkt = (rel > 0) ? 160 : 0;
  int n = (rel < 0) ? -rel : rel;
  if (n < 80) bkt += n;
  else {
    int large = 80 + (int)(logf((float)n / 80.f) / logf(10.f) * 80.f);
    bkt += (large < 159) ? large : 159;
  }
  tab[h * NREL + rr] = rel_emb[bkt * NHEAD + h];
}

// ---- gated rel-pos gate values; sigmoid AFTER 4-logit sums ----
__global__ void gate_kernel(const float* __restrict__ x, const float* __restrict__ gwl,
                            const float* __restrict__ gbl, const float* __restrict__ gal,
                            float* __restrict__ gate){
  int idx = blockIdx.x * 256 + threadIdx.x;
  if (idx >= BATCH * NHEAD * SEQ) return;
  int s = idx % SEQ; int bh = idx / SEQ; int h = bh % NHEAD; int b = bh / NHEAD;
  const float* xv = x + ((size_t)(b * SEQ + s)) * DMODEL + h * DHEAD;
  float a0 = 0.f, a1 = 0.f;
#pragma unroll
  for (int gg = 0; gg < 8; gg++){
    float a = gbl[gg];
    const float* wrow = gwl + gg * DHEAD;
#pragma unroll
    for (int d = 0; d < DHEAD; d++) a += xv[d] * wrow[d];
    if (gg < 4) a0 += a; else a1 += a;
  }
  float g0 = 1.f / (1.f + expf(-a0));
  float g1 = 1.f / (1.f + expf(-a1));
  gate[idx] = g0 * (g1 * gal[h] - 1.f) + 2.f;
}

// ---- softmax with fused gate*relbias add, row stride 512, pads untouched ----
__global__ void softmax_bias_kernel(float* __restrict__ sc, const float* __restrict__ gate,
                                    const float* __restrict__ tab){
  int row = blockIdx.x;                 // (b*H+h)*S + i
  int bh = row / SEQ, i = row - bh * SEQ;
  int h = bh % NHEAD;
  float gt = gate[row];
  float* p = sc + ((size_t)bh * SEQ + i) * SP;
  const float* tb = tab + (size_t)h * NREL + (SEQ - 1 - i);
  __shared__ float buf[512];
  __shared__ float red[256];
  int tid = threadIdx.x;
  float mx = -1e30f;
  for (int j = tid; j < SEQ; j += 256){
    float v = p[j] + gt * tb[j];
    buf[j] = v; mx = fmaxf(mx, v);
  }
  red[tid] = mx; __syncthreads();
  for (int st = 128; st > 0; st >>= 1){ if (tid < st) red[tid] = fmaxf(red[tid], red[tid + st]); __syncthreads(); }
  mx = red[0]; __syncthreads();
  float sum = 0.f;
  for (int j = tid; j < SEQ; j += 256){ float e = expf(buf[j] - mx); buf[j] = e; sum += e; }
  red[tid] = sum; __syncthreads();
  for (int st = 128; st > 0; st >>= 1){ if (tid < st) red[tid] += red[tid + st]; __syncthreads(); }
  float inv = 1.0f / red[0];
  for (int j = tid; j < SEQ; j += 256) p[j] = buf[j] * inv;
}

} // anonymous namespace

extern "C" void kernel_launch(void* const* d_in, const int* in_sizes, int n_in,
                              void* d_out, int out_size, void* d_ws, size_t ws_size,
                              hipStream_t stream){
  (void)ws_size;

  static const int DS[34] = {640000,5120,3145728,1048576,3584,3584,512,512,393216,768,
                             4718592,768,768,768,7077888,9216,7077888,9216,7077888,9216,
                             7077888,9216,6144,96,144,9216,9216,28311552,36864,28311552,
                             9216,9216,9216,3840};
  bool ok = (n_in == 34) && (out_size == BATCH * SEQ * DMODEL);
  if (ok) for (int i = 0; i < 34; i++) if (in_sizes[i] != DS[i]) { ok = false; break; }
  if (!ok){
    fill_f32_kernel<<<(out_size + 255) / 256, 256, 0, stream>>>((float*)d_out, out_size, 1000.0f);
    return;
  }

  const float* src  = (const float*)d_in[0];
  const float* w0   = (const float*)d_in[1];
  const float* w14  = (const float*)d_in[2];
  const float* w56  = (const float*)d_in[3];
  const float* clng = (const float*)d_in[4];
  const float* clnb = (const float*)d_in[5];
  const float* flng = (const float*)d_in[6];
  const float* flnb = (const float*)d_in[7];
  const float* pjw  = (const float*)d_in[8];
  const float* pjb  = (const float*)d_in[9];
  const float* pcw  = (const float*)d_in[10];
  const float* pcb  = (const float*)d_in[11];
  const float* eng  = (const float*)d_in[12];
  const float* enb  = (const float*)d_in[13];
  const float* Wq   = (const float*)d_in[14];
  const float* bq   = (const float*)d_in[15];
  const float* Wk   = (const float*)d_in[16];
  const float* bk   = (const float*)d_in[17];
  const float* Wv   = (const float*)d_in[18];
  const float* bv   = (const float*)d_in[19];
  const float* Wo   = (const float*)d_in[20];
  const float* bo   = (const float*)d_in[21];
  const float* gw   = (const float*)d_in[22];
  const float* gbp  = (const float*)d_in[23];
  const float* ga   = (const float*)d_in[24];
  const float* l1g  = (const float*)d_in[25];
  const float* l1b  = (const float*)d_in[26];
  const float* f1w  = (const float*)d_in[27];
  const float* f1b  = (const float*)d_in[28];
  const float* f2w  = (const float*)d_in[29];
  const float* f2b  = (const float*)d_in[30];
  const float* l2g  = (const float*)d_in[31];
  const float* l2b  = (const float*)d_in[32];
  const float* rel  = (const float*)d_in[33];

  float* x = (float*)d_out;  // residual stream lives in d_out (fp32)

  // workspace (~128 MB)
  float* wsf = (float*)d_ws;
  size_t off = 0;
  auto alloc = [&](size_t n){ float* pp = wsf + off; off += (n + 63) & ~(size_t)63; return pp; };
  const size_t XSZ = (size_t)BATCH * SEQ * DMODEL;
  float* attn = alloc((size_t)BATCH * NHEAD * SEQ * SP);   // 12.26M
  float* ffh  = alloc((size_t)BATCH * SEQ * FFN);          // 6.13M
  float* tmp  = alloc(XSZ);
  float* qb   = alloc(XSZ);
  float* kb   = alloc(XSZ);
  float* vb   = alloc(XSZ);
  float* ctx  = alloc(XSZ);
  float* feat = alloc((size_t)BATCH * SEQ * 512);
  float* c6   = alloc((size_t)512 * SEQ);
  float* gate = alloc((size_t)BATCH * NHEAD * SEQ);
  float* tab  = alloc((size_t)NHEAD * NREL);
  float* vt   = alloc((size_t)48 * 64 * SP);               // 1.57M
  bf16* wpad  = (bf16*)alloc((size_t)512 * 512 * 4 / 2);   // conv padded weights (one stage)
  bf16* wposb = (bf16*)alloc((size_t)DMODEL * 48 * 128 / 2);
  // conv ping-pong aliases [attn .. ctx] span (26.06M >= 24.58M needed)
  float* cA = attn;
  float* cB = attn + (size_t)16383488;

  const int Ls[8] = {160000, 31999, 15999, 7999, 3999, 1999, 999, 499};
  const int Mrows = BATCH * SEQ; // 1996

  // ---- conv feature extractor: per batch, full length, MFMA stages ----
  for (int b = 0; b < BATCH; b++){
    conv0_kernel<<<(512 * Ls[1] + 255) / 256, 256, 0, stream>>>(src + (size_t)b * T_IN, w0, cA, Ls[1]);
    ln_gelu_ch_kernel<<<(Ls[1] + 255) / 256, 256, 0, stream>>>(cA, clng, clnb, Ls[1]);
    float* bufs[2] = {cA, cB};
    for (int st = 1; st <= 6; st++){
      const float* inb = bufs[(st + 1) & 1];
      float* outb      = (st == 6) ? c6 : bufs[st & 1];
      int Lin = Ls[st], Lout = Ls[st + 1];
      int oLd = (st == 6) ? SEQ : Lout;
      dim3 grd((Lout + 63) / 64, 8);
      if (st <= 4){
        convw_pad_kernel<3><<<(512 * 512 * 4 + 255) / 256, 256, 0, stream>>>(
            w14 + (size_t)(st - 1) * 512 * 512 * 3, wpad);
        conv_mfma_kernel<3><<<grd, 256, 0, stream>>>(inb, wpad, outb, Lin, Lout, oLd);
      } else {
        convw_pad_kernel<2><<<(512 * 512 * 4 + 255) / 256, 256, 0, stream>>>(
            w56 + (size_t)(st - 5) * 512 * 512 * 2, wpad);
        conv_mfma_kernel<2><<<grd, 256, 0, stream>>>(inb, wpad, outb, Lin, Lout, oLd);
      }
      if (st < 6)
        ln_gelu_ch_kernel<<<(Lout + 255) / 256, 256, 0, stream>>>(outb, clng + st * 512, clnb + st * 512, Lout);
    }
    ln_gelu_ch_kernel<<<(SEQ + 255) / 256, 256, 0, stream>>>(c6, clng + 6 * 512, clnb + 6 * 512, SEQ);
    featln_transpose_kernel<<<(SEQ + 255) / 256, 256, 0, stream>>>(c6, flng, flnb, feat + (size_t)b * SEQ * 512);
  }

  // post_extract_proj
  gemm_mfma_f32<0><<<dim3(DMODEL / 64, (Mrows + 63) / 64), 256, 0, stream>>>(feat, pjw, pjb, x, Mrows, DMODEL, 512, 1.0f);
  // positional conv (MFMA) + gelu-residual + encoder LN
  f2bf_kernel<<<(4718592 + 255) / 256, 256, 0, stream>>>(pcw, wposb, 4718592);
  posconv_mfma<<<dim3(8, 16, BATCH), 256, 0, stream>>>(x, wposb, pcb, tmp);
  add_ln_kernel<1><<<Mrows, 256, 0, stream>>>(x, tmp, eng, enb);
  relbias_kernel<<<(NREL * NHEAD + 255) / 256, 256, 0, stream>>>(rel, tab);

  const size_t WQK = (size_t)DMODEL * DMODEL;
  const size_t WF  = (size_t)FFN * DMODEL;
  for (int l = 0; l < NLAYER; l++){
    gate_kernel<<<(BATCH * NHEAD * SEQ + 255) / 256, 256, 0, stream>>>(
        x, gw + (size_t)l * 8 * DHEAD, gbp + l * 8, ga + l * NHEAD, gate);
    gemm_qkv_mfma<<<dim3(12, 32, 3), 256, 0, stream>>>(
        x, Wq + l * WQK, Wk + l * WQK, Wv + l * WQK,
        bq + l * DMODEL, bk + l * DMODEL, bv + l * DMODEL, qb, kb, vb, Mrows);
    vtrans_kernel<<<(48 * 64 * SP + 255) / 256, 256, 0, stream>>>(vb, vt);
    qk_mfma<<<dim3(8, 8, BATCH * NHEAD), 256, 0, stream>>>(qb, kb, attn);
    softmax_bias_kernel<<<BATCH * NHEAD * SEQ, 256, 0, stream>>>(attn, gate, tab);
    pv_mfma<<<dim3(8, BATCH * NHEAD), 256, 0, stream>>>(attn, vt, ctx);
    gemm_mfma_f32<0><<<dim3(12, 32), 256, 0, stream>>>(ctx, Wo + l * WQK, bo + l * DMODEL, tmp, Mrows, DMODEL, DMODEL, 1.0f);
    add_ln_kernel<0><<<Mrows, 256, 0, stream>>>(x, tmp, l1g + l * DMODEL, l1b + l * DMODEL);
    gemm_mfma_f32<1><<<dim3(FFN / 64, 32), 256, 0, stream>>>(x, f1w + l * WF, f1b + l * FFN, ffh, Mrows, FFN, DMODEL, 1.0f);
    gemm_mfma_f32<0><<<dim3(12, 32), 256, 0, stream>>>(ffh, f2w + l * WF, f2b + l * DMODEL, tmp, Mrows, DMODEL, FFN, 1.0f);
    add_ln_kernel<0><<<Mrows, 256, 0, stream>>>(x, tmp, l2g + l * DMODEL, l2b + l * DMODEL);
  }
  // result is already in d_out
}

// Round 14
// 7928.506 us; speedup vs baseline: 11.4090x; 1.5393x over previous
//
#include <hip/hip_runtime.h>
#include <hip/hip_bf16.h>
#include <math.h>

namespace {

constexpr int BATCH  = 4;
constexpr int T_IN   = 160000;
constexpr int DMODEL = 768;
constexpr int NHEAD  = 12;
constexpr int DHEAD  = 64;
constexpr int FFN    = 3072;
constexpr int NLAYER = 12;
constexpr int SEQ    = 499;
constexpr int SP     = 512;            // padded attention row stride
constexpr int NREL   = 2 * SEQ - 1;

typedef __hip_bfloat16 bf16;
using f32x4 = __attribute__((ext_vector_type(4))) float;
using s16x8 = __attribute__((ext_vector_type(8))) short;

__device__ __forceinline__ float gelu_f(float x){
  return 0.5f * x * (1.0f + erff(x * 0.70710678118654752f));
}

__device__ __forceinline__ unsigned f2bf_rne(float f){
  unsigned u = __float_as_uint(f);
  return (u + 0x7FFFu + ((u >> 16) & 1u)) >> 16;
}

__global__ void fill_f32_kernel(float* __restrict__ out, int n, float val){
  int i = blockIdx.x * 256 + threadIdx.x;
  if (i < n) out[i] = val;
}

__global__ void f2bf_kernel(const float* __restrict__ in, bf16* __restrict__ out, int n){
  int i = blockIdx.x * 256 + threadIdx.x;
  if (i < n) out[i] = __float2bfloat16(in[i]);
}

// ---- conv stage 0: k=10, s=5 ----
__global__ void conv0_kernel(const float* __restrict__ src, const float* __restrict__ w,
                             float* __restrict__ out, int Lout){
  int idx = blockIdx.x * 256 + threadIdx.x;
  if (idx >= 512 * Lout) return;
  int c = idx / Lout, t = idx - c * Lout;
  const float* wr = w + c * 10;
  const float* s  = src + t * 5;
  float acc = 0.f;
#pragma unroll
  for (int k = 0; k < 10; k++) acc += wr[k] * s[k];
  out[idx] = acc;
}

// ---- 2D-parallel LayerNorm over channels + GELU, layout (512, Lt), in place ----
// block = 8 channel-strips x 32 t-positions
__global__ void ln_gelu_ch2_kernel(float* __restrict__ x, const float* __restrict__ g,
                                   const float* __restrict__ b, int Lt){
  const int tid = threadIdx.x;
  const int tt = tid & 31, tc = tid >> 5;
  const int t = blockIdx.x * 32 + tt;
  __shared__ float sred[8][33], qred[8][33];
  __shared__ float mrow[32], rrow[32];
  float s = 0.f, q = 0.f;
  if (t < Lt){
    const float* xc = x + (size_t)(tc * 64) * Lt + t;
#pragma unroll 8
    for (int j = 0; j < 64; j++){ float v = xc[(size_t)j * Lt]; s += v; q += v * v; }
  }
  sred[tc][tt] = s; qred[tc][tt] = q; __syncthreads();
  if (tid < 32){
    float ss = 0.f, qq = 0.f;
#pragma unroll
    for (int c = 0; c < 8; c++){ ss += sred[c][tid]; qq += qred[c][tid]; }
    float m = ss * (1.f / 512.f);
    float var = qq * (1.f / 512.f) - m * m;
    mrow[tid] = m; rrow[tid] = rsqrtf(var + 1e-5f);
  }
  __syncthreads();
  if (t < Lt){
    float m = mrow[tt], rs = rrow[tt];
    float* xc = x + (size_t)(tc * 64) * Lt + t;
#pragma unroll 8
    for (int j = 0; j < 64; j++){
      int c = tc * 64 + j;
      float v = (xc[(size_t)j * Lt] - m) * rs * g[c] + b[c];
      xc[(size_t)j * Lt] = gelu_f(v);
    }
  }
}

// ---- conv stages 1..6 via MFMA, fp32 weights cast+padded in staging ----
// K = ci*4+k (k padded KW->4); block 64co x 64t, 4 waves 2x2
template<int KW>
__global__ void conv_mfma_kernel(const float* __restrict__ in, const float* __restrict__ w,
                                 float* __restrict__ out, int Lin, int Lout, int outLd){
  constexpr int SPAN = 128 + KW;
  __shared__ bf16 As[64][40];
  __shared__ float ins[8][136];
  const int tid = threadIdx.x, wid = tid >> 6, lane = tid & 63;
  const int t0 = blockIdx.x * 64, co0 = blockIdx.y * 64;
  const int wm = (wid >> 1) * 32, wn = (wid & 1) * 32;   // wm: co, wn: t
  const int lrow = tid >> 2, lk = (tid & 3) * 8;
  const int fr = lane & 15, fk = (lane >> 4) * 8;
  const int cir = lk >> 2;                                // ci offset within group of 8
  f32x4 acc[2][2] = {};
  for (int ci0 = 0; ci0 < 512; ci0 += 8){
    // stage weights: 2 ci x KW floats -> 8 bf16 (k padded to 4)
    {
      uint4 pw;
      if (KW == 3){
        const float* wp = w + (size_t)(co0 + lrow) * 1536 + (ci0 + cir) * 3;
        float2 f01 = *reinterpret_cast<const float2*>(wp);
        float2 f23 = *reinterpret_cast<const float2*>(wp + 2);
        float2 f45 = *reinterpret_cast<const float2*>(wp + 4);
        pw.x = f2bf_rne(f01.x) | (f2bf_rne(f01.y) << 16);
        pw.y = f2bf_rne(f23.x);
        pw.z = f2bf_rne(f23.y) | (f2bf_rne(f45.x) << 16);
        pw.w = f2bf_rne(f45.y);
      } else {
        const float* wp = w + (size_t)(co0 + lrow) * 1024 + (ci0 + cir) * 2;
        float4 f = *reinterpret_cast<const float4*>(wp);
        pw.x = f2bf_rne(f.x) | (f2bf_rne(f.y) << 16);
        pw.y = 0u;
        pw.z = f2bf_rne(f.z) | (f2bf_rne(f.w) << 16);
        pw.w = 0u;
      }
      *reinterpret_cast<uint4*>(&As[lrow][lk]) = pw;
    }
    for (int idx = tid; idx < 8 * SPAN; idx += 256){
      int ci = idx / SPAN, j = idx - ci * SPAN;
      int gp = t0 * 2 + j;
      ins[ci][j] = (gp < Lin) ? in[(size_t)(ci0 + ci) * Lin + gp] : 0.f;
    }
    __syncthreads();
    const int cia = fk >> 2;
    auto bfrag = [&](int tr)->s16x8 {
      float2 pa0 = *reinterpret_cast<const float2*>(&ins[cia][2 * tr]);
      float2 pb0 = *reinterpret_cast<const float2*>(&ins[cia + 1][2 * tr]);
      s16x8 r;
      r[0] = (short)f2bf_rne(pa0.x);
      r[1] = (short)f2bf_rne(pa0.y);
      r[2] = (KW > 2) ? (short)f2bf_rne(ins[cia][2 * tr + 2]) : (short)0;
      r[3] = 0;
      r[4] = (short)f2bf_rne(pb0.x);
      r[5] = (short)f2bf_rne(pb0.y);
      r[6] = (KW > 2) ? (short)f2bf_rne(ins[cia + 1][2 * tr + 2]) : (short)0;
      r[7] = 0;
      return r;
    };
    s16x8 a0 = *reinterpret_cast<const s16x8*>(&As[wm + fr][fk]);
    s16x8 a1 = *reinterpret_cast<const s16x8*>(&As[wm + 16 + fr][fk]);
    s16x8 b0 = bfrag(wn + fr);
    s16x8 b1 = bfrag(wn + 16 + fr);
    acc[0][0] = __builtin_amdgcn_mfma_f32_16x16x32_bf16(a0, b0, acc[0][0], 0, 0, 0);
    acc[0][1] = __builtin_amdgcn_mfma_f32_16x16x32_bf16(a0, b1, acc[0][1], 0, 0, 0);
    acc[1][0] = __builtin_amdgcn_mfma_f32_16x16x32_bf16(a1, b0, acc[1][0], 0, 0, 0);
    acc[1][1] = __builtin_amdgcn_mfma_f32_16x16x32_bf16(a1, b1, acc[1][1], 0, 0, 0);
    __syncthreads();
  }
  const int cc = lane & 15, cr = (lane >> 4) * 4;
#pragma unroll
  for (int mi = 0; mi < 2; mi++){
#pragma unroll
    for (int ni = 0; ni < 2; ni++){
      int t = t0 + wn + ni * 16 + cc;
      if (t >= Lout) continue;
#pragma unroll
      for (int r = 0; r < 4; r++){
        int co = co0 + wm + mi * 16 + cr + r;
        out[(size_t)co * outLd + t] = acc[mi][ni][r];
      }
    }
  }
}

// ---- final feature LN + transpose (512,S)->(S,512) ----
__global__ void featln_transpose_kernel(const float* __restrict__ xin,
                                        const float* __restrict__ g, const float* __restrict__ b,
                                        float* __restrict__ feat){
  int t = blockIdx.x * 256 + threadIdx.x;
  if (t >= SEQ) return;
  float s = 0.f, sq = 0.f;
  for (int c = 0; c < 512; c++){ float v = xin[c * SEQ + t]; s += v; sq += v * v; }
  float m = s * (1.f / 512.f), var = sq * (1.f / 512.f) - m * m, rs = rsqrtf(var + 1e-5f);
  for (int c = 0; c < 512; c++)
    feat[t * 512 + c] = (xin[c * SEQ + t] - m) * rs * g[c] + b[c];
}

// ---- MFMA GEMM, fp32 inputs (bf16 cast fused): C = act(alpha*(A @ W^T + bias)) ----
template<int ACT>
__global__ void gemm_mfma_f32(const float* __restrict__ A, const float* __restrict__ W,
                              const float* __restrict__ bias, float* __restrict__ C,
                              int M, int N, int K, float alpha){
  __shared__ bf16 As[64][40];
  __shared__ bf16 Ws[64][40];
  const int tid = threadIdx.x;
  const int wid = tid >> 6, lane = tid & 63;
  const int m0 = blockIdx.y * 64, n0 = blockIdx.x * 64;
  const int wm = (wid >> 1) * 32, wn = (wid & 1) * 32;
  const int lrow = tid >> 2;
  const int lk   = (tid & 3) * 8;
  const int fr = lane & 15, fk = (lane >> 4) * 8;
  f32x4 acc[2][2] = {};
  for (int k0 = 0; k0 < K; k0 += 32){
    float4 a0 = make_float4(0.f,0.f,0.f,0.f), a1 = make_float4(0.f,0.f,0.f,0.f);
    int gm = m0 + lrow;
    if (gm < M){
      const float* ap = &A[(size_t)gm * K + k0 + lk];
      a0 = *reinterpret_cast<const float4*>(ap);
      a1 = *reinterpret_cast<const float4*>(ap + 4);
    }
    uint4 pa;
    pa.x = f2bf_rne(a0.x) | (f2bf_rne(a0.y) << 16);
    pa.y = f2bf_rne(a0.z) | (f2bf_rne(a0.w) << 16);
    pa.z = f2bf_rne(a1.x) | (f2bf_rne(a1.y) << 16);
    pa.w = f2bf_rne(a1.z) | (f2bf_rne(a1.w) << 16);
    *reinterpret_cast<uint4*>(&As[lrow][lk]) = pa;
    const float* wp = &W[(size_t)(n0 + lrow) * K + k0 + lk];
    float4 w0 = *reinterpret_cast<const float4*>(wp);
    float4 w1 = *reinterpret_cast<const float4*>(wp + 4);
    uint4 pw;
    pw.x = f2bf_rne(w0.x) | (f2bf_rne(w0.y) << 16);
    pw.y = f2bf_rne(w0.z) | (f2bf_rne(w0.w) << 16);
    pw.z = f2bf_rne(w1.x) | (f2bf_rne(w1.y) << 16);
    pw.w = f2bf_rne(w1.z) | (f2bf_rne(w1.w) << 16);
    *reinterpret_cast<uint4*>(&Ws[lrow][lk]) = pw;
    __syncthreads();
    s16x8 av0 = *reinterpret_cast<const s16x8*>(&As[wm + fr][fk]);
    s16x8 av1 = *reinterpret_cast<const s16x8*>(&As[wm + 16 + fr][fk]);
    s16x8 bv0 = *reinterpret_cast<const s16x8*>(&Ws[wn + fr][fk]);
    s16x8 bv1 = *reinterpret_cast<const s16x8*>(&Ws[wn + 16 + fr][fk]);
    acc[0][0] = __builtin_amdgcn_mfma_f32_16x16x32_bf16(av0, bv0, acc[0][0], 0, 0, 0);
    acc[0][1] = __builtin_amdgcn_mfma_f32_16x16x32_bf16(av0, bv1, acc[0][1], 0, 0, 0);
    acc[1][0] = __builtin_amdgcn_mfma_f32_16x16x32_bf16(av1, bv0, acc[1][0], 0, 0, 0);
    acc[1][1] = __builtin_amdgcn_mfma_f32_16x16x32_bf16(av1, bv1, acc[1][1], 0, 0, 0);
    __syncthreads();
  }
  const int cc = lane & 15, cr = (lane >> 4) * 4;
#pragma unroll
  for (int mi = 0; mi < 2; mi++){
#pragma unroll
    for (int ni = 0; ni < 2; ni++){
      int n = n0 + wn + ni * 16 + cc;
      float bn = bias[n];
#pragma unroll
      for (int r = 0; r < 4; r++){
        int m = m0 + wm + mi * 16 + cr + r;
        if (m < M){
          float v = alpha * (acc[mi][ni][r] + bn);
          if (ACT == 1) v = gelu_f(v);
          C[(size_t)m * N + n] = v;
        }
      }
    }
  }
}

// ---- fused QKV (z selects Wq/Wk/Wv) ----
__global__ void gemm_qkv_mfma(const float* __restrict__ A,
                              const float* __restrict__ Wq, const float* __restrict__ Wk,
                              const float* __restrict__ Wv,
                              const float* __restrict__ bqv, const float* __restrict__ bkv,
                              const float* __restrict__ bvv,
                              float* __restrict__ qb, float* __restrict__ kb,
                              float* __restrict__ vb, int M){
  const int z = blockIdx.z;
  const float* W   = (z == 0) ? Wq : (z == 1) ? Wk : Wv;
  const float* bia = (z == 0) ? bqv : (z == 1) ? bkv : bvv;
  float* C         = (z == 0) ? qb : (z == 1) ? kb : vb;
  const float alpha = (z == 0) ? 0.125f : 1.0f;
  const int K = DMODEL, N = DMODEL;
  __shared__ bf16 As[64][40];
  __shared__ bf16 Ws[64][40];
  const int tid = threadIdx.x;
  const int wid = tid >> 6, lane = tid & 63;
  const int m0 = blockIdx.y * 64, n0 = blockIdx.x * 64;
  const int wm = (wid >> 1) * 32, wn = (wid & 1) * 32;
  const int lrow = tid >> 2;
  const int lk   = (tid & 3) * 8;
  const int fr = lane & 15, fk = (lane >> 4) * 8;
  f32x4 acc[2][2] = {};
  for (int k0 = 0; k0 < K; k0 += 32){
    float4 a0 = make_float4(0.f,0.f,0.f,0.f), a1 = make_float4(0.f,0.f,0.f,0.f);
    int gm = m0 + lrow;
    if (gm < M){
      const float* ap = &A[(size_t)gm * K + k0 + lk];
      a0 = *reinterpret_cast<const float4*>(ap);
      a1 = *reinterpret_cast<const float4*>(ap + 4);
    }
    uint4 pa;
    pa.x = f2bf_rne(a0.x) | (f2bf_rne(a0.y) << 16);
    pa.y = f2bf_rne(a0.z) | (f2bf_rne(a0.w) << 16);
    pa.z = f2bf_rne(a1.x) | (f2bf_rne(a1.y) << 16);
    pa.w = f2bf_rne(a1.z) | (f2bf_rne(a1.w) << 16);
    *reinterpret_cast<uint4*>(&As[lrow][lk]) = pa;
    const float* wp = &W[(size_t)(n0 + lrow) * K + k0 + lk];
    float4 w0 = *reinterpret_cast<const float4*>(wp);
    float4 w1 = *reinterpret_cast<const float4*>(wp + 4);
    uint4 pw;
    pw.x = f2bf_rne(w0.x) | (f2bf_rne(w0.y) << 16);
    pw.y = f2bf_rne(w0.z) | (f2bf_rne(w0.w) << 16);
    pw.z = f2bf_rne(w1.x) | (f2bf_rne(w1.y) << 16);
    pw.w = f2bf_rne(w1.z) | (f2bf_rne(w1.w) << 16);
    *reinterpret_cast<uint4*>(&Ws[lrow][lk]) = pw;
    __syncthreads();
    s16x8 av0 = *reinterpret_cast<const s16x8*>(&As[wm + fr][fk]);
    s16x8 av1 = *reinterpret_cast<const s16x8*>(&As[wm + 16 + fr][fk]);
    s16x8 bv0 = *reinterpret_cast<const s16x8*>(&Ws[wn + fr][fk]);
    s16x8 bv1 = *reinterpret_cast<const s16x8*>(&Ws[wn + 16 + fr][fk]);
    acc[0][0] = __builtin_amdgcn_mfma_f32_16x16x32_bf16(av0, bv0, acc[0][0], 0, 0, 0);
    acc[0][1] = __builtin_amdgcn_mfma_f32_16x16x32_bf16(av0, bv1, acc[0][1], 0, 0, 0);
    acc[1][0] = __builtin_amdgcn_mfma_f32_16x16x32_bf16(av1, bv0, acc[1][0], 0, 0, 0);
    acc[1][1] = __builtin_amdgcn_mfma_f32_16x16x32_bf16(av1, bv1, acc[1][1], 0, 0, 0);
    __syncthreads();
  }
  const int cc = lane & 15, cr = (lane >> 4) * 4;
#pragma unroll
  for (int mi = 0; mi < 2; mi++){
#pragma unroll
    for (int ni = 0; ni < 2; ni++){
      int n = n0 + wn + ni * 16 + cc;
      float bn = bia[n];
#pragma unroll
      for (int r = 0; r < 4; r++){
        int m = m0 + wm + mi * 16 + cr + r;
        if (m < M) C[(size_t)m * N + n] = alpha * (acc[mi][ni][r] + bn);
      }
    }
  }
}

// ---- posconv via MFMA ----
__global__ void posconv_mfma(const float* __restrict__ x, const bf16* __restrict__ wpos,
                             const float* __restrict__ bias, float* __restrict__ xc){
  const int t0 = blockIdx.x * 64, g = blockIdx.y, b = blockIdx.z;
  __shared__ bf16 As[64][40];
  __shared__ float xw[224];
  const int tid = threadIdx.x, wid = tid >> 6, lane = tid & 63;
  const int wm = (wid >> 1) * 32, wn = (wid & 1) * 32;
  const int lrow = tid >> 2, lk = (tid & 3) * 8;
  const int fr = lane & 15, fk = (lane >> 4) * 8;
  f32x4 acc[2][2] = {};
  for (int ci = 0; ci < 48; ci++){
    for (int idx = tid; idx < 191; idx += 256){
      int p = t0 - 64 + idx;
      xw[idx] = (p >= 0 && p < SEQ) ? x[((size_t)(b * SEQ + p)) * DMODEL + g * 48 + ci] : 0.f;
    }
    for (int kk = 0; kk < 128; kk += 32){
      uint4 wa = make_uint4(0, 0, 0, 0);
      if (lrow < 48)
        wa = *reinterpret_cast<const uint4*>(&wpos[(size_t)(g * 48 + lrow) * 6144 + ci * 128 + kk + lk]);
      *reinterpret_cast<uint4*>(&As[lrow][lk]) = wa;
      __syncthreads();
      auto bfragp = [&](int tr)->s16x8{
        int base = tr + kk + fk;
        s16x8 r;
#pragma unroll
        for (int j = 0; j < 8; j++) r[j] = (short)f2bf_rne(xw[base + j]);
        return r;
      };
      s16x8 a0 = *reinterpret_cast<const s16x8*>(&As[wm + fr][fk]);
      s16x8 a1 = *reinterpret_cast<const s16x8*>(&As[wm + 16 + fr][fk]);
      s16x8 b0 = bfragp(wn + fr);
      s16x8 b1 = bfragp(wn + 16 + fr);
      acc[0][0] = __builtin_amdgcn_mfma_f32_16x16x32_bf16(a0, b0, acc[0][0], 0, 0, 0);
      acc[0][1] = __builtin_amdgcn_mfma_f32_16x16x32_bf16(a0, b1, acc[0][1], 0, 0, 0);
      acc[1][0] = __builtin_amdgcn_mfma_f32_16x16x32_bf16(a1, b0, acc[1][0], 0, 0, 0);
      acc[1][1] = __builtin_amdgcn_mfma_f32_16x16x32_bf16(a1, b1, acc[1][1], 0, 0, 0);
      __syncthreads();
    }
  }
  const int cc = lane & 15, cr = (lane >> 4) * 4;
#pragma unroll
  for (int mi = 0; mi < 2; mi++){
#pragma unroll
    for (int ni = 0; ni < 2; ni++){
      int t = t0 + wn + ni * 16 + cc;
      if (t >= SEQ) continue;
#pragma unroll
      for (int r = 0; r < 4; r++){
        int cop = wm + mi * 16 + cr + r;
        if (cop < 48){
          int co = g * 48 + cop;
          xc[((size_t)(b * SEQ + t)) * DMODEL + co] = acc[mi][ni][r] + bias[co];
        }
      }
    }
  }
}

// ---- qk via MFMA ----
__global__ void qk_mfma(const float* __restrict__ q, const float* __restrict__ k,
                        float* __restrict__ sc){
  const int bh = blockIdx.z, b = bh / NHEAD, h = bh % NHEAD;
  const int m0 = blockIdx.y * 64, n0 = blockIdx.x * 64;
  const float* A  = q + (size_t)b * SEQ * DMODEL + h * DHEAD;
  const float* Bp = k + (size_t)b * SEQ * DMODEL + h * DHEAD;
  __shared__ bf16 As[64][40];
  __shared__ bf16 Ws[64][40];
  const int tid = threadIdx.x, wid = tid >> 6, lane = tid & 63;
  const int wm = (wid >> 1) * 32, wn = (wid & 1) * 32;
  const int lrow = tid >> 2, lk = (tid & 3) * 8;
  const int fr = lane & 15, fk = (lane >> 4) * 8;
  f32x4 acc[2][2] = {};
  for (int k0 = 0; k0 < 64; k0 += 32){
    float4 a0 = make_float4(0.f,0.f,0.f,0.f), a1 = make_float4(0.f,0.f,0.f,0.f);
    if (m0 + lrow < SEQ){
      const float* ap = &A[(size_t)(m0 + lrow) * DMODEL + k0 + lk];
      a0 = *reinterpret_cast<const float4*>(ap);
      a1 = *reinterpret_cast<const float4*>(ap + 4);
    }
    uint4 pa;
    pa.x = f2bf_rne(a0.x) | (f2bf_rne(a0.y) << 16);
    pa.y = f2bf_rne(a0.z) | (f2bf_rne(a0.w) << 16);
    pa.z = f2bf_rne(a1.x) | (f2bf_rne(a1.y) << 16);
    pa.w = f2bf_rne(a1.z) | (f2bf_rne(a1.w) << 16);
    *reinterpret_cast<uint4*>(&As[lrow][lk]) = pa;
    float4 w0 = make_float4(0.f,0.f,0.f,0.f), w1 = make_float4(0.f,0.f,0.f,0.f);
    if (n0 + lrow < SEQ){
      const float* wp = &Bp[(size_t)(n0 + lrow) * DMODEL + k0 + lk];
      w0 = *reinterpret_cast<const float4*>(wp);
      w1 = *reinterpret_cast<const float4*>(wp + 4);
    }
    uint4 pw;
    pw.x = f2bf_rne(w0.x) | (f2bf_rne(w0.y) << 16);
    pw.y = f2bf_rne(w0.z) | (f2bf_rne(w0.w) << 16);
    pw.z = f2bf_rne(w1.x) | (f2bf_rne(w1.y) << 16);
    pw.w = f2bf_rne(w1.z) | (f2bf_rne(w1.w) << 16);
    *reinterpret_cast<uint4*>(&Ws[lrow][lk]) = pw;
    __syncthreads();
    s16x8 av0 = *reinterpret_cast<const s16x8*>(&As[wm + fr][fk]);
    s16x8 av1 = *reinterpret_cast<const s16x8*>(&As[wm + 16 + fr][fk]);
    s16x8 bv0 = *reinterpret_cast<const s16x8*>(&Ws[wn + fr][fk]);
    s16x8 bv1 = *reinterpret_cast<const s16x8*>(&Ws[wn + 16 + fr][fk]);
    acc[0][0] = __builtin_amdgcn_mfma_f32_16x16x32_bf16(av0, bv0, acc[0][0], 0, 0, 0);
    acc[0][1] = __builtin_amdgcn_mfma_f32_16x16x32_bf16(av0, bv1, acc[0][1], 0, 0, 0);
    acc[1][0] = __builtin_amdgcn_mfma_f32_16x16x32_bf16(av1, bv0, acc[1][0], 0, 0, 0);
    acc[1][1] = __builtin_amdgcn_mfma_f32_16x16x32_bf16(av1, bv1, acc[1][1], 0, 0, 0);
    __syncthreads();
  }
  const int cc = lane & 15, cr = (lane >> 4) * 4;
  float* scb = sc + (size_t)bh * SEQ * SP;
#pragma unroll
  for (int mi = 0; mi < 2; mi++){
#pragma unroll
    for (int ni = 0; ni < 2; ni++){
      int j = n0 + wn + ni * 16 + cc;
#pragma unroll
      for (int r = 0; r < 4; r++){
        int i = m0 + wm + mi * 16 + cr + r;
        if (i < SEQ) scb[(size_t)i * SP + j] = acc[mi][ni][r];
      }
    }
  }
}

// ---- V transpose: vt[bh][d][j(512)] with zero pad ----
__global__ void vtrans_kernel(const float* __restrict__ v, float* __restrict__ vt){
  int idx = blockIdx.x * 256 + threadIdx.x;
  if (idx >= 48 * 64 * SP) return;
  int j = idx & (SP - 1), d = (idx >> 9) & 63, bh = idx >> 15;
  int b = bh / NHEAD, h = bh % NHEAD;
  vt[idx] = (j < SEQ) ? v[((size_t)(b * SEQ + j)) * DMODEL + h * DHEAD + d] : 0.f;
}

// ---- pv via MFMA ----
__global__ void pv_mfma(const float* __restrict__ attn, const float* __restrict__ vt,
                        float* __restrict__ ctx){
  const int bh = blockIdx.y, b = bh / NHEAD, h = bh % NHEAD;
  const int m0 = blockIdx.x * 64;
  const float* A  = attn + (size_t)bh * SEQ * SP;
  const float* Bp = vt + (size_t)bh * 64 * SP;
  __shared__ bf16 As[64][40];
  __shared__ bf16 Ws[64][40];
  const int tid = threadIdx.x, wid = tid >> 6, lane = tid & 63;
  const int wm = (wid >> 1) * 32, wn = (wid & 1) * 32;
  const int lrow = tid >> 2, lk = (tid & 3) * 8;
  const int fr = lane & 15, fk = (lane >> 4) * 8;
  f32x4 acc[2][2] = {};
  for (int k0 = 0; k0 < SP; k0 += 32){
    float4 a0 = make_float4(0.f,0.f,0.f,0.f), a1 = make_float4(0.f,0.f,0.f,0.f);
    if (m0 + lrow < SEQ){
      const float* ap = &A[(size_t)(m0 + lrow) * SP + k0 + lk];
      a0 = *reinterpret_cast<const float4*>(ap);
      a1 = *reinterpret_cast<const float4*>(ap + 4);
    }
    uint4 pa;
    pa.x = f2bf_rne(a0.x) | (f2bf_rne(a0.y) << 16);
    pa.y = f2bf_rne(a0.z) | (f2bf_rne(a0.w) << 16);
    pa.z = f2bf_rne(a1.x) | (f2bf_rne(a1.y) << 16);
    pa.w = f2bf_rne(a1.z) | (f2bf_rne(a1.w) << 16);
    *reinterpret_cast<uint4*>(&As[lrow][lk]) = pa;
    const float* wp = &Bp[(size_t)lrow * SP + k0 + lk];
    float4 w0 = *reinterpret_cast<const float4*>(wp);
    float4 w1 = *reinterpret_cast<const float4*>(wp + 4);
    uint4 pw;
    pw.x = f2bf_rne(w0.x) | (f2bf_rne(w0.y) << 16);
    pw.y = f2bf_rne(w0.z) | (f2bf_rne(w0.w) << 16);
    pw.z = f2bf_rne(w1.x) | (f2bf_rne(w1.y) << 16);
    pw.w = f2bf_rne(w1.z) | (f2bf_rne(w1.w) << 16);
    *reinterpret_cast<uint4*>(&Ws[lrow][lk]) = pw;
    __syncthreads();
    s16x8 av0 = *reinterpret_cast<const s16x8*>(&As[wm + fr][fk]);
    s16x8 av1 = *reinterpret_cast<const s16x8*>(&As[wm + 16 + fr][fk]);
    s16x8 bv0 = *reinterpret_cast<const s16x8*>(&Ws[wn + fr][fk]);
    s16x8 bv1 = *reinterpret_cast<const s16x8*>(&Ws[wn + 16 + fr][fk]);
    acc[0][0] = __builtin_amdgcn_mfma_f32_16x16x32_bf16(av0, bv0, acc[0][0], 0, 0, 0);
    acc[0][1] = __builtin_amdgcn_mfma_f32_16x16x32_bf16(av0, bv1, acc[0][1], 0, 0, 0);
    acc[1][0] = __builtin_amdgcn_mfma_f32_16x16x32_bf16(av1, bv0, acc[1][0], 0, 0, 0);
    acc[1][1] = __builtin_amdgcn_mfma_f32_16x16x32_bf16(av1, bv1, acc[1][1], 0, 0, 0);
    __syncthreads();
  }
  const int cc = lane & 15, cr = (lane >> 4) * 4;
#pragma unroll
  for (int mi = 0; mi < 2; mi++){
#pragma unroll
    for (int ni = 0; ni < 2; ni++){
      int d = wn + ni * 16 + cc;
      if (d >= 64) continue;
#pragma unroll
      for (int r = 0; r < 4; r++){
        int i = m0 + wm + mi * 16 + cr + r;
        if (i < SEQ)
          ctx[((size_t)(b * SEQ + i)) * DMODEL + h * DHEAD + d] = acc[mi][ni][r];
      }
    }
  }
}

// ---- wave-per-row residual add (+optional GELU) + LayerNorm; 4 rows/block ----
template<int GELU_ADD>
__global__ void add_ln_wave(float* __restrict__ x, const float* __restrict__ add,
                            const float* __restrict__ g, const float* __restrict__ b){
  int row = blockIdx.x * 4 + (threadIdx.x >> 6);
  if (row >= BATCH * SEQ) return;
  int lane = threadIdx.x & 63;
  float* xr = x + (size_t)row * DMODEL;
  const float* ar = add + (size_t)row * DMODEL;
  float buf[12];
  float s = 0.f;
#pragma unroll
  for (int it = 0; it < 12; it++){
    int i = lane + it * 64;
    float v = ar[i];
    if (GELU_ADD) v = gelu_f(v);
    v += xr[i];
    buf[it] = v; s += v;
  }
#pragma unroll
  for (int m = 32; m > 0; m >>= 1) s += __shfl_xor(s, m);
  float mean = s * (1.f / 768.f);
  float q = 0.f;
#pragma unroll
  for (int it = 0; it < 12; it++){ float d = buf[it] - mean; q += d * d; }
#pragma unroll
  for (int m = 32; m > 0; m >>= 1) q += __shfl_xor(q, m);
  float rs = rsqrtf(q * (1.f / 768.f) + 1e-5f);
#pragma unroll
  for (int it = 0; it < 12; it++){
    int i = lane + it * 64;
    xr[i] = (buf[it] - mean) * rs * g[i] + b[i];
  }
}

// ---- T5-style relative position bias table ----
__global__ void relbias_kernel(const float* __restrict__ rel_emb, float* __restrict__ tab){
  int idx = blockIdx.x * 256 + threadIdx.x;
  if (idx >= NREL * NHEAD) return;
  int rr = idx / NHEAD, h = idx - rr * NHEAD;
  int rel = rr - (SEQ - 1);
  int bkt = (rel > 0) ? 160 : 0;
  int n = (rel < 0) ? -rel : rel;
  if (n < 80) bkt += n;
  else {
    int large = 80 + (int)(logf((float)n / 80.f) / logf(10.f) * 80.f);
    bkt += (large < 159) ? large : 159;
  }
  tab[h * NREL + rr] = rel_emb[bkt * NHEAD + h];
}

// ---- gate: block = (gg 8) x (ss 32); grid = B*H*16 ----
__global__ void gate_kernel2(const float* __restrict__ x, const float* __restrict__ gw,
                             const float* __restrict__ gb, const float* __restrict__ ga,
                             float* __restrict__ gate){
  const int blk = blockIdx.x;
  const int st = blk & 15, bh = blk >> 4;
  const int h = bh % NHEAD, b = bh / NHEAD;
  const int ss = threadIdx.x & 31, gg = threadIdx.x >> 5;
  const int s = st * 32 + ss;
  __shared__ float red[8][33];
  float a = 0.f;
  if (s < SEQ){
    const float* xv = x + ((size_t)(b * SEQ + s)) * DMODEL + h * DHEAD;
    const float* wrow = gw + gg * DHEAD;
    a = gb[gg];
#pragma unroll
    for (int d = 0; d < 64; d++) a += xv[d] * wrow[d];
  }
  red[gg][ss] = a; __syncthreads();
  if (threadIdx.x < 32){
    int s2 = st * 32 + threadIdx.x;
    if (s2 < SEQ){
      float a0 = red[0][threadIdx.x] + red[1][threadIdx.x] + red[2][threadIdx.x] + red[3][threadIdx.x];
      float a1 = red[4][threadIdx.x] + red[5][threadIdx.x] + red[6][threadIdx.x] + red[7][threadIdx.x];
      float g0 = 1.f / (1.f + expf(-a0));
      float g1 = 1.f / (1.f + expf(-a1));
      gate[(size_t)bh * SEQ + s2] = g0 * (g1 * ga[h] - 1.f) + 2.f;
    }
  }
}

// ---- wave-per-row softmax with fused gate*relbias; 4 rows/block ----
__global__ void softmax_bias_wave(float* __restrict__ sc, const float* __restrict__ gate,
                                  const float* __restrict__ tab){
  int row = blockIdx.x * 4 + (threadIdx.x >> 6);
  if (row >= BATCH * NHEAD * SEQ) return;
  int lane = threadIdx.x & 63;
  int bh = row / SEQ, i = row - bh * SEQ;
  int h = bh % NHEAD;
  float gt = gate[row];
  float* p = sc + ((size_t)bh * SEQ + i) * SP;
  const float* tb = tab + (size_t)h * NREL + (SEQ - 1 - i);
  float bufr[8];
  float mx = -1e30f;
#pragma unroll
  for (int it = 0; it < 8; it++){
    int j = lane + it * 64;
    float v = (j < SEQ) ? (p[j] + gt * tb[j]) : -1e30f;
    bufr[it] = v; mx = fmaxf(mx, v);
  }
#pragma unroll
  for (int m = 32; m > 0; m >>= 1) mx = fmaxf(mx, __shfl_xor(mx, m));
  float sum = 0.f;
#pragma unroll
  for (int it = 0; it < 8; it++){
    float e = expf(bufr[it] - mx);
    bufr[it] = e; sum += e;
  }
#pragma unroll
  for (int m = 32; m > 0; m >>= 1) sum += __shfl_xor(sum, m);
  float inv = 1.f / sum;
#pragma unroll
  for (int it = 0; it < 8; it++){
    int j = lane + it * 64;
    if (j < SEQ) p[j] = bufr[it] * inv;
  }
}

} // anonymous namespace

extern "C" void kernel_launch(void* const* d_in, const int* in_sizes, int n_in,
                              void* d_out, int out_size, void* d_ws, size_t ws_size,
                              hipStream_t stream){
  (void)ws_size;

  static const int DS[34] = {640000,5120,3145728,1048576,3584,3584,512,512,393216,768,
                             4718592,768,768,768,7077888,9216,7077888,9216,7077888,9216,
                             7077888,9216,6144,96,144,9216,9216,28311552,36864,28311552,
                             9216,9216,9216,3840};
  bool ok = (n_in == 34) && (out_size == BATCH * SEQ * DMODEL);
  if (ok) for (int i = 0; i < 34; i++) if (in_sizes[i] != DS[i]) { ok = false; break; }
  if (!ok){
    fill_f32_kernel<<<(out_size + 255) / 256, 256, 0, stream>>>((float*)d_out, out_size, 1000.0f);
    return;
  }

  const float* src  = (const float*)d_in[0];
  const float* w0   = (const float*)d_in[1];
  const float* w14  = (const float*)d_in[2];
  const float* w56  = (const float*)d_in[3];
  const float* clng = (const float*)d_in[4];
  const float* clnb = (const float*)d_in[5];
  const float* flng = (const float*)d_in[6];
  const float* flnb = (const float*)d_in[7];
  const float* pjw  = (const float*)d_in[8];
  const float* pjb  = (const float*)d_in[9];
  const float* pcw  = (const float*)d_in[10];
  const float* pcb  = (const float*)d_in[11];
  const float* eng  = (const float*)d_in[12];
  const float* enb  = (const float*)d_in[13];
  const float* Wq   = (const float*)d_in[14];
  const float* bq   = (const float*)d_in[15];
  const float* Wk   = (const float*)d_in[16];
  const float* bk   = (const float*)d_in[17];
  const float* Wv   = (const float*)d_in[18];
  const float* bv   = (const float*)d_in[19];
  const float* Wo   = (const float*)d_in[20];
  const float* bo   = (const float*)d_in[21];
  const float* gw   = (const float*)d_in[22];
  const float* gbp  = (const float*)d_in[23];
  const float* ga   = (const float*)d_in[24];
  const float* l1g  = (const float*)d_in[25];
  const float* l1b  = (const float*)d_in[26];
  const float* f1w  = (const float*)d_in[27];
  const float* f1b  = (const float*)d_in[28];
  const float* f2w  = (const float*)d_in[29];
  const float* f2b  = (const float*)d_in[30];
  const float* l2g  = (const float*)d_in[31];
  const float* l2b  = (const float*)d_in[32];
  const float* rel  = (const float*)d_in[33];

  float* x = (float*)d_out;  // residual stream lives in d_out (fp32)

  // workspace (~130 MB)
  float* wsf = (float*)d_ws;
  size_t off = 0;
  auto alloc = [&](size_t n){ float* pp = wsf + off; off += (n + 63) & ~(size_t)63; return pp; };
  const size_t XSZ = (size_t)BATCH * SEQ * DMODEL;
  float* attn = alloc((size_t)BATCH * NHEAD * SEQ * SP);   // 12.26M
  float* ffh  = alloc((size_t)BATCH * SEQ * FFN);          // 6.13M
  float* tmp  = alloc(XSZ);
  float* qb   = alloc(XSZ);
  float* kb   = alloc(XSZ);
  float* vb   = alloc(XSZ);
  float* ctx  = alloc(XSZ);
  float* feat = alloc((size_t)BATCH * SEQ * 512);
  float* c6   = alloc((size_t)512 * SEQ);
  float* gate = alloc((size_t)BATCH * NHEAD * SEQ);
  float* tab  = alloc((size_t)NHEAD * NREL);
  float* vt   = alloc((size_t)48 * 64 * SP);               // 1.57M
  bf16* wposb = (bf16*)alloc((size_t)DMODEL * 48 * 128 / 2);
  // conv ping-pong aliases [attn .. ctx] span (dead during conv phase)
  float* cA = attn;
  float* cB = attn + (size_t)16383488;

  const int Ls[8] = {160000, 31999, 15999, 7999, 3999, 1999, 999, 499};
  const int Mrows = BATCH * SEQ; // 1996

  // ---- conv feature extractor: per batch, full length, MFMA stages ----
  for (int b = 0; b < BATCH; b++){
    conv0_kernel<<<(512 * Ls[1] + 255) / 256, 256, 0, stream>>>(src + (size_t)b * T_IN, w0, cA, Ls[1]);
    ln_gelu_ch2_kernel<<<(Ls[1] + 31) / 32, 256, 0, stream>>>(cA, clng, clnb, Ls[1]);
    float* bufs[2] = {cA, cB};
    for (int st = 1; st <= 6; st++){
      const float* inb = bufs[(st + 1) & 1];
      float* outb      = (st == 6) ? c6 : bufs[st & 1];
      int Lin = Ls[st], Lout = Ls[st + 1];
      int oLd = (st == 6) ? SEQ : Lout;
      dim3 grd((Lout + 63) / 64, 8);
      if (st <= 4)
        conv_mfma_kernel<3><<<grd, 256, 0, stream>>>(inb, w14 + (size_t)(st - 1) * 512 * 512 * 3, outb, Lin, Lout, oLd);
      else
        conv_mfma_kernel<2><<<grd, 256, 0, stream>>>(inb, w56 + (size_t)(st - 5) * 512 * 512 * 2, outb, Lin, Lout, oLd);
      if (st < 6)
        ln_gelu_ch2_kernel<<<(Lout + 31) / 32, 256, 0, stream>>>(outb, clng + st * 512, clnb + st * 512, Lout);
    }
    ln_gelu_ch2_kernel<<<(SEQ + 31) / 32, 256, 0, stream>>>(c6, clng + 6 * 512, clnb + 6 * 512, SEQ);
    featln_transpose_kernel<<<(SEQ + 255) / 256, 256, 0, stream>>>(c6, flng, flnb, feat + (size_t)b * SEQ * 512);
  }

  // post_extract_proj
  gemm_mfma_f32<0><<<dim3(DMODEL / 64, (Mrows + 63) / 64), 256, 0, stream>>>(feat, pjw, pjb, x, Mrows, DMODEL, 512, 1.0f);
  // positional conv (MFMA) + gelu-residual + encoder LN
  f2bf_kernel<<<(4718592 + 255) / 256, 256, 0, stream>>>(pcw, wposb, 4718592);
  posconv_mfma<<<dim3(8, 16, BATCH), 256, 0, stream>>>(x, wposb, pcb, tmp);
  add_ln_wave<1><<<(Mrows + 3) / 4, 256, 0, stream>>>(x, tmp, eng, enb);
  relbias_kernel<<<(NREL * NHEAD + 255) / 256, 256, 0, stream>>>(rel, tab);

  const size_t WQK = (size_t)DMODEL * DMODEL;
  const size_t WF  = (size_t)FFN * DMODEL;
  for (int l = 0; l < NLAYER; l++){
    gate_kernel2<<<48 * 16, 256, 0, stream>>>(
        x, gw + (size_t)l * 8 * DHEAD, gbp + l * 8, ga + l * NHEAD, gate);
    gemm_qkv_mfma<<<dim3(12, 32, 3), 256, 0, stream>>>(
        x, Wq + l * WQK, Wk + l * WQK, Wv + l * WQK,
        bq + l * DMODEL, bk + l * DMODEL, bv + l * DMODEL, qb, kb, vb, Mrows);
    vtrans_kernel<<<(48 * 64 * SP + 255) / 256, 256, 0, stream>>>(vb, vt);
    qk_mfma<<<dim3(8, 8, BATCH * NHEAD), 256, 0, stream>>>(qb, kb, attn);
    softmax_bias_wave<<<(BATCH * NHEAD * SEQ + 3) / 4, 256, 0, stream>>>(attn, gate, tab);
    pv_mfma<<<dim3(8, BATCH * NHEAD), 256, 0, stream>>>(attn, vt, ctx);
    gemm_mfma_f32<0><<<dim3(12, 32), 256, 0, stream>>>(ctx, Wo + l * WQK, bo + l * DMODEL, tmp, Mrows, DMODEL, DMODEL, 1.0f);
    add_ln_wave<0><<<(Mrows + 3) / 4, 256, 0, stream>>>(x, tmp, l1g + l * DMODEL, l1b + l * DMODEL);
    gemm_mfma_f32<1><<<dim3(FFN / 64, 32), 256, 0, stream>>>(x, f1w + l * WF, f1b + l * FFN, ffh, Mrows, FFN, DMODEL, 1.0f);
    gemm_mfma_f32<0><<<dim3(12, 32), 256, 0, stream>>>(ffh, f2w + l * WF, f2b + l * DMODEL, tmp, Mrows, DMODEL, FFN, 1.0f);
    add_ln_wave<0><<<(Mrows + 3) / 4, 256, 0, stream>>>(x, tmp, l2g + l * DMODEL, l2b + l * DMODEL);
  }
  // result is already in d_out
}

// Round 15
// 7724.463 us; speedup vs baseline: 11.7104x; 1.0264x over previous
//
#include <hip/hip_runtime.h>
#include <hip/hip_bf16.h>
#include <math.h>

namespace {

constexpr int BATCH  = 4;
constexpr int T_IN   = 160000;
constexpr int DMODEL = 768;
constexpr int NHEAD  = 12;
constexpr int DHEAD  = 64;
constexpr int FFN    = 3072;
constexpr int NLAYER = 12;
constexpr int SEQ    = 499;
constexpr int SP     = 512;
constexpr int NREL   = 2 * SEQ - 1;

typedef __hip_bfloat16 bf16;
using f32x4 = __attribute__((ext_vector_type(4))) float;
using s16x8 = __attribute__((ext_vector_type(8))) short;

__device__ __forceinline__ float gelu_f(float x){
  return 0.5f * x * (1.0f + erff(x * 0.70710678118654752f));
}

__device__ __forceinline__ unsigned f2bf_rne(float f){
  unsigned u = __float_as_uint(f);
  return (u + 0x7FFFu + ((u >> 16) & 1u)) >> 16;
}

__global__ void fill_f32_kernel(float* __restrict__ out, int n, float val){
  int i = blockIdx.x * 256 + threadIdx.x;
  if (i < n) out[i] = val;
}

__global__ void f2bf_kernel(const float* __restrict__ in, bf16* __restrict__ out, int n){
  int i = blockIdx.x * 256 + threadIdx.x;
  if (i < n) out[i] = __float2bfloat16(in[i]);
}

// ---- conv stage 0: k=10, s=5 ----
__global__ void conv0_kernel(const float* __restrict__ src, const float* __restrict__ w,
                             float* __restrict__ out, int Lout){
  int idx = blockIdx.x * 256 + threadIdx.x;
  if (idx >= 512 * Lout) return;
  int c = idx / Lout, t = idx - c * Lout;
  const float* wr = w + c * 10;
  const float* s  = src + t * 5;
  float acc = 0.f;
#pragma unroll
  for (int k = 0; k < 10; k++) acc += wr[k] * s[k];
  out[idx] = acc;
}

// ---- 2D-parallel LayerNorm over channels + GELU, layout (512, Lt), in place ----
__global__ void ln_gelu_ch2_kernel(float* __restrict__ x, const float* __restrict__ g,
                                   const float* __restrict__ b, int Lt){
  const int tid = threadIdx.x;
  const int tt = tid & 31, tc = tid >> 5;
  const int t = blockIdx.x * 32 + tt;
  __shared__ float sred[8][33], qred[8][33];
  __shared__ float mrow[32], rrow[32];
  float s = 0.f, q = 0.f;
  if (t < Lt){
    const float* xc = x + (size_t)(tc * 64) * Lt + t;
#pragma unroll 8
    for (int j = 0; j < 64; j++){ float v = xc[(size_t)j * Lt]; s += v; q += v * v; }
  }
  sred[tc][tt] = s; qred[tc][tt] = q; __syncthreads();
  if (tid < 32){
    float ss = 0.f, qq = 0.f;
#pragma unroll
    for (int c = 0; c < 8; c++){ ss += sred[c][tid]; qq += qred[c][tid]; }
    float m = ss * (1.f / 512.f);
    float var = qq * (1.f / 512.f) - m * m;
    mrow[tid] = m; rrow[tid] = rsqrtf(var + 1e-5f);
  }
  __syncthreads();
  if (t < Lt){
    float m = mrow[tt], rs = rrow[tt];
    float* xc = x + (size_t)(tc * 64) * Lt + t;
#pragma unroll 8
    for (int j = 0; j < 64; j++){
      int c = tc * 64 + j;
      float v = (xc[(size_t)j * Lt] - m) * rs * g[c] + b[c];
      xc[(size_t)j * Lt] = gelu_f(v);
    }
  }
}

// ---- conv stages 1..6 via MFMA; grid (co, t) so co-blocks sharing input are adjacent ----
template<int KW>
__global__ void conv_mfma_kernel(const float* __restrict__ in, const float* __restrict__ w,
                                 float* __restrict__ out, int Lin, int Lout, int outLd){
  constexpr int SPAN = 128 + KW;
  __shared__ bf16 As[64][40];
  __shared__ float ins[8][136];
  const int tid = threadIdx.x, wid = tid >> 6, lane = tid & 63;
  const int co0 = blockIdx.x * 64, t0 = blockIdx.y * 64;   // SWAPPED for L3 locality
  const int wm = (wid >> 1) * 32, wn = (wid & 1) * 32;
  const int lrow = tid >> 2, lk = (tid & 3) * 8;
  const int fr = lane & 15, fk = (lane >> 4) * 8;
  const int cir = lk >> 2;
  f32x4 acc[2][2] = {};
  for (int ci0 = 0; ci0 < 512; ci0 += 8){
    {
      uint4 pw;
      if (KW == 3){
        const float* wp = w + (size_t)(co0 + lrow) * 1536 + (ci0 + cir) * 3;
        float2 f01 = *reinterpret_cast<const float2*>(wp);
        float2 f23 = *reinterpret_cast<const float2*>(wp + 2);
        float2 f45 = *reinterpret_cast<const float2*>(wp + 4);
        pw.x = f2bf_rne(f01.x) | (f2bf_rne(f01.y) << 16);
        pw.y = f2bf_rne(f23.x);
        pw.z = f2bf_rne(f23.y) | (f2bf_rne(f45.x) << 16);
        pw.w = f2bf_rne(f45.y);
      } else {
        const float* wp = w + (size_t)(co0 + lrow) * 1024 + (ci0 + cir) * 2;
        float4 f = *reinterpret_cast<const float4*>(wp);
        pw.x = f2bf_rne(f.x) | (f2bf_rne(f.y) << 16);
        pw.y = 0u;
        pw.z = f2bf_rne(f.z) | (f2bf_rne(f.w) << 16);
        pw.w = 0u;
      }
      *reinterpret_cast<uint4*>(&As[lrow][lk]) = pw;
    }
    for (int idx = tid; idx < 8 * SPAN; idx += 256){
      int ci = idx / SPAN, j = idx - ci * SPAN;
      int gp = t0 * 2 + j;
      ins[ci][j] = (gp < Lin) ? in[(size_t)(ci0 + ci) * Lin + gp] : 0.f;
    }
    __syncthreads();
    const int cia = fk >> 2;
    auto bfrag = [&](int tr)->s16x8 {
      float2 pa0 = *reinterpret_cast<const float2*>(&ins[cia][2 * tr]);
      float2 pb0 = *reinterpret_cast<const float2*>(&ins[cia + 1][2 * tr]);
      s16x8 r;
      r[0] = (short)f2bf_rne(pa0.x);
      r[1] = (short)f2bf_rne(pa0.y);
      r[2] = (KW > 2) ? (short)f2bf_rne(ins[cia][2 * tr + 2]) : (short)0;
      r[3] = 0;
      r[4] = (short)f2bf_rne(pb0.x);
      r[5] = (short)f2bf_rne(pb0.y);
      r[6] = (KW > 2) ? (short)f2bf_rne(ins[cia + 1][2 * tr + 2]) : (short)0;
      r[7] = 0;
      return r;
    };
    s16x8 a0 = *reinterpret_cast<const s16x8*>(&As[wm + fr][fk]);
    s16x8 a1 = *reinterpret_cast<const s16x8*>(&As[wm + 16 + fr][fk]);
    s16x8 b0 = bfrag(wn + fr);
    s16x8 b1 = bfrag(wn + 16 + fr);
    acc[0][0] = __builtin_amdgcn_mfma_f32_16x16x32_bf16(a0, b0, acc[0][0], 0, 0, 0);
    acc[0][1] = __builtin_amdgcn_mfma_f32_16x16x32_bf16(a0, b1, acc[0][1], 0, 0, 0);
    acc[1][0] = __builtin_amdgcn_mfma_f32_16x16x32_bf16(a1, b0, acc[1][0], 0, 0, 0);
    acc[1][1] = __builtin_amdgcn_mfma_f32_16x16x32_bf16(a1, b1, acc[1][1], 0, 0, 0);
    __syncthreads();
  }
  const int cc = lane & 15, cr = (lane >> 4) * 4;
#pragma unroll
  for (int mi = 0; mi < 2; mi++){
#pragma unroll
    for (int ni = 0; ni < 2; ni++){
      int t = t0 + wn + ni * 16 + cc;
      if (t >= Lout) continue;
#pragma unroll
      for (int r = 0; r < 4; r++){
        int co = co0 + wm + mi * 16 + cr + r;
        out[(size_t)co * outLd + t] = acc[mi][ni][r];
      }
    }
  }
}

// ---- final feature LN + transpose (512,S)->(S,512) ----
__global__ void featln_transpose_kernel(const float* __restrict__ xin,
                                        const float* __restrict__ g, const float* __restrict__ b,
                                        float* __restrict__ feat){
  int t = blockIdx.x * 256 + threadIdx.x;
  if (t >= SEQ) return;
  float s = 0.f, sq = 0.f;
  for (int c = 0; c < 512; c++){ float v = xin[c * SEQ + t]; s += v; sq += v * v; }
  float m = s * (1.f / 512.f), var = sq * (1.f / 512.f) - m * m, rs = rsqrtf(var + 1e-5f);
  for (int c = 0; c < 512; c++)
    feat[t * 512 + c] = (xin[c * SEQ + t] - m) * rs * g[c] + b[c];
}

// ---- MFMA GEMM, fp32 inputs (bf16 cast fused): C = act(alpha*(A @ W^T + bias)) ----
template<int ACT>
__global__ void gemm_mfma_f32(const float* __restrict__ A, const float* __restrict__ W,
                              const float* __restrict__ bias, float* __restrict__ C,
                              int M, int N, int K, float alpha){
  __shared__ bf16 As[64][40];
  __shared__ bf16 Ws[64][40];
  const int tid = threadIdx.x;
  const int wid = tid >> 6, lane = tid & 63;
  const int m0 = blockIdx.y * 64, n0 = blockIdx.x * 64;
  const int wm = (wid >> 1) * 32, wn = (wid & 1) * 32;
  const int lrow = tid >> 2;
  const int lk   = (tid & 3) * 8;
  const int fr = lane & 15, fk = (lane >> 4) * 8;
  f32x4 acc[2][2] = {};
  for (int k0 = 0; k0 < K; k0 += 32){
    float4 a0 = make_float4(0.f,0.f,0.f,0.f), a1 = make_float4(0.f,0.f,0.f,0.f);
    int gm = m0 + lrow;
    if (gm < M){
      const float* ap = &A[(size_t)gm * K + k0 + lk];
      a0 = *reinterpret_cast<const float4*>(ap);
      a1 = *reinterpret_cast<const float4*>(ap + 4);
    }
    uint4 pa;
    pa.x = f2bf_rne(a0.x) | (f2bf_rne(a0.y) << 16);
    pa.y = f2bf_rne(a0.z) | (f2bf_rne(a0.w) << 16);
    pa.z = f2bf_rne(a1.x) | (f2bf_rne(a1.y) << 16);
    pa.w = f2bf_rne(a1.z) | (f2bf_rne(a1.w) << 16);
    *reinterpret_cast<uint4*>(&As[lrow][lk]) = pa;
    const float* wp = &W[(size_t)(n0 + lrow) * K + k0 + lk];
    float4 w0 = *reinterpret_cast<const float4*>(wp);
    float4 w1 = *reinterpret_cast<const float4*>(wp + 4);
    uint4 pw;
    pw.x = f2bf_rne(w0.x) | (f2bf_rne(w0.y) << 16);
    pw.y = f2bf_rne(w0.z) | (f2bf_rne(w0.w) << 16);
    pw.z = f2bf_rne(w1.x) | (f2bf_rne(w1.y) << 16);
    pw.w = f2bf_rne(w1.z) | (f2bf_rne(w1.w) << 16);
    *reinterpret_cast<uint4*>(&Ws[lrow][lk]) = pw;
    __syncthreads();
    s16x8 av0 = *reinterpret_cast<const s16x8*>(&As[wm + fr][fk]);
    s16x8 av1 = *reinterpret_cast<const s16x8*>(&As[wm + 16 + fr][fk]);
    s16x8 bv0 = *reinterpret_cast<const s16x8*>(&Ws[wn + fr][fk]);
    s16x8 bv1 = *reinterpret_cast<const s16x8*>(&Ws[wn + 16 + fr][fk]);
    acc[0][0] = __builtin_amdgcn_mfma_f32_16x16x32_bf16(av0, bv0, acc[0][0], 0, 0, 0);
    acc[0][1] = __builtin_amdgcn_mfma_f32_16x16x32_bf16(av0, bv1, acc[0][1], 0, 0, 0);
    acc[1][0] = __builtin_amdgcn_mfma_f32_16x16x32_bf16(av1, bv0, acc[1][0], 0, 0, 0);
    acc[1][1] = __builtin_amdgcn_mfma_f32_16x16x32_bf16(av1, bv1, acc[1][1], 0, 0, 0);
    __syncthreads();
  }
  const int cc = lane & 15, cr = (lane >> 4) * 4;
#pragma unroll
  for (int mi = 0; mi < 2; mi++){
#pragma unroll
    for (int ni = 0; ni < 2; ni++){
      int n = n0 + wn + ni * 16 + cc;
      float bn = bias[n];
#pragma unroll
      for (int r = 0; r < 4; r++){
        int m = m0 + wm + mi * 16 + cr + r;
        if (m < M){
          float v = alpha * (acc[mi][ni][r] + bn);
          if (ACT == 1) v = gelu_f(v);
          C[(size_t)m * N + n] = v;
        }
      }
    }
  }
}

// ---- fused QKV (z selects Wq/Wk/Wv) ----
__global__ void gemm_qkv_mfma(const float* __restrict__ A,
                              const float* __restrict__ Wq, const float* __restrict__ Wk,
                              const float* __restrict__ Wv,
                              const float* __restrict__ bqv, const float* __restrict__ bkv,
                              const float* __restrict__ bvv,
                              float* __restrict__ qb, float* __restrict__ kb,
                              float* __restrict__ vb, int M){
  const int z = blockIdx.z;
  const float* W   = (z == 0) ? Wq : (z == 1) ? Wk : Wv;
  const float* bia = (z == 0) ? bqv : (z == 1) ? bkv : bvv;
  float* C         = (z == 0) ? qb : (z == 1) ? kb : vb;
  const float alpha = (z == 0) ? 0.125f : 1.0f;
  const int K = DMODEL, N = DMODEL;
  __shared__ bf16 As[64][40];
  __shared__ bf16 Ws[64][40];
  const int tid = threadIdx.x;
  const int wid = tid >> 6, lane = tid & 63;
  const int m0 = blockIdx.y * 64, n0 = blockIdx.x * 64;
  const int wm = (wid >> 1) * 32, wn = (wid & 1) * 32;
  const int lrow = tid >> 2;
  const int lk   = (tid & 3) * 8;
  const int fr = lane & 15, fk = (lane >> 4) * 8;
  f32x4 acc[2][2] = {};
  for (int k0 = 0; k0 < K; k0 += 32){
    float4 a0 = make_float4(0.f,0.f,0.f,0.f), a1 = make_float4(0.f,0.f,0.f,0.f);
    int gm = m0 + lrow;
    if (gm < M){
      const float* ap = &A[(size_t)gm * K + k0 + lk];
      a0 = *reinterpret_cast<const float4*>(ap);
      a1 = *reinterpret_cast<const float4*>(ap + 4);
    }
    uint4 pa;
    pa.x = f2bf_rne(a0.x) | (f2bf_rne(a0.y) << 16);
    pa.y = f2bf_rne(a0.z) | (f2bf_rne(a0.w) << 16);
    pa.z = f2bf_rne(a1.x) | (f2bf_rne(a1.y) << 16);
    pa.w = f2bf_rne(a1.z) | (f2bf_rne(a1.w) << 16);
    *reinterpret_cast<uint4*>(&As[lrow][lk]) = pa;
    const float* wp = &W[(size_t)(n0 + lrow) * K + k0 + lk];
    float4 w0 = *reinterpret_cast<const float4*>(wp);
    float4 w1 = *reinterpret_cast<const float4*>(wp + 4);
    uint4 pw;
    pw.x = f2bf_rne(w0.x) | (f2bf_rne(w0.y) << 16);
    pw.y = f2bf_rne(w0.z) | (f2bf_rne(w0.w) << 16);
    pw.z = f2bf_rne(w1.x) | (f2bf_rne(w1.y) << 16);
    pw.w = f2bf_rne(w1.z) | (f2bf_rne(w1.w) << 16);
    *reinterpret_cast<uint4*>(&Ws[lrow][lk]) = pw;
    __syncthreads();
    s16x8 av0 = *reinterpret_cast<const s16x8*>(&As[wm + fr][fk]);
    s16x8 av1 = *reinterpret_cast<const s16x8*>(&As[wm + 16 + fr][fk]);
    s16x8 bv0 = *reinterpret_cast<const s16x8*>(&Ws[wn + fr][fk]);
    s16x8 bv1 = *reinterpret_cast<const s16x8*>(&Ws[wn + 16 + fr][fk]);
    acc[0][0] = __builtin_amdgcn_mfma_f32_16x16x32_bf16(av0, bv0, acc[0][0], 0, 0, 0);
    acc[0][1] = __builtin_amdgcn_mfma_f32_16x16x32_bf16(av0, bv1, acc[0][1], 0, 0, 0);
    acc[1][0] = __builtin_amdgcn_mfma_f32_16x16x32_bf16(av1, bv0, acc[1][0], 0, 0, 0);
    acc[1][1] = __builtin_amdgcn_mfma_f32_16x16x32_bf16(av1, bv1, acc[1][1], 0, 0, 0);
    __syncthreads();
  }
  const int cc = lane & 15, cr = (lane >> 4) * 4;
#pragma unroll
  for (int mi = 0; mi < 2; mi++){
#pragma unroll
    for (int ni = 0; ni < 2; ni++){
      int n = n0 + wn + ni * 16 + cc;
      float bn = bia[n];
#pragma unroll
      for (int r = 0; r < 4; r++){
        int m = m0 + wm + mi * 16 + cr + r;
        if (m < M) C[(size_t)m * N + n] = alpha * (acc[mi][ni][r] + bn);
      }
    }
  }
}

// ---- posconv via MFMA ----
__global__ void posconv_mfma(const float* __restrict__ x, const bf16* __restrict__ wpos,
                             const float* __restrict__ bias, float* __restrict__ xc){
  const int t0 = blockIdx.x * 64, g = blockIdx.y, b = blockIdx.z;
  __shared__ bf16 As[64][40];
  __shared__ float xw[224];
  const int tid = threadIdx.x, wid = tid >> 6, lane = tid & 63;
  const int wm = (wid >> 1) * 32, wn = (wid & 1) * 32;
  const int lrow = tid >> 2, lk = (tid & 3) * 8;
  const int fr = lane & 15, fk = (lane >> 4) * 8;
  f32x4 acc[2][2] = {};
  for (int ci = 0; ci < 48; ci++){
    for (int idx = tid; idx < 191; idx += 256){
      int p = t0 - 64 + idx;
      xw[idx] = (p >= 0 && p < SEQ) ? x[((size_t)(b * SEQ + p)) * DMODEL + g * 48 + ci] : 0.f;
    }
    for (int kk = 0; kk < 128; kk += 32){
      uint4 wa = make_uint4(0, 0, 0, 0);
      if (lrow < 48)
        wa = *reinterpret_cast<const uint4*>(&wpos[(size_t)(g * 48 + lrow) * 6144 + ci * 128 + kk + lk]);
      *reinterpret_cast<uint4*>(&As[lrow][lk]) = wa;
      __syncthreads();
      auto bfragp = [&](int tr)->s16x8{
        int base = tr + kk + fk;
        s16x8 r;
#pragma unroll
        for (int j = 0; j < 8; j++) r[j] = (short)f2bf_rne(xw[base + j]);
        return r;
      };
      s16x8 a0 = *reinterpret_cast<const s16x8*>(&As[wm + fr][fk]);
      s16x8 a1 = *reinterpret_cast<const s16x8*>(&As[wm + 16 + fr][fk]);
      s16x8 b0 = bfragp(wn + fr);
      s16x8 b1 = bfragp(wn + 16 + fr);
      acc[0][0] = __builtin_amdgcn_mfma_f32_16x16x32_bf16(a0, b0, acc[0][0], 0, 0, 0);
      acc[0][1] = __builtin_amdgcn_mfma_f32_16x16x32_bf16(a0, b1, acc[0][1], 0, 0, 0);
      acc[1][0] = __builtin_amdgcn_mfma_f32_16x16x32_bf16(a1, b0, acc[1][0], 0, 0, 0);
      acc[1][1] = __builtin_amdgcn_mfma_f32_16x16x32_bf16(a1, b1, acc[1][1], 0, 0, 0);
      __syncthreads();
    }
  }
  const int cc = lane & 15, cr = (lane >> 4) * 4;
#pragma unroll
  for (int mi = 0; mi < 2; mi++){
#pragma unroll
    for (int ni = 0; ni < 2; ni++){
      int t = t0 + wn + ni * 16 + cc;
      if (t >= SEQ) continue;
#pragma unroll
      for (int r = 0; r < 4; r++){
        int cop = wm + mi * 16 + cr + r;
        if (cop < 48){
          int co = g * 48 + cop;
          xc[((size_t)(b * SEQ + t)) * DMODEL + co] = acc[mi][ni][r] + bias[co];
        }
      }
    }
  }
}

// ---- FUSED attention: per (16 q-rows, bh): QK^T -> softmax(+gate*relbias) -> PV ----
// block 256 threads (4 waves); wave w owns j/d strip w*16 within each 64-tile.
__global__ void attn_fused(const float* __restrict__ q, const float* __restrict__ k,
                           const float* __restrict__ v, const float* __restrict__ gate,
                           const float* __restrict__ tab, float* __restrict__ ctx){
  const int bh = blockIdx.y, b = bh / NHEAD, h = bh % NHEAD;
  const int i0 = blockIdx.x * 16;
  const int tid = threadIdx.x, w = tid >> 6, lane = tid & 63;
  const int fr = lane & 15, fk = (lane >> 4) * 8;
  const int cr = (lane >> 4) * 4;
  __shared__ float sc[16][524];
  __shared__ short qs[16][72];
  __shared__ short kv[64][72];
  // stage Q (16x64) as bf16
  {
    int r = tid >> 4, c = (tid & 15) * 4;
    int gi = i0 + r;
    float4 qv = make_float4(0.f,0.f,0.f,0.f);
    if (gi < SEQ) qv = *reinterpret_cast<const float4*>(&q[((size_t)(b*SEQ+gi))*DMODEL + h*DHEAD + c]);
    uint2 p;
    p.x = f2bf_rne(qv.x) | (f2bf_rne(qv.y) << 16);
    p.y = f2bf_rne(qv.z) | (f2bf_rne(qv.w) << 16);
    *reinterpret_cast<uint2*>(&qs[r][c]) = p;
  }
  // ---- QK phase ----
  for (int j0 = 0; j0 < SP; j0 += 64){
    __syncthreads();
    {
      int jr = tid >> 2, c0 = (tid & 3) * 16;
      int gj = j0 + jr;
      float4 f0 = make_float4(0.f,0.f,0.f,0.f), f1 = f0, f2 = f0, f3 = f0;
      if (gj < SEQ){
        const float* kp = &k[((size_t)(b*SEQ+gj))*DMODEL + h*DHEAD + c0];
        f0 = *reinterpret_cast<const float4*>(kp);
        f1 = *reinterpret_cast<const float4*>(kp + 4);
        f2 = *reinterpret_cast<const float4*>(kp + 8);
        f3 = *reinterpret_cast<const float4*>(kp + 12);
      }
      uint4 pa;
      pa.x = f2bf_rne(f0.x) | (f2bf_rne(f0.y) << 16);
      pa.y = f2bf_rne(f0.z) | (f2bf_rne(f0.w) << 16);
      pa.z = f2bf_rne(f1.x) | (f2bf_rne(f1.y) << 16);
      pa.w = f2bf_rne(f1.z) | (f2bf_rne(f1.w) << 16);
      *reinterpret_cast<uint4*>(&kv[jr][c0]) = pa;
      uint4 pb;
      pb.x = f2bf_rne(f2.x) | (f2bf_rne(f2.y) << 16);
      pb.y = f2bf_rne(f2.z) | (f2bf_rne(f2.w) << 16);
      pb.z = f2bf_rne(f3.x) | (f2bf_rne(f3.y) << 16);
      pb.w = f2bf_rne(f3.z) | (f2bf_rne(f3.w) << 16);
      *reinterpret_cast<uint4*>(&kv[jr][c0 + 8]) = pb;
    }
    __syncthreads();
    f32x4 accqk = {};
#pragma unroll
    for (int kk = 0; kk < 2; kk++){
      s16x8 a = *reinterpret_cast<const s16x8*>(&qs[fr][kk*32 + fk]);
      s16x8 bb = *reinterpret_cast<const s16x8*>(&kv[w*16 + fr][kk*32 + fk]);
      accqk = __builtin_amdgcn_mfma_f32_16x16x32_bf16(a, bb, accqk, 0, 0, 0);
    }
#pragma unroll
    for (int r = 0; r < 4; r++)
      sc[cr + r][j0 + w*16 + fr] = accqk[r];
  }
  __syncthreads();
  // ---- softmax phase: wave w handles rows w*4 .. w*4+3 ----
  for (int r = 0; r < 4; r++){
    int row = w * 4 + r;
    int gi = i0 + row;
    if (gi >= SEQ) continue;
    float gt = gate[(size_t)bh * SEQ + gi];
    const float* tb = tab + (size_t)h * NREL + (SEQ - 1 - gi);
    float vals[8];
    float mx = -1e30f;
#pragma unroll
    for (int it = 0; it < 8; it++){
      int j = lane + it * 64;
      float vv = (j < SEQ) ? (sc[row][j] + gt * tb[j]) : -1e30f;
      vals[it] = vv; mx = fmaxf(mx, vv);
    }
#pragma unroll
    for (int m = 32; m > 0; m >>= 1) mx = fmaxf(mx, __shfl_xor(mx, m));
    float sum = 0.f;
#pragma unroll
    for (int it = 0; it < 8; it++){
      int j = lane + it * 64;
      float e = (j < SEQ) ? expf(vals[it] - mx) : 0.f;
      vals[it] = e; sum += e;
    }
#pragma unroll
    for (int m = 32; m > 0; m >>= 1) sum += __shfl_xor(sum, m);
    float inv = 1.f / sum;
#pragma unroll
    for (int it = 0; it < 8; it++){
      int j = lane + it * 64;
      sc[row][j] = vals[it] * inv;     // zeros for j>=SEQ
    }
  }
  __syncthreads();
  // ---- PV phase: ctx[i][d] = sum_j p[i][j] * v[j][d]; wave w owns d-strip w*16 ----
  f32x4 accpv = {};
  for (int j0 = 0; j0 < SP; j0 += 64){
    __syncthreads();
    {
      int jr = tid >> 2, c0 = (tid & 3) * 16;
      int gj = j0 + jr;
      float4 f0 = make_float4(0.f,0.f,0.f,0.f), f1 = f0, f2 = f0, f3 = f0;
      if (gj < SEQ){
        const float* vp = &v[((size_t)(b*SEQ+gj))*DMODEL + h*DHEAD + c0];
        f0 = *reinterpret_cast<const float4*>(vp);
        f1 = *reinterpret_cast<const float4*>(vp + 4);
        f2 = *reinterpret_cast<const float4*>(vp + 8);
        f3 = *reinterpret_cast<const float4*>(vp + 12);
      }
      uint4 pa;
      pa.x = f2bf_rne(f0.x) | (f2bf_rne(f0.y) << 16);
      pa.y = f2bf_rne(f0.z) | (f2bf_rne(f0.w) << 16);
      pa.z = f2bf_rne(f1.x) | (f2bf_rne(f1.y) << 16);
      pa.w = f2bf_rne(f1.z) | (f2bf_rne(f1.w) << 16);
      *reinterpret_cast<uint4*>(&kv[jr][c0]) = pa;
      uint4 pb;
      pb.x = f2bf_rne(f2.x) | (f2bf_rne(f2.y) << 16);
      pb.y = f2bf_rne(f2.z) | (f2bf_rne(f2.w) << 16);
      pb.z = f2bf_rne(f3.x) | (f2bf_rne(f3.y) << 16);
      pb.w = f2bf_rne(f3.z) | (f2bf_rne(f3.w) << 16);
      *reinterpret_cast<uint4*>(&kv[jr][c0 + 8]) = pb;
    }
    __syncthreads();
#pragma unroll
    for (int kk = 0; kk < 2; kk++){
      s16x8 a, bb;
#pragma unroll
      for (int e = 0; e < 8; e++){
        a[e]  = (short)f2bf_rne(sc[fr][j0 + kk*32 + fk + e]);
        bb[e] = kv[kk*32 + fk + e][w*16 + fr];
      }
      accpv = __builtin_amdgcn_mfma_f32_16x16x32_bf16(a, bb, accpv, 0, 0, 0);
    }
  }
#pragma unroll
  for (int r = 0; r < 4; r++){
    int gi = i0 + cr + r;
    if (gi < SEQ)
      ctx[((size_t)(b*SEQ+gi))*DMODEL + h*DHEAD + w*16 + fr] = accpv[r];
  }
}

// ---- wave-per-row residual add (+optional GELU) + LayerNorm; 4 rows/block ----
template<int GELU_ADD>
__global__ void add_ln_wave(float* __restrict__ x, const float* __restrict__ add,
                            const float* __restrict__ g, const float* __restrict__ b){
  int row = blockIdx.x * 4 + (threadIdx.x >> 6);
  if (row >= BATCH * SEQ) return;
  int lane = threadIdx.x & 63;
  float* xr = x + (size_t)row * DMODEL;
  const float* ar = add + (size_t)row * DMODEL;
  float buf[12];
  float s = 0.f;
#pragma unroll
  for (int it = 0; it < 12; it++){
    int i = lane + it * 64;
    float v = ar[i];
    if (GELU_ADD) v = gelu_f(v);
    v += xr[i];
    buf[it] = v; s += v;
  }
#pragma unroll
  for (int m = 32; m > 0; m >>= 1) s += __shfl_xor(s, m);
  float mean = s * (1.f / 768.f);
  float q = 0.f;
#pragma unroll
  for (int it = 0; it < 12; it++){ float d = buf[it] - mean; q += d * d; }
#pragma unroll
  for (int m = 32; m > 0; m >>= 1) q += __shfl_xor(q, m);
  float rs = rsqrtf(q * (1.f / 768.f) + 1e-5f);
#pragma unroll
  for (int it = 0; it < 12; it++){
    int i = lane + it * 64;
    xr[i] = (buf[it] - mean) * rs * g[i] + b[i];
  }
}

// ---- T5-style relative position bias table ----
__global__ void relbias_kernel(const float* __restrict__ rel_emb, float* __restrict__ tab){
  int idx = blockIdx.x * 256 + threadIdx.x;
  if (idx >= NREL * NHEAD) return;
  int rr = idx / NHEAD, h = idx - rr * NHEAD;
  int rel = rr - (SEQ - 1);
  int bkt = (rel > 0) ? 160 : 0;
  int n = (rel < 0) ? -rel : rel;
  if (n < 80) bkt += n;
  else {
    int large = 80 + (int)(logf((float)n / 80.f) / logf(10.f) * 80.f);
    bkt += (large < 159) ? large : 159;
  }
  tab[h * NREL + rr] = rel_emb[bkt * NHEAD + h];
}

// ---- gate: block = (gg 8) x (ss 32); grid = B*H*16 ----
__global__ void gate_kernel2(const float* __restrict__ x, const float* __restrict__ gw,
                             const float* __restrict__ gb, const float* __restrict__ ga,
                             float* __restrict__ gate){
  const int blk = blockIdx.x;
  const int st = blk & 15, bh = blk >> 4;
  const int h = bh % NHEAD, b = bh / NHEAD;
  const int ss = threadIdx.x & 31, gg = threadIdx.x >> 5;
  const int s = st * 32 + ss;
  __shared__ float red[8][33];
  float a = 0.f;
  if (s < SEQ){
    const float* xv = x + ((size_t)(b * SEQ + s)) * DMODEL + h * DHEAD;
    const float* wrow = gw + gg * DHEAD;
    a = gb[gg];
#pragma unroll
    for (int d = 0; d < 64; d++) a += xv[d] * wrow[d];
  }
  red[gg][ss] = a; __syncthreads();
  if (threadIdx.x < 32){
    int s2 = st * 32 + threadIdx.x;
    if (s2 < SEQ){
      float a0 = red[0][threadIdx.x] + red[1][threadIdx.x] + red[2][threadIdx.x] + red[3][threadIdx.x];
      float a1 = red[4][threadIdx.x] + red[5][threadIdx.x] + red[6][threadIdx.x] + red[7][threadIdx.x];
      float g0 = 1.f / (1.f + expf(-a0));
      float g1 = 1.f / (1.f + expf(-a1));
      gate[(size_t)bh * SEQ + s2] = g0 * (g1 * ga[h] - 1.f) + 2.f;
    }
  }
}

} // anonymous namespace

extern "C" void kernel_launch(void* const* d_in, const int* in_sizes, int n_in,
                              void* d_out, int out_size, void* d_ws, size_t ws_size,
                              hipStream_t stream){
  (void)ws_size;

  static const int DS[34] = {640000,5120,3145728,1048576,3584,3584,512,512,393216,768,
                             4718592,768,768,768,7077888,9216,7077888,9216,7077888,9216,
                             7077888,9216,6144,96,144,9216,9216,28311552,36864,28311552,
                             9216,9216,9216,3840};
  bool ok = (n_in == 34) && (out_size == BATCH * SEQ * DMODEL);
  if (ok) for (int i = 0; i < 34; i++) if (in_sizes[i] != DS[i]) { ok = false; break; }
  if (!ok){
    fill_f32_kernel<<<(out_size + 255) / 256, 256, 0, stream>>>((float*)d_out, out_size, 1000.0f);
    return;
  }

  const float* src  = (const float*)d_in[0];
  const float* w0   = (const float*)d_in[1];
  const float* w14  = (const float*)d_in[2];
  const float* w56  = (const float*)d_in[3];
  const float* clng = (const float*)d_in[4];
  const float* clnb = (const float*)d_in[5];
  const float* flng = (const float*)d_in[6];
  const float* flnb = (const float*)d_in[7];
  const float* pjw  = (const float*)d_in[8];
  const float* pjb  = (const float*)d_in[9];
  const float* pcw  = (const float*)d_in[10];
  const float* pcb  = (const float*)d_in[11];
  const float* eng  = (const float*)d_in[12];
  const float* enb  = (const float*)d_in[13];
  const float* Wq   = (const float*)d_in[14];
  const float* bq   = (const float*)d_in[15];
  const float* Wk   = (const float*)d_in[16];
  const float* bk   = (const float*)d_in[17];
  const float* Wv   = (const float*)d_in[18];
  const float* bv   = (const float*)d_in[19];
  const float* Wo   = (const float*)d_in[20];
  const float* bo   = (const float*)d_in[21];
  const float* gw   = (const float*)d_in[22];
  const float* gbp  = (const float*)d_in[23];
  const float* ga   = (const float*)d_in[24];
  const float* l1g  = (const float*)d_in[25];
  const float* l1b  = (const float*)d_in[26];
  const float* f1w  = (const float*)d_in[27];
  const float* f1b  = (const float*)d_in[28];
  const float* f2w  = (const float*)d_in[29];
  const float* f2b  = (const float*)d_in[30];
  const float* l2g  = (const float*)d_in[31];
  const float* l2b  = (const float*)d_in[32];
  const float* rel  = (const float*)d_in[33];

  float* x = (float*)d_out;  // residual stream lives in d_out (fp32)

  // workspace
  float* wsf = (float*)d_ws;
  size_t off = 0;
  auto alloc = [&](size_t n){ float* pp = wsf + off; off += (n + 63) & ~(size_t)63; return pp; };
  const size_t XSZ = (size_t)BATCH * SEQ * DMODEL;
  float* convws = alloc((size_t)16383488 + 8191488);       // conv ping-pong (24.6M floats)
  float* ffh  = alloc((size_t)BATCH * SEQ * FFN);
  float* tmp  = alloc(XSZ);
  float* qb   = alloc(XSZ);
  float* kb   = alloc(XSZ);
  float* vb   = alloc(XSZ);
  float* ctx  = alloc(XSZ);
  float* feat = alloc((size_t)BATCH * SEQ * 512);
  float* c6   = alloc((size_t)512 * SEQ);
  float* gate = alloc((size_t)BATCH * NHEAD * SEQ);
  float* tab  = alloc((size_t)NHEAD * NREL);
  bf16* wposb = (bf16*)alloc((size_t)DMODEL * 48 * 128 / 2);
  float* cA = convws;
  float* cB = convws + (size_t)16383488;

  const int Ls[8] = {160000, 31999, 15999, 7999, 3999, 1999, 999, 499};
  const int Mrows = BATCH * SEQ; // 1996

  // ---- conv feature extractor ----
  for (int b = 0; b < BATCH; b++){
    conv0_kernel<<<(512 * Ls[1] + 255) / 256, 256, 0, stream>>>(src + (size_t)b * T_IN, w0, cA, Ls[1]);
    ln_gelu_ch2_kernel<<<(Ls[1] + 31) / 32, 256, 0, stream>>>(cA, clng, clnb, Ls[1]);
    float* bufs[2] = {cA, cB};
    for (int st = 1; st <= 6; st++){
      const float* inb = bufs[(st + 1) & 1];
      float* outb      = (st == 6) ? c6 : bufs[st & 1];
      int Lin = Ls[st], Lout = Ls[st + 1];
      int oLd = (st == 6) ? SEQ : Lout;
      dim3 grd(8, (Lout + 63) / 64);          // co-major for L3 locality
      if (st <= 4)
        conv_mfma_kernel<3><<<grd, 256, 0, stream>>>(inb, w14 + (size_t)(st - 1) * 512 * 512 * 3, outb, Lin, Lout, oLd);
      else
        conv_mfma_kernel<2><<<grd, 256, 0, stream>>>(inb, w56 + (size_t)(st - 5) * 512 * 512 * 2, outb, Lin, Lout, oLd);
      if (st < 6)
        ln_gelu_ch2_kernel<<<(Lout + 31) / 32, 256, 0, stream>>>(outb, clng + st * 512, clnb + st * 512, Lout);
    }
    ln_gelu_ch2_kernel<<<(SEQ + 31) / 32, 256, 0, stream>>>(c6, clng + 6 * 512, clnb + 6 * 512, SEQ);
    featln_transpose_kernel<<<(SEQ + 255) / 256, 256, 0, stream>>>(c6, flng, flnb, feat + (size_t)b * SEQ * 512);
  }

  gemm_mfma_f32<0><<<dim3(DMODEL / 64, (Mrows + 63) / 64), 256, 0, stream>>>(feat, pjw, pjb, x, Mrows, DMODEL, 512, 1.0f);
  f2bf_kernel<<<(4718592 + 255) / 256, 256, 0, stream>>>(pcw, wposb, 4718592);
  posconv_mfma<<<dim3(8, 16, BATCH), 256, 0, stream>>>(x, wposb, pcb, tmp);
  add_ln_wave<1><<<(Mrows + 3) / 4, 256, 0, stream>>>(x, tmp, eng, enb);
  relbias_kernel<<<(NREL * NHEAD + 255) / 256, 256, 0, stream>>>(rel, tab);

  const size_t WQK = (size_t)DMODEL * DMODEL;
  const size_t WF  = (size_t)FFN * DMODEL;
  for (int l = 0; l < NLAYER; l++){
    gate_kernel2<<<48 * 16, 256, 0, stream>>>(
        x, gw + (size_t)l * 8 * DHEAD, gbp + l * 8, ga + l * NHEAD, gate);
    gemm_qkv_mfma<<<dim3(12, 32, 3), 256, 0, stream>>>(
        x, Wq + l * WQK, Wk + l * WQK, Wv + l * WQK,
        bq + l * DMODEL, bk + l * DMODEL, bv + l * DMODEL, qb, kb, vb, Mrows);
    attn_fused<<<dim3(32, BATCH * NHEAD), 256, 0, stream>>>(qb, kb, vb, gate, tab, ctx);
    gemm_mfma_f32<0><<<dim3(12, 32), 256, 0, stream>>>(ctx, Wo + l * WQK, bo + l * DMODEL, tmp, Mrows, DMODEL, DMODEL, 1.0f);
    add_ln_wave<0><<<(Mrows + 3) / 4, 256, 0, stream>>>(x, tmp, l1g + l * DMODEL, l1b + l * DMODEL);
    gemm_mfma_f32<1><<<dim3(FFN / 64, 32), 256, 0, stream>>>(x, f1w + l * WF, f1b + l * FFN, ffh, Mrows, FFN, DMODEL, 1.0f);
    gemm_mfma_f32<0><<<dim3(12, 32), 256, 0, stream>>>(ffh, f2w + l * WF, f2b + l * DMODEL, tmp, Mrows, DMODEL, FFN, 1.0f);
    add_ln_wave<0><<<(Mrows + 3) / 4, 256, 0, stream>>>(x, tmp, l2g + l * DMODEL, l2b + l * DMODEL);
  }
  // result is already in d_out
}

// Round 16
// 7411.789 us; speedup vs baseline: 12.2044x; 1.0422x over previous
//
#include <hip/hip_runtime.h>
#include <hip/hip_bf16.h>
#include <math.h>

namespace {

constexpr int BATCH  = 4;
constexpr int T_IN   = 160000;
constexpr int DMODEL = 768;
constexpr int NHEAD  = 12;
constexpr int DHEAD  = 64;
constexpr int FFN    = 3072;
constexpr int NLAYER = 12;
constexpr int SEQ    = 499;
constexpr int SP     = 512;
constexpr int NREL   = 2 * SEQ - 1;

typedef __hip_bfloat16 bf16;
using f32x4 = __attribute__((ext_vector_type(4))) float;
using s16x8 = __attribute__((ext_vector_type(8))) short;

__device__ __forceinline__ float gelu_f(float x){
  return 0.5f * x * (1.0f + erff(x * 0.70710678118654752f));
}

__device__ __forceinline__ unsigned f2bf_rne(float f){
  unsigned u = __float_as_uint(f);
  return (u + 0x7FFFu + ((u >> 16) & 1u)) >> 16;
}

__global__ void fill_f32_kernel(float* __restrict__ out, int n, float val){
  int i = blockIdx.x * 256 + threadIdx.x;
  if (i < n) out[i] = val;
}

__global__ void f2bf_kernel(const float* __restrict__ in, bf16* __restrict__ out, int n){
  int i = blockIdx.x * 256 + threadIdx.x;
  if (i < n) out[i] = __float2bfloat16(in[i]);
}

// ---- conv stage 0: k=10, s=5 ----
__global__ void conv0_kernel(const float* __restrict__ src, const float* __restrict__ w,
                             float* __restrict__ out, int Lout){
  int idx = blockIdx.x * 256 + threadIdx.x;
  if (idx >= 512 * Lout) return;
  int c = idx / Lout, t = idx - c * Lout;
  const float* wr = w + c * 10;
  const float* s  = src + t * 5;
  float acc = 0.f;
#pragma unroll
  for (int k = 0; k < 10; k++) acc += wr[k] * s[k];
  out[idx] = acc;
}

// ---- 2D-parallel channel LN + GELU; BFOUT=1: write bf16 to `ob`, else fp32 in place ----
template<int BFOUT>
__global__ void ln_gelu_ch2_kernel(float* __restrict__ x, bf16* __restrict__ ob,
                                   const float* __restrict__ g, const float* __restrict__ b,
                                   int Lt){
  const int tid = threadIdx.x;
  const int tt = tid & 31, tc = tid >> 5;
  const int t = blockIdx.x * 32 + tt;
  __shared__ float sred[8][33], qred[8][33];
  __shared__ float mrow[32], rrow[32];
  float s = 0.f, q = 0.f;
  if (t < Lt){
    const float* xc = x + (size_t)(tc * 64) * Lt + t;
#pragma unroll 8
    for (int j = 0; j < 64; j++){ float v = xc[(size_t)j * Lt]; s += v; q += v * v; }
  }
  sred[tc][tt] = s; qred[tc][tt] = q; __syncthreads();
  if (tid < 32){
    float ss = 0.f, qq = 0.f;
#pragma unroll
    for (int c = 0; c < 8; c++){ ss += sred[c][tid]; qq += qred[c][tid]; }
    float m = ss * (1.f / 512.f);
    float var = qq * (1.f / 512.f) - m * m;
    mrow[tid] = m; rrow[tid] = rsqrtf(var + 1e-5f);
  }
  __syncthreads();
  if (t < Lt){
    float m = mrow[tt], rs = rrow[tt];
    float* xc = x + (size_t)(tc * 64) * Lt + t;
#pragma unroll 8
    for (int j = 0; j < 64; j++){
      int c = tc * 64 + j;
      float v = gelu_f((xc[(size_t)j * Lt] - m) * rs * g[c] + b[c]);
      if (BFOUT) ob[(size_t)c * Lt + t] = __float2bfloat16(v);
      else       xc[(size_t)j * Lt] = v;
    }
  }
}

// ---- conv stages 1..6 via MFMA, bf16 input, zero-ALU B-fragments ----
template<int KW>
__global__ void conv_mfma_kernel(const bf16* __restrict__ in, const float* __restrict__ w,
                                 float* __restrict__ out, int Lin, int Lout, int outLd){
  constexpr int SPAN = 128 + KW;
  __shared__ bf16 As[64][40];
  __shared__ bf16 insb[8][132];
  const int tid = threadIdx.x, wid = tid >> 6, lane = tid & 63;
  const int co0 = blockIdx.x * 64, t0 = blockIdx.y * 64;
  const int wm = (wid >> 1) * 32, wn = (wid & 1) * 32;
  const int lrow = tid >> 2, lk = (tid & 3) * 8;
  const int fr = lane & 15, fk = (lane >> 4) * 8;
  const int cir = lk >> 2;
  f32x4 acc[2][2] = {};
  for (int ci0 = 0; ci0 < 512; ci0 += 8){
    {
      uint4 pw;
      if (KW == 3){
        const float* wp = w + (size_t)(co0 + lrow) * 1536 + (ci0 + cir) * 3;
        float2 f01 = *reinterpret_cast<const float2*>(wp);
        float2 f23 = *reinterpret_cast<const float2*>(wp + 2);
        float2 f45 = *reinterpret_cast<const float2*>(wp + 4);
        pw.x = f2bf_rne(f01.x) | (f2bf_rne(f01.y) << 16);
        pw.y = f2bf_rne(f23.x);                       // k=3 weight = 0
        pw.z = f2bf_rne(f23.y) | (f2bf_rne(f45.x) << 16);
        pw.w = f2bf_rne(f45.y);
      } else {
        const float* wp = w + (size_t)(co0 + lrow) * 1024 + (ci0 + cir) * 2;
        float4 f = *reinterpret_cast<const float4*>(wp);
        pw.x = f2bf_rne(f.x) | (f2bf_rne(f.y) << 16);
        pw.y = 0u;                                    // k=2,3 weights = 0
        pw.z = f2bf_rne(f.z) | (f2bf_rne(f.w) << 16);
        pw.w = 0u;
      }
      *reinterpret_cast<uint4*>(&As[lrow][lk]) = pw;
    }
    for (int idx = tid; idx < 8 * 132; idx += 256){
      int ci = idx >> 7; ci = idx / 132; int j = idx - ci * 132;
      int gp = t0 * 2 + j;
      unsigned short v = 0;
      if (j < SPAN && gp < Lin)
        v = *reinterpret_cast<const unsigned short*>(&in[(size_t)(ci0 + ci) * Lin + gp]);
      *reinterpret_cast<unsigned short*>(&insb[ci][j]) = v;
    }
    __syncthreads();
    const int cia = fk >> 2;
    auto bfrag = [&](int tr)->s16x8 {
      uint4 pk;
      pk.x = *reinterpret_cast<const uint*>(&insb[cia][2 * tr]);
      pk.y = (KW > 2) ? *reinterpret_cast<const uint*>(&insb[cia][2 * tr + 2]) : 0u;
      pk.z = *reinterpret_cast<const uint*>(&insb[cia + 1][2 * tr]);
      pk.w = (KW > 2) ? *reinterpret_cast<const uint*>(&insb[cia + 1][2 * tr + 2]) : 0u;
      return *reinterpret_cast<s16x8*>(&pk);
    };
    s16x8 a0 = *reinterpret_cast<const s16x8*>(&As[wm + fr][fk]);
    s16x8 a1 = *reinterpret_cast<const s16x8*>(&As[wm + 16 + fr][fk]);
    s16x8 b0 = bfrag(wn + fr);
    s16x8 b1 = bfrag(wn + 16 + fr);
    acc[0][0] = __builtin_amdgcn_mfma_f32_16x16x32_bf16(a0, b0, acc[0][0], 0, 0, 0);
    acc[0][1] = __builtin_amdgcn_mfma_f32_16x16x32_bf16(a0, b1, acc[0][1], 0, 0, 0);
    acc[1][0] = __builtin_amdgcn_mfma_f32_16x16x32_bf16(a1, b0, acc[1][0], 0, 0, 0);
    acc[1][1] = __builtin_amdgcn_mfma_f32_16x16x32_bf16(a1, b1, acc[1][1], 0, 0, 0);
    __syncthreads();
  }
  const int cc = lane & 15, cr = (lane >> 4) * 4;
#pragma unroll
  for (int mi = 0; mi < 2; mi++){
#pragma unroll
    for (int ni = 0; ni < 2; ni++){
      int t = t0 + wn + ni * 16 + cc;
      if (t >= Lout) continue;
#pragma unroll
      for (int r = 0; r < 4; r++){
        int co = co0 + wm + mi * 16 + cr + r;
        out[(size_t)co * outLd + t] = acc[mi][ni][r];
      }
    }
  }
}

// ---- final feature LN + transpose (512,S)->(S,512) ----
__global__ void featln_transpose_kernel(const float* __restrict__ xin,
                                        const float* __restrict__ g, const float* __restrict__ b,
                                        float* __restrict__ feat){
  int t = blockIdx.x * 256 + threadIdx.x;
  if (t >= SEQ) return;
  float s = 0.f, sq = 0.f;
  for (int c = 0; c < 512; c++){ float v = xin[c * SEQ + t]; s += v; sq += v * v; }
  float m = s * (1.f / 512.f), var = sq * (1.f / 512.f) - m * m, rs = rsqrtf(var + 1e-5f);
  for (int c = 0; c < 512; c++)
    feat[t * 512 + c] = (xin[c * SEQ + t] - m) * rs * g[c] + b[c];
}

// ---- MFMA GEMM, fp32 inputs (bf16 cast fused): C = act(alpha*(A @ W^T + bias)) ----
template<int ACT>
__global__ void gemm_mfma_f32(const float* __restrict__ A, const float* __restrict__ W,
                              const float* __restrict__ bias, float* __restrict__ C,
                              int M, int N, int K, float alpha){
  __shared__ bf16 As[64][40];
  __shared__ bf16 Ws[64][40];
  const int tid = threadIdx.x;
  const int wid = tid >> 6, lane = tid & 63;
  const int m0 = blockIdx.y * 64, n0 = blockIdx.x * 64;
  const int wm = (wid >> 1) * 32, wn = (wid & 1) * 32;
  const int lrow = tid >> 2;
  const int lk   = (tid & 3) * 8;
  const int fr = lane & 15, fk = (lane >> 4) * 8;
  f32x4 acc[2][2] = {};
  for (int k0 = 0; k0 < K; k0 += 32){
    float4 a0 = make_float4(0.f,0.f,0.f,0.f), a1 = make_float4(0.f,0.f,0.f,0.f);
    int gm = m0 + lrow;
    if (gm < M){
      const float* ap = &A[(size_t)gm * K + k0 + lk];
      a0 = *reinterpret_cast<const float4*>(ap);
      a1 = *reinterpret_cast<const float4*>(ap + 4);
    }
    uint4 pa;
    pa.x = f2bf_rne(a0.x) | (f2bf_rne(a0.y) << 16);
    pa.y = f2bf_rne(a0.z) | (f2bf_rne(a0.w) << 16);
    pa.z = f2bf_rne(a1.x) | (f2bf_rne(a1.y) << 16);
    pa.w = f2bf_rne(a1.z) | (f2bf_rne(a1.w) << 16);
    *reinterpret_cast<uint4*>(&As[lrow][lk]) = pa;
    const float* wp = &W[(size_t)(n0 + lrow) * K + k0 + lk];
    float4 w0 = *reinterpret_cast<const float4*>(wp);
    float4 w1 = *reinterpret_cast<const float4*>(wp + 4);
    uint4 pw;
    pw.x = f2bf_rne(w0.x) | (f2bf_rne(w0.y) << 16);
    pw.y = f2bf_rne(w0.z) | (f2bf_rne(w0.w) << 16);
    pw.z = f2bf_rne(w1.x) | (f2bf_rne(w1.y) << 16);
    pw.w = f2bf_rne(w1.z) | (f2bf_rne(w1.w) << 16);
    *reinterpret_cast<uint4*>(&Ws[lrow][lk]) = pw;
    __syncthreads();
    s16x8 av0 = *reinterpret_cast<const s16x8*>(&As[wm + fr][fk]);
    s16x8 av1 = *reinterpret_cast<const s16x8*>(&As[wm + 16 + fr][fk]);
    s16x8 bv0 = *reinterpret_cast<const s16x8*>(&Ws[wn + fr][fk]);
    s16x8 bv1 = *reinterpret_cast<const s16x8*>(&Ws[wn + 16 + fr][fk]);
    acc[0][0] = __builtin_amdgcn_mfma_f32_16x16x32_bf16(av0, bv0, acc[0][0], 0, 0, 0);
    acc[0][1] = __builtin_amdgcn_mfma_f32_16x16x32_bf16(av0, bv1, acc[0][1], 0, 0, 0);
    acc[1][0] = __builtin_amdgcn_mfma_f32_16x16x32_bf16(av1, bv0, acc[1][0], 0, 0, 0);
    acc[1][1] = __builtin_amdgcn_mfma_f32_16x16x32_bf16(av1, bv1, acc[1][1], 0, 0, 0);
    __syncthreads();
  }
  const int cc = lane & 15, cr = (lane >> 4) * 4;
#pragma unroll
  for (int mi = 0; mi < 2; mi++){
#pragma unroll
    for (int ni = 0; ni < 2; ni++){
      int n = n0 + wn + ni * 16 + cc;
      float bn = bias[n];
#pragma unroll
      for (int r = 0; r < 4; r++){
        int m = m0 + wm + mi * 16 + cr + r;
        if (m < M){
          float v = alpha * (acc[mi][ni][r] + bn);
          if (ACT == 1) v = gelu_f(v);
          C[(size_t)m * N + n] = v;
        }
      }
    }
  }
}

// ---- fused QKV (z selects Wq/Wk/Wv) ----
__global__ void gemm_qkv_mfma(const float* __restrict__ A,
                              const float* __restrict__ Wq, const float* __restrict__ Wk,
                              const float* __restrict__ Wv,
                              const float* __restrict__ bqv, const float* __restrict__ bkv,
                              const float* __restrict__ bvv,
                              float* __restrict__ qb, float* __restrict__ kb,
                              float* __restrict__ vb, int M){
  const int z = blockIdx.z;
  const float* W   = (z == 0) ? Wq : (z == 1) ? Wk : Wv;
  const float* bia = (z == 0) ? bqv : (z == 1) ? bkv : bvv;
  float* C         = (z == 0) ? qb : (z == 1) ? kb : vb;
  const float alpha = (z == 0) ? 0.125f : 1.0f;
  const int K = DMODEL, N = DMODEL;
  __shared__ bf16 As[64][40];
  __shared__ bf16 Ws[64][40];
  const int tid = threadIdx.x;
  const int wid = tid >> 6, lane = tid & 63;
  const int m0 = blockIdx.y * 64, n0 = blockIdx.x * 64;
  const int wm = (wid >> 1) * 32, wn = (wid & 1) * 32;
  const int lrow = tid >> 2;
  const int lk   = (tid & 3) * 8;
  const int fr = lane & 15, fk = (lane >> 4) * 8;
  f32x4 acc[2][2] = {};
  for (int k0 = 0; k0 < K; k0 += 32){
    float4 a0 = make_float4(0.f,0.f,0.f,0.f), a1 = make_float4(0.f,0.f,0.f,0.f);
    int gm = m0 + lrow;
    if (gm < M){
      const float* ap = &A[(size_t)gm * K + k0 + lk];
      a0 = *reinterpret_cast<const float4*>(ap);
      a1 = *reinterpret_cast<const float4*>(ap + 4);
    }
    uint4 pa;
    pa.x = f2bf_rne(a0.x) | (f2bf_rne(a0.y) << 16);
    pa.y = f2bf_rne(a0.z) | (f2bf_rne(a0.w) << 16);
    pa.z = f2bf_rne(a1.x) | (f2bf_rne(a1.y) << 16);
    pa.w = f2bf_rne(a1.z) | (f2bf_rne(a1.w) << 16);
    *reinterpret_cast<uint4*>(&As[lrow][lk]) = pa;
    const float* wp = &W[(size_t)(n0 + lrow) * K + k0 + lk];
    float4 w0 = *reinterpret_cast<const float4*>(wp);
    float4 w1 = *reinterpret_cast<const float4*>(wp + 4);
    uint4 pw;
    pw.x = f2bf_rne(w0.x) | (f2bf_rne(w0.y) << 16);
    pw.y = f2bf_rne(w0.z) | (f2bf_rne(w0.w) << 16);
    pw.z = f2bf_rne(w1.x) | (f2bf_rne(w1.y) << 16);
    pw.w = f2bf_rne(w1.z) | (f2bf_rne(w1.w) << 16);
    *reinterpret_cast<uint4*>(&Ws[lrow][lk]) = pw;
    __syncthreads();
    s16x8 av0 = *reinterpret_cast<const s16x8*>(&As[wm + fr][fk]);
    s16x8 av1 = *reinterpret_cast<const s16x8*>(&As[wm + 16 + fr][fk]);
    s16x8 bv0 = *reinterpret_cast<const s16x8*>(&Ws[wn + fr][fk]);
    s16x8 bv1 = *reinterpret_cast<const s16x8*>(&Ws[wn + 16 + fr][fk]);
    acc[0][0] = __builtin_amdgcn_mfma_f32_16x16x32_bf16(av0, bv0, acc[0][0], 0, 0, 0);
    acc[0][1] = __builtin_amdgcn_mfma_f32_16x16x32_bf16(av0, bv1, acc[0][1], 0, 0, 0);
    acc[1][0] = __builtin_amdgcn_mfma_f32_16x16x32_bf16(av1, bv0, acc[1][0], 0, 0, 0);
    acc[1][1] = __builtin_amdgcn_mfma_f32_16x16x32_bf16(av1, bv1, acc[1][1], 0, 0, 0);
    __syncthreads();
  }
  const int cc = lane & 15, cr = (lane >> 4) * 4;
#pragma unroll
  for (int mi = 0; mi < 2; mi++){
#pragma unroll
    for (int ni = 0; ni < 2; ni++){
      int n = n0 + wn + ni * 16 + cc;
      float bn = bia[n];
#pragma unroll
      for (int r = 0; r < 4; r++){
        int m = m0 + wm + mi * 16 + cr + r;
        if (m < M) C[(size_t)m * N + n] = alpha * (acc[mi][ni][r] + bn);
      }
    }
  }
}

// ---- posconv via MFMA ----
__global__ void posconv_mfma(const float* __restrict__ x, const bf16* __restrict__ wpos,
                             const float* __restrict__ bias, float* __restrict__ xc){
  const int t0 = blockIdx.x * 64, g = blockIdx.y, b = blockIdx.z;
  __shared__ bf16 As[64][40];
  __shared__ float xw[224];
  const int tid = threadIdx.x, wid = tid >> 6, lane = tid & 63;
  const int wm = (wid >> 1) * 32, wn = (wid & 1) * 32;
  const int lrow = tid >> 2, lk = (tid & 3) * 8;
  const int fr = lane & 15, fk = (lane >> 4) * 8;
  f32x4 acc[2][2] = {};
  for (int ci = 0; ci < 48; ci++){
    for (int idx = tid; idx < 191; idx += 256){
      int p = t0 - 64 + idx;
      xw[idx] = (p >= 0 && p < SEQ) ? x[((size_t)(b * SEQ + p)) * DMODEL + g * 48 + ci] : 0.f;
    }
    for (int kk = 0; kk < 128; kk += 32){
      uint4 wa = make_uint4(0, 0, 0, 0);
      if (lrow < 48)
        wa = *reinterpret_cast<const uint4*>(&wpos[(size_t)(g * 48 + lrow) * 6144 + ci * 128 + kk + lk]);
      *reinterpret_cast<uint4*>(&As[lrow][lk]) = wa;
      __syncthreads();
      auto bfragp = [&](int tr)->s16x8{
        int base = tr + kk + fk;
        s16x8 r;
#pragma unroll
        for (int j = 0; j < 8; j++) r[j] = (short)f2bf_rne(xw[base + j]);
        return r;
      };
      s16x8 a0 = *reinterpret_cast<const s16x8*>(&As[wm + fr][fk]);
      s16x8 a1 = *reinterpret_cast<const s16x8*>(&As[wm + 16 + fr][fk]);
      s16x8 b0 = bfragp(wn + fr);
      s16x8 b1 = bfragp(wn + 16 + fr);
      acc[0][0] = __builtin_amdgcn_mfma_f32_16x16x32_bf16(a0, b0, acc[0][0], 0, 0, 0);
      acc[0][1] = __builtin_amdgcn_mfma_f32_16x16x32_bf16(a0, b1, acc[0][1], 0, 0, 0);
      acc[1][0] = __builtin_amdgcn_mfma_f32_16x16x32_bf16(a1, b0, acc[1][0], 0, 0, 0);
      acc[1][1] = __builtin_amdgcn_mfma_f32_16x16x32_bf16(a1, b1, acc[1][1], 0, 0, 0);
      __syncthreads();
    }
  }
  const int cc = lane & 15, cr = (lane >> 4) * 4;
#pragma unroll
  for (int mi = 0; mi < 2; mi++){
#pragma unroll
    for (int ni = 0; ni < 2; ni++){
      int t = t0 + wn + ni * 16 + cc;
      if (t >= SEQ) continue;
#pragma unroll
      for (int r = 0; r < 4; r++){
        int cop = wm + mi * 16 + cr + r;
        if (cop < 48){
          int co = g * 48 + cop;
          xc[((size_t)(b * SEQ + t)) * DMODEL + co] = acc[mi][ni][r] + bias[co];
        }
      }
    }
  }
}

// ---- FUSED attention with in-block gate: QK^T -> softmax(+gate*relbias) -> PV ----
__global__ void attn_fused(const float* __restrict__ q, const float* __restrict__ k,
                           const float* __restrict__ v, const float* __restrict__ x,
                           const float* __restrict__ gwl, const float* __restrict__ gbl,
                           const float* __restrict__ gal,
                           const float* __restrict__ tab, float* __restrict__ ctx){
  const int bh = blockIdx.y, b = bh / NHEAD, h = bh % NHEAD;
  const int i0 = blockIdx.x * 16;
  const int tid = threadIdx.x, w = tid >> 6, lane = tid & 63;
  const int fr = lane & 15, fk = (lane >> 4) * 8;
  const int cr = (lane >> 4) * 4;
  __shared__ float sc[16][524];
  __shared__ short qs[16][72];
  __shared__ short kv[64][72];
  __shared__ float gtmp[16][9];
  __shared__ float gl[16];
  // stage Q (16x64) as bf16
  {
    int r = tid >> 4, c = (tid & 15) * 4;
    int gi = i0 + r;
    float4 qv = make_float4(0.f,0.f,0.f,0.f);
    if (gi < SEQ) qv = *reinterpret_cast<const float4*>(&q[((size_t)(b*SEQ+gi))*DMODEL + h*DHEAD + c]);
    uint2 p;
    p.x = f2bf_rne(qv.x) | (f2bf_rne(qv.y) << 16);
    p.y = f2bf_rne(qv.z) | (f2bf_rne(qv.w) << 16);
    *reinterpret_cast<uint2*>(&qs[r][c]) = p;
  }
  // gate logits: 128 threads, one (row, g) dot each
  if (tid < 128){
    int r = tid >> 3, g = tid & 7;
    int gi = i0 + r;
    float a = gbl[g];
    if (gi < SEQ){
      const float* xv = x + ((size_t)(b * SEQ + gi)) * DMODEL + h * DHEAD;
      const float* wrow = gwl + g * DHEAD;
#pragma unroll
      for (int d = 0; d < 64; d++) a += xv[d] * wrow[d];
    }
    gtmp[r][g] = a;
  }
  __syncthreads();
  if (tid < 16){
    float a0 = gtmp[tid][0] + gtmp[tid][1] + gtmp[tid][2] + gtmp[tid][3];
    float a1 = gtmp[tid][4] + gtmp[tid][5] + gtmp[tid][6] + gtmp[tid][7];
    float g0 = 1.f / (1.f + expf(-a0));
    float g1 = 1.f / (1.f + expf(-a1));
    gl[tid] = g0 * (g1 * gal[h] - 1.f) + 2.f;
  }
  // ---- QK phase ----
  for (int j0 = 0; j0 < SP; j0 += 64){
    __syncthreads();
    {
      int jr = tid >> 2, c0 = (tid & 3) * 16;
      int gj = j0 + jr;
      float4 f0 = make_float4(0.f,0.f,0.f,0.f), f1 = f0, f2 = f0, f3 = f0;
      if (gj < SEQ){
        const float* kp = &k[((size_t)(b*SEQ+gj))*DMODEL + h*DHEAD + c0];
        f0 = *reinterpret_cast<const float4*>(kp);
        f1 = *reinterpret_cast<const float4*>(kp + 4);
        f2 = *reinterpret_cast<const float4*>(kp + 8);
        f3 = *reinterpret_cast<const float4*>(kp + 12);
      }
      uint4 pa;
      pa.x = f2bf_rne(f0.x) | (f2bf_rne(f0.y) << 16);
      pa.y = f2bf_rne(f0.z) | (f2bf_rne(f0.w) << 16);
      pa.z = f2bf_rne(f1.x) | (f2bf_rne(f1.y) << 16);
      pa.w = f2bf_rne(f1.z) | (f2bf_rne(f1.w) << 16);
      *reinterpret_cast<uint4*>(&kv[jr][c0]) = pa;
      uint4 pb;
      pb.x = f2bf_rne(f2.x) | (f2bf_rne(f2.y) << 16);
      pb.y = f2bf_rne(f2.z) | (f2bf_rne(f2.w) << 16);
      pb.z = f2bf_rne(f3.x) | (f2bf_rne(f3.y) << 16);
      pb.w = f2bf_rne(f3.z) | (f2bf_rne(f3.w) << 16);
      *reinterpret_cast<uint4*>(&kv[jr][c0 + 8]) = pb;
    }
    __syncthreads();
    f32x4 accqk = {};
#pragma unroll
    for (int kk = 0; kk < 2; kk++){
      s16x8 a = *reinterpret_cast<const s16x8*>(&qs[fr][kk*32 + fk]);
      s16x8 bb = *reinterpret_cast<const s16x8*>(&kv[w*16 + fr][kk*32 + fk]);
      accqk = __builtin_amdgcn_mfma_f32_16x16x32_bf16(a, bb, accqk, 0, 0, 0);
    }
#pragma unroll
    for (int r = 0; r < 4; r++)
      sc[cr + r][j0 + w*16 + fr] = accqk[r];
  }
  __syncthreads();
  // ---- softmax phase ----
  for (int r = 0; r < 4; r++){
    int row = w * 4 + r;
    int gi = i0 + row;
    if (gi >= SEQ) continue;
    float gt = gl[row];
    const float* tb = tab + (size_t)h * NREL + (SEQ - 1 - gi);
    float vals[8];
    float mx = -1e30f;
#pragma unroll
    for (int it = 0; it < 8; it++){
      int j = lane + it * 64;
      float vv = (j < SEQ) ? (sc[row][j] + gt * tb[j]) : -1e30f;
      vals[it] = vv; mx = fmaxf(mx, vv);
    }
#pragma unroll
    for (int m = 32; m > 0; m >>= 1) mx = fmaxf(mx, __shfl_xor(mx, m));
    float sum = 0.f;
#pragma unroll
    for (int it = 0; it < 8; it++){
      int j = lane + it * 64;
      float e = (j < SEQ) ? expf(vals[it] - mx) : 0.f;
      vals[it] = e; sum += e;
    }
#pragma unroll
    for (int m = 32; m > 0; m >>= 1) sum += __shfl_xor(sum, m);
    float inv = 1.f / sum;
#pragma unroll
    for (int it = 0; it < 8; it++){
      int j = lane + it * 64;
      sc[row][j] = vals[it] * inv;
    }
  }
  __syncthreads();
  // ---- PV phase ----
  f32x4 accpv = {};
  for (int j0 = 0; j0 < SP; j0 += 64){
    __syncthreads();
    {
      int jr = tid >> 2, c0 = (tid & 3) * 16;
      int gj = j0 + jr;
      float4 f0 = make_float4(0.f,0.f,0.f,0.f), f1 = f0, f2 = f0, f3 = f0;
      if (gj < SEQ){
        const float* vp = &v[((size_t)(b*SEQ+gj))*DMODEL + h*DHEAD + c0];
        f0 = *reinterpret_cast<const float4*>(vp);
        f1 = *reinterpret_cast<const float4*>(vp + 4);
        f2 = *reinterpret_cast<const float4*>(vp + 8);
        f3 = *reinterpret_cast<const float4*>(vp + 12);
      }
      uint4 pa;
      pa.x = f2bf_rne(f0.x) | (f2bf_rne(f0.y) << 16);
      pa.y = f2bf_rne(f0.z) | (f2bf_rne(f0.w) << 16);
      pa.z = f2bf_rne(f1.x) | (f2bf_rne(f1.y) << 16);
      pa.w = f2bf_rne(f1.z) | (f2bf_rne(f1.w) << 16);
      *reinterpret_cast<uint4*>(&kv[jr][c0]) = pa;
      uint4 pb;
      pb.x = f2bf_rne(f2.x) | (f2bf_rne(f2.y) << 16);
      pb.y = f2bf_rne(f2.z) | (f2bf_rne(f2.w) << 16);
      pb.z = f2bf_rne(f3.x) | (f2bf_rne(f3.y) << 16);
      pb.w = f2bf_rne(f3.z) | (f2bf_rne(f3.w) << 16);
      *reinterpret_cast<uint4*>(&kv[jr][c0 + 8]) = pb;
    }
    __syncthreads();
#pragma unroll
    for (int kk = 0; kk < 2; kk++){
      s16x8 a, bb;
#pragma unroll
      for (int e = 0; e < 8; e++){
        a[e]  = (short)f2bf_rne(sc[fr][j0 + kk*32 + fk + e]);
        bb[e] = kv[kk*32 + fk + e][w*16 + fr];
      }
      accpv = __builtin_amdgcn_mfma_f32_16x16x32_bf16(a, bb, accpv, 0, 0, 0);
    }
  }
#pragma unroll
  for (int r = 0; r < 4; r++){
    int gi = i0 + cr + r;
    if (gi < SEQ)
      ctx[((size_t)(b*SEQ+gi))*DMODEL + h*DHEAD + w*16 + fr] = accpv[r];
  }
}

// ---- wave-per-row residual add (+optional GELU) + LayerNorm; 4 rows/block ----
template<int GELU_ADD>
__global__ void add_ln_wave(float* __restrict__ x, const float* __restrict__ add,
                            const float* __restrict__ g, const float* __restrict__ b){
  int row = blockIdx.x * 4 + (threadIdx.x >> 6);
  if (row >= BATCH * SEQ) return;
  int lane = threadIdx.x & 63;
  float* xr = x + (size_t)row * DMODEL;
  const float* ar = add + (size_t)row * DMODEL;
  float buf[12];
  float s = 0.f;
#pragma unroll
  for (int it = 0; it < 12; it++){
    int i = lane + it * 64;
    float v = ar[i];
    if (GELU_ADD) v = gelu_f(v);
    v += xr[i];
    buf[it] = v; s += v;
  }
#pragma unroll
  for (int m = 32; m > 0; m >>= 1) s += __shfl_xor(s, m);
  float mean = s * (1.f / 768.f);
  float q = 0.f;
#pragma unroll
  for (int it = 0; it < 12; it++){ float d = buf[it] - mean; q += d * d; }
#pragma unroll
  for (int m = 32; m > 0; m >>= 1) q += __shfl_xor(q, m);
  float rs = rsqrtf(q * (1.f / 768.f) + 1e-5f);
#pragma unroll
  for (int it = 0; it < 12; it++){
    int i = lane + it * 64;
    xr[i] = (buf[it] - mean) * rs * g[i] + b[i];
  }
}

// ---- T5-style relative position bias table ----
__global__ void relbias_kernel(const float* __restrict__ rel_emb, float* __restrict__ tab){
  int idx = blockIdx.x * 256 + threadIdx.x;
  if (idx >= NREL * NHEAD) return;
  int rr = idx / NHEAD, h = idx - rr * NHEAD;
  int rel = rr - (SEQ - 1);
  int bkt = (rel > 0) ? 160 : 0;
  int n = (rel < 0) ? -rel : rel;
  if (n < 80) bkt += n;
  else {
    int large = 80 + (int)(logf((float)n / 80.f) / logf(10.f) * 80.f);
    bkt += (large < 159) ? large : 159;
  }
  tab[h * NREL + rr] = rel_emb[bkt * NHEAD + h];
}

} // anonymous namespace

extern "C" void kernel_launch(void* const* d_in, const int* in_sizes, int n_in,
                              void* d_out, int out_size, void* d_ws, size_t ws_size,
                              hipStream_t stream){
  (void)ws_size;

  static const int DS[34] = {640000,5120,3145728,1048576,3584,3584,512,512,393216,768,
                             4718592,768,768,768,7077888,9216,7077888,9216,7077888,9216,
                             7077888,9216,6144,96,144,9216,9216,28311552,36864,28311552,
                             9216,9216,9216,3840};
  bool ok = (n_in == 34) && (out_size == BATCH * SEQ * DMODEL);
  if (ok) for (int i = 0; i < 34; i++) if (in_sizes[i] != DS[i]) { ok = false; break; }
  if (!ok){
    fill_f32_kernel<<<(out_size + 255) / 256, 256, 0, stream>>>((float*)d_out, out_size, 1000.0f);
    return;
  }

  const float* src  = (const float*)d_in[0];
  const float* w0   = (const float*)d_in[1];
  const float* w14  = (const float*)d_in[2];
  const float* w56  = (const float*)d_in[3];
  const float* clng = (const float*)d_in[4];
  const float* clnb = (const float*)d_in[5];
  const float* flng = (const float*)d_in[6];
  const float* flnb = (const float*)d_in[7];
  const float* pjw  = (const float*)d_in[8];
  const float* pjb  = (const float*)d_in[9];
  const float* pcw  = (const float*)d_in[10];
  const float* pcb  = (const float*)d_in[11];
  const float* eng  = (const float*)d_in[12];
  const float* enb  = (const float*)d_in[13];
  const float* Wq   = (const float*)d_in[14];
  const float* bq   = (const float*)d_in[15];
  const float* Wk   = (const float*)d_in[16];
  const float* bk   = (const float*)d_in[17];
  const float* Wv   = (const float*)d_in[18];
  const float* bv   = (const float*)d_in[19];
  const float* Wo   = (const float*)d_in[20];
  const float* bo   = (const float*)d_in[21];
  const float* gw   = (const float*)d_in[22];
  const float* gbp  = (const float*)d_in[23];
  const float* ga   = (const float*)d_in[24];
  const float* l1g  = (const float*)d_in[25];
  const float* l1b  = (const float*)d_in[26];
  const float* f1w  = (const float*)d_in[27];
  const float* f1b  = (const float*)d_in[28];
  const float* f2w  = (const float*)d_in[29];
  const float* f2b  = (const float*)d_in[30];
  const float* l2g  = (const float*)d_in[31];
  const float* l2b  = (const float*)d_in[32];
  const float* rel  = (const float*)d_in[33];

  float* x = (float*)d_out;  // residual stream lives in d_out (fp32)

  // workspace (~130 MB): conv region U unions with transformer buffers
  float* wsf = (float*)d_ws;
  size_t off = 0;
  auto alloc = [&](size_t n){ float* pp = wsf + off; off += (n + 63) & ~(size_t)63; return pp; };
  const size_t XSZ = (size_t)BATCH * SEQ * DMODEL;
  constexpr size_t F_N   = (size_t)512 * 31999;              // 16,383,488 fp32
  constexpr size_t BFA_N = (size_t)512 * 31999 / 2 + 32;     // bf16 as fp32 units
  constexpr size_t BFB_N = (size_t)512 * 15999 / 2 + 32;
  float* U = alloc(F_N + BFA_N + BFB_N);                     // 28.67M floats
  float* F    = U;
  bf16* bfA   = (bf16*)(U + F_N);
  bf16* bfB   = (bf16*)(U + F_N + BFA_N);
  // transformer views inside U (disjoint lifetime vs conv)
  float* ffh  = U;
  float* tmp  = U + 6131776;
  float* qb   = tmp + 1532992;
  float* kb   = qb + 1532992;
  float* vb   = kb + 1532992;
  float* ctx  = vb + 1532992;
  // persistent
  float* feat = alloc((size_t)BATCH * SEQ * 512);
  float* c6   = alloc((size_t)512 * SEQ);
  float* tab  = alloc((size_t)NHEAD * NREL);
  bf16* wposb = (bf16*)alloc((size_t)DMODEL * 48 * 128 / 2);

  const int Ls[8] = {160000, 31999, 15999, 7999, 3999, 1999, 999, 499};
  const int Mrows = BATCH * SEQ; // 1996

  // ---- conv feature extractor ----
  for (int b = 0; b < BATCH; b++){
    conv0_kernel<<<(512 * Ls[1] + 255) / 256, 256, 0, stream>>>(src + (size_t)b * T_IN, w0, F, Ls[1]);
    ln_gelu_ch2_kernel<1><<<(Ls[1] + 31) / 32, 256, 0, stream>>>(F, bfA, clng, clnb, Ls[1]);
    bf16* bfin[2] = {bfA, bfB};
    for (int st = 1; st <= 6; st++){
      const bf16* inb = bfin[(st + 1) & 1];
      int Lin = Ls[st], Lout = Ls[st + 1];
      float* outf = (st == 6) ? c6 : F;
      int oLd = (st == 6) ? SEQ : Lout;
      dim3 grd(8, (Lout + 63) / 64);
      if (st <= 4)
        conv_mfma_kernel<3><<<grd, 256, 0, stream>>>(inb, w14 + (size_t)(st - 1) * 512 * 512 * 3, outf, Lin, Lout, oLd);
      else
        conv_mfma_kernel<2><<<grd, 256, 0, stream>>>(inb, w56 + (size_t)(st - 5) * 512 * 512 * 2, outf, Lin, Lout, oLd);
      if (st < 6)
        ln_gelu_ch2_kernel<1><<<(Lout + 31) / 32, 256, 0, stream>>>(F, bfin[st & 1], clng + st * 512, clnb + st * 512, Lout);
    }
    ln_gelu_ch2_kernel<0><<<(SEQ + 31) / 32, 256, 0, stream>>>(c6, nullptr, clng + 6 * 512, clnb + 6 * 512, SEQ);
    featln_transpose_kernel<<<(SEQ + 255) / 256, 256, 0, stream>>>(c6, flng, flnb, feat + (size_t)b * SEQ * 512);
  }

  gemm_mfma_f32<0><<<dim3(DMODEL / 64, (Mrows + 63) / 64), 256, 0, stream>>>(feat, pjw, pjb, x, Mrows, DMODEL, 512, 1.0f);
  f2bf_kernel<<<(4718592 + 255) / 256, 256, 0, stream>>>(pcw, wposb, 4718592);
  posconv_mfma<<<dim3(8, 16, BATCH), 256, 0, stream>>>(x, wposb, pcb, tmp);
  add_ln_wave<1><<<(Mrows + 3) / 4, 256, 0, stream>>>(x, tmp, eng, enb);
  relbias_kernel<<<(NREL * NHEAD + 255) / 256, 256, 0, stream>>>(rel, tab);

  const size_t WQK = (size_t)DMODEL * DMODEL;
  const size_t WF  = (size_t)FFN * DMODEL;
  for (int l = 0; l < NLAYER; l++){
    gemm_qkv_mfma<<<dim3(12, 32, 3), 256, 0, stream>>>(
        x, Wq + l * WQK, Wk + l * WQK, Wv + l * WQK,
        bq + l * DMODEL, bk + l * DMODEL, bv + l * DMODEL, qb, kb, vb, Mrows);
    attn_fused<<<dim3(32, BATCH * NHEAD), 256, 0, stream>>>(
        qb, kb, vb, x, gw + (size_t)l * 8 * DHEAD, gbp + l * 8, ga + l * NHEAD, tab, ctx);
    gemm_mfma_f32<0><<<dim3(12, 32), 256, 0, stream>>>(ctx, Wo + l * WQK, bo + l * DMODEL, tmp, Mrows, DMODEL, DMODEL, 1.0f);
    add_ln_wave<0><<<(Mrows + 3) / 4, 256, 0, stream>>>(x, tmp, l1g + l * DMODEL, l1b + l * DMODEL);
    gemm_mfma_f32<1><<<dim3(FFN / 64, 32), 256, 0, stream>>>(x, f1w + l * WF, f1b + l * FFN, ffh, Mrows, FFN, DMODEL, 1.0f);
    gemm_mfma_f32<0><<<dim3(12, 32), 256, 0, stream>>>(ffh, f2w + l * WF, f2b + l * DMODEL, tmp, Mrows, DMODEL, FFN, 1.0f);
    add_ln_wave<0><<<(Mrows + 3) / 4, 256, 0, stream>>>(x, tmp, l2g + l * DMODEL, l2b + l * DMODEL);
  }
  // result is already in d_out
}

// Round 17
// 6746.568 us; speedup vs baseline: 13.4078x; 1.0986x over previous
//
#include <hip/hip_runtime.h>
#include <hip/hip_bf16.h>
#include <math.h>

namespace {

constexpr int BATCH  = 4;
constexpr int T_IN   = 160000;
constexpr int DMODEL = 768;
constexpr int NHEAD  = 12;
constexpr int DHEAD  = 64;
constexpr int FFN    = 3072;
constexpr int NLAYER = 12;
constexpr int SEQ    = 499;
constexpr int SP     = 512;
constexpr int NREL   = 2 * SEQ - 1;

typedef __hip_bfloat16 bf16;
using f32x4 = __attribute__((ext_vector_type(4))) float;
using s16x8 = __attribute__((ext_vector_type(8))) short;

__device__ __forceinline__ float gelu_f(float x){
  return 0.5f * x * (1.0f + erff(x * 0.70710678118654752f));
}

__device__ __forceinline__ unsigned f2bf_rne(float f){
  unsigned u = __float_as_uint(f);
  return (u + 0x7FFFu + ((u >> 16) & 1u)) >> 16;
}

__global__ void fill_f32_kernel(float* __restrict__ out, int n, float val){
  int i = blockIdx.x * 256 + threadIdx.x;
  if (i < n) out[i] = val;
}

__global__ void f2bf_kernel(const float* __restrict__ in, bf16* __restrict__ out, int n){
  int i = blockIdx.x * 256 + threadIdx.x;
  if (i < n) out[i] = __float2bfloat16(in[i]);
}

// ---- conv stage 0: k=10, s=5 ----
__global__ void conv0_kernel(const float* __restrict__ src, const float* __restrict__ w,
                             float* __restrict__ out, int Lout){
  int idx = blockIdx.x * 256 + threadIdx.x;
  if (idx >= 512 * Lout) return;
  int c = idx / Lout, t = idx - c * Lout;
  const float* wr = w + c * 10;
  const float* s  = src + t * 5;
  float acc = 0.f;
#pragma unroll
  for (int k = 0; k < 10; k++) acc += wr[k] * s[k];
  out[idx] = acc;
}

// ---- 2D-parallel channel LN + GELU; BFOUT=1: write bf16 to `ob`, else fp32 in place ----
template<int BFOUT>
__global__ void ln_gelu_ch2_kernel(float* __restrict__ x, bf16* __restrict__ ob,
                                   const float* __restrict__ g, const float* __restrict__ b,
                                   int Lt){
  const int tid = threadIdx.x;
  const int tt = tid & 31, tc = tid >> 5;
  const int t = blockIdx.x * 32 + tt;
  __shared__ float sred[8][33], qred[8][33];
  __shared__ float mrow[32], rrow[32];
  float s = 0.f, q = 0.f;
  if (t < Lt){
    const float* xc = x + (size_t)(tc * 64) * Lt + t;
#pragma unroll 8
    for (int j = 0; j < 64; j++){ float v = xc[(size_t)j * Lt]; s += v; q += v * v; }
  }
  sred[tc][tt] = s; qred[tc][tt] = q; __syncthreads();
  if (tid < 32){
    float ss = 0.f, qq = 0.f;
#pragma unroll
    for (int c = 0; c < 8; c++){ ss += sred[c][tid]; qq += qred[c][tid]; }
    float m = ss * (1.f / 512.f);
    float var = qq * (1.f / 512.f) - m * m;
    mrow[tid] = m; rrow[tid] = rsqrtf(var + 1e-5f);
  }
  __syncthreads();
  if (t < Lt){
    float m = mrow[tt], rs = rrow[tt];
    float* xc = x + (size_t)(tc * 64) * Lt + t;
#pragma unroll 8
    for (int j = 0; j < 64; j++){
      int c = tc * 64 + j;
      float v = gelu_f((xc[(size_t)j * Lt] - m) * rs * g[c] + b[c]);
      if (BFOUT) ob[(size_t)c * Lt + t] = __float2bfloat16(v);
      else       xc[(size_t)j * Lt] = v;
    }
  }
}

// ---- conv stages 1..6 via per-k-tap MFMA GEMM; 64co x 128t tile, K=32 ci chunks ----
// comb[jp][ci] holds uint = (bf16 in[2jp], bf16 in[2jp+1]); tap k -> parity k&1, row shift k>>1.
template<int KW>
__global__ void conv_mfma_kernel(const bf16* __restrict__ in, const float* __restrict__ w,
                                 float* __restrict__ out, int Lin, int Lout, int outLd){
  __shared__ unsigned comb[130][33];
  __shared__ bf16 As[KW][64][40];
  const int tid = threadIdx.x, wid = tid >> 6, lane = tid & 63;
  const int co0 = blockIdx.x * 64, t0 = blockIdx.y * 128;
  const int wm = (wid >> 1) * 32, wn = (wid & 1) * 64;
  const int fr = lane & 15, fk = (lane >> 4) * 8;
  const int wco = tid >> 2, wci = (tid & 3) * 8;
  f32x4 acc[2][4] = {};
  for (int ci0 = 0; ci0 < 512; ci0 += 32){
    // ---- stage weights: 8 ci x KW floats per thread, all taps ----
    {
      const float* wp = w + (size_t)(co0 + wco) * (512 * KW) + (size_t)(ci0 + wci) * KW;
      float f[KW * 8];
#pragma unroll
      for (int q = 0; q < (KW * 8) / 4; q++)
        *reinterpret_cast<float4*>(&f[q * 4]) = *reinterpret_cast<const float4*>(wp + q * 4);
#pragma unroll
      for (int k = 0; k < KW; k++){
        uint4 pw;
        pw.x = f2bf_rne(f[0 * KW + k]) | (f2bf_rne(f[1 * KW + k]) << 16);
        pw.y = f2bf_rne(f[2 * KW + k]) | (f2bf_rne(f[3 * KW + k]) << 16);
        pw.z = f2bf_rne(f[4 * KW + k]) | (f2bf_rne(f[5 * KW + k]) << 16);
        pw.w = f2bf_rne(f[6 * KW + k]) | (f2bf_rne(f[7 * KW + k]) << 16);
        *reinterpret_cast<uint4*>(&As[k][wco][wci]) = pw;
      }
    }
    // ---- stage input pairs, jp-major (coalesced) ----
    for (int idx = tid; idx < 4096; idx += 256){
      int jp = idx & 127, ci = idx >> 7;
      int gp = t0 * 2 + 2 * jp;
      const bf16* rp = in + (size_t)(ci0 + ci) * Lin;
      unsigned pr = 0;
      if (gp + 1 < Lin) pr = *reinterpret_cast<const unsigned*>(&rp[gp]);
      else if (gp < Lin) pr = *reinterpret_cast<const unsigned short*>(&rp[gp]);
      comb[jp][ci] = pr;
    }
    if (tid < 64){
      int jp = 128 + (tid >> 5), ci = tid & 31;
      int gp = t0 * 2 + 2 * jp;
      const bf16* rp = in + (size_t)(ci0 + ci) * Lin;
      unsigned pr = 0;
      if (gp + 1 < Lin) pr = *reinterpret_cast<const unsigned*>(&rp[gp]);
      else if (gp < Lin) pr = *reinterpret_cast<const unsigned short*>(&rp[gp]);
      comb[jp][ci] = pr;
    }
    __syncthreads();
#pragma unroll
    for (int k = 0; k < KW; k++){
      const int ro = k >> 1, par = k & 1;
      s16x8 a0 = *reinterpret_cast<const s16x8*>(&As[k][wm + fr][fk]);
      s16x8 a1 = *reinterpret_cast<const s16x8*>(&As[k][wm + 16 + fr][fk]);
#pragma unroll
      for (int ni = 0; ni < 4; ni++){
        const unsigned* cp = &comb[wn + ni * 16 + fr + ro][fk];
        unsigned u0 = cp[0], u1 = cp[1], u2 = cp[2], u3 = cp[3];
        unsigned u4 = cp[4], u5 = cp[5], u6 = cp[6], u7 = cp[7];
        uint4 pb;
        if (par){
          pb.x = (u0 >> 16) | (u1 & 0xFFFF0000u);
          pb.y = (u2 >> 16) | (u3 & 0xFFFF0000u);
          pb.z = (u4 >> 16) | (u5 & 0xFFFF0000u);
          pb.w = (u6 >> 16) | (u7 & 0xFFFF0000u);
        } else {
          pb.x = (u0 & 0xFFFFu) | (u1 << 16);
          pb.y = (u2 & 0xFFFFu) | (u3 << 16);
          pb.z = (u4 & 0xFFFFu) | (u5 << 16);
          pb.w = (u6 & 0xFFFFu) | (u7 << 16);
        }
        s16x8 bb = *reinterpret_cast<s16x8*>(&pb);
        acc[0][ni] = __builtin_amdgcn_mfma_f32_16x16x32_bf16(a0, bb, acc[0][ni], 0, 0, 0);
        acc[1][ni] = __builtin_amdgcn_mfma_f32_16x16x32_bf16(a1, bb, acc[1][ni], 0, 0, 0);
      }
    }
    __syncthreads();
  }
  const int cc = lane & 15, crr = (lane >> 4) * 4;
#pragma unroll
  for (int mi = 0; mi < 2; mi++){
#pragma unroll
    for (int ni = 0; ni < 4; ni++){
      int t = t0 + wn + ni * 16 + cc;
      if (t >= Lout) continue;
#pragma unroll
      for (int r = 0; r < 4; r++){
        int co = co0 + wm + mi * 16 + crr + r;
        out[(size_t)co * outLd + t] = acc[mi][ni][r];
      }
    }
  }
}

// ---- final feature LN + transpose (512,S)->(S,512) ----
__global__ void featln_transpose_kernel(const float* __restrict__ xin,
                                        const float* __restrict__ g, const float* __restrict__ b,
                                        float* __restrict__ feat){
  int t = blockIdx.x * 256 + threadIdx.x;
  if (t >= SEQ) return;
  float s = 0.f, sq = 0.f;
  for (int c = 0; c < 512; c++){ float v = xin[c * SEQ + t]; s += v; sq += v * v; }
  float m = s * (1.f / 512.f), var = sq * (1.f / 512.f) - m * m, rs = rsqrtf(var + 1e-5f);
  for (int c = 0; c < 512; c++)
    feat[t * 512 + c] = (xin[c * SEQ + t] - m) * rs * g[c] + b[c];
}

// ---- MFMA GEMM, fp32 inputs (bf16 cast fused): C = act(alpha*(A @ W^T + bias)) ----
template<int ACT>
__global__ void gemm_mfma_f32(const float* __restrict__ A, const float* __restrict__ W,
                              const float* __restrict__ bias, float* __restrict__ C,
                              int M, int N, int K, float alpha){
  __shared__ bf16 As[64][40];
  __shared__ bf16 Ws[64][40];
  const int tid = threadIdx.x;
  const int wid = tid >> 6, lane = tid & 63;
  const int m0 = blockIdx.y * 64, n0 = blockIdx.x * 64;
  const int wm = (wid >> 1) * 32, wn = (wid & 1) * 32;
  const int lrow = tid >> 2;
  const int lk   = (tid & 3) * 8;
  const int fr = lane & 15, fk = (lane >> 4) * 8;
  f32x4 acc[2][2] = {};
  for (int k0 = 0; k0 < K; k0 += 32){
    float4 a0 = make_float4(0.f,0.f,0.f,0.f), a1 = make_float4(0.f,0.f,0.f,0.f);
    int gm = m0 + lrow;
    if (gm < M){
      const float* ap = &A[(size_t)gm * K + k0 + lk];
      a0 = *reinterpret_cast<const float4*>(ap);
      a1 = *reinterpret_cast<const float4*>(ap + 4);
    }
    uint4 pa;
    pa.x = f2bf_rne(a0.x) | (f2bf_rne(a0.y) << 16);
    pa.y = f2bf_rne(a0.z) | (f2bf_rne(a0.w) << 16);
    pa.z = f2bf_rne(a1.x) | (f2bf_rne(a1.y) << 16);
    pa.w = f2bf_rne(a1.z) | (f2bf_rne(a1.w) << 16);
    *reinterpret_cast<uint4*>(&As[lrow][lk]) = pa;
    const float* wp = &W[(size_t)(n0 + lrow) * K + k0 + lk];
    float4 w0 = *reinterpret_cast<const float4*>(wp);
    float4 w1 = *reinterpret_cast<const float4*>(wp + 4);
    uint4 pw;
    pw.x = f2bf_rne(w0.x) | (f2bf_rne(w0.y) << 16);
    pw.y = f2bf_rne(w0.z) | (f2bf_rne(w0.w) << 16);
    pw.z = f2bf_rne(w1.x) | (f2bf_rne(w1.y) << 16);
    pw.w = f2bf_rne(w1.z) | (f2bf_rne(w1.w) << 16);
    *reinterpret_cast<uint4*>(&Ws[lrow][lk]) = pw;
    __syncthreads();
    s16x8 av0 = *reinterpret_cast<const s16x8*>(&As[wm + fr][fk]);
    s16x8 av1 = *reinterpret_cast<const s16x8*>(&As[wm + 16 + fr][fk]);
    s16x8 bv0 = *reinterpret_cast<const s16x8*>(&Ws[wn + fr][fk]);
    s16x8 bv1 = *reinterpret_cast<const s16x8*>(&Ws[wn + 16 + fr][fk]);
    acc[0][0] = __builtin_amdgcn_mfma_f32_16x16x32_bf16(av0, bv0, acc[0][0], 0, 0, 0);
    acc[0][1] = __builtin_amdgcn_mfma_f32_16x16x32_bf16(av0, bv1, acc[0][1], 0, 0, 0);
    acc[1][0] = __builtin_amdgcn_mfma_f32_16x16x32_bf16(av1, bv0, acc[1][0], 0, 0, 0);
    acc[1][1] = __builtin_amdgcn_mfma_f32_16x16x32_bf16(av1, bv1, acc[1][1], 0, 0, 0);
    __syncthreads();
  }
  const int cc = lane & 15, cr = (lane >> 4) * 4;
#pragma unroll
  for (int mi = 0; mi < 2; mi++){
#pragma unroll
    for (int ni = 0; ni < 2; ni++){
      int n = n0 + wn + ni * 16 + cc;
      float bn = bias[n];
#pragma unroll
      for (int r = 0; r < 4; r++){
        int m = m0 + wm + mi * 16 + cr + r;
        if (m < M){
          float v = alpha * (acc[mi][ni][r] + bn);
          if (ACT == 1) v = gelu_f(v);
          C[(size_t)m * N + n] = v;
        }
      }
    }
  }
}

// ---- fused QKV (z selects Wq/Wk/Wv) ----
__global__ void gemm_qkv_mfma(const float* __restrict__ A,
                              const float* __restrict__ Wq, const float* __restrict__ Wk,
                              const float* __restrict__ Wv,
                              const float* __restrict__ bqv, const float* __restrict__ bkv,
                              const float* __restrict__ bvv,
                              float* __restrict__ qb, float* __restrict__ kb,
                              float* __restrict__ vb, int M){
  const int z = blockIdx.z;
  const float* W   = (z == 0) ? Wq : (z == 1) ? Wk : Wv;
  const float* bia = (z == 0) ? bqv : (z == 1) ? bkv : bvv;
  float* C         = (z == 0) ? qb : (z == 1) ? kb : vb;
  const float alpha = (z == 0) ? 0.125f : 1.0f;
  const int K = DMODEL, N = DMODEL;
  __shared__ bf16 As[64][40];
  __shared__ bf16 Ws[64][40];
  const int tid = threadIdx.x;
  const int wid = tid >> 6, lane = tid & 63;
  const int m0 = blockIdx.y * 64, n0 = blockIdx.x * 64;
  const int wm = (wid >> 1) * 32, wn = (wid & 1) * 32;
  const int lrow = tid >> 2;
  const int lk   = (tid & 3) * 8;
  const int fr = lane & 15, fk = (lane >> 4) * 8;
  f32x4 acc[2][2] = {};
  for (int k0 = 0; k0 < K; k0 += 32){
    float4 a0 = make_float4(0.f,0.f,0.f,0.f), a1 = make_float4(0.f,0.f,0.f,0.f);
    int gm = m0 + lrow;
    if (gm < M){
      const float* ap = &A[(size_t)gm * K + k0 + lk];
      a0 = *reinterpret_cast<const float4*>(ap);
      a1 = *reinterpret_cast<const float4*>(ap + 4);
    }
    uint4 pa;
    pa.x = f2bf_rne(a0.x) | (f2bf_rne(a0.y) << 16);
    pa.y = f2bf_rne(a0.z) | (f2bf_rne(a0.w) << 16);
    pa.z = f2bf_rne(a1.x) | (f2bf_rne(a1.y) << 16);
    pa.w = f2bf_rne(a1.z) | (f2bf_rne(a1.w) << 16);
    *reinterpret_cast<uint4*>(&As[lrow][lk]) = pa;
    const float* wp = &W[(size_t)(n0 + lrow) * K + k0 + lk];
    float4 w0 = *reinterpret_cast<const float4*>(wp);
    float4 w1 = *reinterpret_cast<const float4*>(wp + 4);
    uint4 pw;
    pw.x = f2bf_rne(w0.x) | (f2bf_rne(w0.y) << 16);
    pw.y = f2bf_rne(w0.z) | (f2bf_rne(w0.w) << 16);
    pw.z = f2bf_rne(w1.x) | (f2bf_rne(w1.y) << 16);
    pw.w = f2bf_rne(w1.z) | (f2bf_rne(w1.w) << 16);
    *reinterpret_cast<uint4*>(&Ws[lrow][lk]) = pw;
    __syncthreads();
    s16x8 av0 = *reinterpret_cast<const s16x8*>(&As[wm + fr][fk]);
    s16x8 av1 = *reinterpret_cast<const s16x8*>(&As[wm + 16 + fr][fk]);
    s16x8 bv0 = *reinterpret_cast<const s16x8*>(&Ws[wn + fr][fk]);
    s16x8 bv1 = *reinterpret_cast<const s16x8*>(&Ws[wn + 16 + fr][fk]);
    acc[0][0] = __builtin_amdgcn_mfma_f32_16x16x32_bf16(av0, bv0, acc[0][0], 0, 0, 0);
    acc[0][1] = __builtin_amdgcn_mfma_f32_16x16x32_bf16(av0, bv1, acc[0][1], 0, 0, 0);
    acc[1][0] = __builtin_amdgcn_mfma_f32_16x16x32_bf16(av1, bv0, acc[1][0], 0, 0, 0);
    acc[1][1] = __builtin_amdgcn_mfma_f32_16x16x32_bf16(av1, bv1, acc[1][1], 0, 0, 0);
    __syncthreads();
  }
  const int cc = lane & 15, cr = (lane >> 4) * 4;
#pragma unroll
  for (int mi = 0; mi < 2; mi++){
#pragma unroll
    for (int ni = 0; ni < 2; ni++){
      int n = n0 + wn + ni * 16 + cc;
      float bn = bia[n];
#pragma unroll
      for (int r = 0; r < 4; r++){
        int m = m0 + wm + mi * 16 + cr + r;
        if (m < M) C[(size_t)m * N + n] = alpha * (acc[mi][ni][r] + bn);
      }
    }
  }
}

// ---- posconv via MFMA ----
__global__ void posconv_mfma(const float* __restrict__ x, const bf16* __restrict__ wpos,
                             const float* __restrict__ bias, float* __restrict__ xc){
  const int t0 = blockIdx.x * 64, g = blockIdx.y, b = blockIdx.z;
  __shared__ bf16 As[64][40];
  __shared__ float xw[224];
  const int tid = threadIdx.x, wid = tid >> 6, lane = tid & 63;
  const int wm = (wid >> 1) * 32, wn = (wid & 1) * 32;
  const int lrow = tid >> 2, lk = (tid & 3) * 8;
  const int fr = lane & 15, fk = (lane >> 4) * 8;
  f32x4 acc[2][2] = {};
  for (int ci = 0; ci < 48; ci++){
    for (int idx = tid; idx < 191; idx += 256){
      int p = t0 - 64 + idx;
      xw[idx] = (p >= 0 && p < SEQ) ? x[((size_t)(b * SEQ + p)) * DMODEL + g * 48 + ci] : 0.f;
    }
    for (int kk = 0; kk < 128; kk += 32){
      uint4 wa = make_uint4(0, 0, 0, 0);
      if (lrow < 48)
        wa = *reinterpret_cast<const uint4*>(&wpos[(size_t)(g * 48 + lrow) * 6144 + ci * 128 + kk + lk]);
      *reinterpret_cast<uint4*>(&As[lrow][lk]) = wa;
      __syncthreads();
      auto bfragp = [&](int tr)->s16x8{
        int base = tr + kk + fk;
        s16x8 r;
#pragma unroll
        for (int j = 0; j < 8; j++) r[j] = (short)f2bf_rne(xw[base + j]);
        return r;
      };
      s16x8 a0 = *reinterpret_cast<const s16x8*>(&As[wm + fr][fk]);
      s16x8 a1 = *reinterpret_cast<const s16x8*>(&As[wm + 16 + fr][fk]);
      s16x8 b0 = bfragp(wn + fr);
      s16x8 b1 = bfragp(wn + 16 + fr);
      acc[0][0] = __builtin_amdgcn_mfma_f32_16x16x32_bf16(a0, b0, acc[0][0], 0, 0, 0);
      acc[0][1] = __builtin_amdgcn_mfma_f32_16x16x32_bf16(a0, b1, acc[0][1], 0, 0, 0);
      acc[1][0] = __builtin_amdgcn_mfma_f32_16x16x32_bf16(a1, b0, acc[1][0], 0, 0, 0);
      acc[1][1] = __builtin_amdgcn_mfma_f32_16x16x32_bf16(a1, b1, acc[1][1], 0, 0, 0);
      __syncthreads();
    }
  }
  const int cc = lane & 15, cr = (lane >> 4) * 4;
#pragma unroll
  for (int mi = 0; mi < 2; mi++){
#pragma unroll
    for (int ni = 0; ni < 2; ni++){
      int t = t0 + wn + ni * 16 + cc;
      if (t >= SEQ) continue;
#pragma unroll
      for (int r = 0; r < 4; r++){
        int cop = wm + mi * 16 + cr + r;
        if (cop < 48){
          int co = g * 48 + cop;
          xc[((size_t)(b * SEQ + t)) * DMODEL + co] = acc[mi][ni][r] + bias[co];
        }
      }
    }
  }
}

// ---- FUSED attention with in-block gate: QK^T -> softmax(+gate*relbias) -> PV ----
__global__ void attn_fused(const float* __restrict__ q, const float* __restrict__ k,
                           const float* __restrict__ v, const float* __restrict__ x,
                           const float* __restrict__ gwl, const float* __restrict__ gbl,
                           const float* __restrict__ gal,
                           const float* __restrict__ tab, float* __restrict__ ctx){
  const int bh = blockIdx.y, b = bh / NHEAD, h = bh % NHEAD;
  const int i0 = blockIdx.x * 16;
  const int tid = threadIdx.x, w = tid >> 6, lane = tid & 63;
  const int fr = lane & 15, fk = (lane >> 4) * 8;
  const int cr = (lane >> 4) * 4;
  __shared__ float sc[16][524];
  __shared__ short qs[16][72];
  __shared__ short kv[64][72];
  __shared__ float gtmp[16][9];
  __shared__ float gl[16];
  {
    int r = tid >> 4, c = (tid & 15) * 4;
    int gi = i0 + r;
    float4 qv = make_float4(0.f,0.f,0.f,0.f);
    if (gi < SEQ) qv = *reinterpret_cast<const float4*>(&q[((size_t)(b*SEQ+gi))*DMODEL + h*DHEAD + c]);
    uint2 p;
    p.x = f2bf_rne(qv.x) | (f2bf_rne(qv.y) << 16);
    p.y = f2bf_rne(qv.z) | (f2bf_rne(qv.w) << 16);
    *reinterpret_cast<uint2*>(&qs[r][c]) = p;
  }
  if (tid < 128){
    int r = tid >> 3, g = tid & 7;
    int gi = i0 + r;
    float a = gbl[g];
    if (gi < SEQ){
      const float* xv = x + ((size_t)(b * SEQ + gi)) * DMODEL + h * DHEAD;
      const float* wrow = gwl + g * DHEAD;
#pragma unroll
      for (int d = 0; d < 64; d++) a += xv[d] * wrow[d];
    }
    gtmp[r][g] = a;
  }
  __syncthreads();
  if (tid < 16){
    float a0 = gtmp[tid][0] + gtmp[tid][1] + gtmp[tid][2] + gtmp[tid][3];
    float a1 = gtmp[tid][4] + gtmp[tid][5] + gtmp[tid][6] + gtmp[tid][7];
    float g0 = 1.f / (1.f + expf(-a0));
    float g1 = 1.f / (1.f + expf(-a1));
    gl[tid] = g0 * (g1 * gal[h] - 1.f) + 2.f;
  }
  for (int j0 = 0; j0 < SP; j0 += 64){
    __syncthreads();
    {
      int jr = tid >> 2, c0 = (tid & 3) * 16;
      int gj = j0 + jr;
      float4 f0 = make_float4(0.f,0.f,0.f,0.f), f1 = f0, f2 = f0, f3 = f0;
      if (gj < SEQ){
        const float* kp = &k[((size_t)(b*SEQ+gj))*DMODEL + h*DHEAD + c0];
        f0 = *reinterpret_cast<const float4*>(kp);
        f1 = *reinterpret_cast<const float4*>(kp + 4);
        f2 = *reinterpret_cast<const float4*>(kp + 8);
        f3 = *reinterpret_cast<const float4*>(kp + 12);
      }
      uint4 pa;
      pa.x = f2bf_rne(f0.x) | (f2bf_rne(f0.y) << 16);
      pa.y = f2bf_rne(f0.z) | (f2bf_rne(f0.w) << 16);
      pa.z = f2bf_rne(f1.x) | (f2bf_rne(f1.y) << 16);
      pa.w = f2bf_rne(f1.z) | (f2bf_rne(f1.w) << 16);
      *reinterpret_cast<uint4*>(&kv[jr][c0]) = pa;
      uint4 pb;
      pb.x = f2bf_rne(f2.x) | (f2bf_rne(f2.y) << 16);
      pb.y = f2bf_rne(f2.z) | (f2bf_rne(f2.w) << 16);
      pb.z = f2bf_rne(f3.x) | (f2bf_rne(f3.y) << 16);
      pb.w = f2bf_rne(f3.z) | (f2bf_rne(f3.w) << 16);
      *reinterpret_cast<uint4*>(&kv[jr][c0 + 8]) = pb;
    }
    __syncthreads();
    f32x4 accqk = {};
#pragma unroll
    for (int kk = 0; kk < 2; kk++){
      s16x8 a = *reinterpret_cast<const s16x8*>(&qs[fr][kk*32 + fk]);
      s16x8 bb = *reinterpret_cast<const s16x8*>(&kv[w*16 + fr][kk*32 + fk]);
      accqk = __builtin_amdgcn_mfma_f32_16x16x32_bf16(a, bb, accqk, 0, 0, 0);
    }
#pragma unroll
    for (int r = 0; r < 4; r++)
      sc[cr + r][j0 + w*16 + fr] = accqk[r];
  }
  __syncthreads();
  for (int r = 0; r < 4; r++){
    int row = w * 4 + r;
    int gi = i0 + row;
    if (gi >= SEQ) continue;
    float gt = gl[row];
    const float* tb = tab + (size_t)h * NREL + (SEQ - 1 - gi);
    float vals[8];
    float mx = -1e30f;
#pragma unroll
    for (int it = 0; it < 8; it++){
      int j = lane + it * 64;
      float vv = (j < SEQ) ? (sc[row][j] + gt * tb[j]) : -1e30f;
      vals[it] = vv; mx = fmaxf(mx, vv);
    }
#pragma unroll
    for (int m = 32; m > 0; m >>= 1) mx = fmaxf(mx, __shfl_xor(mx, m));
    float sum = 0.f;
#pragma unroll
    for (int it = 0; it < 8; it++){
      int j = lane + it * 64;
      float e = (j < SEQ) ? expf(vals[it] - mx) : 0.f;
      vals[it] = e; sum += e;
    }
#pragma unroll
    for (int m = 32; m > 0; m >>= 1) sum += __shfl_xor(sum, m);
    float inv = 1.f / sum;
#pragma unroll
    for (int it = 0; it < 8; it++){
      int j = lane + it * 64;
      sc[row][j] = vals[it] * inv;
    }
  }
  __syncthreads();
  f32x4 accpv = {};
  for (int j0 = 0; j0 < SP; j0 += 64){
    __syncthreads();
    {
      int jr = tid >> 2, c0 = (tid & 3) * 16;
      int gj = j0 + jr;
      float4 f0 = make_float4(0.f,0.f,0.f,0.f), f1 = f0, f2 = f0, f3 = f0;
      if (gj < SEQ){
        const float* vp = &v[((size_t)(b*SEQ+gj))*DMODEL + h*DHEAD + c0];
        f0 = *reinterpret_cast<const float4*>(vp);
        f1 = *reinterpret_cast<const float4*>(vp + 4);
        f2 = *reinterpret_cast<const float4*>(vp + 8);
        f3 = *reinterpret_cast<const float4*>(vp + 12);
      }
      uint4 pa;
      pa.x = f2bf_rne(f0.x) | (f2bf_rne(f0.y) << 16);
      pa.y = f2bf_rne(f0.z) | (f2bf_rne(f0.w) << 16);
      pa.z = f2bf_rne(f1.x) | (f2bf_rne(f1.y) << 16);
      pa.w = f2bf_rne(f1.z) | (f2bf_rne(f1.w) << 16);
      *reinterpret_cast<uint4*>(&kv[jr][c0]) = pa;
      uint4 pb;
      pb.x = f2bf_rne(f2.x) | (f2bf_rne(f2.y) << 16);
      pb.y = f2bf_rne(f2.z) | (f2bf_rne(f2.w) << 16);
      pb.z = f2bf_rne(f3.x) | (f2bf_rne(f3.y) << 16);
      pb.w = f2bf_rne(f3.z) | (f2bf_rne(f3.w) << 16);
      *reinterpret_cast<uint4*>(&kv[jr][c0 + 8]) = pb;
    }
    __syncthreads();
#pragma unroll
    for (int kk = 0; kk < 2; kk++){
      s16x8 a, bb;
#pragma unroll
      for (int e = 0; e < 8; e++){
        a[e]  = (short)f2bf_rne(sc[fr][j0 + kk*32 + fk + e]);
        bb[e] = kv[kk*32 + fk + e][w*16 + fr];
      }
      accpv = __builtin_amdgcn_mfma_f32_16x16x32_bf16(a, bb, accpv, 0, 0, 0);
    }
  }
#pragma unroll
  for (int r = 0; r < 4; r++){
    int gi = i0 + cr + r;
    if (gi < SEQ)
      ctx[((size_t)(b*SEQ+gi))*DMODEL + h*DHEAD + w*16 + fr] = accpv[r];
  }
}

// ---- wave-per-row residual add (+optional GELU) + LayerNorm; 4 rows/block ----
template<int GELU_ADD>
__global__ void add_ln_wave(float* __restrict__ x, const float* __restrict__ add,
                            const float* __restrict__ g, const float* __restrict__ b){
  int row = blockIdx.x * 4 + (threadIdx.x >> 6);
  if (row >= BATCH * SEQ) return;
  int lane = threadIdx.x & 63;
  float* xr = x + (size_t)row * DMODEL;
  const float* ar = add + (size_t)row * DMODEL;
  float buf[12];
  float s = 0.f;
#pragma unroll
  for (int it = 0; it < 12; it++){
    int i = lane + it * 64;
    float v = ar[i];
    if (GELU_ADD) v = gelu_f(v);
    v += xr[i];
    buf[it] = v; s += v;
  }
#pragma unroll
  for (int m = 32; m > 0; m >>= 1) s += __shfl_xor(s, m);
  float mean = s * (1.f / 768.f);
  float q = 0.f;
#pragma unroll
  for (int it = 0; it < 12; it++){ float d = buf[it] - mean; q += d * d; }
#pragma unroll
  for (int m = 32; m > 0; m >>= 1) q += __shfl_xor(q, m);
  float rs = rsqrtf(q * (1.f / 768.f) + 1e-5f);
#pragma unroll
  for (int it = 0; it < 12; it++){
    int i = lane + it * 64;
    xr[i] = (buf[it] - mean) * rs * g[i] + b[i];
  }
}

// ---- T5-style relative position bias table ----
__global__ void relbias_kernel(const float* __restrict__ rel_emb, float* __restrict__ tab){
  int idx = blockIdx.x * 256 + threadIdx.x;
  if (idx >= NREL * NHEAD) return;
  int rr = idx / NHEAD, h = idx - rr * NHEAD;
  int rel = rr - (SEQ - 1);
  int bkt = (rel > 0) ? 160 : 0;
  int n = (rel < 0) ? -rel : rel;
  if (n < 80) bkt += n;
  else {
    int large = 80 + (int)(logf((float)n / 80.f) / logf(10.f) * 80.f);
    bkt += (large < 159) ? large : 159;
  }
  tab[h * NREL + rr] = rel_emb[bkt * NHEAD + h];
}

} // anonymous namespace

extern "C" void kernel_launch(void* const* d_in, const int* in_sizes, int n_in,
                              void* d_out, int out_size, void* d_ws, size_t ws_size,
                              hipStream_t stream){
  (void)ws_size;

  static const int DS[34] = {640000,5120,3145728,1048576,3584,3584,512,512,393216,768,
                             4718592,768,768,768,7077888,9216,7077888,9216,7077888,9216,
                             7077888,9216,6144,96,144,9216,9216,28311552,36864,28311552,
                             9216,9216,9216,3840};
  bool ok = (n_in == 34) && (out_size == BATCH * SEQ * DMODEL);
  if (ok) for (int i = 0; i < 34; i++) if (in_sizes[i] != DS[i]) { ok = false; break; }
  if (!ok){
    fill_f32_kernel<<<(out_size + 255) / 256, 256, 0, stream>>>((float*)d_out, out_size, 1000.0f);
    return;
  }

  const float* src  = (const float*)d_in[0];
  const float* w0   = (const float*)d_in[1];
  const float* w14  = (const float*)d_in[2];
  const float* w56  = (const float*)d_in[3];
  const float* clng = (const float*)d_in[4];
  const float* clnb = (const float*)d_in[5];
  const float* flng = (const float*)d_in[6];
  const float* flnb = (const float*)d_in[7];
  const float* pjw  = (const float*)d_in[8];
  const float* pjb  = (const float*)d_in[9];
  const float* pcw  = (const float*)d_in[10];
  const float* pcb  = (const float*)d_in[11];
  const float* eng  = (const float*)d_in[12];
  const float* enb  = (const float*)d_in[13];
  const float* Wq   = (const float*)d_in[14];
  const float* bq   = (const float*)d_in[15];
  const float* Wk   = (const float*)d_in[16];
  const float* bk   = (const float*)d_in[17];
  const float* Wv   = (const float*)d_in[18];
  const float* bv   = (const float*)d_in[19];
  const float* Wo   = (const float*)d_in[20];
  const float* bo   = (const float*)d_in[21];
  const float* gw   = (const float*)d_in[22];
  const float* gbp  = (const float*)d_in[23];
  const float* ga   = (const float*)d_in[24];
  const float* l1g  = (const float*)d_in[25];
  const float* l1b  = (const float*)d_in[26];
  const float* f1w  = (const float*)d_in[27];
  const float* f1b  = (const float*)d_in[28];
  const float* f2w  = (const float*)d_in[29];
  const float* f2b  = (const float*)d_in[30];
  const float* l2g  = (const float*)d_in[31];
  const float* l2b  = (const float*)d_in[32];
  const float* rel  = (const float*)d_in[33];

  float* x = (float*)d_out;  // residual stream lives in d_out (fp32)

  // workspace (~130 MB): conv region U unions with transformer buffers
  float* wsf = (float*)d_ws;
  size_t off = 0;
  auto alloc = [&](size_t n){ float* pp = wsf + off; off += (n + 63) & ~(size_t)63; return pp; };
  const size_t XSZ = (size_t)BATCH * SEQ * DMODEL;
  constexpr size_t F_N   = (size_t)512 * 31999;              // 16,383,488 fp32
  constexpr size_t BFA_N = (size_t)512 * 31999 / 2 + 32;     // bf16 as fp32 units
  constexpr size_t BFB_N = (size_t)512 * 15999 / 2 + 32;
  float* U = alloc(F_N + BFA_N + BFB_N);                     // 28.67M floats
  float* F    = U;
  bf16* bfA   = (bf16*)(U + F_N);
  bf16* bfB   = (bf16*)(U + F_N + BFA_N);
  // transformer views inside U (disjoint lifetime vs conv)
  float* ffh  = U;
  float* tmp  = U + 6131776;
  float* qb   = tmp + 1532992;
  float* kb   = qb + 1532992;
  float* vb   = kb + 1532992;
  float* ctx  = vb + 1532992;
  // persistent
  float* feat = alloc((size_t)BATCH * SEQ * 512);
  float* c6   = alloc((size_t)512 * SEQ);
  float* tab  = alloc((size_t)NHEAD * NREL);
  bf16* wposb = (bf16*)alloc((size_t)DMODEL * 48 * 128 / 2);

  const int Ls[8] = {160000, 31999, 15999, 7999, 3999, 1999, 999, 499};
  const int Mrows = BATCH * SEQ; // 1996

  // ---- conv feature extractor ----
  for (int b = 0; b < BATCH; b++){
    conv0_kernel<<<(512 * Ls[1] + 255) / 256, 256, 0, stream>>>(src + (size_t)b * T_IN, w0, F, Ls[1]);
    ln_gelu_ch2_kernel<1><<<(Ls[1] + 31) / 32, 256, 0, stream>>>(F, bfA, clng, clnb, Ls[1]);
    bf16* bfin[2] = {bfA, bfB};
    for (int st = 1; st <= 6; st++){
      const bf16* inb = bfin[(st + 1) & 1];
      int Lin = Ls[st], Lout = Ls[st + 1];
      float* outf = (st == 6) ? c6 : F;
      int oLd = (st == 6) ? SEQ : Lout;
      dim3 grd(8, (Lout + 127) / 128);
      if (st <= 4)
        conv_mfma_kernel<3><<<grd, 256, 0, stream>>>(inb, w14 + (size_t)(st - 1) * 512 * 512 * 3, outf, Lin, Lout, oLd);
      else
        conv_mfma_kernel<2><<<grd, 256, 0, stream>>>(inb, w56 + (size_t)(st - 5) * 512 * 512 * 2, outf, Lin, Lout, oLd);
      if (st < 6)
        ln_gelu_ch2_kernel<1><<<(Lout + 31) / 32, 256, 0, stream>>>(F, bfin[st & 1], clng + st * 512, clnb + st * 512, Lout);
    }
    ln_gelu_ch2_kernel<0><<<(SEQ + 31) / 32, 256, 0, stream>>>(c6, nullptr, clng + 6 * 512, clnb + 6 * 512, SEQ);
    featln_transpose_kernel<<<(SEQ + 255) / 256, 256, 0, stream>>>(c6, flng, flnb, feat + (size_t)b * SEQ * 512);
  }

  gemm_mfma_f32<0><<<dim3(DMODEL / 64, (Mrows + 63) / 64), 256, 0, stream>>>(feat, pjw, pjb, x, Mrows, DMODEL, 512, 1.0f);
  f2bf_kernel<<<(4718592 + 255) / 256, 256, 0, stream>>>(pcw, wposb, 4718592);
  posconv_mfma<<<dim3(8, 16, BATCH), 256, 0, stream>>>(x, wposb, pcb, tmp);
  add_ln_wave<1><<<(Mrows + 3) / 4, 256, 0, stream>>>(x, tmp, eng, enb);
  relbias_kernel<<<(NREL * NHEAD + 255) / 256, 256, 0, stream>>>(rel, tab);

  const size_t WQK = (size_t)DMODEL * DMODEL;
  const size_t WF  = (size_t)FFN * DMODEL;
  for (int l = 0; l < NLAYER; l++){
    gemm_qkv_mfma<<<dim3(12, 32, 3), 256, 0, stream>>>(
        x, Wq + l * WQK, Wk + l * WQK, Wv + l * WQK,
        bq + l * DMODEL, bk + l * DMODEL, bv + l * DMODEL, qb, kb, vb, Mrows);
    attn_fused<<<dim3(32, BATCH * NHEAD), 256, 0, stream>>>(
        qb, kb, vb, x, gw + (size_t)l * 8 * DHEAD, gbp + l * 8, ga + l * NHEAD, tab, ctx);
    gemm_mfma_f32<0><<<dim3(12, 32), 256, 0, stream>>>(ctx, Wo + l * WQK, bo + l * DMODEL, tmp, Mrows, DMODEL, DMODEL, 1.0f);
    add_ln_wave<0><<<(Mrows + 3) / 4, 256, 0, stream>>>(x, tmp, l1g + l * DMODEL, l1b + l * DMODEL);
    gemm_mfma_f32<1><<<dim3(FFN / 64, 32), 256, 0, stream>>>(x, f1w + l * WF, f1b + l * FFN, ffh, Mrows, FFN, DMODEL, 1.0f);
    gemm_mfma_f32<0><<<dim3(12, 32), 256, 0, stream>>>(ffh, f2w + l * WF, f2b + l * DMODEL, tmp, Mrows, DMODEL, FFN, 1.0f);
    add_ln_wave<0><<<(Mrows + 3) / 4, 256, 0, stream>>>(x, tmp, l2g + l * DMODEL, l2b + l * DMODEL);
  }
  // result is already in d_out
}

// Round 18
// 5807.781 us; speedup vs baseline: 15.5750x; 1.1616x over previous
//
#include <hip/hip_runtime.h>
#include <hip/hip_bf16.h>
#include <math.h>

namespace {

constexpr int BATCH  = 4;
constexpr int T_IN   = 160000;
constexpr int DMODEL = 768;
constexpr int NHEAD  = 12;
constexpr int DHEAD  = 64;
constexpr int FFN    = 3072;
constexpr int NLAYER = 12;
constexpr int SEQ    = 499;
constexpr int SP     = 512;
constexpr int NREL   = 2 * SEQ - 1;

typedef __hip_bfloat16 bf16;
using f32x4 = __attribute__((ext_vector_type(4))) float;
using s16x8 = __attribute__((ext_vector_type(8))) short;

__device__ __forceinline__ float gelu_f(float x){
  return 0.5f * x * (1.0f + erff(x * 0.70710678118654752f));
}

__device__ __forceinline__ unsigned f2bf_rne(float f){
  unsigned u = __float_as_uint(f);
  return (u + 0x7FFFu + ((u >> 16) & 1u)) >> 16;
}

__global__ void fill_f32_kernel(float* __restrict__ out, int n, float val){
  int i = blockIdx.x * 256 + threadIdx.x;
  if (i < n) out[i] = val;
}

__global__ void f2bf_kernel(const float* __restrict__ in, bf16* __restrict__ out, int n){
  int i = blockIdx.x * 256 + threadIdx.x;
  if (i < n) out[i] = __float2bfloat16(in[i]);
}

// ---- per-layer weight cast: z selects one of 6 regions ----
__global__ void castw6(const float* __restrict__ wq, const float* __restrict__ wk,
                       const float* __restrict__ wv, const float* __restrict__ wo,
                       const float* __restrict__ f1, const float* __restrict__ f2,
                       bf16* __restrict__ d0, bf16* __restrict__ d1, bf16* __restrict__ d2,
                       bf16* __restrict__ d3, bf16* __restrict__ d4, bf16* __restrict__ d5){
  int z = blockIdx.y;
  int idx = blockIdx.x * 256 + threadIdx.x;
  const float* s; bf16* d; int n;
  switch (z){
    case 0: s = wq; d = d0; n = 589824; break;
    case 1: s = wk; d = d1; n = 589824; break;
    case 2: s = wv; d = d2; n = 589824; break;
    case 3: s = wo; d = d3; n = 589824; break;
    case 4: s = f1; d = d4; n = 2359296; break;
    default: s = f2; d = d5; n = 2359296; break;
  }
  if (idx < n) d[idx] = __float2bfloat16(s[idx]);
}

// ---- conv weight pre-pack: w[co][ci][KW] fp32 -> dst[k][co][ci] bf16 ----
template<int KW>
__global__ void pack_convw(const float* __restrict__ w, bf16* __restrict__ dst){
  int idx = blockIdx.x * 256 + threadIdx.x;
  if (idx >= KW * 512 * 512) return;
  int ci = idx & 511, co = (idx >> 9) & 511, k = idx >> 18;
  dst[idx] = __float2bfloat16(w[((size_t)co * 512 + ci) * KW + k]);
}

// ---- conv stage 0: k=10, s=5 ----
__global__ void conv0_kernel(const float* __restrict__ src, const float* __restrict__ w,
                             float* __restrict__ out, int Lout){
  int idx = blockIdx.x * 256 + threadIdx.x;
  if (idx >= 512 * Lout) return;
  int c = idx / Lout, t = idx - c * Lout;
  const float* wr = w + c * 10;
  const float* s  = src + t * 5;
  float acc = 0.f;
#pragma unroll
  for (int k = 0; k < 10; k++) acc += wr[k] * s[k];
  out[idx] = acc;
}

// ---- 2D-parallel channel LN + GELU; BFOUT=1: write bf16 to `ob`, else fp32 in place ----
template<int BFOUT>
__global__ void ln_gelu_ch2_kernel(float* __restrict__ x, bf16* __restrict__ ob,
                                   const float* __restrict__ g, const float* __restrict__ b,
                                   int Lt){
  const int tid = threadIdx.x;
  const int tt = tid & 31, tc = tid >> 5;
  const int t = blockIdx.x * 32 + tt;
  __shared__ float sred[8][33], qred[8][33];
  __shared__ float mrow[32], rrow[32];
  float s = 0.f, q = 0.f;
  if (t < Lt){
    const float* xc = x + (size_t)(tc * 64) * Lt + t;
#pragma unroll 8
    for (int j = 0; j < 64; j++){ float v = xc[(size_t)j * Lt]; s += v; q += v * v; }
  }
  sred[tc][tt] = s; qred[tc][tt] = q; __syncthreads();
  if (tid < 32){
    float ss = 0.f, qq = 0.f;
#pragma unroll
    for (int c = 0; c < 8; c++){ ss += sred[c][tid]; qq += qred[c][tid]; }
    float m = ss * (1.f / 512.f);
    float var = qq * (1.f / 512.f) - m * m;
    mrow[tid] = m; rrow[tid] = rsqrtf(var + 1e-5f);
  }
  __syncthreads();
  if (t < Lt){
    float m = mrow[tt], rs = rrow[tt];
    float* xc = x + (size_t)(tc * 64) * Lt + t;
#pragma unroll 8
    for (int j = 0; j < 64; j++){
      int c = tc * 64 + j;
      float v = gelu_f((xc[(size_t)j * Lt] - m) * rs * g[c] + b[c]);
      if (BFOUT) ob[(size_t)c * Lt + t] = __float2bfloat16(v);
      else       xc[(size_t)j * Lt] = v;
    }
  }
}

// ---- conv stages 1..6: per-k-tap MFMA GEMM; 64co x 128t tile, K=32 ci chunks ----
// wpk[k][co][ci] bf16 pre-packed; comb[jp][ci] = (in[2jp], in[2jp+1]) bf16 pair.
template<int KW>
__global__ void conv_mfma_kernel(const bf16* __restrict__ in, const bf16* __restrict__ wpk,
                                 float* __restrict__ out, int Lin, int Lout, int outLd){
  __shared__ unsigned comb[130][33];
  __shared__ bf16 As[KW][64][40];
  const int tid = threadIdx.x, wid = tid >> 6, lane = tid & 63;
  const int co0 = blockIdx.x * 64, t0 = blockIdx.y * 128;
  const int wm = (wid >> 1) * 32, wn = (wid & 1) * 64;
  const int fr = lane & 15, fk = (lane >> 4) * 8;
  const int wco = tid >> 2, wci = (tid & 3) * 8;
  f32x4 acc[2][4] = {};
  for (int ci0 = 0; ci0 < 512; ci0 += 32){
#pragma unroll
    for (int k = 0; k < KW; k++)
      *reinterpret_cast<uint4*>(&As[k][wco][wci]) =
        *reinterpret_cast<const uint4*>(&wpk[(size_t)k * 262144 + (size_t)(co0 + wco) * 512 + ci0 + wci]);
    for (int idx = tid; idx < 4096; idx += 256){
      int jp = idx & 127, ci = idx >> 7;
      int gp = t0 * 2 + 2 * jp;
      const bf16* rp = in + (size_t)(ci0 + ci) * Lin;
      unsigned pr = 0;
      if (gp + 1 < Lin) pr = *reinterpret_cast<const unsigned*>(&rp[gp]);
      else if (gp < Lin) pr = *reinterpret_cast<const unsigned short*>(&rp[gp]);
      comb[jp][ci] = pr;
    }
    if (tid < 64){
      int jp = 128 + (tid >> 5), ci = tid & 31;
      int gp = t0 * 2 + 2 * jp;
      const bf16* rp = in + (size_t)(ci0 + ci) * Lin;
      unsigned pr = 0;
      if (gp + 1 < Lin) pr = *reinterpret_cast<const unsigned*>(&rp[gp]);
      else if (gp < Lin) pr = *reinterpret_cast<const unsigned short*>(&rp[gp]);
      comb[jp][ci] = pr;
    }
    __syncthreads();
#pragma unroll
    for (int k = 0; k < KW; k++){
      const int ro = k >> 1, par = k & 1;
      s16x8 a0 = *reinterpret_cast<const s16x8*>(&As[k][wm + fr][fk]);
      s16x8 a1 = *reinterpret_cast<const s16x8*>(&As[k][wm + 16 + fr][fk]);
#pragma unroll
      for (int ni = 0; ni < 4; ni++){
        const unsigned* cp = &comb[wn + ni * 16 + fr + ro][fk];
        unsigned u0 = cp[0], u1 = cp[1], u2 = cp[2], u3 = cp[3];
        unsigned u4 = cp[4], u5 = cp[5], u6 = cp[6], u7 = cp[7];
        uint4 pb;
        if (par){
          pb.x = (u0 >> 16) | (u1 & 0xFFFF0000u);
          pb.y = (u2 >> 16) | (u3 & 0xFFFF0000u);
          pb.z = (u4 >> 16) | (u5 & 0xFFFF0000u);
          pb.w = (u6 >> 16) | (u7 & 0xFFFF0000u);
        } else {
          pb.x = (u0 & 0xFFFFu) | (u1 << 16);
          pb.y = (u2 & 0xFFFFu) | (u3 << 16);
          pb.z = (u4 & 0xFFFFu) | (u5 << 16);
          pb.w = (u6 & 0xFFFFu) | (u7 << 16);
        }
        s16x8 bb = *reinterpret_cast<s16x8*>(&pb);
        acc[0][ni] = __builtin_amdgcn_mfma_f32_16x16x32_bf16(a0, bb, acc[0][ni], 0, 0, 0);
        acc[1][ni] = __builtin_amdgcn_mfma_f32_16x16x32_bf16(a1, bb, acc[1][ni], 0, 0, 0);
      }
    }
    __syncthreads();
  }
  const int cc = lane & 15, crr = (lane >> 4) * 4;
#pragma unroll
  for (int mi = 0; mi < 2; mi++){
#pragma unroll
    for (int ni = 0; ni < 4; ni++){
      int t = t0 + wn + ni * 16 + cc;
      if (t >= Lout) continue;
#pragma unroll
      for (int r = 0; r < 4; r++){
        int co = co0 + wm + mi * 16 + crr + r;
        out[(size_t)co * outLd + t] = acc[mi][ni][r];
      }
    }
  }
}

// ---- final feature LN + transpose (512,S)->(S,512) ----
__global__ void featln_transpose_kernel(const float* __restrict__ xin,
                                        const float* __restrict__ g, const float* __restrict__ b,
                                        float* __restrict__ feat){
  int t = blockIdx.x * 256 + threadIdx.x;
  if (t >= SEQ) return;
  float s = 0.f, sq = 0.f;
  for (int c = 0; c < 512; c++){ float v = xin[c * SEQ + t]; s += v; sq += v * v; }
  float m = s * (1.f / 512.f), var = sq * (1.f / 512.f) - m * m, rs = rsqrtf(var + 1e-5f);
  for (int c = 0; c < 512; c++)
    feat[t * 512 + c] = (xin[c * SEQ + t] - m) * rs * g[c] + b[c];
}

// ---- MFMA GEMM, fp32 inputs (cast fused) — used only for the proj GEMM ----
template<int ACT>
__global__ void gemm_mfma_f32(const float* __restrict__ A, const float* __restrict__ W,
                              const float* __restrict__ bias, float* __restrict__ C,
                              int M, int N, int K, float alpha){
  __shared__ bf16 As[64][40];
  __shared__ bf16 Ws[64][40];
  const int tid = threadIdx.x;
  const int wid = tid >> 6, lane = tid & 63;
  const int m0 = blockIdx.y * 64, n0 = blockIdx.x * 64;
  const int wm = (wid >> 1) * 32, wn = (wid & 1) * 32;
  const int lrow = tid >> 2;
  const int lk   = (tid & 3) * 8;
  const int fr = lane & 15, fk = (lane >> 4) * 8;
  f32x4 acc[2][2] = {};
  for (int k0 = 0; k0 < K; k0 += 32){
    float4 a0 = make_float4(0.f,0.f,0.f,0.f), a1 = make_float4(0.f,0.f,0.f,0.f);
    int gm = m0 + lrow;
    if (gm < M){
      const float* ap = &A[(size_t)gm * K + k0 + lk];
      a0 = *reinterpret_cast<const float4*>(ap);
      a1 = *reinterpret_cast<const float4*>(ap + 4);
    }
    uint4 pa;
    pa.x = f2bf_rne(a0.x) | (f2bf_rne(a0.y) << 16);
    pa.y = f2bf_rne(a0.z) | (f2bf_rne(a0.w) << 16);
    pa.z = f2bf_rne(a1.x) | (f2bf_rne(a1.y) << 16);
    pa.w = f2bf_rne(a1.z) | (f2bf_rne(a1.w) << 16);
    *reinterpret_cast<uint4*>(&As[lrow][lk]) = pa;
    const float* wp = &W[(size_t)(n0 + lrow) * K + k0 + lk];
    float4 w0 = *reinterpret_cast<const float4*>(wp);
    float4 w1 = *reinterpret_cast<const float4*>(wp + 4);
    uint4 pw;
    pw.x = f2bf_rne(w0.x) | (f2bf_rne(w0.y) << 16);
    pw.y = f2bf_rne(w0.z) | (f2bf_rne(w0.w) << 16);
    pw.z = f2bf_rne(w1.x) | (f2bf_rne(w1.y) << 16);
    pw.w = f2bf_rne(w1.z) | (f2bf_rne(w1.w) << 16);
    *reinterpret_cast<uint4*>(&Ws[lrow][lk]) = pw;
    __syncthreads();
    s16x8 av0 = *reinterpret_cast<const s16x8*>(&As[wm + fr][fk]);
    s16x8 av1 = *reinterpret_cast<const s16x8*>(&As[wm + 16 + fr][fk]);
    s16x8 bv0 = *reinterpret_cast<const s16x8*>(&Ws[wn + fr][fk]);
    s16x8 bv1 = *reinterpret_cast<const s16x8*>(&Ws[wn + 16 + fr][fk]);
    acc[0][0] = __builtin_amdgcn_mfma_f32_16x16x32_bf16(av0, bv0, acc[0][0], 0, 0, 0);
    acc[0][1] = __builtin_amdgcn_mfma_f32_16x16x32_bf16(av0, bv1, acc[0][1], 0, 0, 0);
    acc[1][0] = __builtin_amdgcn_mfma_f32_16x16x32_bf16(av1, bv0, acc[1][0], 0, 0, 0);
    acc[1][1] = __builtin_amdgcn_mfma_f32_16x16x32_bf16(av1, bv1, acc[1][1], 0, 0, 0);
    __syncthreads();
  }
  const int cc = lane & 15, cr = (lane >> 4) * 4;
#pragma unroll
  for (int mi = 0; mi < 2; mi++){
#pragma unroll
    for (int ni = 0; ni < 2; ni++){
      int n = n0 + wn + ni * 16 + cc;
      float bn = bias[n];
#pragma unroll
      for (int r = 0; r < 4; r++){
        int m = m0 + wm + mi * 16 + cr + r;
        if (m < M){
          float v = alpha * (acc[mi][ni][r] + bn);
          if (ACT == 1) v = gelu_f(v);
          C[(size_t)m * N + n] = v;
        }
      }
    }
  }
}

// ---- bf16 GEMM, BK=64, pure-copy staging: C = act(alpha*(A @ W^T + bias)) ----
// OUTBF: 0 -> fp32 C, 1 -> bf16 C. N%64==0, K%64==0, M guarded.
template<int ACT, int OUTBF>
__global__ void gemm_bf(const bf16* __restrict__ A, const bf16* __restrict__ W,
                        const float* __restrict__ bias, void* __restrict__ Cp,
                        int M, int N, int K, float alpha){
  __shared__ bf16 As[64][72];
  __shared__ bf16 Ws[64][72];
  const int tid = threadIdx.x, wid = tid >> 6, lane = tid & 63;
  const int m0 = blockIdx.y * 64, n0 = blockIdx.x * 64;
  const int wm = (wid >> 1) * 32, wn = (wid & 1) * 32;
  const int lrow = tid >> 2, lcol = (tid & 3) * 16;
  const int fr = lane & 15, fk = (lane >> 4) * 8;
  f32x4 acc[2][2] = {};
  for (int k0 = 0; k0 < K; k0 += 64){
    uint4 a0 = make_uint4(0,0,0,0), a1 = make_uint4(0,0,0,0);
    if (m0 + lrow < M){
      const bf16* ap = &A[(size_t)(m0 + lrow) * K + k0 + lcol];
      a0 = *reinterpret_cast<const uint4*>(ap);
      a1 = *reinterpret_cast<const uint4*>(ap + 8);
    }
    *reinterpret_cast<uint4*>(&As[lrow][lcol])     = a0;
    *reinterpret_cast<uint4*>(&As[lrow][lcol + 8]) = a1;
    const bf16* wp = &W[(size_t)(n0 + lrow) * K + k0 + lcol];
    *reinterpret_cast<uint4*>(&Ws[lrow][lcol])     = *reinterpret_cast<const uint4*>(wp);
    *reinterpret_cast<uint4*>(&Ws[lrow][lcol + 8]) = *reinterpret_cast<const uint4*>(wp + 8);
    __syncthreads();
#pragma unroll
    for (int kk = 0; kk < 2; kk++){
      const int c = kk * 32 + fk;
      s16x8 av0 = *reinterpret_cast<const s16x8*>(&As[wm + fr][c]);
      s16x8 av1 = *reinterpret_cast<const s16x8*>(&As[wm + 16 + fr][c]);
      s16x8 bv0 = *reinterpret_cast<const s16x8*>(&Ws[wn + fr][c]);
      s16x8 bv1 = *reinterpret_cast<const s16x8*>(&Ws[wn + 16 + fr][c]);
      acc[0][0] = __builtin_amdgcn_mfma_f32_16x16x32_bf16(av0, bv0, acc[0][0], 0, 0, 0);
      acc[0][1] = __builtin_amdgcn_mfma_f32_16x16x32_bf16(av0, bv1, acc[0][1], 0, 0, 0);
      acc[1][0] = __builtin_amdgcn_mfma_f32_16x16x32_bf16(av1, bv0, acc[1][0], 0, 0, 0);
      acc[1][1] = __builtin_amdgcn_mfma_f32_16x16x32_bf16(av1, bv1, acc[1][1], 0, 0, 0);
    }
    __syncthreads();
  }
  const int cc = lane & 15, cr = (lane >> 4) * 4;
#pragma unroll
  for (int mi = 0; mi < 2; mi++){
#pragma unroll
    for (int ni = 0; ni < 2; ni++){
      int n = n0 + wn + ni * 16 + cc;
      float bn = bias[n];
#pragma unroll
      for (int r = 0; r < 4; r++){
        int m = m0 + wm + mi * 16 + cr + r;
        if (m < M){
          float v = alpha * (acc[mi][ni][r] + bn);
          if (ACT == 1) v = gelu_f(v);
          if (OUTBF) ((bf16*)Cp)[(size_t)m * N + n] = __float2bfloat16(v);
          else       ((float*)Cp)[(size_t)m * N + n] = v;
        }
      }
    }
  }
}

// ---- fused QKV in bf16 (z selects W/bias/out/alpha), out bf16 ----
__global__ void qkv_bf(const bf16* __restrict__ A,
                       const bf16* __restrict__ Wq, const bf16* __restrict__ Wk,
                       const bf16* __restrict__ Wv,
                       const float* __restrict__ bqv, const float* __restrict__ bkv,
                       const float* __restrict__ bvv,
                       bf16* __restrict__ qb, bf16* __restrict__ kb,
                       bf16* __restrict__ vb, int M){
  const int z = blockIdx.z;
  const bf16* W   = (z == 0) ? Wq : (z == 1) ? Wk : Wv;
  const float* bia = (z == 0) ? bqv : (z == 1) ? bkv : bvv;
  bf16* C         = (z == 0) ? qb : (z == 1) ? kb : vb;
  const float alpha = (z == 0) ? 0.125f : 1.0f;
  const int K = DMODEL, N = DMODEL;
  __shared__ bf16 As[64][72];
  __shared__ bf16 Ws[64][72];
  const int tid = threadIdx.x, wid = tid >> 6, lane = tid & 63;
  const int m0 = blockIdx.y * 64, n0 = blockIdx.x * 64;
  const int wm = (wid >> 1) * 32, wn = (wid & 1) * 32;
  const int lrow = tid >> 2, lcol = (tid & 3) * 16;
  const int fr = lane & 15, fk = (lane >> 4) * 8;
  f32x4 acc[2][2] = {};
  for (int k0 = 0; k0 < K; k0 += 64){
    uint4 a0 = make_uint4(0,0,0,0), a1 = make_uint4(0,0,0,0);
    if (m0 + lrow < M){
      const bf16* ap = &A[(size_t)(m0 + lrow) * K + k0 + lcol];
      a0 = *reinterpret_cast<const uint4*>(ap);
      a1 = *reinterpret_cast<const uint4*>(ap + 8);
    }
    *reinterpret_cast<uint4*>(&As[lrow][lcol])     = a0;
    *reinterpret_cast<uint4*>(&As[lrow][lcol + 8]) = a1;
    const bf16* wp = &W[(size_t)(n0 + lrow) * K + k0 + lcol];
    *reinterpret_cast<uint4*>(&Ws[lrow][lcol])     = *reinterpret_cast<const uint4*>(wp);
    *reinterpret_cast<uint4*>(&Ws[lrow][lcol + 8]) = *reinterpret_cast<const uint4*>(wp + 8);
    __syncthreads();
#pragma unroll
    for (int kk = 0; kk < 2; kk++){
      const int c = kk * 32 + fk;
      s16x8 av0 = *reinterpret_cast<const s16x8*>(&As[wm + fr][c]);
      s16x8 av1 = *reinterpret_cast<const s16x8*>(&As[wm + 16 + fr][c]);
      s16x8 bv0 = *reinterpret_cast<const s16x8*>(&Ws[wn + fr][c]);
      s16x8 bv1 = *reinterpret_cast<const s16x8*>(&Ws[wn + 16 + fr][c]);
      acc[0][0] = __builtin_amdgcn_mfma_f32_16x16x32_bf16(av0, bv0, acc[0][0], 0, 0, 0);
      acc[0][1] = __builtin_amdgcn_mfma_f32_16x16x32_bf16(av0, bv1, acc[0][1], 0, 0, 0);
      acc[1][0] = __builtin_amdgcn_mfma_f32_16x16x32_bf16(av1, bv0, acc[1][0], 0, 0, 0);
      acc[1][1] = __builtin_amdgcn_mfma_f32_16x16x32_bf16(av1, bv1, acc[1][1], 0, 0, 0);
    }
    __syncthreads();
  }
  const int cc = lane & 15, cr = (lane >> 4) * 4;
#pragma unroll
  for (int mi = 0; mi < 2; mi++){
#pragma unroll
    for (int ni = 0; ni < 2; ni++){
      int n = n0 + wn + ni * 16 + cc;
      float bn = bia[n];
#pragma unroll
      for (int r = 0; r < 4; r++){
        int m = m0 + wm + mi * 16 + cr + r;
        if (m < M) C[(size_t)m * N + n] = __float2bfloat16(alpha * (acc[mi][ni][r] + bn));
      }
    }
  }
}

// ---- posconv via MFMA ----
__global__ void posconv_mfma(const float* __restrict__ x, const bf16* __restrict__ wpos,
                             const float* __restrict__ bias, float* __restrict__ xc){
  const int t0 = blockIdx.x * 64, g = blockIdx.y, b = blockIdx.z;
  __shared__ bf16 As[64][40];
  __shared__ float xw[224];
  const int tid = threadIdx.x, wid = tid >> 6, lane = tid & 63;
  const int wm = (wid >> 1) * 32, wn = (wid & 1) * 32;
  const int lrow = tid >> 2, lk = (tid & 3) * 8;
  const int fr = lane & 15, fk = (lane >> 4) * 8;
  f32x4 acc[2][2] = {};
  for (int ci = 0; ci < 48; ci++){
    for (int idx = tid; idx < 191; idx += 256){
      int p = t0 - 64 + idx;
      xw[idx] = (p >= 0 && p < SEQ) ? x[((size_t)(b * SEQ + p)) * DMODEL + g * 48 + ci] : 0.f;
    }
    for (int kk = 0; kk < 128; kk += 32){
      uint4 wa = make_uint4(0, 0, 0, 0);
      if (lrow < 48)
        wa = *reinterpret_cast<const uint4*>(&wpos[(size_t)(g * 48 + lrow) * 6144 + ci * 128 + kk + lk]);
      *reinterpret_cast<uint4*>(&As[lrow][lk]) = wa;
      __syncthreads();
      auto bfragp = [&](int tr)->s16x8{
        int base = tr + kk + fk;
        s16x8 r;
#pragma unroll
        for (int j = 0; j < 8; j++) r[j] = (short)f2bf_rne(xw[base + j]);
        return r;
      };
      s16x8 a0 = *reinterpret_cast<const s16x8*>(&As[wm + fr][fk]);
      s16x8 a1 = *reinterpret_cast<const s16x8*>(&As[wm + 16 + fr][fk]);
      s16x8 b0 = bfragp(wn + fr);
      s16x8 b1 = bfragp(wn + 16 + fr);
      acc[0][0] = __builtin_amdgcn_mfma_f32_16x16x32_bf16(a0, b0, acc[0][0], 0, 0, 0);
      acc[0][1] = __builtin_amdgcn_mfma_f32_16x16x32_bf16(a0, b1, acc[0][1], 0, 0, 0);
      acc[1][0] = __builtin_amdgcn_mfma_f32_16x16x32_bf16(a1, b0, acc[1][0], 0, 0, 0);
      acc[1][1] = __builtin_amdgcn_mfma_f32_16x16x32_bf16(a1, b1, acc[1][1], 0, 0, 0);
      __syncthreads();
    }
  }
  const int cc = lane & 15, cr = (lane >> 4) * 4;
#pragma unroll
  for (int mi = 0; mi < 2; mi++){
#pragma unroll
    for (int ni = 0; ni < 2; ni++){
      int t = t0 + wn + ni * 16 + cc;
      if (t >= SEQ) continue;
#pragma unroll
      for (int r = 0; r < 4; r++){
        int cop = wm + mi * 16 + cr + r;
        if (cop < 48){
          int co = g * 48 + cop;
          xc[((size_t)(b * SEQ + t)) * DMODEL + co] = acc[mi][ni][r] + bias[co];
        }
      }
    }
  }
}

// ---- FUSED attention, bf16 q/k/v in, bf16 ctx out; in-block gate ----
__global__ void attn_fused(const bf16* __restrict__ q, const bf16* __restrict__ k,
                           const bf16* __restrict__ v, const float* __restrict__ x,
                           const float* __restrict__ gwl, const float* __restrict__ gbl,
                           const float* __restrict__ gal,
                           const float* __restrict__ tab, bf16* __restrict__ ctx){
  const int bh = blockIdx.y, b = bh / NHEAD, h = bh % NHEAD;
  const int i0 = blockIdx.x * 16;
  const int tid = threadIdx.x, w = tid >> 6, lane = tid & 63;
  const int fr = lane & 15, fk = (lane >> 4) * 8;
  const int cr = (lane >> 4) * 4;
  __shared__ float sc[16][524];
  __shared__ short qs[16][72];
  __shared__ short kv[64][72];
  __shared__ float gtmp[16][9];
  __shared__ float gl[16];
  {
    int r = tid >> 4, c = (tid & 15) * 4;
    int gi = i0 + r;
    uint2 p = make_uint2(0, 0);
    if (gi < SEQ) p = *reinterpret_cast<const uint2*>(&q[((size_t)(b*SEQ+gi))*DMODEL + h*DHEAD + c]);
    *reinterpret_cast<uint2*>(&qs[r][c]) = p;
  }
  if (tid < 128){
    int r = tid >> 3, g = tid & 7;
    int gi = i0 + r;
    float a = gbl[g];
    if (gi < SEQ){
      const float* xv = x + ((size_t)(b * SEQ + gi)) * DMODEL + h * DHEAD;
      const float* wrow = gwl + g * DHEAD;
#pragma unroll
      for (int d = 0; d < 64; d++) a += xv[d] * wrow[d];
    }
    gtmp[r][g] = a;
  }
  __syncthreads();
  if (tid < 16){
    float a0 = gtmp[tid][0] + gtmp[tid][1] + gtmp[tid][2] + gtmp[tid][3];
    float a1 = gtmp[tid][4] + gtmp[tid][5] + gtmp[tid][6] + gtmp[tid][7];
    float g0 = 1.f / (1.f + expf(-a0));
    float g1 = 1.f / (1.f + expf(-a1));
    gl[tid] = g0 * (g1 * gal[h] - 1.f) + 2.f;
  }
  for (int j0 = 0; j0 < SP; j0 += 64){
    __syncthreads();
    {
      int jr = tid >> 2, c0 = (tid & 3) * 16;
      int gj = j0 + jr;
      uint4 p0 = make_uint4(0,0,0,0), p1 = make_uint4(0,0,0,0);
      if (gj < SEQ){
        const bf16* kp = &k[((size_t)(b*SEQ+gj))*DMODEL + h*DHEAD + c0];
        p0 = *reinterpret_cast<const uint4*>(kp);
        p1 = *reinterpret_cast<const uint4*>(kp + 8);
      }
      *reinterpret_cast<uint4*>(&kv[jr][c0])     = p0;
      *reinterpret_cast<uint4*>(&kv[jr][c0 + 8]) = p1;
    }
    __syncthreads();
    f32x4 accqk = {};
#pragma unroll
    for (int kk = 0; kk < 2; kk++){
      s16x8 a = *reinterpret_cast<const s16x8*>(&qs[fr][kk*32 + fk]);
      s16x8 bb = *reinterpret_cast<const s16x8*>(&kv[w*16 + fr][kk*32 + fk]);
      accqk = __builtin_amdgcn_mfma_f32_16x16x32_bf16(a, bb, accqk, 0, 0, 0);
    }
#pragma unroll
    for (int r = 0; r < 4; r++)
      sc[cr + r][j0 + w*16 + fr] = accqk[r];
  }
  __syncthreads();
  for (int r = 0; r < 4; r++){
    int row = w * 4 + r;
    int gi = i0 + row;
    if (gi >= SEQ) continue;
    float gt = gl[row];
    const float* tb = tab + (size_t)h * NREL + (SEQ - 1 - gi);
    float vals[8];
    float mx = -1e30f;
#pragma unroll
    for (int it = 0; it < 8; it++){
      int j = lane + it * 64;
      float vv = (j < SEQ) ? (sc[row][j] + gt * tb[j]) : -1e30f;
      vals[it] = vv; mx = fmaxf(mx, vv);
    }
#pragma unroll
    for (int m = 32; m > 0; m >>= 1) mx = fmaxf(mx, __shfl_xor(mx, m));
    float sum = 0.f;
#pragma unroll
    for (int it = 0; it < 8; it++){
      int j = lane + it * 64;
      float e = (j < SEQ) ? expf(vals[it] - mx) : 0.f;
      vals[it] = e; sum += e;
    }
#pragma unroll
    for (int m = 32; m > 0; m >>= 1) sum += __shfl_xor(sum, m);
    float inv = 1.f / sum;
#pragma unroll
    for (int it = 0; it < 8; it++){
      int j = lane + it * 64;
      sc[row][j] = vals[it] * inv;
    }
  }
  __syncthreads();
  f32x4 accpv = {};
  for (int j0 = 0; j0 < SP; j0 += 64){
    __syncthreads();
    {
      int jr = tid >> 2, c0 = (tid & 3) * 16;
      int gj = j0 + jr;
      uint4 p0 = make_uint4(0,0,0,0), p1 = make_uint4(0,0,0,0);
      if (gj < SEQ){
        const bf16* vp = &v[((size_t)(b*SEQ+gj))*DMODEL + h*DHEAD + c0];
        p0 = *reinterpret_cast<const uint4*>(vp);
        p1 = *reinterpret_cast<const uint4*>(vp + 8);
      }
      *reinterpret_cast<uint4*>(&kv[jr][c0])     = p0;
      *reinterpret_cast<uint4*>(&kv[jr][c0 + 8]) = p1;
    }
    __syncthreads();
#pragma unroll
    for (int kk = 0; kk < 2; kk++){
      s16x8 a, bb;
#pragma unroll
      for (int e = 0; e < 8; e++){
        a[e]  = (short)f2bf_rne(sc[fr][j0 + kk*32 + fk + e]);
        bb[e] = kv[kk*32 + fk + e][w*16 + fr];
      }
      accpv = __builtin_amdgcn_mfma_f32_16x16x32_bf16(a, bb, accpv, 0, 0, 0);
    }
  }
#pragma unroll
  for (int r = 0; r < 4; r++){
    int gi = i0 + cr + r;
    if (gi < SEQ)
      ctx[((size_t)(b*SEQ+gi))*DMODEL + h*DHEAD + w*16 + fr] = __float2bfloat16(accpv[r]);
  }
}

// ---- wave-per-row residual add (+optional GELU) + LN; writes fp32 x and bf16 xb ----
template<int GELU_ADD>
__global__ void add_ln_wave(float* __restrict__ x, const float* __restrict__ add,
                            const float* __restrict__ g, const float* __restrict__ b,
                            bf16* __restrict__ xb){
  int row = blockIdx.x * 4 + (threadIdx.x >> 6);
  if (row >= BATCH * SEQ) return;
  int lane = threadIdx.x & 63;
  float* xr = x + (size_t)row * DMODEL;
  const float* ar = add + (size_t)row * DMODEL;
  float buf[12];
  float s = 0.f;
#pragma unroll
  for (int it = 0; it < 12; it++){
    int i = lane + it * 64;
    float v = ar[i];
    if (GELU_ADD) v = gelu_f(v);
    v += xr[i];
    buf[it] = v; s += v;
  }
#pragma unroll
  for (int m = 32; m > 0; m >>= 1) s += __shfl_xor(s, m);
  float mean = s * (1.f / 768.f);
  float q = 0.f;
#pragma unroll
  for (int it = 0; it < 12; it++){ float d = buf[it] - mean; q += d * d; }
#pragma unroll
  for (int m = 32; m > 0; m >>= 1) q += __shfl_xor(q, m);
  float rs = rsqrtf(q * (1.f / 768.f) + 1e-5f);
#pragma unroll
  for (int it = 0; it < 12; it++){
    int i = lane + it * 64;
    float o = (buf[it] - mean) * rs * g[i] + b[i];
    xr[i] = o;
    xb[(size_t)row * DMODEL + i] = __float2bfloat16(o);
  }
}

// ---- T5-style relative position bias table ----
__global__ void relbias_kernel(const float* __restrict__ rel_emb, float* __restrict__ tab){
  int idx = blockIdx.x * 256 + threadIdx.x;
  if (idx >= NREL * NHEAD) return;
  int rr = idx / NHEAD, h = idx - rr * NHEAD;
  int rel = rr - (SEQ - 1);
  int bkt = (rel > 0) ? 160 : 0;
  int n = (rel < 0) ? -rel : rel;
  if (n < 80) bkt += n;
  else {
    int large = 80 + (int)(logf((float)n / 80.f) / logf(10.f) * 80.f);
    bkt += (large < 159) ? large : 159;
  }
  tab[h * NREL + rr] = rel_emb[bkt * NHEAD + h];
}

} // anonymous namespace

extern "C" void kernel_launch(void* const* d_in, const int* in_sizes, int n_in,
                              void* d_out, int out_size, void* d_ws, size_t ws_size,
                              hipStream_t stream){
  (void)ws_size;

  static const int DS[34] = {640000,5120,3145728,1048576,3584,3584,512,512,393216,768,
                             4718592,768,768,768,7077888,9216,7077888,9216,7077888,9216,
                             7077888,9216,6144,96,144,9216,9216,28311552,36864,28311552,
                             9216,9216,9216,3840};
  bool ok = (n_in == 34) && (out_size == BATCH * SEQ * DMODEL);
  if (ok) for (int i = 0; i < 34; i++) if (in_sizes[i] != DS[i]) { ok = false; break; }
  if (!ok){
    fill_f32_kernel<<<(out_size + 255) / 256, 256, 0, stream>>>((float*)d_out, out_size, 1000.0f);
    return;
  }

  const float* src  = (const float*)d_in[0];
  const float* w0   = (const float*)d_in[1];
  const float* w14  = (const float*)d_in[2];
  const float* w56  = (const float*)d_in[3];
  const float* clng = (const float*)d_in[4];
  const float* clnb = (const float*)d_in[5];
  const float* flng = (const float*)d_in[6];
  const float* flnb = (const float*)d_in[7];
  const float* pjw  = (const float*)d_in[8];
  const float* pjb  = (const float*)d_in[9];
  const float* pcw  = (const float*)d_in[10];
  const float* pcb  = (const float*)d_in[11];
  const float* eng  = (const float*)d_in[12];
  const float* enb  = (const float*)d_in[13];
  const float* Wq   = (const float*)d_in[14];
  const float* bq   = (const float*)d_in[15];
  const float* Wk   = (const float*)d_in[16];
  const float* bk   = (const float*)d_in[17];
  const float* Wv   = (const float*)d_in[18];
  const float* bv   = (const float*)d_in[19];
  const float* Wo   = (const float*)d_in[20];
  const float* bo   = (const float*)d_in[21];
  const float* gw   = (const float*)d_in[22];
  const float* gbp  = (const float*)d_in[23];
  const float* ga   = (const float*)d_in[24];
  const float* l1g  = (const float*)d_in[25];
  const float* l1b  = (const float*)d_in[26];
  const float* f1w  = (const float*)d_in[27];
  const float* f1b  = (const float*)d_in[28];
  const float* f2w  = (const float*)d_in[29];
  const float* f2b  = (const float*)d_in[30];
  const float* l2g  = (const float*)d_in[31];
  const float* l2b  = (const float*)d_in[32];
  const float* rel  = (const float*)d_in[33];

  float* x = (float*)d_out;  // residual stream lives in d_out (fp32)

  // workspace (~138 MB)
  float* wsf = (float*)d_ws;
  size_t off = 0;
  auto alloc = [&](size_t n){ float* pp = wsf + off; off += (n + 63) & ~(size_t)63; return pp; };
  // U: conv phase {F fp32 16.38M | bfA | bfB(inside F tail)} / transformer phase views
  constexpr size_t F_N   = (size_t)512 * 31999;              // 16,383,488
  constexpr size_t BFA_N = (size_t)512 * 31999 / 2 + 32;
  float* U = alloc(F_N + BFA_N);                             // 24.58M floats
  float* F  = U;
  bf16* bfA = (bf16*)(U + F_N);
  bf16* bfB = (bf16*)(U + 9000000);                          // inside F tail (F uses <8.2M after stage1)
  // transformer views (conv dead by then)
  bf16* ffhb = (bf16*)U;                                     // 6.13M bf16 = 3.07M floats
  float* tmp = U + 3100000;                                  // 1.53M
  bf16* qbb  = (bf16*)(U + 4700000);
  bf16* kbb  = (bf16*)(U + 5500000);
  bf16* vbb  = (bf16*)(U + 6300000);
  bf16* ctxb = (bf16*)(U + 7100000);
  bf16* xb   = (bf16*)(U + 7900000);
  bf16* wposb= (bf16*)(U + 8700000);                         // 2.36M floats, ends 11.06M < 24.58M
  // persistent
  float* feat = alloc((size_t)BATCH * SEQ * 512);
  float* c6   = alloc((size_t)512 * SEQ);
  float* tab  = alloc((size_t)NHEAD * NREL);
  bf16* wpk   = (bf16*)alloc(2097152);                       // conv packed weights, 6 stages
  bf16* wqb  = (bf16*)alloc(294912);
  bf16* wkb  = (bf16*)alloc(294912);
  bf16* wvb  = (bf16*)alloc(294912);
  bf16* wob  = (bf16*)alloc(294912);
  bf16* wf1b = (bf16*)alloc(1179648);
  bf16* wf2b = (bf16*)alloc(1179648);

  const int Ls[8] = {160000, 31999, 15999, 7999, 3999, 1999, 999, 499};
  const int Mrows = BATCH * SEQ; // 1996

  // ---- pre-pack conv weights (once) ----
  size_t wpkOff[7];
  {
    size_t o = 0;
    for (int st = 1; st <= 6; st++){ wpkOff[st] = o; o += (st <= 4 ? 3 : 2) * 262144; }
  }
  for (int st = 1; st <= 4; st++)
    pack_convw<3><<<(3 * 262144 + 255) / 256, 256, 0, stream>>>(
        w14 + (size_t)(st - 1) * 512 * 512 * 3, wpk + wpkOff[st]);
  for (int st = 5; st <= 6; st++)
    pack_convw<2><<<(2 * 262144 + 255) / 256, 256, 0, stream>>>(
        w56 + (size_t)(st - 5) * 512 * 512 * 2, wpk + wpkOff[st]);

  // ---- conv feature extractor ----
  for (int b = 0; b < BATCH; b++){
    conv0_kernel<<<(512 * Ls[1] + 255) / 256, 256, 0, stream>>>(src + (size_t)b * T_IN, w0, F, Ls[1]);
    ln_gelu_ch2_kernel<1><<<(Ls[1] + 31) / 32, 256, 0, stream>>>(F, bfA, clng, clnb, Ls[1]);
    bf16* bfin[2] = {bfA, bfB};
    for (int st = 1; st <= 6; st++){
      const bf16* inb = bfin[(st + 1) & 1];
      int Lin = Ls[st], Lout = Ls[st + 1];
      float* outf = (st == 6) ? c6 : F;
      int oLd = (st == 6) ? SEQ : Lout;
      dim3 grd(8, (Lout + 127) / 128);
      if (st <= 4)
        conv_mfma_kernel<3><<<grd, 256, 0, stream>>>(inb, wpk + wpkOff[st], outf, Lin, Lout, oLd);
      else
        conv_mfma_kernel<2><<<grd, 256, 0, stream>>>(inb, wpk + wpkOff[st], outf, Lin, Lout, oLd);
      if (st < 6)
        ln_gelu_ch2_kernel<1><<<(Lout + 31) / 32, 256, 0, stream>>>(F, bfin[st & 1], clng + st * 512, clnb + st * 512, Lout);
    }
    ln_gelu_ch2_kernel<0><<<(SEQ + 31) / 32, 256, 0, stream>>>(c6, nullptr, clng + 6 * 512, clnb + 6 * 512, SEQ);
    featln_transpose_kernel<<<(SEQ + 255) / 256, 256, 0, stream>>>(c6, flng, flnb, feat + (size_t)b * SEQ * 512);
  }

  gemm_mfma_f32<0><<<dim3(DMODEL / 64, (Mrows + 63) / 64), 256, 0, stream>>>(feat, pjw, pjb, x, Mrows, DMODEL, 512, 1.0f);
  f2bf_kernel<<<(4718592 + 255) / 256, 256, 0, stream>>>(pcw, wposb, 4718592);
  posconv_mfma<<<dim3(8, 16, BATCH), 256, 0, stream>>>(x, wposb, pcb, tmp);
  add_ln_wave<1><<<(Mrows + 3) / 4, 256, 0, stream>>>(x, tmp, eng, enb, xb);
  relbias_kernel<<<(NREL * NHEAD + 255) / 256, 256, 0, stream>>>(rel, tab);

  const size_t WQK = (size_t)DMODEL * DMODEL;
  const size_t WF  = (size_t)FFN * DMODEL;
  for (int l = 0; l < NLAYER; l++){
    castw6<<<dim3(9216, 6), 256, 0, stream>>>(
        Wq + l * WQK, Wk + l * WQK, Wv + l * WQK, Wo + l * WQK,
        f1w + l * WF, f2w + l * WF, wqb, wkb, wvb, wob, wf1b, wf2b);
    qkv_bf<<<dim3(12, 32, 3), 256, 0, stream>>>(
        xb, wqb, wkb, wvb, bq + l * DMODEL, bk + l * DMODEL, bv + l * DMODEL,
        qbb, kbb, vbb, Mrows);
    attn_fused<<<dim3(32, BATCH * NHEAD), 256, 0, stream>>>(
        qbb, kbb, vbb, x, gw + (size_t)l * 8 * DHEAD, gbp + l * 8, ga + l * NHEAD, tab, ctxb);
    gemm_bf<0, 0><<<dim3(12, 32), 256, 0, stream>>>(ctxb, wob, bo + l * DMODEL, tmp, Mrows, DMODEL, DMODEL, 1.0f);
    add_ln_wave<0><<<(Mrows + 3) / 4, 256, 0, stream>>>(x, tmp, l1g + l * DMODEL, l1b + l * DMODEL, xb);
    gemm_bf<1, 1><<<dim3(FFN / 64, 32), 256, 0, stream>>>(xb, wf1b, f1b + l * FFN, ffhb, Mrows, FFN, DMODEL, 1.0f);
    gemm_bf<0, 0><<<dim3(12, 32), 256, 0, stream>>>(ffhb, wf2b, f2b + l * DMODEL, tmp, Mrows, DMODEL, FFN, 1.0f);
    add_ln_wave<0><<<(Mrows + 3) / 4, 256, 0, stream>>>(x, tmp, l2g + l * DMODEL, l2b + l * DMODEL, xb);
  }
  // result is already in d_out
}

// Round 19
// 5044.851 us; speedup vs baseline: 17.9304x; 1.1512x over previous
//
#include <hip/hip_runtime.h>
#include <hip/hip_bf16.h>
#include <math.h>

namespace {

constexpr int BATCH  = 4;
constexpr int T_IN   = 160000;
constexpr int DMODEL = 768;
constexpr int NHEAD  = 12;
constexpr int DHEAD  = 64;
constexpr int FFN    = 3072;
constexpr int NLAYER = 12;
constexpr int SEQ    = 499;
constexpr int SP     = 512;
constexpr int NREL   = 2 * SEQ - 1;

typedef __hip_bfloat16 bf16;
using f32x4 = __attribute__((ext_vector_type(4))) float;
using s16x8 = __attribute__((ext_vector_type(8))) short;

__device__ __forceinline__ float gelu_f(float x){
  return 0.5f * x * (1.0f + erff(x * 0.70710678118654752f));
}

__device__ __forceinline__ unsigned f2bf_rne(float f){
  unsigned u = __float_as_uint(f);
  return (u + 0x7FFFu + ((u >> 16) & 1u)) >> 16;
}

__global__ void fill_f32_kernel(float* __restrict__ out, int n, float val){
  int i = blockIdx.x * 256 + threadIdx.x;
  if (i < n) out[i] = val;
}

__global__ void f2bf_kernel(const float* __restrict__ in, bf16* __restrict__ out, int n){
  int i = blockIdx.x * 256 + threadIdx.x;
  if (i < n) out[i] = __float2bfloat16(in[i]);
}

// ---- per-layer weight cast: z selects one of 6 regions ----
__global__ void castw6(const float* __restrict__ wq, const float* __restrict__ wk,
                       const float* __restrict__ wv, const float* __restrict__ wo,
                       const float* __restrict__ f1, const float* __restrict__ f2,
                       bf16* __restrict__ d0, bf16* __restrict__ d1, bf16* __restrict__ d2,
                       bf16* __restrict__ d3, bf16* __restrict__ d4, bf16* __restrict__ d5){
  int z = blockIdx.y;
  int idx = blockIdx.x * 256 + threadIdx.x;
  const float* s; bf16* d; int n;
  switch (z){
    case 0: s = wq; d = d0; n = 589824; break;
    case 1: s = wk; d = d1; n = 589824; break;
    case 2: s = wv; d = d2; n = 589824; break;
    case 3: s = wo; d = d3; n = 589824; break;
    case 4: s = f1; d = d4; n = 2359296; break;
    default: s = f2; d = d5; n = 2359296; break;
  }
  if (idx < n) d[idx] = __float2bfloat16(s[idx]);
}

// ---- conv weight pre-pack: w[co][ci][KW] fp32 -> dst[k][co][ci] bf16 ----
template<int KW>
__global__ void pack_convw(const float* __restrict__ w, bf16* __restrict__ dst){
  int idx = blockIdx.x * 256 + threadIdx.x;
  if (idx >= KW * 512 * 512) return;
  int ci = idx & 511, co = (idx >> 9) & 511, k = idx >> 18;
  dst[idx] = __float2bfloat16(w[((size_t)co * 512 + ci) * KW + k]);
}

// ---- conv stage 0: k=10, s=5 ----
__global__ void conv0_kernel(const float* __restrict__ src, const float* __restrict__ w,
                             float* __restrict__ out, int Lout){
  int idx = blockIdx.x * 256 + threadIdx.x;
  if (idx >= 512 * Lout) return;
  int c = idx / Lout, t = idx - c * Lout;
  const float* wr = w + c * 10;
  const float* s  = src + t * 5;
  float acc = 0.f;
#pragma unroll
  for (int k = 0; k < 10; k++) acc += wr[k] * s[k];
  out[idx] = acc;
}

// ---- 2D-parallel channel LN + GELU; BFOUT=1: write bf16 to `ob`, else fp32 in place ----
template<int BFOUT>
__global__ void ln_gelu_ch2_kernel(float* __restrict__ x, bf16* __restrict__ ob,
                                   const float* __restrict__ g, const float* __restrict__ b,
                                   int Lt){
  const int tid = threadIdx.x;
  const int tt = tid & 31, tc = tid >> 5;
  const int t = blockIdx.x * 32 + tt;
  __shared__ float sred[8][33], qred[8][33];
  __shared__ float mrow[32], rrow[32];
  float s = 0.f, q = 0.f;
  if (t < Lt){
    const float* xc = x + (size_t)(tc * 64) * Lt + t;
#pragma unroll 8
    for (int j = 0; j < 64; j++){ float v = xc[(size_t)j * Lt]; s += v; q += v * v; }
  }
  sred[tc][tt] = s; qred[tc][tt] = q; __syncthreads();
  if (tid < 32){
    float ss = 0.f, qq = 0.f;
#pragma unroll
    for (int c = 0; c < 8; c++){ ss += sred[c][tid]; qq += qred[c][tid]; }
    float m = ss * (1.f / 512.f);
    float var = qq * (1.f / 512.f) - m * m;
    mrow[tid] = m; rrow[tid] = rsqrtf(var + 1e-5f);
  }
  __syncthreads();
  if (t < Lt){
    float m = mrow[tt], rs = rrow[tt];
    float* xc = x + (size_t)(tc * 64) * Lt + t;
#pragma unroll 8
    for (int j = 0; j < 64; j++){
      int c = tc * 64 + j;
      float v = gelu_f((xc[(size_t)j * Lt] - m) * rs * g[c] + b[c]);
      if (BFOUT) ob[(size_t)c * Lt + t] = __float2bfloat16(v);
      else       xc[(size_t)j * Lt] = v;
    }
  }
}

// ---- conv stages 1..6: per-k-tap MFMA GEMM with register prefetch ----
template<int KW>
__global__ void conv_mfma_kernel(const bf16* __restrict__ in, const bf16* __restrict__ wpk,
                                 float* __restrict__ out, int Lin, int Lout, int outLd){
  __shared__ unsigned comb[130][33];
  __shared__ bf16 As[KW][64][40];
  const int tid = threadIdx.x, wid = tid >> 6, lane = tid & 63;
  const int co0 = blockIdx.x * 64, t0 = blockIdx.y * 128;
  const int wm = (wid >> 1) * 32, wn = (wid & 1) * 64;
  const int fr = lane & 15, fk = (lane >> 4) * 8;
  const int wco = tid >> 2, wci = (tid & 3) * 8;
  f32x4 acc[2][4] = {};
  uint4 rw[KW];
  unsigned rin[16], rex = 0;
  auto LOAD = [&](int ci0){
#pragma unroll
    for (int k = 0; k < KW; k++)
      rw[k] = *reinterpret_cast<const uint4*>(&wpk[(size_t)k * 262144 + (size_t)(co0 + wco) * 512 + ci0 + wci]);
#pragma unroll
    for (int s = 0; s < 16; s++){
      int idx = s * 256 + tid;
      int jp = idx & 127, ci = idx >> 7;
      int gp = t0 * 2 + 2 * jp;
      const bf16* rp = in + (size_t)(ci0 + ci) * Lin;
      unsigned pr = 0;
      if (gp + 1 < Lin) pr = *reinterpret_cast<const unsigned*>(&rp[gp]);
      else if (gp < Lin) pr = *reinterpret_cast<const unsigned short*>(&rp[gp]);
      rin[s] = pr;
    }
    if (tid < 64){
      int jp = 128 + (tid >> 5), ci = tid & 31;
      int gp = t0 * 2 + 2 * jp;
      const bf16* rp = in + (size_t)(ci0 + ci) * Lin;
      unsigned pr = 0;
      if (gp + 1 < Lin) pr = *reinterpret_cast<const unsigned*>(&rp[gp]);
      else if (gp < Lin) pr = *reinterpret_cast<const unsigned short*>(&rp[gp]);
      rex = pr;
    }
  };
  LOAD(0);
  for (int ci0 = 0; ci0 < 512; ci0 += 32){
    // write staged regs -> LDS
#pragma unroll
    for (int k = 0; k < KW; k++)
      *reinterpret_cast<uint4*>(&As[k][wco][wci]) = rw[k];
#pragma unroll
    for (int s = 0; s < 16; s++){
      int idx = s * 256 + tid;
      comb[idx & 127][idx >> 7] = rin[s];
    }
    if (tid < 64) comb[128 + (tid >> 5)][tid & 31] = rex;
    __syncthreads();
    if (ci0 + 32 < 512) LOAD(ci0 + 32);
#pragma unroll
    for (int k = 0; k < KW; k++){
      const int ro = k >> 1, par = k & 1;
      s16x8 a0 = *reinterpret_cast<const s16x8*>(&As[k][wm + fr][fk]);
      s16x8 a1 = *reinterpret_cast<const s16x8*>(&As[k][wm + 16 + fr][fk]);
#pragma unroll
      for (int ni = 0; ni < 4; ni++){
        const unsigned* cp = &comb[wn + ni * 16 + fr + ro][fk];
        unsigned u0 = cp[0], u1 = cp[1], u2 = cp[2], u3 = cp[3];
        unsigned u4 = cp[4], u5 = cp[5], u6 = cp[6], u7 = cp[7];
        uint4 pb;
        if (par){
          pb.x = (u0 >> 16) | (u1 & 0xFFFF0000u);
          pb.y = (u2 >> 16) | (u3 & 0xFFFF0000u);
          pb.z = (u4 >> 16) | (u5 & 0xFFFF0000u);
          pb.w = (u6 >> 16) | (u7 & 0xFFFF0000u);
        } else {
          pb.x = (u0 & 0xFFFFu) | (u1 << 16);
          pb.y = (u2 & 0xFFFFu) | (u3 << 16);
          pb.z = (u4 & 0xFFFFu) | (u5 << 16);
          pb.w = (u6 & 0xFFFFu) | (u7 << 16);
        }
        s16x8 bb = *reinterpret_cast<s16x8*>(&pb);
        acc[0][ni] = __builtin_amdgcn_mfma_f32_16x16x32_bf16(a0, bb, acc[0][ni], 0, 0, 0);
        acc[1][ni] = __builtin_amdgcn_mfma_f32_16x16x32_bf16(a1, bb, acc[1][ni], 0, 0, 0);
      }
    }
    __syncthreads();
  }
  const int cc = lane & 15, crr = (lane >> 4) * 4;
#pragma unroll
  for (int mi = 0; mi < 2; mi++){
#pragma unroll
    for (int ni = 0; ni < 4; ni++){
      int t = t0 + wn + ni * 16 + cc;
      if (t >= Lout) continue;
#pragma unroll
      for (int r = 0; r < 4; r++){
        int co = co0 + wm + mi * 16 + crr + r;
        out[(size_t)co * outLd + t] = acc[mi][ni][r];
      }
    }
  }
}

// ---- final feature LN + transpose (512,S)->(S,512) ----
__global__ void featln_transpose_kernel(const float* __restrict__ xin,
                                        const float* __restrict__ g, const float* __restrict__ b,
                                        float* __restrict__ feat){
  int t = blockIdx.x * 256 + threadIdx.x;
  if (t >= SEQ) return;
  float s = 0.f, sq = 0.f;
  for (int c = 0; c < 512; c++){ float v = xin[c * SEQ + t]; s += v; sq += v * v; }
  float m = s * (1.f / 512.f), var = sq * (1.f / 512.f) - m * m, rs = rsqrtf(var + 1e-5f);
  for (int c = 0; c < 512; c++)
    feat[t * 512 + c] = (xin[c * SEQ + t] - m) * rs * g[c] + b[c];
}

// ---- MFMA GEMM, fp32 inputs (cast fused) — used only for the proj GEMM ----
template<int ACT>
__global__ void gemm_mfma_f32(const float* __restrict__ A, const float* __restrict__ W,
                              const float* __restrict__ bias, float* __restrict__ C,
                              int M, int N, int K, float alpha){
  __shared__ bf16 As[64][40];
  __shared__ bf16 Ws[64][40];
  const int tid = threadIdx.x;
  const int wid = tid >> 6, lane = tid & 63;
  const int m0 = blockIdx.y * 64, n0 = blockIdx.x * 64;
  const int wm = (wid >> 1) * 32, wn = (wid & 1) * 32;
  const int lrow = tid >> 2;
  const int lk   = (tid & 3) * 8;
  const int fr = lane & 15, fk = (lane >> 4) * 8;
  f32x4 acc[2][2] = {};
  for (int k0 = 0; k0 < K; k0 += 32){
    float4 a0 = make_float4(0.f,0.f,0.f,0.f), a1 = make_float4(0.f,0.f,0.f,0.f);
    int gm = m0 + lrow;
    if (gm < M){
      const float* ap = &A[(size_t)gm * K + k0 + lk];
      a0 = *reinterpret_cast<const float4*>(ap);
      a1 = *reinterpret_cast<const float4*>(ap + 4);
    }
    uint4 pa;
    pa.x = f2bf_rne(a0.x) | (f2bf_rne(a0.y) << 16);
    pa.y = f2bf_rne(a0.z) | (f2bf_rne(a0.w) << 16);
    pa.z = f2bf_rne(a1.x) | (f2bf_rne(a1.y) << 16);
    pa.w = f2bf_rne(a1.z) | (f2bf_rne(a1.w) << 16);
    *reinterpret_cast<uint4*>(&As[lrow][lk]) = pa;
    const float* wp = &W[(size_t)(n0 + lrow) * K + k0 + lk];
    float4 w0 = *reinterpret_cast<const float4*>(wp);
    float4 w1 = *reinterpret_cast<const float4*>(wp + 4);
    uint4 pw;
    pw.x = f2bf_rne(w0.x) | (f2bf_rne(w0.y) << 16);
    pw.y = f2bf_rne(w0.z) | (f2bf_rne(w0.w) << 16);
    pw.z = f2bf_rne(w1.x) | (f2bf_rne(w1.y) << 16);
    pw.w = f2bf_rne(w1.z) | (f2bf_rne(w1.w) << 16);
    *reinterpret_cast<uint4*>(&Ws[lrow][lk]) = pw;
    __syncthreads();
    s16x8 av0 = *reinterpret_cast<const s16x8*>(&As[wm + fr][fk]);
    s16x8 av1 = *reinterpret_cast<const s16x8*>(&As[wm + 16 + fr][fk]);
    s16x8 bv0 = *reinterpret_cast<const s16x8*>(&Ws[wn + fr][fk]);
    s16x8 bv1 = *reinterpret_cast<const s16x8*>(&Ws[wn + 16 + fr][fk]);
    acc[0][0] = __builtin_amdgcn_mfma_f32_16x16x32_bf16(av0, bv0, acc[0][0], 0, 0, 0);
    acc[0][1] = __builtin_amdgcn_mfma_f32_16x16x32_bf16(av0, bv1, acc[0][1], 0, 0, 0);
    acc[1][0] = __builtin_amdgcn_mfma_f32_16x16x32_bf16(av1, bv0, acc[1][0], 0, 0, 0);
    acc[1][1] = __builtin_amdgcn_mfma_f32_16x16x32_bf16(av1, bv1, acc[1][1], 0, 0, 0);
    __syncthreads();
  }
  const int cc = lane & 15, cr = (lane >> 4) * 4;
#pragma unroll
  for (int mi = 0; mi < 2; mi++){
#pragma unroll
    for (int ni = 0; ni < 2; ni++){
      int n = n0 + wn + ni * 16 + cc;
      float bn = bias[n];
#pragma unroll
      for (int r = 0; r < 4; r++){
        int m = m0 + wm + mi * 16 + cr + r;
        if (m < M){
          float v = alpha * (acc[mi][ni][r] + bn);
          if (ACT == 1) v = gelu_f(v);
          C[(size_t)m * N + n] = v;
        }
      }
    }
  }
}

// ---- bf16 GEMM, BK=64, reg-prefetch, optional K-offset/length (split-K) ----
// bias == nullptr -> 0. OUTBF: 0 fp32, 1 bf16.
template<int ACT, int OUTBF>
__global__ void gemm_bf(const bf16* __restrict__ A, const bf16* __restrict__ W,
                        const float* __restrict__ bias, void* __restrict__ Cp,
                        int M, int N, int K, int kOff, int kLen, float alpha){
  __shared__ bf16 As[64][72];
  __shared__ bf16 Ws[64][72];
  const int tid = threadIdx.x, wid = tid >> 6, lane = tid & 63;
  const int m0 = blockIdx.y * 64, n0 = blockIdx.x * 64;
  const int wm = (wid >> 1) * 32, wn = (wid & 1) * 32;
  const int lrow = tid >> 2, lcol = (tid & 3) * 16;
  const int fr = lane & 15, fk = (lane >> 4) * 8;
  f32x4 acc[2][2] = {};
  uint4 ra0, ra1, rw0, rw1;
  auto LOAD = [&](int k0){
    ra0 = make_uint4(0,0,0,0); ra1 = make_uint4(0,0,0,0);
    if (m0 + lrow < M){
      const bf16* ap = &A[(size_t)(m0 + lrow) * K + kOff + k0 + lcol];
      ra0 = *reinterpret_cast<const uint4*>(ap);
      ra1 = *reinterpret_cast<const uint4*>(ap + 8);
    }
    const bf16* wp = &W[(size_t)(n0 + lrow) * K + kOff + k0 + lcol];
    rw0 = *reinterpret_cast<const uint4*>(wp);
    rw1 = *reinterpret_cast<const uint4*>(wp + 8);
  };
  LOAD(0);
  for (int k0 = 0; k0 < kLen; k0 += 64){
    *reinterpret_cast<uint4*>(&As[lrow][lcol])     = ra0;
    *reinterpret_cast<uint4*>(&As[lrow][lcol + 8]) = ra1;
    *reinterpret_cast<uint4*>(&Ws[lrow][lcol])     = rw0;
    *reinterpret_cast<uint4*>(&Ws[lrow][lcol + 8]) = rw1;
    __syncthreads();
    if (k0 + 64 < kLen) LOAD(k0 + 64);
#pragma unroll
    for (int kk = 0; kk < 2; kk++){
      const int c = kk * 32 + fk;
      s16x8 av0 = *reinterpret_cast<const s16x8*>(&As[wm + fr][c]);
      s16x8 av1 = *reinterpret_cast<const s16x8*>(&As[wm + 16 + fr][c]);
      s16x8 bv0 = *reinterpret_cast<const s16x8*>(&Ws[wn + fr][c]);
      s16x8 bv1 = *reinterpret_cast<const s16x8*>(&Ws[wn + 16 + fr][c]);
      acc[0][0] = __builtin_amdgcn_mfma_f32_16x16x32_bf16(av0, bv0, acc[0][0], 0, 0, 0);
      acc[0][1] = __builtin_amdgcn_mfma_f32_16x16x32_bf16(av0, bv1, acc[0][1], 0, 0, 0);
      acc[1][0] = __builtin_amdgcn_mfma_f32_16x16x32_bf16(av1, bv0, acc[1][0], 0, 0, 0);
      acc[1][1] = __builtin_amdgcn_mfma_f32_16x16x32_bf16(av1, bv1, acc[1][1], 0, 0, 0);
    }
    __syncthreads();
  }
  const int cc = lane & 15, cr = (lane >> 4) * 4;
#pragma unroll
  for (int mi = 0; mi < 2; mi++){
#pragma unroll
    for (int ni = 0; ni < 2; ni++){
      int n = n0 + wn + ni * 16 + cc;
      float bn = bias ? bias[n] : 0.f;
#pragma unroll
      for (int r = 0; r < 4; r++){
        int m = m0 + wm + mi * 16 + cr + r;
        if (m < M){
          float v = alpha * (acc[mi][ni][r] + bn);
          if (ACT == 1) v = gelu_f(v);
          if (OUTBF) ((bf16*)Cp)[(size_t)m * N + n] = __float2bfloat16(v);
          else       ((float*)Cp)[(size_t)m * N + n] = v;
        }
      }
    }
  }
}

// ---- fused QKV in bf16 with reg-prefetch (z selects W/bias/out/alpha), out bf16 ----
__global__ void qkv_bf(const bf16* __restrict__ A,
                       const bf16* __restrict__ Wq, const bf16* __restrict__ Wk,
                       const bf16* __restrict__ Wv,
                       const float* __restrict__ bqv, const float* __restrict__ bkv,
                       const float* __restrict__ bvv,
                       bf16* __restrict__ qb, bf16* __restrict__ kb,
                       bf16* __restrict__ vb, int M){
  const int z = blockIdx.z;
  const bf16* W   = (z == 0) ? Wq : (z == 1) ? Wk : Wv;
  const float* bia = (z == 0) ? bqv : (z == 1) ? bkv : bvv;
  bf16* C         = (z == 0) ? qb : (z == 1) ? kb : vb;
  const float alpha = (z == 0) ? 0.125f : 1.0f;
  const int K = DMODEL, N = DMODEL;
  __shared__ bf16 As[64][72];
  __shared__ bf16 Ws[64][72];
  const int tid = threadIdx.x, wid = tid >> 6, lane = tid & 63;
  const int m0 = blockIdx.y * 64, n0 = blockIdx.x * 64;
  const int wm = (wid >> 1) * 32, wn = (wid & 1) * 32;
  const int lrow = tid >> 2, lcol = (tid & 3) * 16;
  const int fr = lane & 15, fk = (lane >> 4) * 8;
  f32x4 acc[2][2] = {};
  uint4 ra0, ra1, rw0, rw1;
  auto LOAD = [&](int k0){
    ra0 = make_uint4(0,0,0,0); ra1 = make_uint4(0,0,0,0);
    if (m0 + lrow < M){
      const bf16* ap = &A[(size_t)(m0 + lrow) * K + k0 + lcol];
      ra0 = *reinterpret_cast<const uint4*>(ap);
      ra1 = *reinterpret_cast<const uint4*>(ap + 8);
    }
    const bf16* wp = &W[(size_t)(n0 + lrow) * K + k0 + lcol];
    rw0 = *reinterpret_cast<const uint4*>(wp);
    rw1 = *reinterpret_cast<const uint4*>(wp + 8);
  };
  LOAD(0);
  for (int k0 = 0; k0 < K; k0 += 64){
    *reinterpret_cast<uint4*>(&As[lrow][lcol])     = ra0;
    *reinterpret_cast<uint4*>(&As[lrow][lcol + 8]) = ra1;
    *reinterpret_cast<uint4*>(&Ws[lrow][lcol])     = rw0;
    *reinterpret_cast<uint4*>(&Ws[lrow][lcol + 8]) = rw1;
    __syncthreads();
    if (k0 + 64 < K) LOAD(k0 + 64);
#pragma unroll
    for (int kk = 0; kk < 2; kk++){
      const int c = kk * 32 + fk;
      s16x8 av0 = *reinterpret_cast<const s16x8*>(&As[wm + fr][c]);
      s16x8 av1 = *reinterpret_cast<const s16x8*>(&As[wm + 16 + fr][c]);
      s16x8 bv0 = *reinterpret_cast<const s16x8*>(&Ws[wn + fr][c]);
      s16x8 bv1 = *reinterpret_cast<const s16x8*>(&Ws[wn + 16 + fr][c]);
      acc[0][0] = __builtin_amdgcn_mfma_f32_16x16x32_bf16(av0, bv0, acc[0][0], 0, 0, 0);
      acc[0][1] = __builtin_amdgcn_mfma_f32_16x16x32_bf16(av0, bv1, acc[0][1], 0, 0, 0);
      acc[1][0] = __builtin_amdgcn_mfma_f32_16x16x32_bf16(av1, bv0, acc[1][0], 0, 0, 0);
      acc[1][1] = __builtin_amdgcn_mfma_f32_16x16x32_bf16(av1, bv1, acc[1][1], 0, 0, 0);
    }
    __syncthreads();
  }
  const int cc = lane & 15, cr = (lane >> 4) * 4;
#pragma unroll
  for (int mi = 0; mi < 2; mi++){
#pragma unroll
    for (int ni = 0; ni < 2; ni++){
      int n = n0 + wn + ni * 16 + cc;
      float bn = bia[n];
#pragma unroll
      for (int r = 0; r < 4; r++){
        int m = m0 + wm + mi * 16 + cr + r;
        if (m < M) C[(size_t)m * N + n] = __float2bfloat16(alpha * (acc[mi][ni][r] + bn));
      }
    }
  }
}

// ---- posconv via MFMA ----
__global__ void posconv_mfma(const float* __restrict__ x, const bf16* __restrict__ wpos,
                             const float* __restrict__ bias, float* __restrict__ xc){
  const int t0 = blockIdx.x * 64, g = blockIdx.y, b = blockIdx.z;
  __shared__ bf16 As[64][40];
  __shared__ float xw[224];
  const int tid = threadIdx.x, wid = tid >> 6, lane = tid & 63;
  const int wm = (wid >> 1) * 32, wn = (wid & 1) * 32;
  const int lrow = tid >> 2, lk = (tid & 3) * 8;
  const int fr = lane & 15, fk = (lane >> 4) * 8;
  f32x4 acc[2][2] = {};
  for (int ci = 0; ci < 48; ci++){
    for (int idx = tid; idx < 191; idx += 256){
      int p = t0 - 64 + idx;
      xw[idx] = (p >= 0 && p < SEQ) ? x[((size_t)(b * SEQ + p)) * DMODEL + g * 48 + ci] : 0.f;
    }
    for (int kk = 0; kk < 128; kk += 32){
      uint4 wa = make_uint4(0, 0, 0, 0);
      if (lrow < 48)
        wa = *reinterpret_cast<const uint4*>(&wpos[(size_t)(g * 48 + lrow) * 6144 + ci * 128 + kk + lk]);
      *reinterpret_cast<uint4*>(&As[lrow][lk]) = wa;
      __syncthreads();
      auto bfragp = [&](int tr)->s16x8{
        int base = tr + kk + fk;
        s16x8 r;
#pragma unroll
        for (int j = 0; j < 8; j++) r[j] = (short)f2bf_rne(xw[base + j]);
        return r;
      };
      s16x8 a0 = *reinterpret_cast<const s16x8*>(&As[wm + fr][fk]);
      s16x8 a1 = *reinterpret_cast<const s16x8*>(&As[wm + 16 + fr][fk]);
      s16x8 b0 = bfragp(wn + fr);
      s16x8 b1 = bfragp(wn + 16 + fr);
      acc[0][0] = __builtin_amdgcn_mfma_f32_16x16x32_bf16(a0, b0, acc[0][0], 0, 0, 0);
      acc[0][1] = __builtin_amdgcn_mfma_f32_16x16x32_bf16(a0, b1, acc[0][1], 0, 0, 0);
      acc[1][0] = __builtin_amdgcn_mfma_f32_16x16x32_bf16(a1, b0, acc[1][0], 0, 0, 0);
      acc[1][1] = __builtin_amdgcn_mfma_f32_16x16x32_bf16(a1, b1, acc[1][1], 0, 0, 0);
      __syncthreads();
    }
  }
  const int cc = lane & 15, cr = (lane >> 4) * 4;
#pragma unroll
  for (int mi = 0; mi < 2; mi++){
#pragma unroll
    for (int ni = 0; ni < 2; ni++){
      int t = t0 + wn + ni * 16 + cc;
      if (t >= SEQ) continue;
#pragma unroll
      for (int r = 0; r < 4; r++){
        int cop = wm + mi * 16 + cr + r;
        if (cop < 48){
          int co = g * 48 + cop;
          xc[((size_t)(b * SEQ + t)) * DMODEL + co] = acc[mi][ni][r] + bias[co];
        }
      }
    }
  }
}

// ---- FUSED attention, bf16 q/k/v in, bf16 ctx out; in-block gate ----
__global__ void attn_fused(const bf16* __restrict__ q, const bf16* __restrict__ k,
                           const bf16* __restrict__ v, const float* __restrict__ x,
                           const float* __restrict__ gwl, const float* __restrict__ gbl,
                           const float* __restrict__ gal,
                           const float* __restrict__ tab, bf16* __restrict__ ctx){
  const int bh = blockIdx.y, b = bh / NHEAD, h = bh % NHEAD;
  const int i0 = blockIdx.x * 16;
  const int tid = threadIdx.x, w = tid >> 6, lane = tid & 63;
  const int fr = lane & 15, fk = (lane >> 4) * 8;
  const int cr = (lane >> 4) * 4;
  __shared__ float sc[16][524];
  __shared__ short qs[16][72];
  __shared__ short kv[64][72];
  __shared__ float gtmp[16][9];
  __shared__ float gl[16];
  {
    int r = tid >> 4, c = (tid & 15) * 4;
    int gi = i0 + r;
    uint2 p = make_uint2(0, 0);
    if (gi < SEQ) p = *reinterpret_cast<const uint2*>(&q[((size_t)(b*SEQ+gi))*DMODEL + h*DHEAD + c]);
    *reinterpret_cast<uint2*>(&qs[r][c]) = p;
  }
  if (tid < 128){
    int r = tid >> 3, g = tid & 7;
    int gi = i0 + r;
    float a = gbl[g];
    if (gi < SEQ){
      const float* xv = x + ((size_t)(b * SEQ + gi)) * DMODEL + h * DHEAD;
      const float* wrow = gwl + g * DHEAD;
#pragma unroll
      for (int d = 0; d < 64; d++) a += xv[d] * wrow[d];
    }
    gtmp[r][g] = a;
  }
  __syncthreads();
  if (tid < 16){
    float a0 = gtmp[tid][0] + gtmp[tid][1] + gtmp[tid][2] + gtmp[tid][3];
    float a1 = gtmp[tid][4] + gtmp[tid][5] + gtmp[tid][6] + gtmp[tid][7];
    float g0 = 1.f / (1.f + expf(-a0));
    float g1 = 1.f / (1.f + expf(-a1));
    gl[tid] = g0 * (g1 * gal[h] - 1.f) + 2.f;
  }
  for (int j0 = 0; j0 < SP; j0 += 64){
    __syncthreads();
    {
      int jr = tid >> 2, c0 = (tid & 3) * 16;
      int gj = j0 + jr;
      uint4 p0 = make_uint4(0,0,0,0), p1 = make_uint4(0,0,0,0);
      if (gj < SEQ){
        const bf16* kp = &k[((size_t)(b*SEQ+gj))*DMODEL + h*DHEAD + c0];
        p0 = *reinterpret_cast<const uint4*>(kp);
        p1 = *reinterpret_cast<const uint4*>(kp + 8);
      }
      *reinterpret_cast<uint4*>(&kv[jr][c0])     = p0;
      *reinterpret_cast<uint4*>(&kv[jr][c0 + 8]) = p1;
    }
    __syncthreads();
    f32x4 accqk = {};
#pragma unroll
    for (int kk = 0; kk < 2; kk++){
      s16x8 a = *reinterpret_cast<const s16x8*>(&qs[fr][kk*32 + fk]);
      s16x8 bb = *reinterpret_cast<const s16x8*>(&kv[w*16 + fr][kk*32 + fk]);
      accqk = __builtin_amdgcn_mfma_f32_16x16x32_bf16(a, bb, accqk, 0, 0, 0);
    }
#pragma unroll
    for (int r = 0; r < 4; r++)
      sc[cr + r][j0 + w*16 + fr] = accqk[r];
  }
  __syncthreads();
  for (int r = 0; r < 4; r++){
    int row = w * 4 + r;
    int gi = i0 + row;
    if (gi >= SEQ) continue;
    float gt = gl[row];
    const float* tb = tab + (size_t)h * NREL + (SEQ - 1 - gi);
    float vals[8];
    float mx = -1e30f;
#pragma unroll
    for (int it = 0; it < 8; it++){
      int j = lane + it * 64;
      float vv = (j < SEQ) ? (sc[row][j] + gt * tb[j]) : -1e30f;
      vals[it] = vv; mx = fmaxf(mx, vv);
    }
#pragma unroll
    for (int m = 32; m > 0; m >>= 1) mx = fmaxf(mx, __shfl_xor(mx, m));
    float sum = 0.f;
#pragma unroll
    for (int it = 0; it < 8; it++){
      int j = lane + it * 64;
      float e = (j < SEQ) ? expf(vals[it] - mx) : 0.f;
      vals[it] = e; sum += e;
    }
#pragma unroll
    for (int m = 32; m > 0; m >>= 1) sum += __shfl_xor(sum, m);
    float inv = 1.f / sum;
#pragma unroll
    for (int it = 0; it < 8; it++){
      int j = lane + it * 64;
      sc[row][j] = vals[it] * inv;
    }
  }
  __syncthreads();
  f32x4 accpv = {};
  for (int j0 = 0; j0 < SP; j0 += 64){
    __syncthreads();
    {
      int jr = tid >> 2, c0 = (tid & 3) * 16;
      int gj = j0 + jr;
      uint4 p0 = make_uint4(0,0,0,0), p1 = make_uint4(0,0,0,0);
      if (gj < SEQ){
        const bf16* vp = &v[((size_t)(b*SEQ+gj))*DMODEL + h*DHEAD + c0];
        p0 = *reinterpret_cast<const uint4*>(vp);
        p1 = *reinterpret_cast<const uint4*>(vp + 8);
      }
      *reinterpret_cast<uint4*>(&kv[jr][c0])     = p0;
      *reinterpret_cast<uint4*>(&kv[jr][c0 + 8]) = p1;
    }
    __syncthreads();
#pragma unroll
    for (int kk = 0; kk < 2; kk++){
      s16x8 a, bb;
#pragma unroll
      for (int e = 0; e < 8; e++){
        a[e]  = (short)f2bf_rne(sc[fr][j0 + kk*32 + fk + e]);
        bb[e] = kv[kk*32 + fk + e][w*16 + fr];
      }
      accpv = __builtin_amdgcn_mfma_f32_16x16x32_bf16(a, bb, accpv, 0, 0, 0);
    }
  }
#pragma unroll
  for (int r = 0; r < 4; r++){
    int gi = i0 + cr + r;
    if (gi < SEQ)
      ctx[((size_t)(b*SEQ+gi))*DMODEL + h*DHEAD + w*16 + fr] = __float2bfloat16(accpv[r]);
  }
}

// ---- wave-per-row residual add (+GELU / +second addend) + LN; fp32 x + bf16 xb ----
template<int GELU_ADD, int TWO>
__global__ void add_ln_wave(float* __restrict__ x, const float* __restrict__ add,
                            const float* __restrict__ add2,
                            const float* __restrict__ g, const float* __restrict__ b,
                            bf16* __restrict__ xb){
  int row = blockIdx.x * 4 + (threadIdx.x >> 6);
  if (row >= BATCH * SEQ) return;
  int lane = threadIdx.x & 63;
  float* xr = x + (size_t)row * DMODEL;
  const float* ar = add + (size_t)row * DMODEL;
  const float* ar2 = TWO ? add2 + (size_t)row * DMODEL : nullptr;
  float buf[12];
  float s = 0.f;
#pragma unroll
  for (int it = 0; it < 12; it++){
    int i = lane + it * 64;
    float v = ar[i];
    if (TWO) v += ar2[i];
    if (GELU_ADD) v = gelu_f(v);
    v += xr[i];
    buf[it] = v; s += v;
  }
#pragma unroll
  for (int m = 32; m > 0; m >>= 1) s += __shfl_xor(s, m);
  float mean = s * (1.f / 768.f);
  float q = 0.f;
#pragma unroll
  for (int it = 0; it < 12; it++){ float d = buf[it] - mean; q += d * d; }
#pragma unroll
  for (int m = 32; m > 0; m >>= 1) q += __shfl_xor(q, m);
  float rs = rsqrtf(q * (1.f / 768.f) + 1e-5f);
#pragma unroll
  for (int it = 0; it < 12; it++){
    int i = lane + it * 64;
    float o = (buf[it] - mean) * rs * g[i] + b[i];
    xr[i] = o;
    xb[(size_t)row * DMODEL + i] = __float2bfloat16(o);
  }
}

// ---- T5-style relative position bias table ----
__global__ void relbias_kernel(const float* __restrict__ rel_emb, float* __restrict__ tab){
  int idx = blockIdx.x * 256 + threadIdx.x;
  if (idx >= NREL * NHEAD) return;
  int rr = idx / NHEAD, h = idx - rr * NHEAD;
  int rel = rr - (SEQ - 1);
  int bkt = (rel > 0) ? 160 : 0;
  int n = (rel < 0) ? -rel : rel;
  if (n < 80) bkt += n;
  else {
    int large = 80 + (int)(logf((float)n / 80.f) / logf(10.f) * 80.f);
    bkt += (large < 159) ? large : 159;
  }
  tab[h * NREL + rr] = rel_emb[bkt * NHEAD + h];
}

} // anonymous namespace

extern "C" void kernel_launch(void* const* d_in, const int* in_sizes, int n_in,
                              void* d_out, int out_size, void* d_ws, size_t ws_size,
                              hipStream_t stream){
  (void)ws_size;

  static const int DS[34] = {640000,5120,3145728,1048576,3584,3584,512,512,393216,768,
                             4718592,768,768,768,7077888,9216,7077888,9216,7077888,9216,
                             7077888,9216,6144,96,144,9216,9216,28311552,36864,28311552,
                             9216,9216,9216,3840};
  bool ok = (n_in == 34) && (out_size == BATCH * SEQ * DMODEL);
  if (ok) for (int i = 0; i < 34; i++) if (in_sizes[i] != DS[i]) { ok = false; break; }
  if (!ok){
    fill_f32_kernel<<<(out_size + 255) / 256, 256, 0, stream>>>((float*)d_out, out_size, 1000.0f);
    return;
  }

  const float* src  = (const float*)d_in[0];
  const float* w0   = (const float*)d_in[1];
  const float* w14  = (const float*)d_in[2];
  const float* w56  = (const float*)d_in[3];
  const float* clng = (const float*)d_in[4];
  const float* clnb = (const float*)d_in[5];
  const float* flng = (const float*)d_in[6];
  const float* flnb = (const float*)d_in[7];
  const float* pjw  = (const float*)d_in[8];
  const float* pjb  = (const float*)d_in[9];
  const float* pcw  = (const float*)d_in[10];
  const float* pcb  = (const float*)d_in[11];
  const float* eng  = (const float*)d_in[12];
  const float* enb  = (const float*)d_in[13];
  const float* Wq   = (const float*)d_in[14];
  const float* bq   = (const float*)d_in[15];
  const float* Wk   = (const float*)d_in[16];
  const float* bk   = (const float*)d_in[17];
  const float* Wv   = (const float*)d_in[18];
  const float* bv   = (const float*)d_in[19];
  const float* Wo   = (const float*)d_in[20];
  const float* bo   = (const float*)d_in[21];
  const float* gw   = (const float*)d_in[22];
  const float* gbp  = (const float*)d_in[23];
  const float* ga   = (const float*)d_in[24];
  const float* l1g  = (const float*)d_in[25];
  const float* l1b  = (const float*)d_in[26];
  const float* f1w  = (const float*)d_in[27];
  const float* f1b  = (const float*)d_in[28];
  const float* f2w  = (const float*)d_in[29];
  const float* f2b  = (const float*)d_in[30];
  const float* l2g  = (const float*)d_in[31];
  const float* l2b  = (const float*)d_in[32];
  const float* rel  = (const float*)d_in[33];

  float* x = (float*)d_out;  // residual stream lives in d_out (fp32)

  // workspace (~140 MB)
  float* wsf = (float*)d_ws;
  size_t off = 0;
  auto alloc = [&](size_t n){ float* pp = wsf + off; off += (n + 63) & ~(size_t)63; return pp; };
  constexpr size_t F_N   = (size_t)512 * 31999;              // 16,383,488
  constexpr size_t BFA_N = (size_t)512 * 31999 / 2 + 32;
  float* U = alloc(F_N + BFA_N);                             // 24.58M floats
  float* F  = U;
  bf16* bfA = (bf16*)(U + F_N);
  bf16* bfB = (bf16*)(U + 9000000);
  // transformer views (conv dead by then)
  bf16* ffhb = (bf16*)U;                                     // 3.07M floats
  float* tmp = U + 3100000;                                  // 1.53M
  bf16* qbb  = (bf16*)(U + 4700000);
  bf16* kbb  = (bf16*)(U + 5500000);
  bf16* vbb  = (bf16*)(U + 6300000);
  bf16* ctxb = (bf16*)(U + 7100000);
  bf16* xb   = (bf16*)(U + 7900000);
  bf16* wposb= (bf16*)(U + 8700000);
  float* tmp2 = U + 11100000;                                // 1.53M, ends 12.64M < 24.58M
  // persistent
  float* feat = alloc((size_t)BATCH * SEQ * 512);
  float* c6   = alloc((size_t)512 * SEQ);
  float* tab  = alloc((size_t)NHEAD * NREL);
  bf16* wpk   = (bf16*)alloc(2097152);
  bf16* wqb  = (bf16*)alloc(294912);
  bf16* wkb  = (bf16*)alloc(294912);
  bf16* wvb  = (bf16*)alloc(294912);
  bf16* wob  = (bf16*)alloc(294912);
  bf16* wf1b = (bf16*)alloc(1179648);
  bf16* wf2b = (bf16*)alloc(1179648);

  const int Ls[8] = {160000, 31999, 15999, 7999, 3999, 1999, 999, 499};
  const int Mrows = BATCH * SEQ; // 1996

  // ---- pre-pack conv weights ----
  size_t wpkOff[7];
  {
    size_t o = 0;
    for (int st = 1; st <= 6; st++){ wpkOff[st] = o; o += (st <= 4 ? 3 : 2) * 262144; }
  }
  for (int st = 1; st <= 4; st++)
    pack_convw<3><<<(3 * 262144 + 255) / 256, 256, 0, stream>>>(
        w14 + (size_t)(st - 1) * 512 * 512 * 3, wpk + wpkOff[st]);
  for (int st = 5; st <= 6; st++)
    pack_convw<2><<<(2 * 262144 + 255) / 256, 256, 0, stream>>>(
        w56 + (size_t)(st - 5) * 512 * 512 * 2, wpk + wpkOff[st]);

  // ---- conv feature extractor ----
  for (int b = 0; b < BATCH; b++){
    conv0_kernel<<<(512 * Ls[1] + 255) / 256, 256, 0, stream>>>(src + (size_t)b * T_IN, w0, F, Ls[1]);
    ln_gelu_ch2_kernel<1><<<(Ls[1] + 31) / 32, 256, 0, stream>>>(F, bfA, clng, clnb, Ls[1]);
    bf16* bfin[2] = {bfA, bfB};
    for (int st = 1; st <= 6; st++){
      const bf16* inb = bfin[(st + 1) & 1];
      int Lin = Ls[st], Lout = Ls[st + 1];
      float* outf = (st == 6) ? c6 : F;
      int oLd = (st == 6) ? SEQ : Lout;
      dim3 grd(8, (Lout + 127) / 128);
      if (st <= 4)
        conv_mfma_kernel<3><<<grd, 256, 0, stream>>>(inb, wpk + wpkOff[st], outf, Lin, Lout, oLd);
      else
        conv_mfma_kernel<2><<<grd, 256, 0, stream>>>(inb, wpk + wpkOff[st], outf, Lin, Lout, oLd);
      if (st < 6)
        ln_gelu_ch2_kernel<1><<<(Lout + 31) / 32, 256, 0, stream>>>(F, bfin[st & 1], clng + st * 512, clnb + st * 512, Lout);
    }
    ln_gelu_ch2_kernel<0><<<(SEQ + 31) / 32, 256, 0, stream>>>(c6, nullptr, clng + 6 * 512, clnb + 6 * 512, SEQ);
    featln_transpose_kernel<<<(SEQ + 255) / 256, 256, 0, stream>>>(c6, flng, flnb, feat + (size_t)b * SEQ * 512);
  }

  gemm_mfma_f32<0><<<dim3(DMODEL / 64, (Mrows + 63) / 64), 256, 0, stream>>>(feat, pjw, pjb, x, Mrows, DMODEL, 512, 1.0f);
  f2bf_kernel<<<(4718592 + 255) / 256, 256, 0, stream>>>(pcw, wposb, 4718592);
  posconv_mfma<<<dim3(8, 16, BATCH), 256, 0, stream>>>(x, wposb, pcb, tmp);
  add_ln_wave<1, 0><<<(Mrows + 3) / 4, 256, 0, stream>>>(x, tmp, nullptr, eng, enb, xb);
  relbias_kernel<<<(NREL * NHEAD + 255) / 256, 256, 0, stream>>>(rel, tab);

  const size_t WQK = (size_t)DMODEL * DMODEL;
  const size_t WF  = (size_t)FFN * DMODEL;
  for (int l = 0; l < NLAYER; l++){
    castw6<<<dim3(9216, 6), 256, 0, stream>>>(
        Wq + l * WQK, Wk + l * WQK, Wv + l * WQK, Wo + l * WQK,
        f1w + l * WF, f2w + l * WF, wqb, wkb, wvb, wob, wf1b, wf2b);
    qkv_bf<<<dim3(12, 32, 3), 256, 0, stream>>>(
        xb, wqb, wkb, wvb, bq + l * DMODEL, bk + l * DMODEL, bv + l * DMODEL,
        qbb, kbb, vbb, Mrows);
    attn_fused<<<dim3(32, BATCH * NHEAD), 256, 0, stream>>>(
        qbb, kbb, vbb, x, gw + (size_t)l * 8 * DHEAD, gbp + l * 8, ga + l * NHEAD, tab, ctxb);
    // Wo: split-K x2 (384 each)
    gemm_bf<0, 0><<<dim3(12, 32), 256, 0, stream>>>(ctxb, wob, bo + l * DMODEL, tmp,  Mrows, DMODEL, DMODEL, 0,   384, 1.0f);
    gemm_bf<0, 0><<<dim3(12, 32), 256, 0, stream>>>(ctxb, wob, nullptr,         tmp2, Mrows, DMODEL, DMODEL, 384, 384, 1.0f);
    add_ln_wave<0, 1><<<(Mrows + 3) / 4, 256, 0, stream>>>(x, tmp, tmp2, l1g + l * DMODEL, l1b + l * DMODEL, xb);
    gemm_bf<1, 1><<<dim3(FFN / 64, 32), 256, 0, stream>>>(xb, wf1b, f1b + l * FFN, ffhb, Mrows, FFN, DMODEL, 0, DMODEL, 1.0f);
    // fc2: split-K x2 (1536 each)
    gemm_bf<0, 0><<<dim3(12, 32), 256, 0, stream>>>(ffhb, wf2b, f2b + l * DMODEL, tmp,  Mrows, DMODEL, FFN, 0,    1536, 1.0f);
    gemm_bf<0, 0><<<dim3(12, 32), 256, 0, stream>>>(ffhb, wf2b, nullptr,          tmp2, Mrows, DMODEL, FFN, 1536, 1536, 1.0f);
    add_ln_wave<0, 1><<<(Mrows + 3) / 4, 256, 0, stream>>>(x, tmp, tmp2, l2g + l * DMODEL, l2b + l * DMODEL, xb);
  }
  // result is already in d_out
}